// Round 4
// baseline (1717.861 us; speedup 1.0000x reference)
//
#include <hip/hip_runtime.h>
#include <hip/hip_bf16.h>
#include <math.h>

typedef unsigned short u16;
typedef unsigned int   u32;
typedef unsigned long long u64;

__device__ __forceinline__ float bf2f(u16 u) {
  union { u32 i; float f; } v; v.i = ((u32)u) << 16; return v.f;
}
__device__ __forceinline__ u16 f2bf(float f) {  // round-to-nearest-even
  union { float f; u32 i; } v; v.f = f;
  u32 r = (v.i + 0x7FFFu + ((v.i >> 16) & 1u)) >> 16;
  return (u16)r;
}
__device__ __forceinline__ void ld4bf(const u16* p, float* o) {  // 8B-aligned
  uint2 u = *reinterpret_cast<const uint2*>(p);
  o[0]=bf2f((u16)(u.x)); o[1]=bf2f((u16)(u.x>>16));
  o[2]=bf2f((u16)(u.y)); o[3]=bf2f((u16)(u.y>>16));
}
__device__ __forceinline__ void ld8f(const float* p, float* o) {  // 16B-aligned
  float4 a = *reinterpret_cast<const float4*>(p);
  float4 b = *reinterpret_cast<const float4*>(p + 4);
  o[0]=a.x; o[1]=a.y; o[2]=a.z; o[3]=a.w;
  o[4]=b.x; o[5]=b.y; o[6]=b.z; o[7]=b.w;
}

// ---------------- conv1 + bn1 + relu + maxpool2 : (16,3,256,256)f32 -> (BC,64,128,128)bf16
__global__ __launch_bounds__(256) void k_conv1(
    const float* __restrict__ x, const float* __restrict__ w,
    const float* __restrict__ cb, const float* __restrict__ g, const float* __restrict__ bb,
    u16* __restrict__ feat1, int b0)
{
  __shared__ float sIn[3][34][34];
  __shared__ float sW[64][27];
  __shared__ float sB[64];
  const int bl = blockIdx.z, ty = blockIdx.y, tx = blockIdx.x;
  const int b = b0 + bl;
  const int tid = threadIdx.x;
  for (int i = tid; i < 64*27; i += 256) {
    int oc = i / 27;
    float sc = g[oc] * rsqrtf(1.0f + 1e-5f);
    sW[oc][i % 27] = w[i] * sc;
  }
  if (tid < 64) {
    float sc = g[tid] * rsqrtf(1.0f + 1e-5f);
    sB[tid] = cb[tid] * sc + bb[tid];
  }
  const int iy0 = ty*32 - 1, ix0 = tx*32 - 1;
  for (int i = tid; i < 3*34*34; i += 256) {
    int c = i / (34*34); int r = (i / 34) % 34; int q = i % 34;
    int yy = iy0 + r, xx = ix0 + q;
    float v = 0.f;
    if (yy >= 0 && xx >= 0 && yy < 256 && xx < 256)
      v = x[(((size_t)b*3 + c)*256 + yy)*256 + xx];
    sIn[c][r][q] = v;
  }
  __syncthreads();
  const int py = tid >> 4, px = tid & 15;
  float win[3][4][4];
  #pragma unroll
  for (int c = 0; c < 3; c++)
    #pragma unroll
    for (int r = 0; r < 4; r++)
      #pragma unroll
      for (int q = 0; q < 4; q++)
        win[c][r][q] = sIn[c][2*py + r][2*px + q];
  const int oy = ty*16 + py, ox = tx*16 + px;
  u16* outp = feat1 + ((size_t)bl*64*128 + oy)*128 + ox;
  for (int oc = 0; oc < 64; oc++) {
    float s00=0.f, s01=0.f, s10=0.f, s11=0.f;
    #pragma unroll
    for (int c = 0; c < 3; c++)
      #pragma unroll
      for (int ky = 0; ky < 3; ky++)
        #pragma unroll
        for (int kx = 0; kx < 3; kx++) {
          float wv = sW[oc][(c*3+ky)*3+kx];
          s00 += win[c][ky  ][kx  ] * wv;
          s01 += win[c][ky  ][kx+1] * wv;
          s10 += win[c][ky+1][kx  ] * wv;
          s11 += win[c][ky+1][kx+1] * wv;
        }
    float m = fmaxf(fmaxf(s00,s01), fmaxf(s10,s11)) + sB[oc];
    outp[(size_t)oc*128*128] = f2bf(fmaxf(m, 0.f));
  }
}

// ---------------- conv2 + bn2 + relu + maxpool2 : (BC,64,128,128)bf16 -> (BC,64,64,64)bf16
__global__ __launch_bounds__(256) void k_conv2(
    const u16* __restrict__ feat1, const float* __restrict__ w,
    const float* __restrict__ cb, const float* __restrict__ g, const float* __restrict__ bb,
    u16* __restrict__ feat2)
{
  __shared__ float sIn[16][18][18];   // 20736 B
  __shared__ float sW[64][16][9];     // 36864 B
  __shared__ float sB[64];
  const int bl = blockIdx.z, ty = blockIdx.y, tx = blockIdx.x;
  const int tid = threadIdx.x;
  if (tid < 64) {
    float sc = g[tid] * rsqrtf(1.0f + 1e-5f);
    sB[tid] = cb[tid] * sc + bb[tid];
  }
  const int pix = tid & 63, ocg = tid >> 6;   // wave-uniform oc group
  const int py = pix >> 3, px = pix & 7;
  float acc[16][4];
  #pragma unroll
  for (int o = 0; o < 16; o++) { acc[o][0]=0.f; acc[o][1]=0.f; acc[o][2]=0.f; acc[o][3]=0.f; }
  const int iy0 = ty*16 - 1, ix0 = tx*16 - 1;
  for (int ch = 0; ch < 4; ch++) {
    __syncthreads();
    for (int i = tid; i < 16*18*18; i += 256) {
      int c = i / 324, r = (i / 18) % 18, q = i % 18;
      int yy = iy0 + r, xx = ix0 + q;
      float v = 0.f;
      if (yy >= 0 && xx >= 0 && yy < 128 && xx < 128)
        v = bf2f(feat1[(((size_t)bl*64 + ch*16 + c)*128 + yy)*128 + xx]);
      sIn[c][r][q] = v;
    }
    for (int i = tid; i < 64*16*9; i += 256) {
      int oc = i / 144, c = (i / 9) % 16, kk = i % 9;
      float sc = g[oc] * rsqrtf(1.0f + 1e-5f);
      sW[oc][c][kk] = w[(oc*64 + ch*16 + c)*9 + kk] * sc;
    }
    __syncthreads();
    #pragma unroll 1
    for (int c = 0; c < 16; c++) {
      float win[4][4];
      #pragma unroll
      for (int r = 0; r < 4; r++)
        #pragma unroll
        for (int q = 0; q < 4; q++)
          win[r][q] = sIn[c][2*py + r][2*px + q];
      #pragma unroll
      for (int o = 0; o < 16; o++) {
        float a0=acc[o][0], a1=acc[o][1], a2=acc[o][2], a3=acc[o][3];
        #pragma unroll
        for (int ky = 0; ky < 3; ky++)
          #pragma unroll
          for (int kx = 0; kx < 3; kx++) {
            float wv = sW[ocg*16 + o][c][ky*3+kx];
            a0 += win[ky  ][kx  ] * wv;
            a1 += win[ky  ][kx+1] * wv;
            a2 += win[ky+1][kx  ] * wv;
            a3 += win[ky+1][kx+1] * wv;
          }
        acc[o][0]=a0; acc[o][1]=a1; acc[o][2]=a2; acc[o][3]=a3;
      }
    }
  }
  const int oy = ty*8 + py, ox = tx*8 + px;
  #pragma unroll
  for (int o = 0; o < 16; o++) {
    int oc = ocg*16 + o;
    float m = fmaxf(fmaxf(acc[o][0],acc[o][1]), fmaxf(acc[o][2],acc[o][3])) + sB[oc];
    feat2[(((size_t)bl*64 + oc)*64 + oy)*64 + ox] = f2bf(fmaxf(m, 0.f));
  }
}

// ---------------- adjacency (input-independent, 1 block)
__global__ __launch_bounds__(256) void k_adj(int* __restrict__ nbr1, u64* __restrict__ mask2)
{
  __shared__ int snbr[225][8];
  const int i = threadIdx.x;
  if (i < 225) {
    const int ii = i / 15, jj = i % 15;
    int bd[8], bj[8];
    #pragma unroll
    for (int t = 0; t < 8; t++) { bd[t] = 1<<30; bj[t] = -1; }
    for (int j = 0; j < 225; j++) {
      if (j == i) continue;
      int di = ii - j/15, dj = jj - j%15;
      int d2 = di*di + dj*dj;
      if (d2 < bd[7]) {                 // strict: equal-d2 keeps earlier j (stable argsort)
        int p = 7;
        while (p > 0 && d2 < bd[p-1]) { bd[p]=bd[p-1]; bj[p]=bj[p-1]; p--; }
        bd[p] = d2; bj[p] = j;
      }
    }
    #pragma unroll
    for (int t = 0; t < 8; t++) { snbr[i][t] = bj[t]; nbr1[i*8+t] = bj[t]; }
  }
  __syncthreads();
  if (i < 225) {
    u64 m[4] = {0,0,0,0};
    #pragma unroll
    for (int t = 0; t < 8; t++) {
      int tt = snbr[i][t];
      #pragma unroll
      for (int u = 0; u < 8; u++) {
        int j = snbr[tt][u];
        m[j >> 6] |= 1ull << (j & 63);
      }
    }
    m[i >> 6] &= ~(1ull << (i & 63));
    #pragma unroll
    for (int wd = 0; wd < 4; wd++) mask2[i*4 + wd] = m[wd];
  }
}

// ---------------- patch gather + projection: nodes = patches @ proj_w^T + b
__global__ __launch_bounds__(128) void k_proj(
    const u16* __restrict__ feat2, const float* __restrict__ pw,
    const float* __restrict__ pb, float* __restrict__ nodes, int b0)
{
  __shared__ float sP[4096];
  const int n = blockIdx.x, bl = blockIdx.y;
  const int b = b0 + bl;
  const int ph = n / 15, pww = n % 15;
  const int tid = threadIdx.x;
  for (int idx = tid; idx < 512; idx += 128) {
    int c = idx >> 3, i = idx & 7;
    const u16* src = &feat2[(((size_t)bl*64 + c)*64 + ph*4 + i)*64 + pww*4];
    float* dst = &sP[c*64 + i*8];
    ld4bf(src, dst); ld4bf(src + 4, dst + 4);
  }
  __syncthreads();
  const int d = tid;
  float acc = pb[d];
  const float* wr = pw + (size_t)d * 4096;
  for (int k = 0; k < 4096; k += 8) {
    float wv[8]; ld8f(wr + k, wv);
    #pragma unroll
    for (int j = 0; j < 8; j++) acc += wv[j] * sP[k + j];
  }
  nodes[((size_t)b*225 + n)*128 + d] = acc;
}

// ---------------- graph conv + gate + score, fused per (b,node)
__global__ __launch_bounds__(128) void k_graph(
    const float* __restrict__ nodes, const int* __restrict__ nbr1,
    const u64* __restrict__ mask2,
    const float* __restrict__ w1w, const float* __restrict__ w1b,
    const float* __restrict__ w2w, const float* __restrict__ w2b,
    const float* __restrict__ gw, const float* __restrict__ gb,
    const float* __restrict__ sw, const float* __restrict__ sb,
    float* __restrict__ zbuf, float* __restrict__ scores)
{
  __shared__ float sA1[128], sA2[128], sC[256], sRed[128];
  const int n = blockIdx.x, b = blockIdx.y;
  const int d = threadIdx.x;
  const float* nb = nodes + (size_t)b * 225 * 128;
  float a1 = 0.f;
  #pragma unroll
  for (int t = 0; t < 8; t++) a1 += nb[(size_t)nbr1[n*8+t]*128 + d];
  float a2 = 0.f;
  for (int wd = 0; wd < 4; wd++) {
    u64 m = mask2[n*4 + wd];
    while (m) {
      int j = wd*64 + __builtin_ctzll(m);
      a2 += nb[(size_t)j*128 + d];
      m &= m - 1;
    }
  }
  sA1[d] = a1; sA2[d] = a2;
  __syncthreads();
  float z1 = w1b[d];
  { const float* wr = w1w + (size_t)d*128;
    for (int k = 0; k < 128; k += 8) {
      float wv[8]; ld8f(wr + k, wv);
      #pragma unroll
      for (int j = 0; j < 8; j++) z1 += wv[j] * sA1[k+j];
    } }
  float z2 = w2b[d];
  { const float* wr = w2w + (size_t)d*128;
    for (int k = 0; k < 128; k += 8) {
      float wv[8]; ld8f(wr + k, wv);
      #pragma unroll
      for (int j = 0; j < 8; j++) z2 += wv[j] * sA2[k+j];
    } }
  sC[d] = z1; sC[128 + d] = z2;
  __syncthreads();
  float gl = gb[d];
  { const float* wr = gw + (size_t)d*256;
    for (int k = 0; k < 256; k += 8) {
      float wv[8]; ld8f(wr + k, wv);
      #pragma unroll
      for (int j = 0; j < 8; j++) gl += wv[j] * sC[k+j];
    } }
  float gg = 1.f / (1.f + expf(-gl));
  float zv = gg * z1 + (1.f - gg) * z2;
  zbuf[((size_t)b*225 + n)*128 + d] = zv;
  sRed[d] = zv * sw[d];
  __syncthreads();
  for (int st = 64; st > 0; st >>= 1) {
    if (d < st) sRed[d] += sRed[d + st];
    __syncthreads();
  }
  if (d == 0) scores[b*225 + n] = sRed[0] + sb[0];
}

// ---------------- top-k (k=112) with jax tie semantics
__global__ __launch_bounds__(256) void k_topk(
    const float* __restrict__ scores, int* __restrict__ sel)
{
  __shared__ float ss[225];
  const int b = blockIdx.x, tid = threadIdx.x;
  if (tid < 112) sel[b*112 + tid] = tid;   // defensive init: no poison survives
  if (tid < 225) ss[tid] = scores[b*225 + tid];
  __syncthreads();
  if (tid < 225) {
    float s = ss[tid];
    int rank = 0;
    for (int j = 0; j < 225; j++) {
      float sj = ss[j];
      rank += (sj > s) || (sj == s && j < tid);
    }
    if (rank < 112) sel[b*112 + rank] = tid;
  }
}

// ---------------- qkv projection per (b, s)
__global__ __launch_bounds__(128) void k_qkv(
    const float* __restrict__ zbuf, const int* __restrict__ sel,
    const float* __restrict__ iw, const float* __restrict__ ib,
    float* __restrict__ q, float* __restrict__ k, float* __restrict__ v)
{
  __shared__ float sx[128];
  const int s = blockIdx.x, b = blockIdx.y, d = threadIdx.x;
  int row = sel[b*112 + s];
  row = row < 0 ? 0 : (row > 224 ? 224 : row);   // clamp: fault-proof
  sx[d] = zbuf[((size_t)b*225 + row)*128 + d];
  __syncthreads();
  const int h = d >> 5, t = d & 31;
  float* outs[3] = {q, k, v};
  #pragma unroll
  for (int part = 0; part < 3; part++) {
    float acc = ib[part*128 + d];
    const float* wr = iw + (size_t)(part*128 + d) * 128;
    for (int kk = 0; kk < 128; kk += 8) {
      float wv[8]; ld8f(wr + kk, wv);
      #pragma unroll
      for (int j = 0; j < 8; j++) acc += wv[j] * sx[kk+j];
    }
    outs[part][(((size_t)b*4 + h)*112 + s)*32 + t] = acc;
  }
}

// ---------------- attention per (b, head), two-pass softmax
__global__ __launch_bounds__(128) void k_attn(
    const float* __restrict__ q, const float* __restrict__ k,
    const float* __restrict__ v, float* __restrict__ o)
{
  __shared__ float sK[112*32], sV[112*32];
  const int h = blockIdx.x, b = blockIdx.y, tid = threadIdx.x;
  const size_t base = ((size_t)b*4 + h) * 112 * 32;
  for (int i = tid; i < 112*32; i += 128) {
    sK[i] = k[base + i];
    sV[i] = v[base + i];
  }
  __syncthreads();
  if (tid < 112) {
    float qv[32];
    const float* qp = q + base + (size_t)tid*32;
    #pragma unroll
    for (int t = 0; t < 32; t++) qv[t] = qp[t];
    const float scale = 0.17677669529663687f; // 1/sqrt(32)
    float mx = -INFINITY;
    for (int j = 0; j < 112; j++) {
      float s = 0.f;
      #pragma unroll
      for (int t = 0; t < 32; t++) s += qv[t] * sK[j*32 + t];
      mx = fmaxf(mx, s * scale);
    }
    float acc[32];
    #pragma unroll
    for (int t = 0; t < 32; t++) acc[t] = 0.f;
    float l = 0.f;
    for (int j = 0; j < 112; j++) {
      float s = 0.f;
      #pragma unroll
      for (int t = 0; t < 32; t++) s += qv[t] * sK[j*32 + t];
      float p = expf(s * scale - mx);
      l += p;
      #pragma unroll
      for (int t = 0; t < 32; t++) acc[t] += p * sV[j*32 + t];
    }
    float inv = 1.f / l;
    float* op = o + ((size_t)b*112 + tid)*128 + h*32;
    #pragma unroll
    for (int t = 0; t < 32; t++) op[t] = acc[t] * inv;
  }
}

// ---------------- out-proj + residual + LN1 per (b, s)
__global__ __launch_bounds__(128) void k_oln(
    const float* __restrict__ o, const float* __restrict__ zbuf,
    const int* __restrict__ sel,
    const float* __restrict__ ow, const float* __restrict__ ob,
    const float* __restrict__ lg, const float* __restrict__ lb,
    float* __restrict__ h1)
{
  __shared__ float so[128], sRed[128], sRed2[128];
  const int s = blockIdx.x, b = blockIdx.y, d = threadIdx.x;
  so[d] = o[((size_t)b*112 + s)*128 + d];
  __syncthreads();
  float acc = ob[d];
  const float* wr = ow + (size_t)d * 128;
  for (int kk = 0; kk < 128; kk += 8) {
    float wv[8]; ld8f(wr + kk, wv);
    #pragma unroll
    for (int j = 0; j < 8; j++) acc += wv[j] * so[kk+j];
  }
  int row = sel[b*112 + s];
  row = row < 0 ? 0 : (row > 224 ? 224 : row);
  acc += zbuf[((size_t)b*225 + row)*128 + d];
  sRed[d] = acc; sRed2[d] = acc * acc;
  __syncthreads();
  for (int st = 64; st > 0; st >>= 1) {
    if (d < st) { sRed[d] += sRed[d+st]; sRed2[d] += sRed2[d+st]; }
    __syncthreads();
  }
  float mean = sRed[0] * (1.f/128.f);
  float var  = sRed2[0] * (1.f/128.f) - mean*mean;
  float r = rsqrtf(var + 1e-5f);
  h1[((size_t)b*112 + s)*128 + d] = (acc - mean) * r * lg[d] + lb[d];
}

// ---------------- FFN + residual + LN2 per (b, s) -> h2 (may alias h1: row-local)
__global__ __launch_bounds__(256) void k_ffn(
    const float* __restrict__ h1,
    const float* __restrict__ f1w, const float* __restrict__ f1b,
    const float* __restrict__ f2w, const float* __restrict__ f2b,
    const float* __restrict__ lg, const float* __restrict__ lb,
    float* __restrict__ h2)
{
  __shared__ float sh[128];
  __shared__ float sf[512];
  __shared__ float sRed[128], sRed2[128];
  const int s = blockIdx.x, b = blockIdx.y, tid = threadIdx.x;
  if (tid < 128) sh[tid] = h1[((size_t)b*112 + s)*128 + tid];
  __syncthreads();
  #pragma unroll
  for (int rdx = 0; rdx < 2; rdx++) {
    int oo = tid + rdx*256;
    float acc = f1b[oo];
    const float* wr = f1w + (size_t)oo * 128;
    for (int kk = 0; kk < 128; kk += 8) {
      float wv[8]; ld8f(wr + kk, wv);
      #pragma unroll
      for (int j = 0; j < 8; j++) acc += wv[j] * sh[kk+j];
    }
    sf[oo] = fmaxf(acc, 0.f);
  }
  __syncthreads();
  float val = 0.f;
  if (tid < 128) {
    float acc = f2b[tid];
    const float* wr = f2w + (size_t)tid * 512;
    for (int kk = 0; kk < 512; kk += 8) {
      float wv[8]; ld8f(wr + kk, wv);
      #pragma unroll
      for (int j = 0; j < 8; j++) acc += wv[j] * sf[kk+j];
    }
    val = sh[tid] + acc;
    sRed[tid] = val; sRed2[tid] = val*val;
  }
  __syncthreads();
  for (int st = 64; st > 0; st >>= 1) {
    if (tid < st) { sRed[tid] += sRed[tid+st]; sRed2[tid] += sRed2[tid+st]; }
    __syncthreads();
  }
  if (tid < 128) {
    float mean = sRed[0] * (1.f/128.f);
    float var  = sRed2[0] * (1.f/128.f) - mean*mean;
    float r = rsqrtf(var + 1e-5f);
    h2[((size_t)b*112 + s)*128 + tid] = (val - mean) * r * lg[tid] + lb[tid];
  }
}

// ---------------- rep = sum_s h2 ; classifier -> logits (f32)
__global__ __launch_bounds__(64) void k_cls(
    const float* __restrict__ h2,
    const float* __restrict__ c1w, const float* __restrict__ c1b,
    const float* __restrict__ c2w, const float* __restrict__ c2b,
    float* __restrict__ out)
{
  __shared__ float sr[128], sc[64];
  const int b = blockIdx.x, tid = threadIdx.x;
  float r0 = 0.f, r1 = 0.f;
  for (int s2 = 0; s2 < 112; s2++) {
    const float* row = h2 + ((size_t)b*112 + s2)*128;
    r0 += row[tid];
    r1 += row[tid + 64];
  }
  sr[tid] = r0; sr[tid + 64] = r1;
  __syncthreads();
  float acc = c1b[tid];
  const float* wr = c1w + (size_t)tid * 128;
  for (int kk = 0; kk < 128; kk += 8) {
    float wv[8]; ld8f(wr + kk, wv);
    #pragma unroll
    for (int j = 0; j < 8; j++) acc += wv[j] * sr[kk+j];
  }
  sc[tid] = fmaxf(acc, 0.f);
  __syncthreads();
  if (tid < 2) {
    float l = c2b[tid];
    for (int kk = 0; kk < 64; kk++) l += c2w[tid*64 + kk] * sc[kk];
    out[b*2 + tid] = l;
  }
}

extern "C" void kernel_launch(void* const* d_in, const int* in_sizes, int n_in,
                              void* d_out, int out_size, void* d_ws, size_t ws_size,
                              hipStream_t stream)
{
  const float* x    = (const float*)d_in[0];
  const float* c1w  = (const float*)d_in[1];
  const float* c1b  = (const float*)d_in[2];
  const float* bn1g = (const float*)d_in[3];
  const float* bn1b = (const float*)d_in[4];
  const float* c2w  = (const float*)d_in[5];
  const float* c2b  = (const float*)d_in[6];
  const float* bn2g = (const float*)d_in[7];
  const float* bn2b = (const float*)d_in[8];
  const float* pjw  = (const float*)d_in[9];
  const float* pjb  = (const float*)d_in[10];
  const float* w1w  = (const float*)d_in[11];
  const float* w1b  = (const float*)d_in[12];
  const float* w2w  = (const float*)d_in[13];
  const float* w2b  = (const float*)d_in[14];
  const float* gw   = (const float*)d_in[15];
  const float* gb   = (const float*)d_in[16];
  const float* scw  = (const float*)d_in[17];
  const float* scb  = (const float*)d_in[18];
  const float* ipw  = (const float*)d_in[19];
  const float* ipb  = (const float*)d_in[20];
  const float* opw  = (const float*)d_in[21];
  const float* opb  = (const float*)d_in[22];
  const float* f1w  = (const float*)d_in[23];
  const float* f1b  = (const float*)d_in[24];
  const float* f2w  = (const float*)d_in[25];
  const float* f2b  = (const float*)d_in[26];
  const float* l1g  = (const float*)d_in[27];
  const float* l1b  = (const float*)d_in[28];
  const float* l2g  = (const float*)d_in[29];
  const float* l2b  = (const float*)d_in[30];
  const float* cl1w = (const float*)d_in[31];
  const float* cl1b = (const float*)d_in[32];
  const float* cl2w = (const float*)d_in[33];
  const float* cl2b = (const float*)d_in[34];

  // ---- bump allocator over d_ws (256-B aligned) ----
  char* p = (char*)d_ws;
  auto alloc = [&](size_t n) { char* r = p; p += (n + 255) & ~(size_t)255; return r; };
  u64*   mask2  = (u64*)  alloc(900    * sizeof(u64));   // 225*4
  int*   nbr1   = (int*)  alloc(1800   * sizeof(int));   // 225*8
  int*   sel    = (int*)  alloc(1792   * sizeof(int));   // 16*112
  float* scores = (float*)alloc(3600   * sizeof(float)); // 16*225
  float* zbuf   = (float*)alloc(460800 * sizeof(float)); // 16*225*128  (live: graph->oln)
  float* nodes  = (float*)alloc(460800 * sizeof(float)); // live: proj->graph, then reused
  const size_t fixed_bytes = (size_t)(p - (char*)d_ws);

  // S3 region: conv feats (BC*(2MB+0.5MB) bf16), later reused for q/k/v (f32)
  const size_t qkv_bytes = 3ull * 229376ull * sizeof(float);
  const size_t per_batch = 64ull*128*128*2 + 64ull*64*64*2;   // 2,621,440 B
  int BC = 16;
  size_t s3 = 0;
  for (;; BC >>= 1) {
    s3 = (size_t)BC * per_batch; if (s3 < qkv_bytes) s3 = qkv_bytes;
    if (fixed_bytes + s3 + 65536 <= ws_size) break;
    if (BC == 1) { return; }  // ws too small for any plan: clean-fail diagnostic
  }
  char* S3 = alloc(s3);

  // aliases (lifetime-disjoint)
  u16*   feat1 = (u16*)S3;                              // conv phase
  u16*   feat2 = (u16*)(S3 + (size_t)BC * 2097152ull);  // conv phase
  float* qb    = (float*)S3;                            // attention phase
  float* kb    = qb + 229376;
  float* vb    = kb + 229376;
  float* obuf  = nodes;                                 // nodes dead after k_graph
  float* hbuf  = nodes + 229376;                        // h1/h2 (row-local in-place)

  k_adj<<<1, 256, 0, stream>>>(nbr1, mask2);

  for (int b0 = 0; b0 < 16; b0 += BC) {
    k_conv1<<<dim3(8,8,BC), 256, 0, stream>>>(x, c1w, c1b, bn1g, bn1b, feat1, b0);
    k_conv2<<<dim3(8,8,BC), 256, 0, stream>>>(feat1, c2w, c2b, bn2g, bn2b, feat2);
    k_proj <<<dim3(225,BC), 128, 0, stream>>>(feat2, pjw, pjb, nodes, b0);
  }

  k_graph<<<dim3(225,16), 128, 0, stream>>>(nodes, nbr1, mask2, w1w, w1b, w2w, w2b,
                                            gw, gb, scw, scb, zbuf, scores);
  k_topk <<<16, 256, 0, stream>>>(scores, sel);
  k_qkv  <<<dim3(112,16), 128, 0, stream>>>(zbuf, sel, ipw, ipb, qb, kb, vb);
  k_attn <<<dim3(4,16), 128, 0, stream>>>(qb, kb, vb, obuf);
  k_oln  <<<dim3(112,16), 128, 0, stream>>>(obuf, zbuf, sel, opw, opb, l1g, l1b, hbuf);
  k_ffn  <<<dim3(112,16), 256, 0, stream>>>(hbuf, f1w, f1b, f2w, f2b, l2g, l2b, hbuf);
  k_cls  <<<16, 64, 0, stream>>>(hbuf, cl1w, cl1b, cl2w, cl2b, (float*)d_out);
}

// Round 5
// 993.858 us; speedup vs baseline: 1.7285x; 1.7285x over previous
//
#include <hip/hip_runtime.h>
#include <hip/hip_bf16.h>
#include <math.h>

typedef unsigned short u16;
typedef unsigned int   u32;
typedef unsigned long long u64;
typedef __attribute__((ext_vector_type(8))) short short8v;
typedef __attribute__((ext_vector_type(4))) float f32x4;

__device__ __forceinline__ float bf2f(u16 u) {
  union { u32 i; float f; } v; v.i = ((u32)u) << 16; return v.f;
}
__device__ __forceinline__ u16 f2bf(float f) {  // round-to-nearest-even
  union { float f; u32 i; } v; v.f = f;
  u32 r = (v.i + 0x7FFFu + ((v.i >> 16) & 1u)) >> 16;
  return (u16)r;
}
__device__ __forceinline__ void ld4bf(const u16* p, float* o) {  // 8B-aligned
  uint2 u = *reinterpret_cast<const uint2*>(p);
  o[0]=bf2f((u16)(u.x)); o[1]=bf2f((u16)(u.x>>16));
  o[2]=bf2f((u16)(u.y)); o[3]=bf2f((u16)(u.y>>16));
}
__device__ __forceinline__ void ld8f(const float* p, float* o) {  // 16B-aligned
  float4 a = *reinterpret_cast<const float4*>(p);
  float4 b = *reinterpret_cast<const float4*>(p + 4);
  o[0]=a.x; o[1]=a.y; o[2]=a.z; o[3]=a.w;
  o[4]=b.x; o[5]=b.y; o[6]=b.z; o[7]=b.w;
}

// ---------------- conv1 + bn1 + relu + maxpool2 : (16,3,256,256)f32 -> (BC,64,128,128)bf16
__global__ __launch_bounds__(256) void k_conv1(
    const float* __restrict__ x, const float* __restrict__ w,
    const float* __restrict__ cb, const float* __restrict__ g, const float* __restrict__ bb,
    u16* __restrict__ feat1, int b0)
{
  __shared__ float sIn[3][34][34];
  __shared__ float sW[64][27];
  __shared__ float sB[64];
  const int bl = blockIdx.z, ty = blockIdx.y, tx = blockIdx.x;
  const int b = b0 + bl;
  const int tid = threadIdx.x;
  for (int i = tid; i < 64*27; i += 256) {
    int oc = i / 27;
    float sc = g[oc] * rsqrtf(1.0f + 1e-5f);
    sW[oc][i % 27] = w[i] * sc;
  }
  if (tid < 64) {
    float sc = g[tid] * rsqrtf(1.0f + 1e-5f);
    sB[tid] = cb[tid] * sc + bb[tid];
  }
  const int iy0 = ty*32 - 1, ix0 = tx*32 - 1;
  for (int i = tid; i < 3*34*34; i += 256) {
    int c = i / (34*34); int r = (i / 34) % 34; int q = i % 34;
    int yy = iy0 + r, xx = ix0 + q;
    float v = 0.f;
    if (yy >= 0 && xx >= 0 && yy < 256 && xx < 256)
      v = x[(((size_t)b*3 + c)*256 + yy)*256 + xx];
    sIn[c][r][q] = v;
  }
  __syncthreads();
  const int py = tid >> 4, px = tid & 15;
  float win[3][4][4];
  #pragma unroll
  for (int c = 0; c < 3; c++)
    #pragma unroll
    for (int r = 0; r < 4; r++)
      #pragma unroll
      for (int q = 0; q < 4; q++)
        win[c][r][q] = sIn[c][2*py + r][2*px + q];
  const int oy = ty*16 + py, ox = tx*16 + px;
  u16* outp = feat1 + ((size_t)bl*64*128 + oy)*128 + ox;
  for (int oc = 0; oc < 64; oc++) {
    float s00=0.f, s01=0.f, s10=0.f, s11=0.f;
    #pragma unroll
    for (int c = 0; c < 3; c++)
      #pragma unroll
      for (int ky = 0; ky < 3; ky++)
        #pragma unroll
        for (int kx = 0; kx < 3; kx++) {
          float wv = sW[oc][(c*3+ky)*3+kx];
          s00 += win[c][ky  ][kx  ] * wv;
          s01 += win[c][ky  ][kx+1] * wv;
          s10 += win[c][ky+1][kx  ] * wv;
          s11 += win[c][ky+1][kx+1] * wv;
        }
    float m = fmaxf(fmaxf(s00,s01), fmaxf(s10,s11)) + sB[oc];
    outp[(size_t)oc*128*128] = f2bf(fmaxf(m, 0.f));
  }
}

// ---------------- conv2 + bn2 + relu + maxpool2 : (BC,64,128,128)bf16 -> (BC,64,64,64)bf16
__global__ __launch_bounds__(256) void k_conv2(
    const u16* __restrict__ feat1, const float* __restrict__ w,
    const float* __restrict__ cb, const float* __restrict__ g, const float* __restrict__ bb,
    u16* __restrict__ feat2)
{
  __shared__ float sIn[16][18][18];   // 20736 B
  __shared__ float sW[64][16][9];     // 36864 B
  __shared__ float sB[64];
  const int bl = blockIdx.z, ty = blockIdx.y, tx = blockIdx.x;
  const int tid = threadIdx.x;
  if (tid < 64) {
    float sc = g[tid] * rsqrtf(1.0f + 1e-5f);
    sB[tid] = cb[tid] * sc + bb[tid];
  }
  const int pix = tid & 63, ocg = tid >> 6;   // wave-uniform oc group
  const int py = pix >> 3, px = pix & 7;
  float acc[16][4];
  #pragma unroll
  for (int o = 0; o < 16; o++) { acc[o][0]=0.f; acc[o][1]=0.f; acc[o][2]=0.f; acc[o][3]=0.f; }
  const int iy0 = ty*16 - 1, ix0 = tx*16 - 1;
  for (int ch = 0; ch < 4; ch++) {
    __syncthreads();
    for (int i = tid; i < 16*18*18; i += 256) {
      int c = i / 324, r = (i / 18) % 18, q = i % 18;
      int yy = iy0 + r, xx = ix0 + q;
      float v = 0.f;
      if (yy >= 0 && xx >= 0 && yy < 128 && xx < 128)
        v = bf2f(feat1[(((size_t)bl*64 + ch*16 + c)*128 + yy)*128 + xx]);
      sIn[c][r][q] = v;
    }
    for (int i = tid; i < 64*16*9; i += 256) {
      int oc = i / 144, c = (i / 9) % 16, kk = i % 9;
      float sc = g[oc] * rsqrtf(1.0f + 1e-5f);
      sW[oc][c][kk] = w[(oc*64 + ch*16 + c)*9 + kk] * sc;
    }
    __syncthreads();
    #pragma unroll 1
    for (int c = 0; c < 16; c++) {
      float win[4][4];
      #pragma unroll
      for (int r = 0; r < 4; r++)
        #pragma unroll
        for (int q = 0; q < 4; q++)
          win[r][q] = sIn[c][2*py + r][2*px + q];
      #pragma unroll
      for (int o = 0; o < 16; o++) {
        float a0=acc[o][0], a1=acc[o][1], a2=acc[o][2], a3=acc[o][3];
        #pragma unroll
        for (int ky = 0; ky < 3; ky++)
          #pragma unroll
          for (int kx = 0; kx < 3; kx++) {
            float wv = sW[ocg*16 + o][c][ky*3+kx];
            a0 += win[ky  ][kx  ] * wv;
            a1 += win[ky  ][kx+1] * wv;
            a2 += win[ky+1][kx  ] * wv;
            a3 += win[ky+1][kx+1] * wv;
          }
        acc[o][0]=a0; acc[o][1]=a1; acc[o][2]=a2; acc[o][3]=a3;
      }
    }
  }
  const int oy = ty*8 + py, ox = tx*8 + px;
  #pragma unroll
  for (int o = 0; o < 16; o++) {
    int oc = ocg*16 + o;
    float m = fmaxf(fmaxf(acc[o][0],acc[o][1]), fmaxf(acc[o][2],acc[o][3])) + sB[oc];
    feat2[(((size_t)bl*64 + oc)*64 + oy)*64 + ox] = f2bf(fmaxf(m, 0.f));
  }
}

// ---------------- adjacency (input-independent, 1 block)
__global__ __launch_bounds__(256) void k_adj(int* __restrict__ nbr1, u64* __restrict__ mask2)
{
  __shared__ int snbr[225][8];
  const int i = threadIdx.x;
  if (i < 225) {
    const int ii = i / 15, jj = i % 15;
    int bd[8], bj[8];
    #pragma unroll
    for (int t = 0; t < 8; t++) { bd[t] = 1<<30; bj[t] = -1; }
    for (int j = 0; j < 225; j++) {
      if (j == i) continue;
      int di = ii - j/15, dj = jj - j%15;
      int d2 = di*di + dj*dj;
      if (d2 < bd[7]) {                 // strict: equal-d2 keeps earlier j (stable argsort)
        int p = 7;
        while (p > 0 && d2 < bd[p-1]) { bd[p]=bd[p-1]; bj[p]=bj[p-1]; p--; }
        bd[p] = d2; bj[p] = j;
      }
    }
    #pragma unroll
    for (int t = 0; t < 8; t++) { snbr[i][t] = bj[t]; nbr1[i*8+t] = bj[t]; }
  }
  __syncthreads();
  if (i < 225) {
    u64 m[4] = {0,0,0,0};
    #pragma unroll
    for (int t = 0; t < 8; t++) {
      int tt = snbr[i][t];
      #pragma unroll
      for (int u = 0; u < 8; u++) {
        int j = snbr[tt][u];
        m[j >> 6] |= 1ull << (j & 63);
      }
    }
    m[i >> 6] &= ~(1ull << (i & 63));
    #pragma unroll
    for (int wd = 0; wd < 4; wd++) mask2[i*4 + wd] = m[wd];
  }
}

// ---------------- split proj_w (f32) -> hi/lo bf16 (once per launch)
__global__ __launch_bounds__(256) void k_cvtw(
    const float* __restrict__ pw, u16* __restrict__ pwh, u16* __restrict__ pwl)
{
  const int i = (blockIdx.x * 256 + threadIdx.x) * 4;   // 524288 elements total
  float4 v = *reinterpret_cast<const float4*>(pw + i);
  float e[4] = {v.x, v.y, v.z, v.w};
  ushort4 h, l;
  u16* hp = &h.x; u16* lp = &l.x;
  #pragma unroll
  for (int j = 0; j < 4; j++) {
    u16 hb = f2bf(e[j]);
    hp[j] = hb;
    lp[j] = f2bf(e[j] - bf2f(hb));
  }
  *reinterpret_cast<ushort4*>(pwh + i) = h;
  *reinterpret_cast<ushort4*>(pwl + i) = l;
}

// ---------------- patch-projection as MFMA GEMM:
// nodes[b, n, :] = patches[b, n, :] @ pw^T + pb ; M-tile 64 rows/block, 4 waves x 16 rows
__global__ __launch_bounds__(256) void k_projm(
    const u16* __restrict__ feat2,                       // (BC,64,64,64) bf16
    const u16* __restrict__ pwh, const u16* __restrict__ pwl,  // (128,4096) bf16
    const float* __restrict__ pb,
    float* __restrict__ nodes, int b0)
{
  __shared__ __align__(16) u16 sA [64][40];   // 80 B pitch (5x16B: conflict-free b128)
  __shared__ __align__(16) u16 sBh[128][40];
  __shared__ __align__(16) u16 sBl[128][40];
  const int cx = blockIdx.x, bl = blockIdx.y;
  const int b  = b0 + bl;
  const int n0 = cx * 64;
  const int rows = (225 - n0) < 64 ? (225 - n0) : 64;    // 64,64,64,33
  const int tid = threadIdx.x;
  const int w = tid >> 6, l = tid & 63;
  const int lr = l & 15, lk = l >> 4;

  f32x4 acc[8];
  #pragma unroll
  for (int i = 0; i < 8; i++) acc[i] = (f32x4){0.f, 0.f, 0.f, 0.f};

  const int ar = tid >> 2, aci = tid & 3;    // A-staging: row, i-chunk
  const int an = n0 + ar;
  const int aph = an / 15, apw = an % 15;

  for (int k0 = 0; k0 < 4096; k0 += 32) {
    const int c  = k0 >> 6;
    const int i0 = (k0 & 63) >> 3;           // 0 or 4
    // stage A: 64 rows x 32 k (patch gather, 8-contig bf16 chunks)
    {
      uint2 g0 = {0u,0u}, g1 = {0u,0u};
      if (ar < rows) {
        const u16* src = feat2 + (((size_t)bl*64 + c)*64 + aph*4 + i0 + aci)*64 + apw*4;
        g0 = *reinterpret_cast<const uint2*>(src);
        g1 = *reinterpret_cast<const uint2*>(src + 4);
      }
      uint4 v; v.x = g0.x; v.y = g0.y; v.z = g1.x; v.w = g1.y;
      *reinterpret_cast<uint4*>(&sA[ar][aci*8]) = v;
    }
    // stage B hi/lo: 128 cols x 32 k
    #pragma unroll
    for (int p = 0; p < 2; p++) {
      int idx = p*256 + tid;
      int col = idx >> 2, seg = idx & 3;
      const size_t off = (size_t)col*4096 + k0 + seg*8;
      *reinterpret_cast<uint4*>(&sBh[col][seg*8]) = *reinterpret_cast<const uint4*>(pwh + off);
      *reinterpret_cast<uint4*>(&sBl[col][seg*8]) = *reinterpret_cast<const uint4*>(pwl + off);
    }
    __syncthreads();
    short8v a = *reinterpret_cast<const short8v*>(&sA[w*16 + lr][lk*8]);
    #pragma unroll
    for (int ct = 0; ct < 8; ct++) {
      short8v bh = *reinterpret_cast<const short8v*>(&sBh[ct*16 + lr][lk*8]);
      short8v bv = *reinterpret_cast<const short8v*>(&sBl[ct*16 + lr][lk*8]);
      acc[ct] = __builtin_amdgcn_mfma_f32_16x16x32_bf16(a, bh, acc[ct], 0, 0, 0);
      acc[ct] = __builtin_amdgcn_mfma_f32_16x16x32_bf16(a, bv, acc[ct], 0, 0, 0);
    }
    __syncthreads();
  }
  // epilogue: C row = w*16 + lk*4 + v, col = ct*16 + lr   (m89-verified layout)
  #pragma unroll
  for (int ct = 0; ct < 8; ct++) {
    const int col = ct*16 + lr;
    const float bias = pb[col];
    #pragma unroll
    for (int v = 0; v < 4; v++) {
      const int r = w*16 + lk*4 + v;
      if (r < rows)
        nodes[((size_t)b*225 + n0 + r)*128 + col] = acc[ct][v] + bias;
    }
  }
}

// ---------------- graph conv + gate + score, fused per (b,node)
__global__ __launch_bounds__(128) void k_graph(
    const float* __restrict__ nodes, const int* __restrict__ nbr1,
    const u64* __restrict__ mask2,
    const float* __restrict__ w1w, const float* __restrict__ w1b,
    const float* __restrict__ w2w, const float* __restrict__ w2b,
    const float* __restrict__ gw, const float* __restrict__ gb,
    const float* __restrict__ sw, const float* __restrict__ sb,
    float* __restrict__ zbuf, float* __restrict__ scores)
{
  __shared__ float sA1[128], sA2[128], sC[256], sRed[128];
  const int n = blockIdx.x, b = blockIdx.y;
  const int d = threadIdx.x;
  const float* nb = nodes + (size_t)b * 225 * 128;
  float a1 = 0.f;
  #pragma unroll
  for (int t = 0; t < 8; t++) a1 += nb[(size_t)nbr1[n*8+t]*128 + d];
  float a2 = 0.f;
  for (int wd = 0; wd < 4; wd++) {
    u64 m = mask2[n*4 + wd];
    while (m) {
      int j = wd*64 + __builtin_ctzll(m);
      a2 += nb[(size_t)j*128 + d];
      m &= m - 1;
    }
  }
  sA1[d] = a1; sA2[d] = a2;
  __syncthreads();
  float z1 = w1b[d];
  { const float* wr = w1w + (size_t)d*128;
    for (int k = 0; k < 128; k += 8) {
      float wv[8]; ld8f(wr + k, wv);
      #pragma unroll
      for (int j = 0; j < 8; j++) z1 += wv[j] * sA1[k+j];
    } }
  float z2 = w2b[d];
  { const float* wr = w2w + (size_t)d*128;
    for (int k = 0; k < 128; k += 8) {
      float wv[8]; ld8f(wr + k, wv);
      #pragma unroll
      for (int j = 0; j < 8; j++) z2 += wv[j] * sA2[k+j];
    } }
  sC[d] = z1; sC[128 + d] = z2;
  __syncthreads();
  float gl = gb[d];
  { const float* wr = gw + (size_t)d*256;
    for (int k = 0; k < 256; k += 8) {
      float wv[8]; ld8f(wr + k, wv);
      #pragma unroll
      for (int j = 0; j < 8; j++) gl += wv[j] * sC[k+j];
    } }
  float gg = 1.f / (1.f + expf(-gl));
  float zv = gg * z1 + (1.f - gg) * z2;
  zbuf[((size_t)b*225 + n)*128 + d] = zv;
  sRed[d] = zv * sw[d];
  __syncthreads();
  for (int st = 64; st > 0; st >>= 1) {
    if (d < st) sRed[d] += sRed[d + st];
    __syncthreads();
  }
  if (d == 0) scores[b*225 + n] = sRed[0] + sb[0];
}

// ---------------- top-k (k=112) with jax tie semantics
__global__ __launch_bounds__(256) void k_topk(
    const float* __restrict__ scores, int* __restrict__ sel)
{
  __shared__ float ss[225];
  const int b = blockIdx.x, tid = threadIdx.x;
  if (tid < 112) sel[b*112 + tid] = tid;   // defensive init: no poison survives
  if (tid < 225) ss[tid] = scores[b*225 + tid];
  __syncthreads();
  if (tid < 225) {
    float s = ss[tid];
    int rank = 0;
    for (int j = 0; j < 225; j++) {
      float sj = ss[j];
      rank += (sj > s) || (sj == s && j < tid);
    }
    if (rank < 112) sel[b*112 + rank] = tid;
  }
}

// ---------------- qkv projection per (b, s)
__global__ __launch_bounds__(128) void k_qkv(
    const float* __restrict__ zbuf, const int* __restrict__ sel,
    const float* __restrict__ iw, const float* __restrict__ ib,
    float* __restrict__ q, float* __restrict__ k, float* __restrict__ v)
{
  __shared__ float sx[128];
  const int s = blockIdx.x, b = blockIdx.y, d = threadIdx.x;
  int row = sel[b*112 + s];
  row = row < 0 ? 0 : (row > 224 ? 224 : row);   // clamp: fault-proof
  sx[d] = zbuf[((size_t)b*225 + row)*128 + d];
  __syncthreads();
  const int h = d >> 5, t = d & 31;
  float* outs[3] = {q, k, v};
  #pragma unroll
  for (int part = 0; part < 3; part++) {
    float acc = ib[part*128 + d];
    const float* wr = iw + (size_t)(part*128 + d) * 128;
    for (int kk = 0; kk < 128; kk += 8) {
      float wv[8]; ld8f(wr + kk, wv);
      #pragma unroll
      for (int j = 0; j < 8; j++) acc += wv[j] * sx[kk+j];
    }
    outs[part][(((size_t)b*4 + h)*112 + s)*32 + t] = acc;
  }
}

// ---------------- attention per (b, head), two-pass softmax
__global__ __launch_bounds__(128) void k_attn(
    const float* __restrict__ q, const float* __restrict__ k,
    const float* __restrict__ v, float* __restrict__ o)
{
  __shared__ float sK[112*32], sV[112*32];
  const int h = blockIdx.x, b = blockIdx.y, tid = threadIdx.x;
  const size_t base = ((size_t)b*4 + h) * 112 * 32;
  for (int i = tid; i < 112*32; i += 128) {
    sK[i] = k[base + i];
    sV[i] = v[base + i];
  }
  __syncthreads();
  if (tid < 112) {
    float qv[32];
    const float* qp = q + base + (size_t)tid*32;
    #pragma unroll
    for (int t = 0; t < 32; t++) qv[t] = qp[t];
    const float scale = 0.17677669529663687f; // 1/sqrt(32)
    float mx = -INFINITY;
    for (int j = 0; j < 112; j++) {
      float s = 0.f;
      #pragma unroll
      for (int t = 0; t < 32; t++) s += qv[t] * sK[j*32 + t];
      mx = fmaxf(mx, s * scale);
    }
    float acc[32];
    #pragma unroll
    for (int t = 0; t < 32; t++) acc[t] = 0.f;
    float l = 0.f;
    for (int j = 0; j < 112; j++) {
      float s = 0.f;
      #pragma unroll
      for (int t = 0; t < 32; t++) s += qv[t] * sK[j*32 + t];
      float p = expf(s * scale - mx);
      l += p;
      #pragma unroll
      for (int t = 0; t < 32; t++) acc[t] += p * sV[j*32 + t];
    }
    float inv = 1.f / l;
    float* op = o + ((size_t)b*112 + tid)*128 + h*32;
    #pragma unroll
    for (int t = 0; t < 32; t++) op[t] = acc[t] * inv;
  }
}

// ---------------- out-proj + residual + LN1 per (b, s)
__global__ __launch_bounds__(128) void k_oln(
    const float* __restrict__ o, const float* __restrict__ zbuf,
    const int* __restrict__ sel,
    const float* __restrict__ ow, const float* __restrict__ ob,
    const float* __restrict__ lg, const float* __restrict__ lb,
    float* __restrict__ h1)
{
  __shared__ float so[128], sRed[128], sRed2[128];
  const int s = blockIdx.x, b = blockIdx.y, d = threadIdx.x;
  so[d] = o[((size_t)b*112 + s)*128 + d];
  __syncthreads();
  float acc = ob[d];
  const float* wr = ow + (size_t)d * 128;
  for (int kk = 0; kk < 128; kk += 8) {
    float wv[8]; ld8f(wr + kk, wv);
    #pragma unroll
    for (int j = 0; j < 8; j++) acc += wv[j] * so[kk+j];
  }
  int row = sel[b*112 + s];
  row = row < 0 ? 0 : (row > 224 ? 224 : row);
  acc += zbuf[((size_t)b*225 + row)*128 + d];
  sRed[d] = acc; sRed2[d] = acc * acc;
  __syncthreads();
  for (int st = 64; st > 0; st >>= 1) {
    if (d < st) { sRed[d] += sRed[d+st]; sRed2[d] += sRed2[d+st]; }
    __syncthreads();
  }
  float mean = sRed[0] * (1.f/128.f);
  float var  = sRed2[0] * (1.f/128.f) - mean*mean;
  float r = rsqrtf(var + 1e-5f);
  h1[((size_t)b*112 + s)*128 + d] = (acc - mean) * r * lg[d] + lb[d];
}

// ---------------- FFN + residual + LN2 per (b, s) -> h2 (may alias h1: row-local)
__global__ __launch_bounds__(256) void k_ffn(
    const float* __restrict__ h1,
    const float* __restrict__ f1w, const float* __restrict__ f1b,
    const float* __restrict__ f2w, const float* __restrict__ f2b,
    const float* __restrict__ lg, const float* __restrict__ lb,
    float* __restrict__ h2)
{
  __shared__ float sh[128];
  __shared__ float sf[512];
  __shared__ float sRed[128], sRed2[128];
  const int s = blockIdx.x, b = blockIdx.y, tid = threadIdx.x;
  if (tid < 128) sh[tid] = h1[((size_t)b*112 + s)*128 + tid];
  __syncthreads();
  #pragma unroll
  for (int rdx = 0; rdx < 2; rdx++) {
    int oo = tid + rdx*256;
    float acc = f1b[oo];
    const float* wr = f1w + (size_t)oo * 128;
    for (int kk = 0; kk < 128; kk += 8) {
      float wv[8]; ld8f(wr + kk, wv);
      #pragma unroll
      for (int j = 0; j < 8; j++) acc += wv[j] * sh[kk+j];
    }
    sf[oo] = fmaxf(acc, 0.f);
  }
  __syncthreads();
  float val = 0.f;
  if (tid < 128) {
    float acc = f2b[tid];
    const float* wr = f2w + (size_t)tid * 512;
    for (int kk = 0; kk < 512; kk += 8) {
      float wv[8]; ld8f(wr + kk, wv);
      #pragma unroll
      for (int j = 0; j < 8; j++) acc += wv[j] * sf[kk+j];
    }
    val = sh[tid] + acc;
    sRed[tid] = val; sRed2[tid] = val*val;
  }
  __syncthreads();
  for (int st = 64; st > 0; st >>= 1) {
    if (tid < st) { sRed[tid] += sRed[tid+st]; sRed2[tid] += sRed2[tid+st]; }
    __syncthreads();
  }
  if (tid < 128) {
    float mean = sRed[0] * (1.f/128.f);
    float var  = sRed2[0] * (1.f/128.f) - mean*mean;
    float r = rsqrtf(var + 1e-5f);
    h2[((size_t)b*112 + s)*128 + tid] = (val - mean) * r * lg[tid] + lb[tid];
  }
}

// ---------------- rep = sum_s h2 ; classifier -> logits (f32)
__global__ __launch_bounds__(64) void k_cls(
    const float* __restrict__ h2,
    const float* __restrict__ c1w, const float* __restrict__ c1b,
    const float* __restrict__ c2w, const float* __restrict__ c2b,
    float* __restrict__ out)
{
  __shared__ float sr[128], sc[64];
  const int b = blockIdx.x, tid = threadIdx.x;
  float r0 = 0.f, r1 = 0.f;
  for (int s2 = 0; s2 < 112; s2++) {
    const float* row = h2 + ((size_t)b*112 + s2)*128;
    r0 += row[tid];
    r1 += row[tid + 64];
  }
  sr[tid] = r0; sr[tid + 64] = r1;
  __syncthreads();
  float acc = c1b[tid];
  const float* wr = c1w + (size_t)tid * 128;
  for (int kk = 0; kk < 128; kk += 8) {
    float wv[8]; ld8f(wr + kk, wv);
    #pragma unroll
    for (int j = 0; j < 8; j++) acc += wv[j] * sr[kk+j];
  }
  sc[tid] = fmaxf(acc, 0.f);
  __syncthreads();
  if (tid < 2) {
    float l = c2b[tid];
    for (int kk = 0; kk < 64; kk++) l += c2w[tid*64 + kk] * sc[kk];
    out[b*2 + tid] = l;
  }
}

extern "C" void kernel_launch(void* const* d_in, const int* in_sizes, int n_in,
                              void* d_out, int out_size, void* d_ws, size_t ws_size,
                              hipStream_t stream)
{
  const float* x    = (const float*)d_in[0];
  const float* c1w  = (const float*)d_in[1];
  const float* c1b  = (const float*)d_in[2];
  const float* bn1g = (const float*)d_in[3];
  const float* bn1b = (const float*)d_in[4];
  const float* c2w  = (const float*)d_in[5];
  const float* c2b  = (const float*)d_in[6];
  const float* bn2g = (const float*)d_in[7];
  const float* bn2b = (const float*)d_in[8];
  const float* pjw  = (const float*)d_in[9];
  const float* pjb  = (const float*)d_in[10];
  const float* w1w  = (const float*)d_in[11];
  const float* w1b  = (const float*)d_in[12];
  const float* w2w  = (const float*)d_in[13];
  const float* w2b  = (const float*)d_in[14];
  const float* gw   = (const float*)d_in[15];
  const float* gb   = (const float*)d_in[16];
  const float* scw  = (const float*)d_in[17];
  const float* scb  = (const float*)d_in[18];
  const float* ipw  = (const float*)d_in[19];
  const float* ipb  = (const float*)d_in[20];
  const float* opw  = (const float*)d_in[21];
  const float* opb  = (const float*)d_in[22];
  const float* f1w  = (const float*)d_in[23];
  const float* f1b  = (const float*)d_in[24];
  const float* f2w  = (const float*)d_in[25];
  const float* f2b  = (const float*)d_in[26];
  const float* l1g  = (const float*)d_in[27];
  const float* l1b  = (const float*)d_in[28];
  const float* l2g  = (const float*)d_in[29];
  const float* l2b  = (const float*)d_in[30];
  const float* cl1w = (const float*)d_in[31];
  const float* cl1b = (const float*)d_in[32];
  const float* cl2w = (const float*)d_in[33];
  const float* cl2b = (const float*)d_in[34];

  // ---- bump allocator over d_ws (256-B aligned) ----
  char* p = (char*)d_ws;
  auto alloc = [&](size_t n) { char* r = p; p += (n + 255) & ~(size_t)255; return r; };
  u64*   mask2  = (u64*)  alloc(900    * sizeof(u64));   // 225*4
  int*   nbr1   = (int*)  alloc(1800   * sizeof(int));   // 225*8
  int*   sel    = (int*)  alloc(1792   * sizeof(int));   // 16*112
  float* scores = (float*)alloc(3600   * sizeof(float)); // 16*225
  u16*   pwh    = (u16*)  alloc(524288 * sizeof(u16));   // 128*4096 bf16 (hi)
  u16*   pwl    = (u16*)  alloc(524288 * sizeof(u16));   // 128*4096 bf16 (lo)
  float* zbuf   = (float*)alloc(460800 * sizeof(float)); // 16*225*128  (live: graph->oln)
  float* nodes  = (float*)alloc(460800 * sizeof(float)); // live: proj->graph, then reused
  const size_t fixed_bytes = (size_t)(p - (char*)d_ws);

  // S3 region: conv feats (BC*(2MB+0.5MB) bf16), later reused for q/k/v (f32)
  const size_t qkv_bytes = 3ull * 229376ull * sizeof(float);
  const size_t per_batch = 64ull*128*128*2 + 64ull*64*64*2;   // 2,621,440 B
  int BC = 16;
  size_t s3 = 0;
  for (;; BC >>= 1) {
    s3 = (size_t)BC * per_batch; if (s3 < qkv_bytes) s3 = qkv_bytes;
    if (fixed_bytes + s3 + 65536 <= ws_size) break;
    if (BC == 1) { return; }  // ws too small for any plan: clean-fail diagnostic
  }
  char* S3 = alloc(s3);

  // aliases (lifetime-disjoint)
  u16*   feat1 = (u16*)S3;                              // conv phase
  u16*   feat2 = (u16*)(S3 + (size_t)BC * 2097152ull);  // conv phase
  float* qb    = (float*)S3;                            // attention phase
  float* kb    = qb + 229376;
  float* vb    = kb + 229376;
  float* obuf  = nodes;                                 // nodes dead after k_graph
  float* hbuf  = nodes + 229376;                        // h1/h2 (row-local in-place)

  k_adj <<<1, 256, 0, stream>>>(nbr1, mask2);
  k_cvtw<<<512, 256, 0, stream>>>(pjw, pwh, pwl);

  for (int b0 = 0; b0 < 16; b0 += BC) {
    k_conv1<<<dim3(8,8,BC), 256, 0, stream>>>(x, c1w, c1b, bn1g, bn1b, feat1, b0);
    k_conv2<<<dim3(8,8,BC), 256, 0, stream>>>(feat1, c2w, c2b, bn2g, bn2b, feat2);
    k_projm<<<dim3(4,BC), 256, 0, stream>>>(feat2, pwh, pwl, pjb, nodes, b0);
  }

  k_graph<<<dim3(225,16), 128, 0, stream>>>(nodes, nbr1, mask2, w1w, w1b, w2w, w2b,
                                            gw, gb, scw, scb, zbuf, scores);
  k_topk <<<16, 256, 0, stream>>>(scores, sel);
  k_qkv  <<<dim3(112,16), 128, 0, stream>>>(zbuf, sel, ipw, ipb, qb, kb, vb);
  k_attn <<<dim3(4,16), 128, 0, stream>>>(qb, kb, vb, obuf);
  k_oln  <<<dim3(112,16), 128, 0, stream>>>(obuf, zbuf, sel, opw, opb, l1g, l1b, hbuf);
  k_ffn  <<<dim3(112,16), 256, 0, stream>>>(hbuf, f1w, f1b, f2w, f2b, l2g, l2b, hbuf);
  k_cls  <<<16, 64, 0, stream>>>(hbuf, cl1w, cl1b, cl2w, cl2b, (float*)d_out);
}

// Round 6
// 753.463 us; speedup vs baseline: 2.2800x; 1.3191x over previous
//
#include <hip/hip_runtime.h>
#include <hip/hip_bf16.h>
#include <math.h>

typedef unsigned short u16;
typedef unsigned int   u32;
typedef unsigned long long u64;
typedef __attribute__((ext_vector_type(8))) short short8v;
typedef __attribute__((ext_vector_type(4))) float f32x4;

__device__ __forceinline__ float bf2f(u16 u) {
  union { u32 i; float f; } v; v.i = ((u32)u) << 16; return v.f;
}
__device__ __forceinline__ u16 f2bf(float f) {  // round-to-nearest-even
  union { float f; u32 i; } v; v.f = f;
  u32 r = (v.i + 0x7FFFu + ((v.i >> 16) & 1u)) >> 16;
  return (u16)r;
}
__device__ __forceinline__ void ld4bf(const u16* p, float* o) {  // 8B-aligned
  uint2 u = *reinterpret_cast<const uint2*>(p);
  o[0]=bf2f((u16)(u.x)); o[1]=bf2f((u16)(u.x>>16));
  o[2]=bf2f((u16)(u.y)); o[3]=bf2f((u16)(u.y>>16));
}
__device__ __forceinline__ void ld8f(const float* p, float* o) {  // 16B-aligned
  float4 a = *reinterpret_cast<const float4*>(p);
  float4 b = *reinterpret_cast<const float4*>(p + 4);
  o[0]=a.x; o[1]=a.y; o[2]=a.z; o[3]=a.w;
  o[4]=b.x; o[5]=b.y; o[6]=b.z; o[7]=b.w;
}

// ---------------- conv1 + bn1 + relu + maxpool2 : (16,3,256,256)f32 -> (BC,128,128,64) NHWC bf16
__global__ __launch_bounds__(256) void k_conv1(
    const float* __restrict__ x, const float* __restrict__ w,
    const float* __restrict__ cb, const float* __restrict__ g, const float* __restrict__ bb,
    u16* __restrict__ feat1, int b0)
{
  __shared__ float sIn[3][34][34];
  __shared__ float sW[64][27];
  __shared__ float sB[64];
  const int bl = blockIdx.z, ty = blockIdx.y, tx = blockIdx.x;
  const int b = b0 + bl;
  const int tid = threadIdx.x;
  for (int i = tid; i < 64*27; i += 256) {
    int oc = i / 27;
    float sc = g[oc] * rsqrtf(1.0f + 1e-5f);
    sW[oc][i % 27] = w[i] * sc;
  }
  if (tid < 64) {
    float sc = g[tid] * rsqrtf(1.0f + 1e-5f);
    sB[tid] = cb[tid] * sc + bb[tid];
  }
  const int iy0 = ty*32 - 1, ix0 = tx*32 - 1;
  for (int i = tid; i < 3*34*34; i += 256) {
    int c = i / (34*34); int r = (i / 34) % 34; int q = i % 34;
    int yy = iy0 + r, xx = ix0 + q;
    float v = 0.f;
    if (yy >= 0 && xx >= 0 && yy < 256 && xx < 256)
      v = x[(((size_t)b*3 + c)*256 + yy)*256 + xx];
    sIn[c][r][q] = v;
  }
  __syncthreads();
  const int py = tid >> 4, px = tid & 15;
  float win[3][4][4];
  #pragma unroll
  for (int c = 0; c < 3; c++)
    #pragma unroll
    for (int r = 0; r < 4; r++)
      #pragma unroll
      for (int q = 0; q < 4; q++)
        win[c][r][q] = sIn[c][2*py + r][2*px + q];
  const int oy = ty*16 + py, ox = tx*16 + px;
  u16* outp = feat1 + (((size_t)bl*128 + oy)*128 + ox)*64;   // NHWC
  u16 pend = 0;
  for (int oc = 0; oc < 64; oc++) {
    float s00=0.f, s01=0.f, s10=0.f, s11=0.f;
    #pragma unroll
    for (int c = 0; c < 3; c++)
      #pragma unroll
      for (int ky = 0; ky < 3; ky++)
        #pragma unroll
        for (int kx = 0; kx < 3; kx++) {
          float wv = sW[oc][(c*3+ky)*3+kx];
          s00 += win[c][ky  ][kx  ] * wv;
          s01 += win[c][ky  ][kx+1] * wv;
          s10 += win[c][ky+1][kx  ] * wv;
          s11 += win[c][ky+1][kx+1] * wv;
        }
    float m = fmaxf(fmaxf(s00,s01), fmaxf(s10,s11)) + sB[oc];
    u16 cur = f2bf(fmaxf(m, 0.f));
    if (oc & 1) {
      u32 pk = (u32)pend | ((u32)cur << 16);
      *reinterpret_cast<u32*>(outp + oc - 1) = pk;
    } else pend = cur;
  }
}

// ---------------- conv2 weights f32 OIHW -> bf16 hi/lo [ky*3+kx][chunk][oc][icL], bn-scaled
__global__ __launch_bounds__(256) void k_cvtw2(
    const float* __restrict__ w, const float* __restrict__ g,
    u16* __restrict__ wh, u16* __restrict__ wl)
{
  const int d = blockIdx.x * 256 + threadIdx.x;      // 36864 total
  if (d >= 36864) return;
  const int icL = d & 31, oc = (d >> 5) & 63, chunk = (d >> 11) & 1, kk = d >> 12;
  const float sc = g[oc] * rsqrtf(1.0f + 1e-5f);
  const float val = w[((size_t)oc*64 + chunk*32 + icL)*9 + kk] * sc;
  const u16 hb = f2bf(val);
  wh[d] = hb;
  wl[d] = f2bf(val - bf2f(hb));
}

// ---------------- conv2 + bn2 + relu + maxpool2 via MFMA implicit GEMM
// feat1 NHWC (BC,128,128,64) bf16 -> feat2 NCHW (BC,64,64,64) bf16
// block: 16x32 conv pixels (tile ty 0..7, tx 0..3) x 64 oc, 4 waves
__global__ __launch_bounds__(256, 2) void k_conv2m(
    const u16* __restrict__ feat1,
    const u16* __restrict__ wh, const u16* __restrict__ wl,
    const float* __restrict__ cb, const float* __restrict__ g, const float* __restrict__ bb,
    u16* __restrict__ feat2)
{
  // sA: halo 18 rows x 34 cols x 32 ic, pitch 40 (80B, odd x16B -> conflict-free b128)
  __shared__ __align__(16) u16 sA[18*34*40];          // 48960 B
  __shared__ __align__(16) u16 sBh[64*40], sBl[64*40]; // 5120 B each
  __shared__ float sBias[64];
  const int tx = blockIdx.x, ty = blockIdx.y, bl = blockIdx.z;
  const int y0 = ty*16, x0 = tx*32;
  const int tid = threadIdx.x;
  const int w = tid >> 6, l = tid & 63;
  const int lr = l & 15, lk = l >> 4;

  if (tid < 64) {
    float sc = g[tid] * rsqrtf(1.0f + 1e-5f);
    sBias[tid] = cb[tid] * sc + bb[tid];
  }

  f32x4 acc[8][4];
  #pragma unroll
  for (int j = 0; j < 8; j++)
    #pragma unroll
    for (int ct = 0; ct < 4; ct++)
      acc[j][ct] = (f32x4){0.f,0.f,0.f,0.f};

  for (int chunk = 0; chunk < 2; chunk++) {
    __syncthreads();
    // stage A: 612 halo pixels x 32 ic (4 x uint4 each)
    for (int idx = tid; idx < 612*4; idx += 256) {
      const int pix = idx >> 2, seg = idx & 3;
      const int r = pix / 34, cc = pix % 34;
      const int yy = y0 - 1 + r, xx = x0 - 1 + cc;
      uint4 v = {0u,0u,0u,0u};
      if (yy >= 0 && yy < 128 && xx >= 0 && xx < 128)
        v = *reinterpret_cast<const uint4*>(
              feat1 + (((size_t)bl*128 + yy)*128 + xx)*64 + chunk*32 + seg*8);
      *reinterpret_cast<uint4*>(&sA[(size_t)(r*34 + cc)*40 + seg*8]) = v;
    }
    for (int kk = 0; kk < 9; kk++) {
      __syncthreads();   // prev compute done (and A staged, on kk=0)
      {  // stage B hi/lo: 64 oc x 32 ic
        const int oc = tid >> 2, s8 = (tid & 3)*8;
        const size_t src = (size_t)(kk*2 + chunk)*2048 + tid*8;
        *reinterpret_cast<uint4*>(&sBh[oc*40 + s8]) = *reinterpret_cast<const uint4*>(wh + src);
        *reinterpret_cast<uint4*>(&sBl[oc*40 + s8]) = *reinterpret_cast<const uint4*>(wl + src);
      }
      __syncthreads();
      const int ky = kk / 3, kx = kk % 3;
      short8v a[8];
      #pragma unroll
      for (int j = 0; j < 8; j++) {
        const int m = w*8 + j;
        const int r = (m >> 1) + ky;
        const int cc = (m & 1)*16 + lr + kx;
        a[j] = *reinterpret_cast<const short8v*>(&sA[(size_t)(r*34 + cc)*40 + lk*8]);
      }
      #pragma unroll
      for (int ct = 0; ct < 4; ct++) {
        const short8v bh = *reinterpret_cast<const short8v*>(&sBh[(ct*16 + lr)*40 + lk*8]);
        const short8v bv = *reinterpret_cast<const short8v*>(&sBl[(ct*16 + lr)*40 + lk*8]);
        #pragma unroll
        for (int j = 0; j < 8; j++) {
          acc[j][ct] = __builtin_amdgcn_mfma_f32_16x16x32_bf16(a[j], bh, acc[j][ct], 0, 0, 0);
          acc[j][ct] = __builtin_amdgcn_mfma_f32_16x16x32_bf16(a[j], bv, acc[j][ct], 0, 0, 0);
        }
      }
    }
  }
  // fused maxpool + bias + relu + bf16, write feat2 NCHW
  // conv pixel p = m*16 + lk*4 + v : y = y0 + (m>>1), x = x0 + (m&1)*16 + lk*4 + v
  #pragma unroll
  for (int u = 0; u < 2; u++) {
    #pragma unroll
    for (int xh = 0; xh < 2; xh++) {
      const int jA = 4*u + xh, jB = 4*u + 2 + xh;
      #pragma unroll
      for (int ct = 0; ct < 4; ct++) {
        const int oc = ct*16 + lr;
        const float bias = sBias[oc];
        const float v0 = fmaxf(fmaxf(acc[jA][ct][0], acc[jA][ct][1]),
                               fmaxf(acc[jB][ct][0], acc[jB][ct][1]));
        const float v1 = fmaxf(fmaxf(acc[jA][ct][2], acc[jA][ct][3]),
                               fmaxf(acc[jB][ct][2], acc[jB][ct][3]));
        const u16 b0v = f2bf(fmaxf(v0 + bias, 0.f));
        const u16 b1v = f2bf(fmaxf(v1 + bias, 0.f));
        const int py = ty*8 + 2*w + u;
        const int px = tx*16 + xh*8 + lk*2;
        u32 pk = (u32)b0v | ((u32)b1v << 16);
        *reinterpret_cast<u32*>(&feat2[(((size_t)bl*64 + oc)*64 + py)*64 + px]) = pk;
      }
    }
  }
}

// ---------------- adjacency (input-independent, 1 block)
__global__ __launch_bounds__(256) void k_adj(int* __restrict__ nbr1, u64* __restrict__ mask2)
{
  __shared__ int snbr[225][8];
  const int i = threadIdx.x;
  if (i < 225) {
    const int ii = i / 15, jj = i % 15;
    int bd[8], bj[8];
    #pragma unroll
    for (int t = 0; t < 8; t++) { bd[t] = 1<<30; bj[t] = -1; }
    for (int j = 0; j < 225; j++) {
      if (j == i) continue;
      int di = ii - j/15, dj = jj - j%15;
      int d2 = di*di + dj*dj;
      if (d2 < bd[7]) {
        int p = 7;
        while (p > 0 && d2 < bd[p-1]) { bd[p]=bd[p-1]; bj[p]=bj[p-1]; p--; }
        bd[p] = d2; bj[p] = j;
      }
    }
    #pragma unroll
    for (int t = 0; t < 8; t++) { snbr[i][t] = bj[t]; nbr1[i*8+t] = bj[t]; }
  }
  __syncthreads();
  if (i < 225) {
    u64 m[4] = {0,0,0,0};
    #pragma unroll
    for (int t = 0; t < 8; t++) {
      int tt = snbr[i][t];
      #pragma unroll
      for (int u = 0; u < 8; u++) {
        int j = snbr[tt][u];
        m[j >> 6] |= 1ull << (j & 63);
      }
    }
    m[i >> 6] &= ~(1ull << (i & 63));
    #pragma unroll
    for (int wd = 0; wd < 4; wd++) mask2[i*4 + wd] = m[wd];
  }
}

// ---------------- split proj_w (f32) -> hi/lo bf16 (once per launch)
__global__ __launch_bounds__(256) void k_cvtw(
    const float* __restrict__ pw, u16* __restrict__ pwh, u16* __restrict__ pwl)
{
  const int i = (blockIdx.x * 256 + threadIdx.x) * 4;   // 524288 elements total
  float4 v = *reinterpret_cast<const float4*>(pw + i);
  float e[4] = {v.x, v.y, v.z, v.w};
  ushort4 h, l;
  u16* hp = &h.x; u16* lp = &l.x;
  #pragma unroll
  for (int j = 0; j < 4; j++) {
    u16 hb = f2bf(e[j]);
    hp[j] = hb;
    lp[j] = f2bf(e[j] - bf2f(hb));
  }
  *reinterpret_cast<ushort4*>(pwh + i) = h;
  *reinterpret_cast<ushort4*>(pwl + i) = l;
}

// ---------------- patch-projection as MFMA GEMM
__global__ __launch_bounds__(256) void k_projm(
    const u16* __restrict__ feat2,
    const u16* __restrict__ pwh, const u16* __restrict__ pwl,
    const float* __restrict__ pb,
    float* __restrict__ nodes, int b0)
{
  __shared__ __align__(16) u16 sA [64][40];
  __shared__ __align__(16) u16 sBh[128][40];
  __shared__ __align__(16) u16 sBl[128][40];
  const int cx = blockIdx.x, bl = blockIdx.y;
  const int b  = b0 + bl;
  const int n0 = cx * 64;
  const int rows = (225 - n0) < 64 ? (225 - n0) : 64;
  const int tid = threadIdx.x;
  const int w = tid >> 6, l = tid & 63;
  const int lr = l & 15, lk = l >> 4;

  f32x4 acc[8];
  #pragma unroll
  for (int i = 0; i < 8; i++) acc[i] = (f32x4){0.f, 0.f, 0.f, 0.f};

  const int ar = tid >> 2, aci = tid & 3;
  const int an = n0 + ar;
  const int aph = an / 15, apw = an % 15;

  for (int k0 = 0; k0 < 4096; k0 += 32) {
    const int c  = k0 >> 6;
    const int i0 = (k0 & 63) >> 3;
    {
      uint2 g0 = {0u,0u}, g1 = {0u,0u};
      if (ar < rows) {
        const u16* src = feat2 + (((size_t)bl*64 + c)*64 + aph*4 + i0 + aci)*64 + apw*4;
        g0 = *reinterpret_cast<const uint2*>(src);
        g1 = *reinterpret_cast<const uint2*>(src + 4);
      }
      uint4 v; v.x = g0.x; v.y = g0.y; v.z = g1.x; v.w = g1.y;
      *reinterpret_cast<uint4*>(&sA[ar][aci*8]) = v;
    }
    #pragma unroll
    for (int p = 0; p < 2; p++) {
      int idx = p*256 + tid;
      int col = idx >> 2, seg = idx & 3;
      const size_t off = (size_t)col*4096 + k0 + seg*8;
      *reinterpret_cast<uint4*>(&sBh[col][seg*8]) = *reinterpret_cast<const uint4*>(pwh + off);
      *reinterpret_cast<uint4*>(&sBl[col][seg*8]) = *reinterpret_cast<const uint4*>(pwl + off);
    }
    __syncthreads();
    short8v a = *reinterpret_cast<const short8v*>(&sA[w*16 + lr][lk*8]);
    #pragma unroll
    for (int ct = 0; ct < 8; ct++) {
      short8v bh = *reinterpret_cast<const short8v*>(&sBh[ct*16 + lr][lk*8]);
      short8v bv = *reinterpret_cast<const short8v*>(&sBl[ct*16 + lr][lk*8]);
      acc[ct] = __builtin_amdgcn_mfma_f32_16x16x32_bf16(a, bh, acc[ct], 0, 0, 0);
      acc[ct] = __builtin_amdgcn_mfma_f32_16x16x32_bf16(a, bv, acc[ct], 0, 0, 0);
    }
    __syncthreads();
  }
  #pragma unroll
  for (int ct = 0; ct < 8; ct++) {
    const int col = ct*16 + lr;
    const float bias = pb[col];
    #pragma unroll
    for (int v = 0; v < 4; v++) {
      const int r = w*16 + lk*4 + v;
      if (r < rows)
        nodes[((size_t)b*225 + n0 + r)*128 + col] = acc[ct][v] + bias;
    }
  }
}

// ---------------- graph conv + gate + score, fused per (b,node)
__global__ __launch_bounds__(128) void k_graph(
    const float* __restrict__ nodes, const int* __restrict__ nbr1,
    const u64* __restrict__ mask2,
    const float* __restrict__ w1w, const float* __restrict__ w1b,
    const float* __restrict__ w2w, const float* __restrict__ w2b,
    const float* __restrict__ gw, const float* __restrict__ gb,
    const float* __restrict__ sw, const float* __restrict__ sb,
    float* __restrict__ zbuf, float* __restrict__ scores)
{
  __shared__ float sA1[128], sA2[128], sC[256], sRed[128];
  const int n = blockIdx.x, b = blockIdx.y;
  const int d = threadIdx.x;
  const float* nb = nodes + (size_t)b * 225 * 128;
  float a1 = 0.f;
  #pragma unroll
  for (int t = 0; t < 8; t++) a1 += nb[(size_t)nbr1[n*8+t]*128 + d];
  float a2 = 0.f;
  for (int wd = 0; wd < 4; wd++) {
    u64 m = mask2[n*4 + wd];
    while (m) {
      int j = wd*64 + __builtin_ctzll(m);
      a2 += nb[(size_t)j*128 + d];
      m &= m - 1;
    }
  }
  sA1[d] = a1; sA2[d] = a2;
  __syncthreads();
  float z1 = w1b[d];
  { const float* wr = w1w + (size_t)d*128;
    for (int k = 0; k < 128; k += 8) {
      float wv[8]; ld8f(wr + k, wv);
      #pragma unroll
      for (int j = 0; j < 8; j++) z1 += wv[j] * sA1[k+j];
    } }
  float z2 = w2b[d];
  { const float* wr = w2w + (size_t)d*128;
    for (int k = 0; k < 128; k += 8) {
      float wv[8]; ld8f(wr + k, wv);
      #pragma unroll
      for (int j = 0; j < 8; j++) z2 += wv[j] * sA2[k+j];
    } }
  sC[d] = z1; sC[128 + d] = z2;
  __syncthreads();
  float gl = gb[d];
  { const float* wr = gw + (size_t)d*256;
    for (int k = 0; k < 256; k += 8) {
      float wv[8]; ld8f(wr + k, wv);
      #pragma unroll
      for (int j = 0; j < 8; j++) gl += wv[j] * sC[k+j];
    } }
  float gg = 1.f / (1.f + expf(-gl));
  float zv = gg * z1 + (1.f - gg) * z2;
  zbuf[((size_t)b*225 + n)*128 + d] = zv;
  sRed[d] = zv * sw[d];
  __syncthreads();
  for (int st = 64; st > 0; st >>= 1) {
    if (d < st) sRed[d] += sRed[d + st];
    __syncthreads();
  }
  if (d == 0) scores[b*225 + n] = sRed[0] + sb[0];
}

// ---------------- top-k (k=112) with jax tie semantics
__global__ __launch_bounds__(256) void k_topk(
    const float* __restrict__ scores, int* __restrict__ sel)
{
  __shared__ float ss[225];
  const int b = blockIdx.x, tid = threadIdx.x;
  if (tid < 112) sel[b*112 + tid] = tid;
  if (tid < 225) ss[tid] = scores[b*225 + tid];
  __syncthreads();
  if (tid < 225) {
    float s = ss[tid];
    int rank = 0;
    for (int j = 0; j < 225; j++) {
      float sj = ss[j];
      rank += (sj > s) || (sj == s && j < tid);
    }
    if (rank < 112) sel[b*112 + rank] = tid;
  }
}

// ---------------- qkv projection per (b, s)
__global__ __launch_bounds__(128) void k_qkv(
    const float* __restrict__ zbuf, const int* __restrict__ sel,
    const float* __restrict__ iw, const float* __restrict__ ib,
    float* __restrict__ q, float* __restrict__ k, float* __restrict__ v)
{
  __shared__ float sx[128];
  const int s = blockIdx.x, b = blockIdx.y, d = threadIdx.x;
  int row = sel[b*112 + s];
  row = row < 0 ? 0 : (row > 224 ? 224 : row);
  sx[d] = zbuf[((size_t)b*225 + row)*128 + d];
  __syncthreads();
  const int h = d >> 5, t = d & 31;
  float* outs[3] = {q, k, v};
  #pragma unroll
  for (int part = 0; part < 3; part++) {
    float acc = ib[part*128 + d];
    const float* wr = iw + (size_t)(part*128 + d) * 128;
    for (int kk = 0; kk < 128; kk += 8) {
      float wv[8]; ld8f(wr + kk, wv);
      #pragma unroll
      for (int j = 0; j < 8; j++) acc += wv[j] * sx[kk+j];
    }
    outs[part][(((size_t)b*4 + h)*112 + s)*32 + t] = acc;
  }
}

// ---------------- attention per (b, head), two-pass softmax
__global__ __launch_bounds__(128) void k_attn(
    const float* __restrict__ q, const float* __restrict__ k,
    const float* __restrict__ v, float* __restrict__ o)
{
  __shared__ float sK[112*32], sV[112*32];
  const int h = blockIdx.x, b = blockIdx.y, tid = threadIdx.x;
  const size_t base = ((size_t)b*4 + h) * 112 * 32;
  for (int i = tid; i < 112*32; i += 128) {
    sK[i] = k[base + i];
    sV[i] = v[base + i];
  }
  __syncthreads();
  if (tid < 112) {
    float qv[32];
    const float* qp = q + base + (size_t)tid*32;
    #pragma unroll
    for (int t = 0; t < 32; t++) qv[t] = qp[t];
    const float scale = 0.17677669529663687f;
    float mx = -INFINITY;
    for (int j = 0; j < 112; j++) {
      float s = 0.f;
      #pragma unroll
      for (int t = 0; t < 32; t++) s += qv[t] * sK[j*32 + t];
      mx = fmaxf(mx, s * scale);
    }
    float acc[32];
    #pragma unroll
    for (int t = 0; t < 32; t++) acc[t] = 0.f;
    float l = 0.f;
    for (int j = 0; j < 112; j++) {
      float s = 0.f;
      #pragma unroll
      for (int t = 0; t < 32; t++) s += qv[t] * sK[j*32 + t];
      float p = expf(s * scale - mx);
      l += p;
      #pragma unroll
      for (int t = 0; t < 32; t++) acc[t] += p * sV[j*32 + t];
    }
    float inv = 1.f / l;
    float* op = o + ((size_t)b*112 + tid)*128 + h*32;
    #pragma unroll
    for (int t = 0; t < 32; t++) op[t] = acc[t] * inv;
  }
}

// ---------------- out-proj + residual + LN1 per (b, s)
__global__ __launch_bounds__(128) void k_oln(
    const float* __restrict__ o, const float* __restrict__ zbuf,
    const int* __restrict__ sel,
    const float* __restrict__ ow, const float* __restrict__ ob,
    const float* __restrict__ lg, const float* __restrict__ lb,
    float* __restrict__ h1)
{
  __shared__ float so[128], sRed[128], sRed2[128];
  const int s = blockIdx.x, b = blockIdx.y, d = threadIdx.x;
  so[d] = o[((size_t)b*112 + s)*128 + d];
  __syncthreads();
  float acc = ob[d];
  const float* wr = ow + (size_t)d * 128;
  for (int kk = 0; kk < 128; kk += 8) {
    float wv[8]; ld8f(wr + kk, wv);
    #pragma unroll
    for (int j = 0; j < 8; j++) acc += wv[j] * so[kk+j];
  }
  int row = sel[b*112 + s];
  row = row < 0 ? 0 : (row > 224 ? 224 : row);
  acc += zbuf[((size_t)b*225 + row)*128 + d];
  sRed[d] = acc; sRed2[d] = acc * acc;
  __syncthreads();
  for (int st = 64; st > 0; st >>= 1) {
    if (d < st) { sRed[d] += sRed[d+st]; sRed2[d] += sRed2[d+st]; }
    __syncthreads();
  }
  float mean = sRed[0] * (1.f/128.f);
  float var  = sRed2[0] * (1.f/128.f) - mean*mean;
  float r = rsqrtf(var + 1e-5f);
  h1[((size_t)b*112 + s)*128 + d] = (acc - mean) * r * lg[d] + lb[d];
}

// ---------------- FFN + residual + LN2 per (b, s) -> h2 (may alias h1: row-local)
__global__ __launch_bounds__(256) void k_ffn(
    const float* __restrict__ h1,
    const float* __restrict__ f1w, const float* __restrict__ f1b,
    const float* __restrict__ f2w, const float* __restrict__ f2b,
    const float* __restrict__ lg, const float* __restrict__ lb,
    float* __restrict__ h2)
{
  __shared__ float sh[128];
  __shared__ float sf[512];
  __shared__ float sRed[128], sRed2[128];
  const int s = blockIdx.x, b = blockIdx.y, tid = threadIdx.x;
  if (tid < 128) sh[tid] = h1[((size_t)b*112 + s)*128 + tid];
  __syncthreads();
  #pragma unroll
  for (int rdx = 0; rdx < 2; rdx++) {
    int oo = tid + rdx*256;
    float acc = f1b[oo];
    const float* wr = f1w + (size_t)oo * 128;
    for (int kk = 0; kk < 128; kk += 8) {
      float wv[8]; ld8f(wr + kk, wv);
      #pragma unroll
      for (int j = 0; j < 8; j++) acc += wv[j] * sh[kk+j];
    }
    sf[oo] = fmaxf(acc, 0.f);
  }
  __syncthreads();
  float val = 0.f;
  if (tid < 128) {
    float acc = f2b[tid];
    const float* wr = f2w + (size_t)tid * 512;
    for (int kk = 0; kk < 512; kk += 8) {
      float wv[8]; ld8f(wr + kk, wv);
      #pragma unroll
      for (int j = 0; j < 8; j++) acc += wv[j] * sf[kk+j];
    }
    val = sh[tid] + acc;
    sRed[tid] = val; sRed2[tid] = val*val;
  }
  __syncthreads();
  for (int st = 64; st > 0; st >>= 1) {
    if (tid < st) { sRed[tid] += sRed[tid+st]; sRed2[tid] += sRed2[tid+st]; }
    __syncthreads();
  }
  if (tid < 128) {
    float mean = sRed[0] * (1.f/128.f);
    float var  = sRed2[0] * (1.f/128.f) - mean*mean;
    float r = rsqrtf(var + 1e-5f);
    h2[((size_t)b*112 + s)*128 + tid] = (val - mean) * r * lg[tid] + lb[tid];
  }
}

// ---------------- rep = sum_s h2 ; classifier -> logits (f32)
__global__ __launch_bounds__(64) void k_cls(
    const float* __restrict__ h2,
    const float* __restrict__ c1w, const float* __restrict__ c1b,
    const float* __restrict__ c2w, const float* __restrict__ c2b,
    float* __restrict__ out)
{
  __shared__ float sr[128], sc[64];
  const int b = blockIdx.x, tid = threadIdx.x;
  float r0 = 0.f, r1 = 0.f;
  for (int s2 = 0; s2 < 112; s2++) {
    const float* row = h2 + ((size_t)b*112 + s2)*128;
    r0 += row[tid];
    r1 += row[tid + 64];
  }
  sr[tid] = r0; sr[tid + 64] = r1;
  __syncthreads();
  float acc = c1b[tid];
  const float* wr = c1w + (size_t)tid * 128;
  for (int kk = 0; kk < 128; kk += 8) {
    float wv[8]; ld8f(wr + kk, wv);
    #pragma unroll
    for (int j = 0; j < 8; j++) acc += wv[j] * sr[kk+j];
  }
  sc[tid] = fmaxf(acc, 0.f);
  __syncthreads();
  if (tid < 2) {
    float l = c2b[tid];
    for (int kk = 0; kk < 64; kk++) l += c2w[tid*64 + kk] * sc[kk];
    out[b*2 + tid] = l;
  }
}

extern "C" void kernel_launch(void* const* d_in, const int* in_sizes, int n_in,
                              void* d_out, int out_size, void* d_ws, size_t ws_size,
                              hipStream_t stream)
{
  const float* x    = (const float*)d_in[0];
  const float* c1w  = (const float*)d_in[1];
  const float* c1b  = (const float*)d_in[2];
  const float* bn1g = (const float*)d_in[3];
  const float* bn1b = (const float*)d_in[4];
  const float* c2w  = (const float*)d_in[5];
  const float* c2b  = (const float*)d_in[6];
  const float* bn2g = (const float*)d_in[7];
  const float* bn2b = (const float*)d_in[8];
  const float* pjw  = (const float*)d_in[9];
  const float* pjb  = (const float*)d_in[10];
  const float* w1w  = (const float*)d_in[11];
  const float* w1b  = (const float*)d_in[12];
  const float* w2w  = (const float*)d_in[13];
  const float* w2b  = (const float*)d_in[14];
  const float* gw   = (const float*)d_in[15];
  const float* gb   = (const float*)d_in[16];
  const float* scw  = (const float*)d_in[17];
  const float* scb  = (const float*)d_in[18];
  const float* ipw  = (const float*)d_in[19];
  const float* ipb  = (const float*)d_in[20];
  const float* opw  = (const float*)d_in[21];
  const float* opb  = (const float*)d_in[22];
  const float* f1w  = (const float*)d_in[23];
  const float* f1b  = (const float*)d_in[24];
  const float* f2w  = (const float*)d_in[25];
  const float* f2b  = (const float*)d_in[26];
  const float* l1g  = (const float*)d_in[27];
  const float* l1b  = (const float*)d_in[28];
  const float* l2g  = (const float*)d_in[29];
  const float* l2b  = (const float*)d_in[30];
  const float* cl1w = (const float*)d_in[31];
  const float* cl1b = (const float*)d_in[32];
  const float* cl2w = (const float*)d_in[33];
  const float* cl2b = (const float*)d_in[34];

  // ---- bump allocator over d_ws (256-B aligned) ----
  char* p = (char*)d_ws;
  auto alloc = [&](size_t n) { char* r = p; p += (n + 255) & ~(size_t)255; return r; };
  u64*   mask2  = (u64*)  alloc(900    * sizeof(u64));
  int*   nbr1   = (int*)  alloc(1800   * sizeof(int));
  int*   sel    = (int*)  alloc(1792   * sizeof(int));
  float* scores = (float*)alloc(3600   * sizeof(float));
  u16*   pwh    = (u16*)  alloc(524288 * sizeof(u16));
  u16*   pwl    = (u16*)  alloc(524288 * sizeof(u16));
  u16*   wc2h   = (u16*)  alloc(36864  * sizeof(u16));   // conv2 weights hi
  u16*   wc2l   = (u16*)  alloc(36864  * sizeof(u16));   // conv2 weights lo
  float* zbuf   = (float*)alloc(460800 * sizeof(float));
  float* nodes  = (float*)alloc(460800 * sizeof(float));
  const size_t fixed_bytes = (size_t)(p - (char*)d_ws);

  const size_t qkv_bytes = 3ull * 229376ull * sizeof(float);
  const size_t per_batch = 64ull*128*128*2 + 64ull*64*64*2;   // 2,621,440 B
  int BC = 16;
  size_t s3 = 0;
  for (;; BC >>= 1) {
    s3 = (size_t)BC * per_batch; if (s3 < qkv_bytes) s3 = qkv_bytes;
    if (fixed_bytes + s3 + 65536 <= ws_size) break;
    if (BC == 1) { return; }
  }
  char* S3 = alloc(s3);

  u16*   feat1 = (u16*)S3;                              // NHWC (BC,128,128,64)
  u16*   feat2 = (u16*)(S3 + (size_t)BC * 2097152ull);  // NCHW (BC,64,64,64)
  float* qb    = (float*)S3;
  float* kb    = qb + 229376;
  float* vb    = kb + 229376;
  float* obuf  = nodes;
  float* hbuf  = nodes + 229376;

  k_adj  <<<1, 256, 0, stream>>>(nbr1, mask2);
  k_cvtw <<<512, 256, 0, stream>>>(pjw, pwh, pwl);
  k_cvtw2<<<144, 256, 0, stream>>>(c2w, bn2g, wc2h, wc2l);

  for (int b0 = 0; b0 < 16; b0 += BC) {
    k_conv1 <<<dim3(8,8,BC), 256, 0, stream>>>(x, c1w, c1b, bn1g, bn1b, feat1, b0);
    k_conv2m<<<dim3(4,8,BC), 256, 0, stream>>>(feat1, wc2h, wc2l, c2b, bn2g, bn2b, feat2);
    k_projm <<<dim3(4,BC), 256, 0, stream>>>(feat2, pwh, pwl, pjb, nodes, b0);
  }

  k_graph<<<dim3(225,16), 128, 0, stream>>>(nodes, nbr1, mask2, w1w, w1b, w2w, w2b,
                                            gw, gb, scw, scb, zbuf, scores);
  k_topk <<<16, 256, 0, stream>>>(scores, sel);
  k_qkv  <<<dim3(112,16), 128, 0, stream>>>(zbuf, sel, ipw, ipb, qb, kb, vb);
  k_attn <<<dim3(4,16), 128, 0, stream>>>(qb, kb, vb, obuf);
  k_oln  <<<dim3(112,16), 128, 0, stream>>>(obuf, zbuf, sel, opw, opb, l1g, l1b, hbuf);
  k_ffn  <<<dim3(112,16), 256, 0, stream>>>(hbuf, f1w, f1b, f2w, f2b, l2g, l2b, hbuf);
  k_cls  <<<16, 64, 0, stream>>>(hbuf, cl1w, cl1b, cl2w, cl2b, (float*)d_out);
}

// Round 7
// 635.678 us; speedup vs baseline: 2.7024x; 1.1853x over previous
//
#include <hip/hip_runtime.h>
#include <hip/hip_bf16.h>
#include <math.h>

typedef unsigned short u16;
typedef unsigned int   u32;
typedef unsigned long long u64;
typedef __attribute__((ext_vector_type(8))) short short8v;
typedef __attribute__((ext_vector_type(4))) float f32x4;

__device__ __forceinline__ float bf2f(u16 u) {
  union { u32 i; float f; } v; v.i = ((u32)u) << 16; return v.f;
}
__device__ __forceinline__ u16 f2bf(float f) {  // round-to-nearest-even
  union { float f; u32 i; } v; v.f = f;
  u32 r = (v.i + 0x7FFFu + ((v.i >> 16) & 1u)) >> 16;
  return (u16)r;
}

// ---------------- conv1 + bn1 + relu + maxpool2 : (16,3,256,256)f32 -> (BC,128,128,64) NHWC bf16
__global__ __launch_bounds__(256) void k_conv1(
    const float* __restrict__ x, const float* __restrict__ w,
    const float* __restrict__ cb, const float* __restrict__ g, const float* __restrict__ bb,
    u16* __restrict__ feat1, int b0)
{
  __shared__ float sIn[3][34][34];
  __shared__ float sW[64][27];
  __shared__ float sB[64];
  const int bl = blockIdx.z, ty = blockIdx.y, tx = blockIdx.x;
  const int b = b0 + bl;
  const int tid = threadIdx.x;
  for (int i = tid; i < 64*27; i += 256) {
    int oc = i / 27;
    float sc = g[oc] * rsqrtf(1.0f + 1e-5f);
    sW[oc][i % 27] = w[i] * sc;
  }
  if (tid < 64) {
    float sc = g[tid] * rsqrtf(1.0f + 1e-5f);
    sB[tid] = cb[tid] * sc + bb[tid];
  }
  const int iy0 = ty*32 - 1, ix0 = tx*32 - 1;
  for (int i = tid; i < 3*34*34; i += 256) {
    int c = i / (34*34); int r = (i / 34) % 34; int q = i % 34;
    int yy = iy0 + r, xx = ix0 + q;
    float v = 0.f;
    if (yy >= 0 && xx >= 0 && yy < 256 && xx < 256)
      v = x[(((size_t)b*3 + c)*256 + yy)*256 + xx];
    sIn[c][r][q] = v;
  }
  __syncthreads();
  const int py = tid >> 4, px = tid & 15;
  float win[3][4][4];
  #pragma unroll
  for (int c = 0; c < 3; c++)
    #pragma unroll
    for (int r = 0; r < 4; r++)
      #pragma unroll
      for (int q = 0; q < 4; q++)
        win[c][r][q] = sIn[c][2*py + r][2*px + q];
  const int oy = ty*16 + py, ox = tx*16 + px;
  u16* outp = feat1 + (((size_t)bl*128 + oy)*128 + ox)*64;   // NHWC
  u16 pend = 0;
  for (int oc = 0; oc < 64; oc++) {
    float s00=0.f, s01=0.f, s10=0.f, s11=0.f;
    #pragma unroll
    for (int c = 0; c < 3; c++)
      #pragma unroll
      for (int ky = 0; ky < 3; ky++)
        #pragma unroll
        for (int kx = 0; kx < 3; kx++) {
          float wv = sW[oc][(c*3+ky)*3+kx];
          s00 += win[c][ky  ][kx  ] * wv;
          s01 += win[c][ky  ][kx+1] * wv;
          s10 += win[c][ky+1][kx  ] * wv;
          s11 += win[c][ky+1][kx+1] * wv;
        }
    float m = fmaxf(fmaxf(s00,s01), fmaxf(s10,s11)) + sB[oc];
    u16 cur = f2bf(fmaxf(m, 0.f));
    if (oc & 1) {
      u32 pk = (u32)pend | ((u32)cur << 16);
      *reinterpret_cast<u32*>(outp + oc - 1) = pk;
    } else pend = cur;
  }
}

// ---------------- conv2 weights f32 OIHW -> bf16 hi/lo [ky*3+kx][chunk][oc][icL], bn-scaled
__global__ __launch_bounds__(256) void k_cvtw2(
    const float* __restrict__ w, const float* __restrict__ g,
    u16* __restrict__ wh, u16* __restrict__ wl)
{
  const int d = blockIdx.x * 256 + threadIdx.x;      // 36864 total
  if (d >= 36864) return;
  const int icL = d & 31, oc = (d >> 5) & 63, chunk = (d >> 11) & 1, kk = d >> 12;
  const float sc = g[oc] * rsqrtf(1.0f + 1e-5f);
  const float val = w[((size_t)oc*64 + chunk*32 + icL)*9 + kk] * sc;
  const u16 hb = f2bf(val);
  wh[d] = hb;
  wl[d] = f2bf(val - bf2f(hb));
}

// ---------------- conv2 + bn2 + relu + maxpool2 via MFMA implicit GEMM
__global__ __launch_bounds__(256, 2) void k_conv2m(
    const u16* __restrict__ feat1,
    const u16* __restrict__ wh, const u16* __restrict__ wl,
    const float* __restrict__ cb, const float* __restrict__ g, const float* __restrict__ bb,
    u16* __restrict__ feat2)
{
  __shared__ __align__(16) u16 sA[18*34*40];
  __shared__ __align__(16) u16 sBh[64*40], sBl[64*40];
  __shared__ float sBias[64];
  const int tx = blockIdx.x, ty = blockIdx.y, bl = blockIdx.z;
  const int y0 = ty*16, x0 = tx*32;
  const int tid = threadIdx.x;
  const int w = tid >> 6, l = tid & 63;
  const int lr = l & 15, lk = l >> 4;

  if (tid < 64) {
    float sc = g[tid] * rsqrtf(1.0f + 1e-5f);
    sBias[tid] = cb[tid] * sc + bb[tid];
  }

  f32x4 acc[8][4];
  #pragma unroll
  for (int j = 0; j < 8; j++)
    #pragma unroll
    for (int ct = 0; ct < 4; ct++)
      acc[j][ct] = (f32x4){0.f,0.f,0.f,0.f};

  for (int chunk = 0; chunk < 2; chunk++) {
    __syncthreads();
    for (int idx = tid; idx < 612*4; idx += 256) {
      const int pix = idx >> 2, seg = idx & 3;
      const int r = pix / 34, cc = pix % 34;
      const int yy = y0 - 1 + r, xx = x0 - 1 + cc;
      uint4 v = {0u,0u,0u,0u};
      if (yy >= 0 && yy < 128 && xx >= 0 && xx < 128)
        v = *reinterpret_cast<const uint4*>(
              feat1 + (((size_t)bl*128 + yy)*128 + xx)*64 + chunk*32 + seg*8);
      *reinterpret_cast<uint4*>(&sA[(size_t)(r*34 + cc)*40 + seg*8]) = v;
    }
    for (int kk = 0; kk < 9; kk++) {
      __syncthreads();
      {
        const int oc = tid >> 2, s8 = (tid & 3)*8;
        const size_t src = (size_t)(kk*2 + chunk)*2048 + tid*8;
        *reinterpret_cast<uint4*>(&sBh[oc*40 + s8]) = *reinterpret_cast<const uint4*>(wh + src);
        *reinterpret_cast<uint4*>(&sBl[oc*40 + s8]) = *reinterpret_cast<const uint4*>(wl + src);
      }
      __syncthreads();
      const int ky = kk / 3, kx = kk % 3;
      short8v a[8];
      #pragma unroll
      for (int j = 0; j < 8; j++) {
        const int m = w*8 + j;
        const int r = (m >> 1) + ky;
        const int cc = (m & 1)*16 + lr + kx;
        a[j] = *reinterpret_cast<const short8v*>(&sA[(size_t)(r*34 + cc)*40 + lk*8]);
      }
      #pragma unroll
      for (int ct = 0; ct < 4; ct++) {
        const short8v bh = *reinterpret_cast<const short8v*>(&sBh[(ct*16 + lr)*40 + lk*8]);
        const short8v bv = *reinterpret_cast<const short8v*>(&sBl[(ct*16 + lr)*40 + lk*8]);
        #pragma unroll
        for (int j = 0; j < 8; j++) {
          acc[j][ct] = __builtin_amdgcn_mfma_f32_16x16x32_bf16(a[j], bh, acc[j][ct], 0, 0, 0);
          acc[j][ct] = __builtin_amdgcn_mfma_f32_16x16x32_bf16(a[j], bv, acc[j][ct], 0, 0, 0);
        }
      }
    }
  }
  #pragma unroll
  for (int u = 0; u < 2; u++) {
    #pragma unroll
    for (int xh = 0; xh < 2; xh++) {
      const int jA = 4*u + xh, jB = 4*u + 2 + xh;
      #pragma unroll
      for (int ct = 0; ct < 4; ct++) {
        const int oc = ct*16 + lr;
        const float bias = sBias[oc];
        const float v0 = fmaxf(fmaxf(acc[jA][ct][0], acc[jA][ct][1]),
                               fmaxf(acc[jB][ct][0], acc[jB][ct][1]));
        const float v1 = fmaxf(fmaxf(acc[jA][ct][2], acc[jA][ct][3]),
                               fmaxf(acc[jB][ct][2], acc[jB][ct][3]));
        const u16 b0v = f2bf(fmaxf(v0 + bias, 0.f));
        const u16 b1v = f2bf(fmaxf(v1 + bias, 0.f));
        const int py = ty*8 + 2*w + u;
        const int px = tx*16 + xh*8 + lk*2;
        u32 pk = (u32)b0v | ((u32)b1v << 16);
        *reinterpret_cast<u32*>(&feat2[(((size_t)bl*64 + oc)*64 + py)*64 + px]) = pk;
      }
    }
  }
}

// ---------------- adjacency (input-independent, 1 block)
__global__ __launch_bounds__(256) void k_adj(int* __restrict__ nbr1, u64* __restrict__ mask2)
{
  __shared__ int snbr[225][8];
  const int i = threadIdx.x;
  if (i < 225) {
    const int ii = i / 15, jj = i % 15;
    int bd[8], bj[8];
    #pragma unroll
    for (int t = 0; t < 8; t++) { bd[t] = 1<<30; bj[t] = -1; }
    for (int j = 0; j < 225; j++) {
      if (j == i) continue;
      int di = ii - j/15, dj = jj - j%15;
      int d2 = di*di + dj*dj;
      if (d2 < bd[7]) {
        int p = 7;
        while (p > 0 && d2 < bd[p-1]) { bd[p]=bd[p-1]; bj[p]=bj[p-1]; p--; }
        bd[p] = d2; bj[p] = j;
      }
    }
    #pragma unroll
    for (int t = 0; t < 8; t++) { snbr[i][t] = bj[t]; nbr1[i*8+t] = bj[t]; }
  }
  __syncthreads();
  if (i < 225) {
    u64 m[4] = {0,0,0,0};
    #pragma unroll
    for (int t = 0; t < 8; t++) {
      int tt = snbr[i][t];
      #pragma unroll
      for (int u = 0; u < 8; u++) {
        int j = snbr[tt][u];
        m[j >> 6] |= 1ull << (j & 63);
      }
    }
    m[i >> 6] &= ~(1ull << (i & 63));
    #pragma unroll
    for (int wd = 0; wd < 4; wd++) mask2[i*4 + wd] = m[wd];
  }
}

// ---------------- split proj_w (f32) -> hi/lo bf16
__global__ __launch_bounds__(256) void k_cvtw(
    const float* __restrict__ pw, u16* __restrict__ pwh, u16* __restrict__ pwl)
{
  const int i = (blockIdx.x * 256 + threadIdx.x) * 4;
  float4 v = *reinterpret_cast<const float4*>(pw + i);
  float e[4] = {v.x, v.y, v.z, v.w};
  ushort4 h, l;
  u16* hp = &h.x; u16* lp = &l.x;
  #pragma unroll
  for (int j = 0; j < 4; j++) {
    u16 hb = f2bf(e[j]);
    hp[j] = hb;
    lp[j] = f2bf(e[j] - bf2f(hb));
  }
  *reinterpret_cast<ushort4*>(pwh + i) = h;
  *reinterpret_cast<ushort4*>(pwl + i) = l;
}

// ---------------- generic weight transpose [O][K] -> [K][O]
__global__ __launch_bounds__(256) void k_wt(
    const float* __restrict__ src, float* __restrict__ dst, int O, int K)
{
  const int idx = blockIdx.x * 256 + threadIdx.x;
  if (idx >= O * K) return;
  const int o = idx / K, k = idx % K;
  dst[(size_t)k * O + o] = src[idx];
}

// ---------------- patch-projection as MFMA GEMM
__global__ __launch_bounds__(256) void k_projm(
    const u16* __restrict__ feat2,
    const u16* __restrict__ pwh, const u16* __restrict__ pwl,
    const float* __restrict__ pb,
    float* __restrict__ nodes, int b0)
{
  __shared__ __align__(16) u16 sA [64][40];
  __shared__ __align__(16) u16 sBh[128][40];
  __shared__ __align__(16) u16 sBl[128][40];
  const int cx = blockIdx.x, bl = blockIdx.y;
  const int b  = b0 + bl;
  const int n0 = cx * 64;
  const int rows = (225 - n0) < 64 ? (225 - n0) : 64;
  const int tid = threadIdx.x;
  const int w = tid >> 6, l = tid & 63;
  const int lr = l & 15, lk = l >> 4;

  f32x4 acc[8];
  #pragma unroll
  for (int i = 0; i < 8; i++) acc[i] = (f32x4){0.f, 0.f, 0.f, 0.f};

  const int ar = tid >> 2, aci = tid & 3;
  const int an = n0 + ar;
  const int aph = an / 15, apw = an % 15;

  for (int k0 = 0; k0 < 4096; k0 += 32) {
    const int c  = k0 >> 6;
    const int i0 = (k0 & 63) >> 3;
    {
      uint2 g0 = {0u,0u}, g1 = {0u,0u};
      if (ar < rows) {
        const u16* src = feat2 + (((size_t)bl*64 + c)*64 + aph*4 + i0 + aci)*64 + apw*4;
        g0 = *reinterpret_cast<const uint2*>(src);
        g1 = *reinterpret_cast<const uint2*>(src + 4);
      }
      uint4 v; v.x = g0.x; v.y = g0.y; v.z = g1.x; v.w = g1.y;
      *reinterpret_cast<uint4*>(&sA[ar][aci*8]) = v;
    }
    #pragma unroll
    for (int p = 0; p < 2; p++) {
      int idx = p*256 + tid;
      int col = idx >> 2, seg = idx & 3;
      const size_t off = (size_t)col*4096 + k0 + seg*8;
      *reinterpret_cast<uint4*>(&sBh[col][seg*8]) = *reinterpret_cast<const uint4*>(pwh + off);
      *reinterpret_cast<uint4*>(&sBl[col][seg*8]) = *reinterpret_cast<const uint4*>(pwl + off);
    }
    __syncthreads();
    short8v a = *reinterpret_cast<const short8v*>(&sA[w*16 + lr][lk*8]);
    #pragma unroll
    for (int ct = 0; ct < 8; ct++) {
      short8v bh = *reinterpret_cast<const short8v*>(&sBh[ct*16 + lr][lk*8]);
      short8v bv = *reinterpret_cast<const short8v*>(&sBl[ct*16 + lr][lk*8]);
      acc[ct] = __builtin_amdgcn_mfma_f32_16x16x32_bf16(a, bh, acc[ct], 0, 0, 0);
      acc[ct] = __builtin_amdgcn_mfma_f32_16x16x32_bf16(a, bv, acc[ct], 0, 0, 0);
    }
    __syncthreads();
  }
  #pragma unroll
  for (int ct = 0; ct < 8; ct++) {
    const int col = ct*16 + lr;
    const float bias = pb[col];
    #pragma unroll
    for (int v = 0; v < 4; v++) {
      const int r = w*16 + lk*4 + v;
      if (r < rows)
        nodes[((size_t)b*225 + n0 + r)*128 + col] = acc[ct][v] + bias;
    }
  }
}

// ---------------- neighbor aggregation: a1/a2 per (b,node)
__global__ __launch_bounds__(128) void k_agg(
    const float* __restrict__ nodes, const int* __restrict__ nbr1,
    const u64* __restrict__ mask2,
    float* __restrict__ a1buf, float* __restrict__ a2buf)
{
  const int n = blockIdx.x, b = blockIdx.y;
  const int d = threadIdx.x;
  const float* nb = nodes + (size_t)b * 225 * 128;
  float a1 = 0.f;
  #pragma unroll
  for (int t = 0; t < 8; t++) a1 += nb[(size_t)nbr1[n*8+t]*128 + d];
  float a2 = 0.f;
  for (int wd = 0; wd < 4; wd++) {
    u64 m = mask2[n*4 + wd];
    while (m) {
      int j = wd*64 + __builtin_ctzll(m);
      a2 += nb[(size_t)j*128 + d];
      m &= m - 1;
    }
  }
  a1buf[((size_t)b*225 + n)*128 + d] = a1;
  a2buf[((size_t)b*225 + n)*128 + d] = a2;
}

// ---------------- z1/z2/gate/score batched: 15 nodes per block
__global__ __launch_bounds__(256) void k_gz(
    const float* __restrict__ a1buf, const float* __restrict__ a2buf,
    const float* __restrict__ w1t, const float* __restrict__ w1b,
    const float* __restrict__ w2t, const float* __restrict__ w2b,
    const float* __restrict__ gwt, const float* __restrict__ gb,
    const float* __restrict__ sw, const float* __restrict__ sb,
    float* __restrict__ zbuf, float* __restrict__ scores)
{
  __shared__ float sA1[15][128], sA2[15][128], sC[15][256], sRed[15][128];
  const int n0 = blockIdx.x * 15, b = blockIdx.y;
  const int tid = threadIdx.x;
  const int d = tid & 127, half = tid >> 7;
  const int r0 = half * 8, nr = half ? 7 : 8;       // rows 0..7 / 8..14

  for (int idx = tid; idx < 15*128; idx += 256) {
    const int r = idx >> 7, dd = idx & 127;
    sA1[r][dd] = a1buf[((size_t)b*225 + n0 + r)*128 + dd];
    sA2[r][dd] = a2buf[((size_t)b*225 + n0 + r)*128 + dd];
  }
  __syncthreads();

  float z1[8], z2[8];
  #pragma unroll
  for (int rr = 0; rr < 8; rr++) { z1[rr] = w1b[d]; z2[rr] = w2b[d]; }
  for (int k = 0; k < 128; k++) {
    const float wv1 = w1t[k*128 + d];
    const float wv2 = w2t[k*128 + d];
    #pragma unroll
    for (int rr = 0; rr < 8; rr++) {
      if (rr < nr) {
        z1[rr] += wv1 * sA1[r0 + rr][k];
        z2[rr] += wv2 * sA2[r0 + rr][k];
      }
    }
  }
  #pragma unroll
  for (int rr = 0; rr < 8; rr++) {
    if (rr < nr) { sC[r0+rr][d] = z1[rr]; sC[r0+rr][128+d] = z2[rr]; }
  }
  __syncthreads();
  float gl[8];
  #pragma unroll
  for (int rr = 0; rr < 8; rr++) gl[rr] = gb[d];
  for (int k = 0; k < 256; k++) {
    const float wv = gwt[k*128 + d];
    #pragma unroll
    for (int rr = 0; rr < 8; rr++)
      if (rr < nr) gl[rr] += wv * sC[r0 + rr][k];
  }
  const float swd = sw[d];
  #pragma unroll
  for (int rr = 0; rr < 8; rr++) {
    if (rr < nr) {
      const float gg = 1.f / (1.f + expf(-gl[rr]));
      const float zv = gg * z1[rr] + (1.f - gg) * z2[rr];
      zbuf[((size_t)b*225 + n0 + r0 + rr)*128 + d] = zv;
      sRed[r0+rr][d] = zv * swd;
    }
  }
  __syncthreads();
  // score reduce: 16 threads per row
  const int r = tid >> 4, j = tid & 15;
  if (r < 15) {
    float part = 0.f;
    #pragma unroll
    for (int i = 0; i < 8; i++) part += sRed[r][j*8 + i];
    #pragma unroll
    for (int m = 8; m >= 1; m >>= 1) part += __shfl_xor(part, m, 64);
    if (j == 0) scores[b*225 + n0 + r] = part + sb[0];
  }
}

// ---------------- top-k (k=112) with jax tie semantics
__global__ __launch_bounds__(256) void k_topk(
    const float* __restrict__ scores, int* __restrict__ sel)
{
  __shared__ float ss[225];
  const int b = blockIdx.x, tid = threadIdx.x;
  if (tid < 112) sel[b*112 + tid] = tid;
  if (tid < 225) ss[tid] = scores[b*225 + tid];
  __syncthreads();
  if (tid < 225) {
    float s = ss[tid];
    int rank = 0;
    for (int j = 0; j < 225; j++) {
      float sj = ss[j];
      rank += (sj > s) || (sj == s && j < tid);
    }
    if (rank < 112) sel[b*112 + rank] = tid;
  }
}

// ---------------- qkv batched: 14 rows per block
__global__ __launch_bounds__(256) void k_qkv(
    const float* __restrict__ zbuf, const int* __restrict__ sel,
    const float* __restrict__ iwt, const float* __restrict__ ib,
    float* __restrict__ q, float* __restrict__ k, float* __restrict__ v)
{
  __shared__ float sx[14][128];
  const int s0 = blockIdx.x * 14, b = blockIdx.y;
  const int tid = threadIdx.x;
  const int c = tid & 127, half = tid >> 7;
  const int r0 = half * 7;

  for (int idx = tid; idx < 14*128; idx += 256) {
    const int r = idx >> 7, dd = idx & 127;
    int row = sel[b*112 + s0 + r];
    row = row < 0 ? 0 : (row > 224 ? 224 : row);
    sx[r][dd] = zbuf[((size_t)b*225 + row)*128 + dd];
  }
  __syncthreads();

  float acc[3][7];
  #pragma unroll
  for (int p = 0; p < 3; p++)
    #pragma unroll
    for (int rr = 0; rr < 7; rr++) acc[p][rr] = ib[p*128 + c];
  for (int kk = 0; kk < 128; kk++) {
    float wv[3];
    #pragma unroll
    for (int p = 0; p < 3; p++) wv[p] = iwt[kk*384 + p*128 + c];
    #pragma unroll
    for (int rr = 0; rr < 7; rr++) {
      const float xv = sx[r0 + rr][kk];
      #pragma unroll
      for (int p = 0; p < 3; p++) acc[p][rr] += wv[p] * xv;
    }
  }
  const int h = c >> 5, t = c & 31;
  float* outs[3] = {q, k, v};
  #pragma unroll
  for (int p = 0; p < 3; p++)
    #pragma unroll
    for (int rr = 0; rr < 7; rr++)
      outs[p][(((size_t)b*4 + h)*112 + s0 + r0 + rr)*32 + t] = acc[p][rr];
}

// ---------------- attention per (b, head), two-pass softmax
__global__ __launch_bounds__(128) void k_attn(
    const float* __restrict__ q, const float* __restrict__ k,
    const float* __restrict__ v, float* __restrict__ o)
{
  __shared__ float sK[112*32], sV[112*32];
  const int h = blockIdx.x, b = blockIdx.y, tid = threadIdx.x;
  const size_t base = ((size_t)b*4 + h) * 112 * 32;
  for (int i = tid; i < 112*32; i += 128) {
    sK[i] = k[base + i];
    sV[i] = v[base + i];
  }
  __syncthreads();
  if (tid < 112) {
    float qv[32];
    const float* qp = q + base + (size_t)tid*32;
    #pragma unroll
    for (int t = 0; t < 32; t++) qv[t] = qp[t];
    const float scale = 0.17677669529663687f;
    float mx = -INFINITY;
    for (int j = 0; j < 112; j++) {
      float s = 0.f;
      #pragma unroll
      for (int t = 0; t < 32; t++) s += qv[t] * sK[j*32 + t];
      mx = fmaxf(mx, s * scale);
    }
    float acc[32];
    #pragma unroll
    for (int t = 0; t < 32; t++) acc[t] = 0.f;
    float l = 0.f;
    for (int j = 0; j < 112; j++) {
      float s = 0.f;
      #pragma unroll
      for (int t = 0; t < 32; t++) s += qv[t] * sK[j*32 + t];
      float p = expf(s * scale - mx);
      l += p;
      #pragma unroll
      for (int t = 0; t < 32; t++) acc[t] += p * sV[j*32 + t];
    }
    float inv = 1.f / l;
    float* op = o + ((size_t)b*112 + tid)*128 + h*32;
    #pragma unroll
    for (int t = 0; t < 32; t++) op[t] = acc[t] * inv;
  }
}

// ---------------- out-proj + residual + LN1, batched 14 rows/block
__global__ __launch_bounds__(256) void k_oln(
    const float* __restrict__ o, const float* __restrict__ zbuf,
    const int* __restrict__ sel,
    const float* __restrict__ owt, const float* __restrict__ ob,
    const float* __restrict__ lg, const float* __restrict__ lb,
    float* __restrict__ h1)
{
  __shared__ float sO[14][128], sV[14][128];
  __shared__ float sMean[14], sRstd[14];
  const int s0 = blockIdx.x * 14, b = blockIdx.y;
  const int tid = threadIdx.x;
  const int d = tid & 127, half = tid >> 7;
  const int r0 = half * 7;

  for (int idx = tid; idx < 14*128; idx += 256) {
    const int r = idx >> 7, dd = idx & 127;
    sO[r][dd] = o[((size_t)b*112 + s0 + r)*128 + dd];
  }
  __syncthreads();

  float acc[7];
  #pragma unroll
  for (int rr = 0; rr < 7; rr++) acc[rr] = ob[d];
  for (int kk = 0; kk < 128; kk++) {
    const float wv = owt[kk*128 + d];
    #pragma unroll
    for (int rr = 0; rr < 7; rr++) acc[rr] += wv * sO[r0 + rr][kk];
  }
  #pragma unroll
  for (int rr = 0; rr < 7; rr++) {
    int row = sel[b*112 + s0 + r0 + rr];
    row = row < 0 ? 0 : (row > 224 ? 224 : row);
    acc[rr] += zbuf[((size_t)b*225 + row)*128 + d];
    sV[r0 + rr][d] = acc[rr];
  }
  __syncthreads();
  // LN reductions: 16 threads per row
  {
    const int r = tid >> 4, j = tid & 15;
    if (r < 14) {
      float p1 = 0.f, p2 = 0.f;
      #pragma unroll
      for (int i = 0; i < 8; i++) { float v = sV[r][j*8 + i]; p1 += v; p2 += v*v; }
      #pragma unroll
      for (int m = 8; m >= 1; m >>= 1) {
        p1 += __shfl_xor(p1, m, 64);
        p2 += __shfl_xor(p2, m, 64);
      }
      if (j == 0) {
        const float mean = p1 * (1.f/128.f);
        sMean[r] = mean;
        sRstd[r] = rsqrtf(p2 * (1.f/128.f) - mean*mean + 1e-5f);
      }
    }
  }
  __syncthreads();
  for (int idx = tid; idx < 14*128; idx += 256) {
    const int r = idx >> 7, dd = idx & 127;
    h1[((size_t)b*112 + s0 + r)*128 + dd] =
        (sV[r][dd] - sMean[r]) * sRstd[r] * lg[dd] + lb[dd];
  }
}

// ---------------- FFN + residual + LN2, batched 14 rows/block (in-place safe)
__global__ __launch_bounds__(256) void k_ffn(
    const float* __restrict__ h1,
    const float* __restrict__ f1wt, const float* __restrict__ f1b,
    const float* __restrict__ f2wt, const float* __restrict__ f2b,
    const float* __restrict__ lg, const float* __restrict__ lb,
    float* __restrict__ h2)
{
  __shared__ float sh[14][128];
  __shared__ float sf[14][512];
  __shared__ float sV[14][128];
  __shared__ float sMean[14], sRstd[14];
  const int s0 = blockIdx.x * 14, b = blockIdx.y;
  const int tid = threadIdx.x;
  const int d = tid & 127, half = tid >> 7;
  const int r0 = half * 7;

  for (int idx = tid; idx < 14*128; idx += 256) {
    const int r = idx >> 7, dd = idx & 127;
    sh[r][dd] = h1[((size_t)b*112 + s0 + r)*128 + dd];
  }
  __syncthreads();
  // FFN1: thread handles outputs tid, tid+256 for all 14 rows
  {
    float a0[14], a1[14];
    const float b0 = f1b[tid], b1 = f1b[tid + 256];
    #pragma unroll
    for (int r = 0; r < 14; r++) { a0[r] = b0; a1[r] = b1; }
    for (int kk = 0; kk < 128; kk++) {
      const float w0 = f1wt[kk*512 + tid];
      const float w1 = f1wt[kk*512 + tid + 256];
      #pragma unroll
      for (int r = 0; r < 14; r++) {
        const float xv = sh[r][kk];
        a0[r] += w0 * xv;
        a1[r] += w1 * xv;
      }
    }
    #pragma unroll
    for (int r = 0; r < 14; r++) {
      sf[r][tid]       = fmaxf(a0[r], 0.f);
      sf[r][tid + 256] = fmaxf(a1[r], 0.f);
    }
  }
  __syncthreads();
  // FFN2: thread (d, half) handles 7 rows
  {
    float acc[7];
    #pragma unroll
    for (int rr = 0; rr < 7; rr++) acc[rr] = f2b[d];
    for (int kk = 0; kk < 512; kk++) {
      const float wv = f2wt[kk*128 + d];
      #pragma unroll
      for (int rr = 0; rr < 7; rr++) acc[rr] += wv * sf[r0 + rr][kk];
    }
    #pragma unroll
    for (int rr = 0; rr < 7; rr++)
      sV[r0 + rr][d] = sh[r0 + rr][d] + acc[rr];
  }
  __syncthreads();
  {
    const int r = tid >> 4, j = tid & 15;
    if (r < 14) {
      float p1 = 0.f, p2 = 0.f;
      #pragma unroll
      for (int i = 0; i < 8; i++) { float v = sV[r][j*8 + i]; p1 += v; p2 += v*v; }
      #pragma unroll
      for (int m = 8; m >= 1; m >>= 1) {
        p1 += __shfl_xor(p1, m, 64);
        p2 += __shfl_xor(p2, m, 64);
      }
      if (j == 0) {
        const float mean = p1 * (1.f/128.f);
        sMean[r] = mean;
        sRstd[r] = rsqrtf(p2 * (1.f/128.f) - mean*mean + 1e-5f);
      }
    }
  }
  __syncthreads();
  for (int idx = tid; idx < 14*128; idx += 256) {
    const int r = idx >> 7, dd = idx & 127;
    h2[((size_t)b*112 + s0 + r)*128 + dd] =
        (sV[r][dd] - sMean[r]) * sRstd[r] * lg[dd] + lb[dd];
  }
}

// ---------------- rep = sum_s h2 ; classifier -> logits (f32)
__global__ __launch_bounds__(64) void k_cls(
    const float* __restrict__ h2,
    const float* __restrict__ c1w, const float* __restrict__ c1b,
    const float* __restrict__ c2w, const float* __restrict__ c2b,
    float* __restrict__ out)
{
  __shared__ float sr[128], sc[64];
  const int b = blockIdx.x, tid = threadIdx.x;
  float r0 = 0.f, r1 = 0.f;
  for (int s2 = 0; s2 < 112; s2++) {
    const float* row = h2 + ((size_t)b*112 + s2)*128;
    r0 += row[tid];
    r1 += row[tid + 64];
  }
  sr[tid] = r0; sr[tid + 64] = r1;
  __syncthreads();
  float acc = c1b[tid];
  const float* wr = c1w + (size_t)tid * 128;
  for (int kk = 0; kk < 128; kk++) acc += wr[kk] * sr[kk];
  sc[tid] = fmaxf(acc, 0.f);
  __syncthreads();
  if (tid < 2) {
    float l = c2b[tid];
    for (int kk = 0; kk < 64; kk++) l += c2w[tid*64 + kk] * sc[kk];
    out[b*2 + tid] = l;
  }
}

extern "C" void kernel_launch(void* const* d_in, const int* in_sizes, int n_in,
                              void* d_out, int out_size, void* d_ws, size_t ws_size,
                              hipStream_t stream)
{
  const float* x    = (const float*)d_in[0];
  const float* c1w  = (const float*)d_in[1];
  const float* c1b  = (const float*)d_in[2];
  const float* bn1g = (const float*)d_in[3];
  const float* bn1b = (const float*)d_in[4];
  const float* c2w  = (const float*)d_in[5];
  const float* c2b  = (const float*)d_in[6];
  const float* bn2g = (const float*)d_in[7];
  const float* bn2b = (const float*)d_in[8];
  const float* pjw  = (const float*)d_in[9];
  const float* pjb  = (const float*)d_in[10];
  const float* w1w  = (const float*)d_in[11];
  const float* w1b  = (const float*)d_in[12];
  const float* w2w  = (const float*)d_in[13];
  const float* w2b  = (const float*)d_in[14];
  const float* gw   = (const float*)d_in[15];
  const float* gb   = (const float*)d_in[16];
  const float* scw  = (const float*)d_in[17];
  const float* scb  = (const float*)d_in[18];
  const float* ipw  = (const float*)d_in[19];
  const float* ipb  = (const float*)d_in[20];
  const float* opw  = (const float*)d_in[21];
  const float* opb  = (const float*)d_in[22];
  const float* f1w  = (const float*)d_in[23];
  const float* f1b  = (const float*)d_in[24];
  const float* f2w  = (const float*)d_in[25];
  const float* f2b  = (const float*)d_in[26];
  const float* l1g  = (const float*)d_in[27];
  const float* l1b  = (const float*)d_in[28];
  const float* l2g  = (const float*)d_in[29];
  const float* l2b  = (const float*)d_in[30];
  const float* cl1w = (const float*)d_in[31];
  const float* cl1b = (const float*)d_in[32];
  const float* cl2w = (const float*)d_in[33];
  const float* cl2b = (const float*)d_in[34];

  // ---- bump allocator over d_ws (256-B aligned) ----
  char* p = (char*)d_ws;
  auto alloc = [&](size_t n) { char* r = p; p += (n + 255) & ~(size_t)255; return r; };
  u64*   mask2  = (u64*)  alloc(900    * sizeof(u64));
  int*   nbr1   = (int*)  alloc(1800   * sizeof(int));
  int*   sel    = (int*)  alloc(1792   * sizeof(int));
  float* scores = (float*)alloc(3600   * sizeof(float));
  u16*   pwh    = (u16*)  alloc(524288 * sizeof(u16));
  u16*   pwl    = (u16*)  alloc(524288 * sizeof(u16));
  u16*   wc2h   = (u16*)  alloc(36864  * sizeof(u16));
  u16*   wc2l   = (u16*)  alloc(36864  * sizeof(u16));
  float* iwt    = (float*)alloc(49152  * sizeof(float));  // [128][384]
  float* owt    = (float*)alloc(16384  * sizeof(float));  // [128][128]
  float* f1wt   = (float*)alloc(65536  * sizeof(float));  // [128][512]
  float* f2wt   = (float*)alloc(65536  * sizeof(float));  // [512][128]
  float* w1t    = (float*)alloc(16384  * sizeof(float));
  float* w2t    = (float*)alloc(16384  * sizeof(float));
  float* gwt    = (float*)alloc(32768  * sizeof(float));  // [256][128]
  float* a1buf  = (float*)alloc(460800 * sizeof(float));
  float* a2buf  = (float*)alloc(460800 * sizeof(float));
  float* zbuf   = (float*)alloc(460800 * sizeof(float));
  float* nodes  = (float*)alloc(460800 * sizeof(float));
  const size_t fixed_bytes = (size_t)(p - (char*)d_ws);

  const size_t qkv_bytes = 3ull * 229376ull * sizeof(float);
  const size_t per_batch = 64ull*128*128*2 + 64ull*64*64*2;   // 2,621,440 B
  int BC = 16;
  size_t s3 = 0;
  for (;; BC >>= 1) {
    s3 = (size_t)BC * per_batch; if (s3 < qkv_bytes) s3 = qkv_bytes;
    if (fixed_bytes + s3 + 65536 <= ws_size) break;
    if (BC == 1) { return; }
  }
  char* S3 = alloc(s3);

  u16*   feat1 = (u16*)S3;                              // NHWC (BC,128,128,64)
  u16*   feat2 = (u16*)(S3 + (size_t)BC * 2097152ull);  // NCHW (BC,64,64,64)
  float* qb    = (float*)S3;
  float* kb    = qb + 229376;
  float* vb    = kb + 229376;
  float* obuf  = nodes;
  float* hbuf  = nodes + 229376;

  k_adj  <<<1, 256, 0, stream>>>(nbr1, mask2);
  k_cvtw <<<512, 256, 0, stream>>>(pjw, pwh, pwl);
  k_cvtw2<<<144, 256, 0, stream>>>(c2w, bn2g, wc2h, wc2l);
  k_wt   <<<192, 256, 0, stream>>>(ipw, iwt, 384, 128);
  k_wt   <<<64,  256, 0, stream>>>(opw, owt, 128, 128);
  k_wt   <<<256, 256, 0, stream>>>(f1w, f1wt, 512, 128);
  k_wt   <<<256, 256, 0, stream>>>(f2w, f2wt, 128, 512);
  k_wt   <<<64,  256, 0, stream>>>(w1w, w1t, 128, 128);
  k_wt   <<<64,  256, 0, stream>>>(w2w, w2t, 128, 128);
  k_wt   <<<128, 256, 0, stream>>>(gw,  gwt, 128, 256);

  for (int b0 = 0; b0 < 16; b0 += BC) {
    k_conv1 <<<dim3(8,8,BC), 256, 0, stream>>>(x, c1w, c1b, bn1g, bn1b, feat1, b0);
    k_conv2m<<<dim3(4,8,BC), 256, 0, stream>>>(feat1, wc2h, wc2l, c2b, bn2g, bn2b, feat2);
    k_projm <<<dim3(4,BC), 256, 0, stream>>>(feat2, pwh, pwl, pjb, nodes, b0);
  }

  k_agg  <<<dim3(225,16), 128, 0, stream>>>(nodes, nbr1, mask2, a1buf, a2buf);
  k_gz   <<<dim3(15,16), 256, 0, stream>>>(a1buf, a2buf, w1t, w1b, w2t, w2b,
                                           gwt, gb, scw, scb, zbuf, scores);
  k_topk <<<16, 256, 0, stream>>>(scores, sel);
  k_qkv  <<<dim3(8,16), 256, 0, stream>>>(zbuf, sel, iwt, ipb, qb, kb, vb);
  k_attn <<<dim3(4,16), 128, 0, stream>>>(qb, kb, vb, obuf);
  k_oln  <<<dim3(8,16), 256, 0, stream>>>(obuf, zbuf, sel, owt, opb, l1g, l1b, hbuf);
  k_ffn  <<<dim3(8,16), 256, 0, stream>>>(hbuf, f1wt, f1b, f2wt, f2b, l2g, l2b, hbuf);
  k_cls  <<<16, 64, 0, stream>>>(hbuf, cl1w, cl1b, cl2w, cl2b, (float*)d_out);
}

// Round 8
// 594.290 us; speedup vs baseline: 2.8906x; 1.0696x over previous
//
#include <hip/hip_runtime.h>
#include <hip/hip_bf16.h>
#include <math.h>

typedef unsigned short u16;
typedef unsigned int   u32;
typedef unsigned long long u64;
typedef __attribute__((ext_vector_type(8))) short short8v;
typedef __attribute__((ext_vector_type(4))) float f32x4;

__device__ __forceinline__ float bf2f(u16 u) {
  union { u32 i; float f; } v; v.i = ((u32)u) << 16; return v.f;
}
__device__ __forceinline__ u16 f2bf(float f) {  // round-to-nearest-even
  union { float f; u32 i; } v; v.f = f;
  u32 r = (v.i + 0x7FFFu + ((v.i >> 16) & 1u)) >> 16;
  return (u16)r;
}

// ---------------- conv1 + bn1 + relu + maxpool2 : (16,3,256,256)f32 -> (BC,128,128,64) NHWC bf16
// Output staged through LDS so global writes are fully coalesced (round-7 fix: 10x write amp).
__global__ __launch_bounds__(256) void k_conv1(
    const float* __restrict__ x, const float* __restrict__ w,
    const float* __restrict__ cb, const float* __restrict__ g, const float* __restrict__ bb,
    u16* __restrict__ feat1, int b0)
{
  __shared__ __align__(16) char sMem[36864];   // union: sIn (13872 B) then sOut (36864 B)
  float* sIn = (float*)sMem;                   // [3][34][34] : idx (c*34+r)*34+q
  u16 (*sOut)[72] = (u16(*)[72])sMem;          // [256][72] pitch 144 B
  __shared__ float sW[64][27];
  __shared__ float sB[64];
  const int bl = blockIdx.z, ty = blockIdx.y, tx = blockIdx.x;
  const int b = b0 + bl;
  const int tid = threadIdx.x;
  for (int i = tid; i < 64*27; i += 256) {
    int oc = i / 27;
    float sc = g[oc] * rsqrtf(1.0f + 1e-5f);
    sW[oc][i % 27] = w[i] * sc;
  }
  if (tid < 64) {
    float sc = g[tid] * rsqrtf(1.0f + 1e-5f);
    sB[tid] = cb[tid] * sc + bb[tid];
  }
  const int iy0 = ty*32 - 1, ix0 = tx*32 - 1;
  for (int i = tid; i < 3*34*34; i += 256) {
    int c = i / (34*34); int r = (i / 34) % 34; int q = i % 34;
    int yy = iy0 + r, xx = ix0 + q;
    float v = 0.f;
    if (yy >= 0 && xx >= 0 && yy < 256 && xx < 256)
      v = x[(((size_t)b*3 + c)*256 + yy)*256 + xx];
    sIn[(c*34 + r)*34 + q] = v;
  }
  __syncthreads();
  const int py = tid >> 4, px = tid & 15;
  float win[3][4][4];
  #pragma unroll
  for (int c = 0; c < 3; c++)
    #pragma unroll
    for (int r = 0; r < 4; r++)
      #pragma unroll
      for (int q = 0; q < 4; q++)
        win[c][r][q] = sIn[(c*34 + 2*py + r)*34 + 2*px + q];
  __syncthreads();            // sIn fully consumed into registers; sOut may now overwrite
  u16 pend = 0;
  for (int oc = 0; oc < 64; oc++) {
    float s00=0.f, s01=0.f, s10=0.f, s11=0.f;
    #pragma unroll
    for (int c = 0; c < 3; c++)
      #pragma unroll
      for (int ky = 0; ky < 3; ky++)
        #pragma unroll
        for (int kx = 0; kx < 3; kx++) {
          float wv = sW[oc][(c*3+ky)*3+kx];
          s00 += win[c][ky  ][kx  ] * wv;
          s01 += win[c][ky  ][kx+1] * wv;
          s10 += win[c][ky+1][kx  ] * wv;
          s11 += win[c][ky+1][kx+1] * wv;
        }
    float m = fmaxf(fmaxf(s00,s01), fmaxf(s10,s11)) + sB[oc];
    u16 cur = f2bf(fmaxf(m, 0.f));
    if (oc & 1) {
      u32 pk = (u32)pend | ((u32)cur << 16);
      *reinterpret_cast<u32*>(&sOut[tid][oc - 1]) = pk;
    } else pend = cur;
  }
  __syncthreads();
  // coalesced write-out: 2048 uint4, consecutive lanes -> consecutive 16B
  const int oy0 = ty*16, ox0 = tx*16;
  #pragma unroll
  for (int it = 0; it < 8; it++) {
    const int i4 = it*256 + tid;
    const int oc8 = i4 & 7, p2 = (i4 >> 3) & 15, r = i4 >> 7;
    uint4 v = *reinterpret_cast<const uint4*>(&sOut[r*16 + p2][oc8*8]);
    *reinterpret_cast<uint4*>(
        feat1 + (((size_t)bl*128 + oy0 + r)*128 + ox0 + p2)*64 + oc8*8) = v;
  }
}

// ---------------- conv2 weights f32 OIHW -> bf16 hi/lo [ky*3+kx][chunk][oc][icL], bn-scaled
__global__ __launch_bounds__(256) void k_cvtw2(
    const float* __restrict__ w, const float* __restrict__ g,
    u16* __restrict__ wh, u16* __restrict__ wl)
{
  const int d = blockIdx.x * 256 + threadIdx.x;      // 36864 total
  if (d >= 36864) return;
  const int icL = d & 31, oc = (d >> 5) & 63, chunk = (d >> 11) & 1, kk = d >> 12;
  const float sc = g[oc] * rsqrtf(1.0f + 1e-5f);
  const float val = w[((size_t)oc*64 + chunk*32 + icL)*9 + kk] * sc;
  const u16 hb = f2bf(val);
  wh[d] = hb;
  wl[d] = f2bf(val - bf2f(hb));
}

// ---------------- conv2 + bn2 + relu + maxpool2 via MFMA implicit GEMM
__global__ __launch_bounds__(256, 2) void k_conv2m(
    const u16* __restrict__ feat1,
    const u16* __restrict__ wh, const u16* __restrict__ wl,
    const float* __restrict__ cb, const float* __restrict__ g, const float* __restrict__ bb,
    u16* __restrict__ feat2)
{
  __shared__ __align__(16) u16 sA[18*34*40];
  __shared__ __align__(16) u16 sBh[64*40], sBl[64*40];
  __shared__ float sBias[64];
  const int tx = blockIdx.x, ty = blockIdx.y, bl = blockIdx.z;
  const int y0 = ty*16, x0 = tx*32;
  const int tid = threadIdx.x;
  const int w = tid >> 6, l = tid & 63;
  const int lr = l & 15, lk = l >> 4;

  if (tid < 64) {
    float sc = g[tid] * rsqrtf(1.0f + 1e-5f);
    sBias[tid] = cb[tid] * sc + bb[tid];
  }

  f32x4 acc[8][4];
  #pragma unroll
  for (int j = 0; j < 8; j++)
    #pragma unroll
    for (int ct = 0; ct < 4; ct++)
      acc[j][ct] = (f32x4){0.f,0.f,0.f,0.f};

  for (int chunk = 0; chunk < 2; chunk++) {
    __syncthreads();
    for (int idx = tid; idx < 612*4; idx += 256) {
      const int pix = idx >> 2, seg = idx & 3;
      const int r = pix / 34, cc = pix % 34;
      const int yy = y0 - 1 + r, xx = x0 - 1 + cc;
      uint4 v = {0u,0u,0u,0u};
      if (yy >= 0 && yy < 128 && xx >= 0 && xx < 128)
        v = *reinterpret_cast<const uint4*>(
              feat1 + (((size_t)bl*128 + yy)*128 + xx)*64 + chunk*32 + seg*8);
      *reinterpret_cast<uint4*>(&sA[(size_t)(r*34 + cc)*40 + seg*8]) = v;
    }
    for (int kk = 0; kk < 9; kk++) {
      __syncthreads();
      {
        const int oc = tid >> 2, s8 = (tid & 3)*8;
        const size_t src = (size_t)(kk*2 + chunk)*2048 + tid*8;
        *reinterpret_cast<uint4*>(&sBh[oc*40 + s8]) = *reinterpret_cast<const uint4*>(wh + src);
        *reinterpret_cast<uint4*>(&sBl[oc*40 + s8]) = *reinterpret_cast<const uint4*>(wl + src);
      }
      __syncthreads();
      const int ky = kk / 3, kx = kk % 3;
      short8v a[8];
      #pragma unroll
      for (int j = 0; j < 8; j++) {
        const int m = w*8 + j;
        const int r = (m >> 1) + ky;
        const int cc = (m & 1)*16 + lr + kx;
        a[j] = *reinterpret_cast<const short8v*>(&sA[(size_t)(r*34 + cc)*40 + lk*8]);
      }
      #pragma unroll
      for (int ct = 0; ct < 4; ct++) {
        const short8v bh = *reinterpret_cast<const short8v*>(&sBh[(ct*16 + lr)*40 + lk*8]);
        const short8v bv = *reinterpret_cast<const short8v*>(&sBl[(ct*16 + lr)*40 + lk*8]);
        #pragma unroll
        for (int j = 0; j < 8; j++) {
          acc[j][ct] = __builtin_amdgcn_mfma_f32_16x16x32_bf16(a[j], bh, acc[j][ct], 0, 0, 0);
          acc[j][ct] = __builtin_amdgcn_mfma_f32_16x16x32_bf16(a[j], bv, acc[j][ct], 0, 0, 0);
        }
      }
    }
  }
  #pragma unroll
  for (int u = 0; u < 2; u++) {
    #pragma unroll
    for (int xh = 0; xh < 2; xh++) {
      const int jA = 4*u + xh, jB = 4*u + 2 + xh;
      #pragma unroll
      for (int ct = 0; ct < 4; ct++) {
        const int oc = ct*16 + lr;
        const float bias = sBias[oc];
        const float v0 = fmaxf(fmaxf(acc[jA][ct][0], acc[jA][ct][1]),
                               fmaxf(acc[jB][ct][0], acc[jB][ct][1]));
        const float v1 = fmaxf(fmaxf(acc[jA][ct][2], acc[jA][ct][3]),
                               fmaxf(acc[jB][ct][2], acc[jB][ct][3]));
        const u16 b0v = f2bf(fmaxf(v0 + bias, 0.f));
        const u16 b1v = f2bf(fmaxf(v1 + bias, 0.f));
        const int py = ty*8 + 2*w + u;
        const int px = tx*16 + xh*8 + lk*2;
        u32 pk = (u32)b0v | ((u32)b1v << 16);
        *reinterpret_cast<u32*>(&feat2[(((size_t)bl*64 + oc)*64 + py)*64 + px]) = pk;
      }
    }
  }
}

// ---------------- adjacency (input-independent, 1 block)
__global__ __launch_bounds__(256) void k_adj(int* __restrict__ nbr1, u64* __restrict__ mask2)
{
  __shared__ int snbr[225][8];
  const int i = threadIdx.x;
  if (i < 225) {
    const int ii = i / 15, jj = i % 15;
    int bd[8], bj[8];
    #pragma unroll
    for (int t = 0; t < 8; t++) { bd[t] = 1<<30; bj[t] = -1; }
    for (int j = 0; j < 225; j++) {
      if (j == i) continue;
      int di = ii - j/15, dj = jj - j%15;
      int d2 = di*di + dj*dj;
      if (d2 < bd[7]) {
        int p = 7;
        while (p > 0 && d2 < bd[p-1]) { bd[p]=bd[p-1]; bj[p]=bj[p-1]; p--; }
        bd[p] = d2; bj[p] = j;
      }
    }
    #pragma unroll
    for (int t = 0; t < 8; t++) { snbr[i][t] = bj[t]; nbr1[i*8+t] = bj[t]; }
  }
  __syncthreads();
  if (i < 225) {
    u64 m[4] = {0,0,0,0};
    #pragma unroll
    for (int t = 0; t < 8; t++) {
      int tt = snbr[i][t];
      #pragma unroll
      for (int u = 0; u < 8; u++) {
        int j = snbr[tt][u];
        m[j >> 6] |= 1ull << (j & 63);
      }
    }
    m[i >> 6] &= ~(1ull << (i & 63));
    #pragma unroll
    for (int wd = 0; wd < 4; wd++) mask2[i*4 + wd] = m[wd];
  }
}

// ---------------- split proj_w (f32) -> hi/lo bf16
__global__ __launch_bounds__(256) void k_cvtw(
    const float* __restrict__ pw, u16* __restrict__ pwh, u16* __restrict__ pwl)
{
  const int i = (blockIdx.x * 256 + threadIdx.x) * 4;
  float4 v = *reinterpret_cast<const float4*>(pw + i);
  float e[4] = {v.x, v.y, v.z, v.w};
  ushort4 h, l;
  u16* hp = &h.x; u16* lp = &l.x;
  #pragma unroll
  for (int j = 0; j < 4; j++) {
    u16 hb = f2bf(e[j]);
    hp[j] = hb;
    lp[j] = f2bf(e[j] - bf2f(hb));
  }
  *reinterpret_cast<ushort4*>(pwh + i) = h;
  *reinterpret_cast<ushort4*>(pwl + i) = l;
}

// ---------------- generic weight transpose [O][K] -> [K][O]
__global__ __launch_bounds__(256) void k_wt(
    const float* __restrict__ src, float* __restrict__ dst, int O, int K)
{
  const int idx = blockIdx.x * 256 + threadIdx.x;
  if (idx >= O * K) return;
  const int o = idx / K, k = idx % K;
  dst[(size_t)k * O + o] = src[idx];
}

// ---------------- patch-projection as MFMA GEMM
__global__ __launch_bounds__(256) void k_projm(
    const u16* __restrict__ feat2,
    const u16* __restrict__ pwh, const u16* __restrict__ pwl,
    const float* __restrict__ pb,
    float* __restrict__ nodes, int b0)
{
  __shared__ __align__(16) u16 sA [64][40];
  __shared__ __align__(16) u16 sBh[128][40];
  __shared__ __align__(16) u16 sBl[128][40];
  const int cx = blockIdx.x, bl = blockIdx.y;
  const int b  = b0 + bl;
  const int n0 = cx * 64;
  const int rows = (225 - n0) < 64 ? (225 - n0) : 64;
  const int tid = threadIdx.x;
  const int w = tid >> 6, l = tid & 63;
  const int lr = l & 15, lk = l >> 4;

  f32x4 acc[8];
  #pragma unroll
  for (int i = 0; i < 8; i++) acc[i] = (f32x4){0.f, 0.f, 0.f, 0.f};

  const int ar = tid >> 2, aci = tid & 3;
  const int an = n0 + ar;
  const int aph = an / 15, apw = an % 15;

  for (int k0 = 0; k0 < 4096; k0 += 32) {
    const int c  = k0 >> 6;
    const int i0 = (k0 & 63) >> 3;
    {
      uint2 g0 = {0u,0u}, g1 = {0u,0u};
      if (ar < rows) {
        const u16* src = feat2 + (((size_t)bl*64 + c)*64 + aph*4 + i0 + aci)*64 + apw*4;
        g0 = *reinterpret_cast<const uint2*>(src);
        g1 = *reinterpret_cast<const uint2*>(src + 4);
      }
      uint4 v; v.x = g0.x; v.y = g0.y; v.z = g1.x; v.w = g1.y;
      *reinterpret_cast<uint4*>(&sA[ar][aci*8]) = v;
    }
    #pragma unroll
    for (int p = 0; p < 2; p++) {
      int idx = p*256 + tid;
      int col = idx >> 2, seg = idx & 3;
      const size_t off = (size_t)col*4096 + k0 + seg*8;
      *reinterpret_cast<uint4*>(&sBh[col][seg*8]) = *reinterpret_cast<const uint4*>(pwh + off);
      *reinterpret_cast<uint4*>(&sBl[col][seg*8]) = *reinterpret_cast<const uint4*>(pwl + off);
    }
    __syncthreads();
    short8v a = *reinterpret_cast<const short8v*>(&sA[w*16 + lr][lk*8]);
    #pragma unroll
    for (int ct = 0; ct < 8; ct++) {
      short8v bh = *reinterpret_cast<const short8v*>(&sBh[ct*16 + lr][lk*8]);
      short8v bv = *reinterpret_cast<const short8v*>(&sBl[ct*16 + lr][lk*8]);
      acc[ct] = __builtin_amdgcn_mfma_f32_16x16x32_bf16(a, bh, acc[ct], 0, 0, 0);
      acc[ct] = __builtin_amdgcn_mfma_f32_16x16x32_bf16(a, bv, acc[ct], 0, 0, 0);
    }
    __syncthreads();
  }
  #pragma unroll
  for (int ct = 0; ct < 8; ct++) {
    const int col = ct*16 + lr;
    const float bias = pb[col];
    #pragma unroll
    for (int v = 0; v < 4; v++) {
      const int r = w*16 + lk*4 + v;
      if (r < rows)
        nodes[((size_t)b*225 + n0 + r)*128 + col] = acc[ct][v] + bias;
    }
  }
}

// ---------------- neighbor aggregation: a1/a2 per (b,node)
__global__ __launch_bounds__(128) void k_agg(
    const float* __restrict__ nodes, const int* __restrict__ nbr1,
    const u64* __restrict__ mask2,
    float* __restrict__ a1buf, float* __restrict__ a2buf)
{
  const int n = blockIdx.x, b = blockIdx.y;
  const int d = threadIdx.x;
  const float* nb = nodes + (size_t)b * 225 * 128;
  float a1 = 0.f;
  #pragma unroll
  for (int t = 0; t < 8; t++) a1 += nb[(size_t)nbr1[n*8+t]*128 + d];
  float a2 = 0.f;
  for (int wd = 0; wd < 4; wd++) {
    u64 m = mask2[n*4 + wd];
    while (m) {
      int j = wd*64 + __builtin_ctzll(m);
      a2 += nb[(size_t)j*128 + d];
      m &= m - 1;
    }
  }
  a1buf[((size_t)b*225 + n)*128 + d] = a1;
  a2buf[((size_t)b*225 + n)*128 + d] = a2;
}

// ---------------- z1/z2/gate/score batched: 15 nodes per block
__global__ __launch_bounds__(256) void k_gz(
    const float* __restrict__ a1buf, const float* __restrict__ a2buf,
    const float* __restrict__ w1t, const float* __restrict__ w1b,
    const float* __restrict__ w2t, const float* __restrict__ w2b,
    const float* __restrict__ gwt, const float* __restrict__ gb,
    const float* __restrict__ sw, const float* __restrict__ sb,
    float* __restrict__ zbuf, float* __restrict__ scores)
{
  __shared__ float sA1[15][128], sA2[15][128], sC[15][256], sRed[15][128];
  const int n0 = blockIdx.x * 15, b = blockIdx.y;
  const int tid = threadIdx.x;
  const int d = tid & 127, half = tid >> 7;
  const int r0 = half * 8, nr = half ? 7 : 8;       // rows 0..7 / 8..14

  for (int idx = tid; idx < 15*128; idx += 256) {
    const int r = idx >> 7, dd = idx & 127;
    sA1[r][dd] = a1buf[((size_t)b*225 + n0 + r)*128 + dd];
    sA2[r][dd] = a2buf[((size_t)b*225 + n0 + r)*128 + dd];
  }
  __syncthreads();

  float z1[8], z2[8];
  #pragma unroll
  for (int rr = 0; rr < 8; rr++) { z1[rr] = w1b[d]; z2[rr] = w2b[d]; }
  for (int k = 0; k < 128; k++) {
    const float wv1 = w1t[k*128 + d];
    const float wv2 = w2t[k*128 + d];
    #pragma unroll
    for (int rr = 0; rr < 8; rr++) {
      if (rr < nr) {
        z1[rr] += wv1 * sA1[r0 + rr][k];
        z2[rr] += wv2 * sA2[r0 + rr][k];
      }
    }
  }
  #pragma unroll
  for (int rr = 0; rr < 8; rr++) {
    if (rr < nr) { sC[r0+rr][d] = z1[rr]; sC[r0+rr][128+d] = z2[rr]; }
  }
  __syncthreads();
  float gl[8];
  #pragma unroll
  for (int rr = 0; rr < 8; rr++) gl[rr] = gb[d];
  for (int k = 0; k < 256; k++) {
    const float wv = gwt[k*128 + d];
    #pragma unroll
    for (int rr = 0; rr < 8; rr++)
      if (rr < nr) gl[rr] += wv * sC[r0 + rr][k];
  }
  const float swd = sw[d];
  #pragma unroll
  for (int rr = 0; rr < 8; rr++) {
    if (rr < nr) {
      const float gg = 1.f / (1.f + expf(-gl[rr]));
      const float zv = gg * z1[rr] + (1.f - gg) * z2[rr];
      zbuf[((size_t)b*225 + n0 + r0 + rr)*128 + d] = zv;
      sRed[r0+rr][d] = zv * swd;
    }
  }
  __syncthreads();
  // score reduce: 16 threads per row
  const int r = tid >> 4, j = tid & 15;
  if (r < 15) {
    float part = 0.f;
    #pragma unroll
    for (int i = 0; i < 8; i++) part += sRed[r][j*8 + i];
    #pragma unroll
    for (int m = 8; m >= 1; m >>= 1) part += __shfl_xor(part, m, 64);
    if (j == 0) scores[b*225 + n0 + r] = part + sb[0];
  }
}

// ---------------- top-k (k=112) with jax tie semantics
__global__ __launch_bounds__(256) void k_topk(
    const float* __restrict__ scores, int* __restrict__ sel)
{
  __shared__ float ss[225];
  const int b = blockIdx.x, tid = threadIdx.x;
  if (tid < 112) sel[b*112 + tid] = tid;
  if (tid < 225) ss[tid] = scores[b*225 + tid];
  __syncthreads();
  if (tid < 225) {
    float s = ss[tid];
    int rank = 0;
    for (int j = 0; j < 225; j++) {
      float sj = ss[j];
      rank += (sj > s) || (sj == s && j < tid);
    }
    if (rank < 112) sel[b*112 + rank] = tid;
  }
}

// ---------------- qkv batched: 14 rows per block
__global__ __launch_bounds__(256) void k_qkv(
    const float* __restrict__ zbuf, const int* __restrict__ sel,
    const float* __restrict__ iwt, const float* __restrict__ ib,
    float* __restrict__ q, float* __restrict__ k, float* __restrict__ v)
{
  __shared__ float sx[14][128];
  const int s0 = blockIdx.x * 14, b = blockIdx.y;
  const int tid = threadIdx.x;
  const int c = tid & 127, half = tid >> 7;
  const int r0 = half * 7;

  for (int idx = tid; idx < 14*128; idx += 256) {
    const int r = idx >> 7, dd = idx & 127;
    int row = sel[b*112 + s0 + r];
    row = row < 0 ? 0 : (row > 224 ? 224 : row);
    sx[r][dd] = zbuf[((size_t)b*225 + row)*128 + dd];
  }
  __syncthreads();

  float acc[3][7];
  #pragma unroll
  for (int p = 0; p < 3; p++)
    #pragma unroll
    for (int rr = 0; rr < 7; rr++) acc[p][rr] = ib[p*128 + c];
  for (int kk = 0; kk < 128; kk++) {
    float wv[3];
    #pragma unroll
    for (int p = 0; p < 3; p++) wv[p] = iwt[kk*384 + p*128 + c];
    #pragma unroll
    for (int rr = 0; rr < 7; rr++) {
      const float xv = sx[r0 + rr][kk];
      #pragma unroll
      for (int p = 0; p < 3; p++) acc[p][rr] += wv[p] * xv;
    }
  }
  const int h = c >> 5, t = c & 31;
  float* outs[3] = {q, k, v};
  #pragma unroll
  for (int p = 0; p < 3; p++)
    #pragma unroll
    for (int rr = 0; rr < 7; rr++)
      outs[p][(((size_t)b*4 + h)*112 + s0 + r0 + rr)*32 + t] = acc[p][rr];
}

// ---------------- attention per (b, head), two-pass softmax
__global__ __launch_bounds__(128) void k_attn(
    const float* __restrict__ q, const float* __restrict__ k,
    const float* __restrict__ v, float* __restrict__ o)
{
  __shared__ float sK[112*32], sV[112*32];
  const int h = blockIdx.x, b = blockIdx.y, tid = threadIdx.x;
  const size_t base = ((size_t)b*4 + h) * 112 * 32;
  for (int i = tid; i < 112*32; i += 128) {
    sK[i] = k[base + i];
    sV[i] = v[base + i];
  }
  __syncthreads();
  if (tid < 112) {
    float qv[32];
    const float* qp = q + base + (size_t)tid*32;
    #pragma unroll
    for (int t = 0; t < 32; t++) qv[t] = qp[t];
    const float scale = 0.17677669529663687f;
    float mx = -INFINITY;
    for (int j = 0; j < 112; j++) {
      float s = 0.f;
      #pragma unroll
      for (int t = 0; t < 32; t++) s += qv[t] * sK[j*32 + t];
      mx = fmaxf(mx, s * scale);
    }
    float acc[32];
    #pragma unroll
    for (int t = 0; t < 32; t++) acc[t] = 0.f;
    float l = 0.f;
    for (int j = 0; j < 112; j++) {
      float s = 0.f;
      #pragma unroll
      for (int t = 0; t < 32; t++) s += qv[t] * sK[j*32 + t];
      float p = expf(s * scale - mx);
      l += p;
      #pragma unroll
      for (int t = 0; t < 32; t++) acc[t] += p * sV[j*32 + t];
    }
    float inv = 1.f / l;
    float* op = o + ((size_t)b*112 + tid)*128 + h*32;
    #pragma unroll
    for (int t = 0; t < 32; t++) op[t] = acc[t] * inv;
  }
}

// ---------------- out-proj + residual + LN1, batched 14 rows/block
__global__ __launch_bounds__(256) void k_oln(
    const float* __restrict__ o, const float* __restrict__ zbuf,
    const int* __restrict__ sel,
    const float* __restrict__ owt, const float* __restrict__ ob,
    const float* __restrict__ lg, const float* __restrict__ lb,
    float* __restrict__ h1)
{
  __shared__ float sO[14][128], sV[14][128];
  __shared__ float sMean[14], sRstd[14];
  const int s0 = blockIdx.x * 14, b = blockIdx.y;
  const int tid = threadIdx.x;
  const int d = tid & 127, half = tid >> 7;
  const int r0 = half * 7;

  for (int idx = tid; idx < 14*128; idx += 256) {
    const int r = idx >> 7, dd = idx & 127;
    sO[r][dd] = o[((size_t)b*112 + s0 + r)*128 + dd];
  }
  __syncthreads();

  float acc[7];
  #pragma unroll
  for (int rr = 0; rr < 7; rr++) acc[rr] = ob[d];
  for (int kk = 0; kk < 128; kk++) {
    const float wv = owt[kk*128 + d];
    #pragma unroll
    for (int rr = 0; rr < 7; rr++) acc[rr] += wv * sO[r0 + rr][kk];
  }
  #pragma unroll
  for (int rr = 0; rr < 7; rr++) {
    int row = sel[b*112 + s0 + r0 + rr];
    row = row < 0 ? 0 : (row > 224 ? 224 : row);
    acc[rr] += zbuf[((size_t)b*225 + row)*128 + d];
    sV[r0 + rr][d] = acc[rr];
  }
  __syncthreads();
  {
    const int r = tid >> 4, j = tid & 15;
    if (r < 14) {
      float p1 = 0.f, p2 = 0.f;
      #pragma unroll
      for (int i = 0; i < 8; i++) { float v = sV[r][j*8 + i]; p1 += v; p2 += v*v; }
      #pragma unroll
      for (int m = 8; m >= 1; m >>= 1) {
        p1 += __shfl_xor(p1, m, 64);
        p2 += __shfl_xor(p2, m, 64);
      }
      if (j == 0) {
        const float mean = p1 * (1.f/128.f);
        sMean[r] = mean;
        sRstd[r] = rsqrtf(p2 * (1.f/128.f) - mean*mean + 1e-5f);
      }
    }
  }
  __syncthreads();
  for (int idx = tid; idx < 14*128; idx += 256) {
    const int r = idx >> 7, dd = idx & 127;
    h1[((size_t)b*112 + s0 + r)*128 + dd] =
        (sV[r][dd] - sMean[r]) * sRstd[r] * lg[dd] + lb[dd];
  }
}

// ---------------- FFN + residual + LN2, batched 14 rows/block (in-place safe)
__global__ __launch_bounds__(256) void k_ffn(
    const float* __restrict__ h1,
    const float* __restrict__ f1wt, const float* __restrict__ f1b,
    const float* __restrict__ f2wt, const float* __restrict__ f2b,
    const float* __restrict__ lg, const float* __restrict__ lb,
    float* __restrict__ h2)
{
  __shared__ float sh[14][128];
  __shared__ float sf[14][512];
  __shared__ float sV[14][128];
  __shared__ float sMean[14], sRstd[14];
  const int s0 = blockIdx.x * 14, b = blockIdx.y;
  const int tid = threadIdx.x;
  const int d = tid & 127, half = tid >> 7;
  const int r0 = half * 7;

  for (int idx = tid; idx < 14*128; idx += 256) {
    const int r = idx >> 7, dd = idx & 127;
    sh[r][dd] = h1[((size_t)b*112 + s0 + r)*128 + dd];
  }
  __syncthreads();
  {
    float a0[14], a1[14];
    const float b0 = f1b[tid], b1 = f1b[tid + 256];
    #pragma unroll
    for (int r = 0; r < 14; r++) { a0[r] = b0; a1[r] = b1; }
    for (int kk = 0; kk < 128; kk++) {
      const float w0 = f1wt[kk*512 + tid];
      const float w1 = f1wt[kk*512 + tid + 256];
      #pragma unroll
      for (int r = 0; r < 14; r++) {
        const float xv = sh[r][kk];
        a0[r] += w0 * xv;
        a1[r] += w1 * xv;
      }
    }
    #pragma unroll
    for (int r = 0; r < 14; r++) {
      sf[r][tid]       = fmaxf(a0[r], 0.f);
      sf[r][tid + 256] = fmaxf(a1[r], 0.f);
    }
  }
  __syncthreads();
  {
    float acc[7];
    #pragma unroll
    for (int rr = 0; rr < 7; rr++) acc[rr] = f2b[d];
    for (int kk = 0; kk < 512; kk++) {
      const float wv = f2wt[kk*128 + d];
      #pragma unroll
      for (int rr = 0; rr < 7; rr++) acc[rr] += wv * sf[r0 + rr][kk];
    }
    #pragma unroll
    for (int rr = 0; rr < 7; rr++)
      sV[r0 + rr][d] = sh[r0 + rr][d] + acc[rr];
  }
  __syncthreads();
  {
    const int r = tid >> 4, j = tid & 15;
    if (r < 14) {
      float p1 = 0.f, p2 = 0.f;
      #pragma unroll
      for (int i = 0; i < 8; i++) { float v = sV[r][j*8 + i]; p1 += v; p2 += v*v; }
      #pragma unroll
      for (int m = 8; m >= 1; m >>= 1) {
        p1 += __shfl_xor(p1, m, 64);
        p2 += __shfl_xor(p2, m, 64);
      }
      if (j == 0) {
        const float mean = p1 * (1.f/128.f);
        sMean[r] = mean;
        sRstd[r] = rsqrtf(p2 * (1.f/128.f) - mean*mean + 1e-5f);
      }
    }
  }
  __syncthreads();
  for (int idx = tid; idx < 14*128; idx += 256) {
    const int r = idx >> 7, dd = idx & 127;
    h2[((size_t)b*112 + s0 + r)*128 + dd] =
        (sV[r][dd] - sMean[r]) * sRstd[r] * lg[dd] + lb[dd];
  }
}

// ---------------- rep = sum_s h2 ; classifier -> logits (f32)
__global__ __launch_bounds__(64) void k_cls(
    const float* __restrict__ h2,
    const float* __restrict__ c1w, const float* __restrict__ c1b,
    const float* __restrict__ c2w, const float* __restrict__ c2b,
    float* __restrict__ out)
{
  __shared__ float sr[128], sc[64];
  const int b = blockIdx.x, tid = threadIdx.x;
  float r0 = 0.f, r1 = 0.f;
  for (int s2 = 0; s2 < 112; s2++) {
    const float* row = h2 + ((size_t)b*112 + s2)*128;
    r0 += row[tid];
    r1 += row[tid + 64];
  }
  sr[tid] = r0; sr[tid + 64] = r1;
  __syncthreads();
  float acc = c1b[tid];
  const float* wr = c1w + (size_t)tid * 128;
  for (int kk = 0; kk < 128; kk++) acc += wr[kk] * sr[kk];
  sc[tid] = fmaxf(acc, 0.f);
  __syncthreads();
  if (tid < 2) {
    float l = c2b[tid];
    for (int kk = 0; kk < 64; kk++) l += c2w[tid*64 + kk] * sc[kk];
    out[b*2 + tid] = l;
  }
}

extern "C" void kernel_launch(void* const* d_in, const int* in_sizes, int n_in,
                              void* d_out, int out_size, void* d_ws, size_t ws_size,
                              hipStream_t stream)
{
  const float* x    = (const float*)d_in[0];
  const float* c1w  = (const float*)d_in[1];
  const float* c1b  = (const float*)d_in[2];
  const float* bn1g = (const float*)d_in[3];
  const float* bn1b = (const float*)d_in[4];
  const float* c2w  = (const float*)d_in[5];
  const float* c2b  = (const float*)d_in[6];
  const float* bn2g = (const float*)d_in[7];
  const float* bn2b = (const float*)d_in[8];
  const float* pjw  = (const float*)d_in[9];
  const float* pjb  = (const float*)d_in[10];
  const float* w1w  = (const float*)d_in[11];
  const float* w1b  = (const float*)d_in[12];
  const float* w2w  = (const float*)d_in[13];
  const float* w2b  = (const float*)d_in[14];
  const float* gw   = (const float*)d_in[15];
  const float* gb   = (const float*)d_in[16];
  const float* scw  = (const float*)d_in[17];
  const float* scb  = (const float*)d_in[18];
  const float* ipw  = (const float*)d_in[19];
  const float* ipb  = (const float*)d_in[20];
  const float* opw  = (const float*)d_in[21];
  const float* opb  = (const float*)d_in[22];
  const float* f1w  = (const float*)d_in[23];
  const float* f1b  = (const float*)d_in[24];
  const float* f2w  = (const float*)d_in[25];
  const float* f2b  = (const float*)d_in[26];
  const float* l1g  = (const float*)d_in[27];
  const float* l1b  = (const float*)d_in[28];
  const float* l2g  = (const float*)d_in[29];
  const float* l2b  = (const float*)d_in[30];
  const float* cl1w = (const float*)d_in[31];
  const float* cl1b = (const float*)d_in[32];
  const float* cl2w = (const float*)d_in[33];
  const float* cl2b = (const float*)d_in[34];

  // ---- bump allocator over d_ws (256-B aligned) ----
  char* p = (char*)d_ws;
  auto alloc = [&](size_t n) { char* r = p; p += (n + 255) & ~(size_t)255; return r; };
  u64*   mask2  = (u64*)  alloc(900    * sizeof(u64));
  int*   nbr1   = (int*)  alloc(1800   * sizeof(int));
  int*   sel    = (int*)  alloc(1792   * sizeof(int));
  float* scores = (float*)alloc(3600   * sizeof(float));
  u16*   pwh    = (u16*)  alloc(524288 * sizeof(u16));
  u16*   pwl    = (u16*)  alloc(524288 * sizeof(u16));
  u16*   wc2h   = (u16*)  alloc(36864  * sizeof(u16));
  u16*   wc2l   = (u16*)  alloc(36864  * sizeof(u16));
  float* iwt    = (float*)alloc(49152  * sizeof(float));
  float* owt    = (float*)alloc(16384  * sizeof(float));
  float* f1wt   = (float*)alloc(65536  * sizeof(float));
  float* f2wt   = (float*)alloc(65536  * sizeof(float));
  float* w1t    = (float*)alloc(16384  * sizeof(float));
  float* w2t    = (float*)alloc(16384  * sizeof(float));
  float* gwt    = (float*)alloc(32768  * sizeof(float));
  float* a1buf  = (float*)alloc(460800 * sizeof(float));
  float* a2buf  = (float*)alloc(460800 * sizeof(float));
  float* zbuf   = (float*)alloc(460800 * sizeof(float));
  float* nodes  = (float*)alloc(460800 * sizeof(float));
  const size_t fixed_bytes = (size_t)(p - (char*)d_ws);

  const size_t qkv_bytes = 3ull * 229376ull * sizeof(float);
  const size_t per_batch = 64ull*128*128*2 + 64ull*64*64*2;   // 2,621,440 B
  int BC = 16;
  size_t s3 = 0;
  for (;; BC >>= 1) {
    s3 = (size_t)BC * per_batch; if (s3 < qkv_bytes) s3 = qkv_bytes;
    if (fixed_bytes + s3 + 65536 <= ws_size) break;
    if (BC == 1) { return; }
  }
  char* S3 = alloc(s3);

  u16*   feat1 = (u16*)S3;                              // NHWC (BC,128,128,64)
  u16*   feat2 = (u16*)(S3 + (size_t)BC * 2097152ull);  // NCHW (BC,64,64,64)
  float* qb    = (float*)S3;
  float* kb    = qb + 229376;
  float* vb    = kb + 229376;
  float* obuf  = nodes;
  float* hbuf  = nodes + 229376;

  k_adj  <<<1, 256, 0, stream>>>(nbr1, mask2);
  k_cvtw <<<512, 256, 0, stream>>>(pjw, pwh, pwl);
  k_cvtw2<<<144, 256, 0, stream>>>(c2w, bn2g, wc2h, wc2l);
  k_wt   <<<192, 256, 0, stream>>>(ipw, iwt, 384, 128);
  k_wt   <<<64,  256, 0, stream>>>(opw, owt, 128, 128);
  k_wt   <<<256, 256, 0, stream>>>(f1w, f1wt, 512, 128);
  k_wt   <<<256, 256, 0, stream>>>(f2w, f2wt, 128, 512);
  k_wt   <<<64,  256, 0, stream>>>(w1w, w1t, 128, 128);
  k_wt   <<<64,  256, 0, stream>>>(w2w, w2t, 128, 128);
  k_wt   <<<128, 256, 0, stream>>>(gw,  gwt, 128, 256);

  for (int b0 = 0; b0 < 16; b0 += BC) {
    k_conv1 <<<dim3(8,8,BC), 256, 0, stream>>>(x, c1w, c1b, bn1g, bn1b, feat1, b0);
    k_conv2m<<<dim3(4,8,BC), 256, 0, stream>>>(feat1, wc2h, wc2l, c2b, bn2g, bn2b, feat2);
    k_projm <<<dim3(4,BC), 256, 0, stream>>>(feat2, pwh, pwl, pjb, nodes, b0);
  }

  k_agg  <<<dim3(225,16), 128, 0, stream>>>(nodes, nbr1, mask2, a1buf, a2buf);
  k_gz   <<<dim3(15,16), 256, 0, stream>>>(a1buf, a2buf, w1t, w1b, w2t, w2b,
                                           gwt, gb, scw, scb, zbuf, scores);
  k_topk <<<16, 256, 0, stream>>>(scores, sel);
  k_qkv  <<<dim3(8,16), 256, 0, stream>>>(zbuf, sel, iwt, ipb, qb, kb, vb);
  k_attn <<<dim3(4,16), 128, 0, stream>>>(qb, kb, vb, obuf);
  k_oln  <<<dim3(8,16), 256, 0, stream>>>(obuf, zbuf, sel, owt, opb, l1g, l1b, hbuf);
  k_ffn  <<<dim3(8,16), 256, 0, stream>>>(hbuf, f1wt, f1b, f2wt, f2b, l2g, l2b, hbuf);
  k_cls  <<<16, 64, 0, stream>>>(hbuf, cl1w, cl1b, cl2w, cl2b, (float*)d_out);
}

// Round 9
// 524.734 us; speedup vs baseline: 3.2738x; 1.1326x over previous
//
#include <hip/hip_runtime.h>
#include <hip/hip_bf16.h>
#include <math.h>

typedef unsigned short u16;
typedef unsigned int   u32;
typedef unsigned long long u64;
typedef __attribute__((ext_vector_type(8))) short short8v;
typedef __attribute__((ext_vector_type(4))) float f32x4;

__device__ __forceinline__ float bf2f(u16 u) {
  union { u32 i; float f; } v; v.i = ((u32)u) << 16; return v.f;
}
__device__ __forceinline__ u16 f2bf(float f) {  // round-to-nearest-even
  union { float f; u32 i; } v; v.f = f;
  u32 r = (v.i + 0x7FFFu + ((v.i >> 16) & 1u)) >> 16;
  return (u16)r;
}

// ---------------- conv1 + bn1 + relu + maxpool2 : (16,3,256,256)f32 -> (BC,128,128,64) NHWC bf16
__global__ __launch_bounds__(256) void k_conv1(
    const float* __restrict__ x, const float* __restrict__ w,
    const float* __restrict__ cb, const float* __restrict__ g, const float* __restrict__ bb,
    u16* __restrict__ feat1, int b0)
{
  __shared__ __align__(16) char sMem[36864];   // union: sIn (13872 B) then sOut (36864 B)
  float* sIn = (float*)sMem;                   // [3][34][34]
  u16 (*sOut)[72] = (u16(*)[72])sMem;          // [256][72]
  __shared__ float sW[64][27];
  __shared__ float sB[64];
  const int bl = blockIdx.z, ty = blockIdx.y, tx = blockIdx.x;
  const int b = b0 + bl;
  const int tid = threadIdx.x;
  for (int i = tid; i < 64*27; i += 256) {
    int oc = i / 27;
    float sc = g[oc] * rsqrtf(1.0f + 1e-5f);
    sW[oc][i % 27] = w[i] * sc;
  }
  if (tid < 64) {
    float sc = g[tid] * rsqrtf(1.0f + 1e-5f);
    sB[tid] = cb[tid] * sc + bb[tid];
  }
  const int iy0 = ty*32 - 1, ix0 = tx*32 - 1;
  for (int i = tid; i < 3*34*34; i += 256) {
    int c = i / (34*34); int r = (i / 34) % 34; int q = i % 34;
    int yy = iy0 + r, xx = ix0 + q;
    float v = 0.f;
    if (yy >= 0 && xx >= 0 && yy < 256 && xx < 256)
      v = x[(((size_t)b*3 + c)*256 + yy)*256 + xx];
    sIn[(c*34 + r)*34 + q] = v;
  }
  __syncthreads();
  const int py = tid >> 4, px = tid & 15;
  float win[3][4][4];
  #pragma unroll
  for (int c = 0; c < 3; c++)
    #pragma unroll
    for (int r = 0; r < 4; r++)
      #pragma unroll
      for (int q = 0; q < 4; q++)
        win[c][r][q] = sIn[(c*34 + 2*py + r)*34 + 2*px + q];
  __syncthreads();            // sIn consumed; sOut may overwrite
  u16 pend = 0;
  for (int oc = 0; oc < 64; oc++) {
    float s00=0.f, s01=0.f, s10=0.f, s11=0.f;
    #pragma unroll
    for (int c = 0; c < 3; c++)
      #pragma unroll
      for (int ky = 0; ky < 3; ky++)
        #pragma unroll
        for (int kx = 0; kx < 3; kx++) {
          float wv = sW[oc][(c*3+ky)*3+kx];
          s00 += win[c][ky  ][kx  ] * wv;
          s01 += win[c][ky  ][kx+1] * wv;
          s10 += win[c][ky+1][kx  ] * wv;
          s11 += win[c][ky+1][kx+1] * wv;
        }
    float m = fmaxf(fmaxf(s00,s01), fmaxf(s10,s11)) + sB[oc];
    u16 cur = f2bf(fmaxf(m, 0.f));
    if (oc & 1) {
      u32 pk = (u32)pend | ((u32)cur << 16);
      *reinterpret_cast<u32*>(&sOut[tid][oc - 1]) = pk;
    } else pend = cur;
  }
  __syncthreads();
  const int oy0 = ty*16, ox0 = tx*16;
  #pragma unroll
  for (int it = 0; it < 8; it++) {
    const int i4 = it*256 + tid;
    const int oc8 = i4 & 7, p2 = (i4 >> 3) & 15, r = i4 >> 7;
    uint4 v = *reinterpret_cast<const uint4*>(&sOut[r*16 + p2][oc8*8]);
    *reinterpret_cast<uint4*>(
        feat1 + (((size_t)bl*128 + oy0 + r)*128 + ox0 + p2)*64 + oc8*8) = v;
  }
}

// ---------------- conv2 weights f32 OIHW -> bf16 hi/lo [ky*3+kx][chunk][oc][icL], bn-scaled
__global__ __launch_bounds__(256) void k_cvtw2(
    const float* __restrict__ w, const float* __restrict__ g,
    u16* __restrict__ wh, u16* __restrict__ wl)
{
  const int d = blockIdx.x * 256 + threadIdx.x;      // 36864 total
  if (d >= 36864) return;
  const int icL = d & 31, oc = (d >> 5) & 63, chunk = (d >> 11) & 1, kk = d >> 12;
  const float sc = g[oc] * rsqrtf(1.0f + 1e-5f);
  const float val = w[((size_t)oc*64 + chunk*32 + icL)*9 + kk] * sc;
  const u16 hb = f2bf(val);
  wh[d] = hb;
  wl[d] = f2bf(val - bf2f(hb));
}

// ---------------- conv2 + bn2 + relu + maxpool2 via MFMA implicit GEMM
__global__ __launch_bounds__(256, 2) void k_conv2m(
    const u16* __restrict__ feat1,
    const u16* __restrict__ wh, const u16* __restrict__ wl,
    const float* __restrict__ cb, const float* __restrict__ g, const float* __restrict__ bb,
    u16* __restrict__ feat2)
{
  __shared__ __align__(16) u16 sA[18*34*40];
  __shared__ __align__(16) u16 sBh[64*40], sBl[64*40];
  __shared__ float sBias[64];
  const int tx = blockIdx.x, ty = blockIdx.y, bl = blockIdx.z;
  const int y0 = ty*16, x0 = tx*32;
  const int tid = threadIdx.x;
  const int w = tid >> 6, l = tid & 63;
  const int lr = l & 15, lk = l >> 4;

  if (tid < 64) {
    float sc = g[tid] * rsqrtf(1.0f + 1e-5f);
    sBias[tid] = cb[tid] * sc + bb[tid];
  }

  f32x4 acc[8][4];
  #pragma unroll
  for (int j = 0; j < 8; j++)
    #pragma unroll
    for (int ct = 0; ct < 4; ct++)
      acc[j][ct] = (f32x4){0.f,0.f,0.f,0.f};

  for (int chunk = 0; chunk < 2; chunk++) {
    __syncthreads();
    for (int idx = tid; idx < 612*4; idx += 256) {
      const int pix = idx >> 2, seg = idx & 3;
      const int r = pix / 34, cc = pix % 34;
      const int yy = y0 - 1 + r, xx = x0 - 1 + cc;
      uint4 v = {0u,0u,0u,0u};
      if (yy >= 0 && yy < 128 && xx >= 0 && xx < 128)
        v = *reinterpret_cast<const uint4*>(
              feat1 + (((size_t)bl*128 + yy)*128 + xx)*64 + chunk*32 + seg*8);
      *reinterpret_cast<uint4*>(&sA[(size_t)(r*34 + cc)*40 + seg*8]) = v;
    }
    for (int kk = 0; kk < 9; kk++) {
      __syncthreads();
      {
        const int oc = tid >> 2, s8 = (tid & 3)*8;
        const size_t src = (size_t)(kk*2 + chunk)*2048 + tid*8;
        *reinterpret_cast<uint4*>(&sBh[oc*40 + s8]) = *reinterpret_cast<const uint4*>(wh + src);
        *reinterpret_cast<uint4*>(&sBl[oc*40 + s8]) = *reinterpret_cast<const uint4*>(wl + src);
      }
      __syncthreads();
      const int ky = kk / 3, kx = kk % 3;
      short8v a[8];
      #pragma unroll
      for (int j = 0; j < 8; j++) {
        const int m = w*8 + j;
        const int r = (m >> 1) + ky;
        const int cc = (m & 1)*16 + lr + kx;
        a[j] = *reinterpret_cast<const short8v*>(&sA[(size_t)(r*34 + cc)*40 + lk*8]);
      }
      #pragma unroll
      for (int ct = 0; ct < 4; ct++) {
        const short8v bh = *reinterpret_cast<const short8v*>(&sBh[(ct*16 + lr)*40 + lk*8]);
        const short8v bv = *reinterpret_cast<const short8v*>(&sBl[(ct*16 + lr)*40 + lk*8]);
        #pragma unroll
        for (int j = 0; j < 8; j++) {
          acc[j][ct] = __builtin_amdgcn_mfma_f32_16x16x32_bf16(a[j], bh, acc[j][ct], 0, 0, 0);
          acc[j][ct] = __builtin_amdgcn_mfma_f32_16x16x32_bf16(a[j], bv, acc[j][ct], 0, 0, 0);
        }
      }
    }
  }
  #pragma unroll
  for (int u = 0; u < 2; u++) {
    #pragma unroll
    for (int xh = 0; xh < 2; xh++) {
      const int jA = 4*u + xh, jB = 4*u + 2 + xh;
      #pragma unroll
      for (int ct = 0; ct < 4; ct++) {
        const int oc = ct*16 + lr;
        const float bias = sBias[oc];
        const float v0 = fmaxf(fmaxf(acc[jA][ct][0], acc[jA][ct][1]),
                               fmaxf(acc[jB][ct][0], acc[jB][ct][1]));
        const float v1 = fmaxf(fmaxf(acc[jA][ct][2], acc[jA][ct][3]),
                               fmaxf(acc[jB][ct][2], acc[jB][ct][3]));
        const u16 b0v = f2bf(fmaxf(v0 + bias, 0.f));
        const u16 b1v = f2bf(fmaxf(v1 + bias, 0.f));
        const int py = ty*8 + 2*w + u;
        const int px = tx*16 + xh*8 + lk*2;
        u32 pk = (u32)b0v | ((u32)b1v << 16);
        *reinterpret_cast<u32*>(&feat2[(((size_t)bl*64 + oc)*64 + py)*64 + px]) = pk;
      }
    }
  }
}

// ---------------- adjacency (input-independent, 1 block)
__global__ __launch_bounds__(256) void k_adj(int* __restrict__ nbr1, u64* __restrict__ mask2)
{
  __shared__ int snbr[225][8];
  const int i = threadIdx.x;
  if (i < 225) {
    const int ii = i / 15, jj = i % 15;
    int bd[8], bj[8];
    #pragma unroll
    for (int t = 0; t < 8; t++) { bd[t] = 1<<30; bj[t] = -1; }
    for (int j = 0; j < 225; j++) {
      if (j == i) continue;
      int di = ii - j/15, dj = jj - j%15;
      int d2 = di*di + dj*dj;
      if (d2 < bd[7]) {
        int p = 7;
        while (p > 0 && d2 < bd[p-1]) { bd[p]=bd[p-1]; bj[p]=bj[p-1]; p--; }
        bd[p] = d2; bj[p] = j;
      }
    }
    #pragma unroll
    for (int t = 0; t < 8; t++) { snbr[i][t] = bj[t]; nbr1[i*8+t] = bj[t]; }
  }
  __syncthreads();
  if (i < 225) {
    u64 m[4] = {0,0,0,0};
    #pragma unroll
    for (int t = 0; t < 8; t++) {
      int tt = snbr[i][t];
      #pragma unroll
      for (int u = 0; u < 8; u++) {
        int j = snbr[tt][u];
        m[j >> 6] |= 1ull << (j & 63);
      }
    }
    m[i >> 6] &= ~(1ull << (i & 63));
    #pragma unroll
    for (int wd = 0; wd < 4; wd++) mask2[i*4 + wd] = m[wd];
  }
}

// ---------------- split proj_w (f32) -> hi/lo bf16
__global__ __launch_bounds__(256) void k_cvtw(
    const float* __restrict__ pw, u16* __restrict__ pwh, u16* __restrict__ pwl)
{
  const int i = (blockIdx.x * 256 + threadIdx.x) * 4;
  float4 v = *reinterpret_cast<const float4*>(pw + i);
  float e[4] = {v.x, v.y, v.z, v.w};
  ushort4 h, l;
  u16* hp = &h.x; u16* lp = &l.x;
  #pragma unroll
  for (int j = 0; j < 4; j++) {
    u16 hb = f2bf(e[j]);
    hp[j] = hb;
    lp[j] = f2bf(e[j] - bf2f(hb));
  }
  *reinterpret_cast<ushort4*>(pwh + i) = h;
  *reinterpret_cast<ushort4*>(pwl + i) = l;
}

// ---------------- generic weight transpose [O][K] -> [K][O]
__global__ __launch_bounds__(256) void k_wt(
    const float* __restrict__ src, float* __restrict__ dst, int O, int K)
{
  const int idx = blockIdx.x * 256 + threadIdx.x;
  if (idx >= O * K) return;
  const int o = idx / K, k = idx % K;
  dst[(size_t)k * O + o] = src[idx];
}

// ---------------- patch-projection MFMA GEMM, split-K=4 + register prefetch
// grid (4 n-tiles, 4 k-chunks, BC); partial[kc][b][n][128] f32 (no bias)
__global__ __launch_bounds__(256, 2) void k_projm(
    const u16* __restrict__ feat2,
    const u16* __restrict__ pwh, const u16* __restrict__ pwl,
    float* __restrict__ partial, int b0)
{
  __shared__ __align__(16) u16 sA [64][40];
  __shared__ __align__(16) u16 sBh[128][40];
  __shared__ __align__(16) u16 sBl[128][40];
  const int cx = blockIdx.x, kc = blockIdx.y, bl = blockIdx.z;
  const int b  = b0 + bl;
  const int n0 = cx * 64;
  const int rows = (225 - n0) < 64 ? (225 - n0) : 64;
  const int tid = threadIdx.x;
  const int w = tid >> 6, l = tid & 63;
  const int lr = l & 15, lk = l >> 4;

  f32x4 acc[8];
  #pragma unroll
  for (int i = 0; i < 8; i++) acc[i] = (f32x4){0.f, 0.f, 0.f, 0.f};

  const int ar = tid >> 2, aci = tid & 3;
  const int an = n0 + ar;
  const int aph = an / 15, apw = an % 15;
  const int kbeg = kc * 1024, kend = kbeg + 1024;

  uint4 pA, pBh[2], pBl[2];
  auto loadstep = [&](int k0) {
    const int c  = k0 >> 6;
    const int i0 = (k0 & 63) >> 3;
    uint2 g0 = {0u,0u}, g1 = {0u,0u};
    if (ar < rows) {
      const u16* src = feat2 + (((size_t)bl*64 + c)*64 + aph*4 + i0 + aci)*64 + apw*4;
      g0 = *reinterpret_cast<const uint2*>(src);
      g1 = *reinterpret_cast<const uint2*>(src + 4);
    }
    pA.x = g0.x; pA.y = g0.y; pA.z = g1.x; pA.w = g1.y;
    #pragma unroll
    for (int p = 0; p < 2; p++) {
      const int idx = p*256 + tid;
      const int col = idx >> 2, seg = idx & 3;
      const size_t off = (size_t)col*4096 + k0 + seg*8;
      pBh[p] = *reinterpret_cast<const uint4*>(pwh + off);
      pBl[p] = *reinterpret_cast<const uint4*>(pwl + off);
    }
  };

  loadstep(kbeg);
  for (int k0 = kbeg; k0 < kend; k0 += 32) {
    __syncthreads();   // previous MFMAs done reading LDS
    *reinterpret_cast<uint4*>(&sA[ar][aci*8]) = pA;
    #pragma unroll
    for (int p = 0; p < 2; p++) {
      const int idx = p*256 + tid;
      const int col = idx >> 2, seg = idx & 3;
      *reinterpret_cast<uint4*>(&sBh[col][seg*8]) = pBh[p];
      *reinterpret_cast<uint4*>(&sBl[col][seg*8]) = pBl[p];
    }
    __syncthreads();
    if (k0 + 32 < kend) loadstep(k0 + 32);   // prefetch overlaps MFMAs below
    short8v a = *reinterpret_cast<const short8v*>(&sA[w*16 + lr][lk*8]);
    #pragma unroll
    for (int ct = 0; ct < 8; ct++) {
      short8v bh = *reinterpret_cast<const short8v*>(&sBh[ct*16 + lr][lk*8]);
      short8v bv = *reinterpret_cast<const short8v*>(&sBl[ct*16 + lr][lk*8]);
      acc[ct] = __builtin_amdgcn_mfma_f32_16x16x32_bf16(a, bh, acc[ct], 0, 0, 0);
      acc[ct] = __builtin_amdgcn_mfma_f32_16x16x32_bf16(a, bv, acc[ct], 0, 0, 0);
    }
  }
  #pragma unroll
  for (int ct = 0; ct < 8; ct++) {
    const int col = ct*16 + lr;
    #pragma unroll
    for (int v = 0; v < 4; v++) {
      const int r = w*16 + lk*4 + v;
      if (r < rows)
        partial[(((size_t)kc*16 + b)*225 + n0 + r)*128 + col] = acc[ct][v];
    }
  }
}

// ---------------- reduce split-K partials + bias -> nodes
__global__ __launch_bounds__(128) void k_projr(
    const float* __restrict__ partial, const float* __restrict__ pb,
    float* __restrict__ nodes, int b0)
{
  const int n = blockIdx.x, bl = blockIdx.y;
  const int b = b0 + bl;
  const int d = threadIdx.x;
  float s = pb[d];
  #pragma unroll
  for (int kc = 0; kc < 4; kc++)
    s += partial[(((size_t)kc*16 + b)*225 + n)*128 + d];
  nodes[((size_t)b*225 + n)*128 + d] = s;
}

// ---------------- neighbor aggregation: a1/a2 per (b,node)
__global__ __launch_bounds__(128) void k_agg(
    const float* __restrict__ nodes, const int* __restrict__ nbr1,
    const u64* __restrict__ mask2,
    float* __restrict__ a1buf, float* __restrict__ a2buf)
{
  const int n = blockIdx.x, b = blockIdx.y;
  const int d = threadIdx.x;
  const float* nb = nodes + (size_t)b * 225 * 128;
  float a1 = 0.f;
  #pragma unroll
  for (int t = 0; t < 8; t++) a1 += nb[(size_t)nbr1[n*8+t]*128 + d];
  float a2 = 0.f;
  for (int wd = 0; wd < 4; wd++) {
    u64 m = mask2[n*4 + wd];
    while (m) {
      int j = wd*64 + __builtin_ctzll(m);
      a2 += nb[(size_t)j*128 + d];
      m &= m - 1;
    }
  }
  a1buf[((size_t)b*225 + n)*128 + d] = a1;
  a2buf[((size_t)b*225 + n)*128 + d] = a2;
}

// ---------------- z1/z2/gate/score batched: 15 nodes per block
__global__ __launch_bounds__(256) void k_gz(
    const float* __restrict__ a1buf, const float* __restrict__ a2buf,
    const float* __restrict__ w1t, const float* __restrict__ w1b,
    const float* __restrict__ w2t, const float* __restrict__ w2b,
    const float* __restrict__ gwt, const float* __restrict__ gb,
    const float* __restrict__ sw, const float* __restrict__ sb,
    float* __restrict__ zbuf, float* __restrict__ scores)
{
  __shared__ float sA1[15][128], sA2[15][128], sC[15][256], sRed[15][128];
  const int n0 = blockIdx.x * 15, b = blockIdx.y;
  const int tid = threadIdx.x;
  const int d = tid & 127, half = tid >> 7;
  const int r0 = half * 8, nr = half ? 7 : 8;

  for (int idx = tid; idx < 15*128; idx += 256) {
    const int r = idx >> 7, dd = idx & 127;
    sA1[r][dd] = a1buf[((size_t)b*225 + n0 + r)*128 + dd];
    sA2[r][dd] = a2buf[((size_t)b*225 + n0 + r)*128 + dd];
  }
  __syncthreads();

  float z1[8], z2[8];
  #pragma unroll
  for (int rr = 0; rr < 8; rr++) { z1[rr] = w1b[d]; z2[rr] = w2b[d]; }
  for (int k = 0; k < 128; k++) {
    const float wv1 = w1t[k*128 + d];
    const float wv2 = w2t[k*128 + d];
    #pragma unroll
    for (int rr = 0; rr < 8; rr++) {
      if (rr < nr) {
        z1[rr] += wv1 * sA1[r0 + rr][k];
        z2[rr] += wv2 * sA2[r0 + rr][k];
      }
    }
  }
  #pragma unroll
  for (int rr = 0; rr < 8; rr++) {
    if (rr < nr) { sC[r0+rr][d] = z1[rr]; sC[r0+rr][128+d] = z2[rr]; }
  }
  __syncthreads();
  float gl[8];
  #pragma unroll
  for (int rr = 0; rr < 8; rr++) gl[rr] = gb[d];
  for (int k = 0; k < 256; k++) {
    const float wv = gwt[k*128 + d];
    #pragma unroll
    for (int rr = 0; rr < 8; rr++)
      if (rr < nr) gl[rr] += wv * sC[r0 + rr][k];
  }
  const float swd = sw[d];
  #pragma unroll
  for (int rr = 0; rr < 8; rr++) {
    if (rr < nr) {
      const float gg = 1.f / (1.f + expf(-gl[rr]));
      const float zv = gg * z1[rr] + (1.f - gg) * z2[rr];
      zbuf[((size_t)b*225 + n0 + r0 + rr)*128 + d] = zv;
      sRed[r0+rr][d] = zv * swd;
    }
  }
  __syncthreads();
  const int r = tid >> 4, j = tid & 15;
  if (r < 15) {
    float part = 0.f;
    #pragma unroll
    for (int i = 0; i < 8; i++) part += sRed[r][j*8 + i];
    #pragma unroll
    for (int m = 8; m >= 1; m >>= 1) part += __shfl_xor(part, m, 64);
    if (j == 0) scores[b*225 + n0 + r] = part + sb[0];
  }
}

// ---------------- top-k (k=112) with jax tie semantics
__global__ __launch_bounds__(256) void k_topk(
    const float* __restrict__ scores, int* __restrict__ sel)
{
  __shared__ float ss[225];
  const int b = blockIdx.x, tid = threadIdx.x;
  if (tid < 112) sel[b*112 + tid] = tid;
  if (tid < 225) ss[tid] = scores[b*225 + tid];
  __syncthreads();
  if (tid < 225) {
    float s = ss[tid];
    int rank = 0;
    for (int j = 0; j < 225; j++) {
      float sj = ss[j];
      rank += (sj > s) || (sj == s && j < tid);
    }
    if (rank < 112) sel[b*112 + rank] = tid;
  }
}

// ---------------- qkv batched: 14 rows per block
__global__ __launch_bounds__(256) void k_qkv(
    const float* __restrict__ zbuf, const int* __restrict__ sel,
    const float* __restrict__ iwt, const float* __restrict__ ib,
    float* __restrict__ q, float* __restrict__ k, float* __restrict__ v)
{
  __shared__ float sx[14][128];
  const int s0 = blockIdx.x * 14, b = blockIdx.y;
  const int tid = threadIdx.x;
  const int c = tid & 127, half = tid >> 7;
  const int r0 = half * 7;

  for (int idx = tid; idx < 14*128; idx += 256) {
    const int r = idx >> 7, dd = idx & 127;
    int row = sel[b*112 + s0 + r];
    row = row < 0 ? 0 : (row > 224 ? 224 : row);
    sx[r][dd] = zbuf[((size_t)b*225 + row)*128 + dd];
  }
  __syncthreads();

  float acc[3][7];
  #pragma unroll
  for (int p = 0; p < 3; p++)
    #pragma unroll
    for (int rr = 0; rr < 7; rr++) acc[p][rr] = ib[p*128 + c];
  for (int kk = 0; kk < 128; kk++) {
    float wv[3];
    #pragma unroll
    for (int p = 0; p < 3; p++) wv[p] = iwt[kk*384 + p*128 + c];
    #pragma unroll
    for (int rr = 0; rr < 7; rr++) {
      const float xv = sx[r0 + rr][kk];
      #pragma unroll
      for (int p = 0; p < 3; p++) acc[p][rr] += wv[p] * xv;
    }
  }
  const int h = c >> 5, t = c & 31;
  float* outs[3] = {q, k, v};
  #pragma unroll
  for (int p = 0; p < 3; p++)
    #pragma unroll
    for (int rr = 0; rr < 7; rr++)
      outs[p][(((size_t)b*4 + h)*112 + s0 + r0 + rr)*32 + t] = acc[p][rr];
}

// ---------------- attention per (b, head), two-pass softmax
__global__ __launch_bounds__(128) void k_attn(
    const float* __restrict__ q, const float* __restrict__ k,
    const float* __restrict__ v, float* __restrict__ o)
{
  __shared__ float sK[112*32], sV[112*32];
  const int h = blockIdx.x, b = blockIdx.y, tid = threadIdx.x;
  const size_t base = ((size_t)b*4 + h) * 112 * 32;
  for (int i = tid; i < 112*32; i += 128) {
    sK[i] = k[base + i];
    sV[i] = v[base + i];
  }
  __syncthreads();
  if (tid < 112) {
    float qv[32];
    const float* qp = q + base + (size_t)tid*32;
    #pragma unroll
    for (int t = 0; t < 32; t++) qv[t] = qp[t];
    const float scale = 0.17677669529663687f;
    float mx = -INFINITY;
    for (int j = 0; j < 112; j++) {
      float s = 0.f;
      #pragma unroll
      for (int t = 0; t < 32; t++) s += qv[t] * sK[j*32 + t];
      mx = fmaxf(mx, s * scale);
    }
    float acc[32];
    #pragma unroll
    for (int t = 0; t < 32; t++) acc[t] = 0.f;
    float l = 0.f;
    for (int j = 0; j < 112; j++) {
      float s = 0.f;
      #pragma unroll
      for (int t = 0; t < 32; t++) s += qv[t] * sK[j*32 + t];
      float p = expf(s * scale - mx);
      l += p;
      #pragma unroll
      for (int t = 0; t < 32; t++) acc[t] += p * sV[j*32 + t];
    }
    float inv = 1.f / l;
    float* op = o + ((size_t)b*112 + tid)*128 + h*32;
    #pragma unroll
    for (int t = 0; t < 32; t++) op[t] = acc[t] * inv;
  }
}

// ---------------- out-proj + residual + LN1, batched 14 rows/block
__global__ __launch_bounds__(256) void k_oln(
    const float* __restrict__ o, const float* __restrict__ zbuf,
    const int* __restrict__ sel,
    const float* __restrict__ owt, const float* __restrict__ ob,
    const float* __restrict__ lg, const float* __restrict__ lb,
    float* __restrict__ h1)
{
  __shared__ float sO[14][128], sV[14][128];
  __shared__ float sMean[14], sRstd[14];
  const int s0 = blockIdx.x * 14, b = blockIdx.y;
  const int tid = threadIdx.x;
  const int d = tid & 127, half = tid >> 7;
  const int r0 = half * 7;

  for (int idx = tid; idx < 14*128; idx += 256) {
    const int r = idx >> 7, dd = idx & 127;
    sO[r][dd] = o[((size_t)b*112 + s0 + r)*128 + dd];
  }
  __syncthreads();

  float acc[7];
  #pragma unroll
  for (int rr = 0; rr < 7; rr++) acc[rr] = ob[d];
  for (int kk = 0; kk < 128; kk++) {
    const float wv = owt[kk*128 + d];
    #pragma unroll
    for (int rr = 0; rr < 7; rr++) acc[rr] += wv * sO[r0 + rr][kk];
  }
  #pragma unroll
  for (int rr = 0; rr < 7; rr++) {
    int row = sel[b*112 + s0 + r0 + rr];
    row = row < 0 ? 0 : (row > 224 ? 224 : row);
    acc[rr] += zbuf[((size_t)b*225 + row)*128 + d];
    sV[r0 + rr][d] = acc[rr];
  }
  __syncthreads();
  {
    const int r = tid >> 4, j = tid & 15;
    if (r < 14) {
      float p1 = 0.f, p2 = 0.f;
      #pragma unroll
      for (int i = 0; i < 8; i++) { float v = sV[r][j*8 + i]; p1 += v; p2 += v*v; }
      #pragma unroll
      for (int m = 8; m >= 1; m >>= 1) {
        p1 += __shfl_xor(p1, m, 64);
        p2 += __shfl_xor(p2, m, 64);
      }
      if (j == 0) {
        const float mean = p1 * (1.f/128.f);
        sMean[r] = mean;
        sRstd[r] = rsqrtf(p2 * (1.f/128.f) - mean*mean + 1e-5f);
      }
    }
  }
  __syncthreads();
  for (int idx = tid; idx < 14*128; idx += 256) {
    const int r = idx >> 7, dd = idx & 127;
    h1[((size_t)b*112 + s0 + r)*128 + dd] =
        (sV[r][dd] - sMean[r]) * sRstd[r] * lg[dd] + lb[dd];
  }
}

// ---------------- FFN + residual + LN2, batched 14 rows/block (in-place safe)
__global__ __launch_bounds__(256) void k_ffn(
    const float* __restrict__ h1,
    const float* __restrict__ f1wt, const float* __restrict__ f1b,
    const float* __restrict__ f2wt, const float* __restrict__ f2b,
    const float* __restrict__ lg, const float* __restrict__ lb,
    float* __restrict__ h2)
{
  __shared__ float sh[14][128];
  __shared__ float sf[14][512];
  __shared__ float sV[14][128];
  __shared__ float sMean[14], sRstd[14];
  const int s0 = blockIdx.x * 14, b = blockIdx.y;
  const int tid = threadIdx.x;
  const int d = tid & 127, half = tid >> 7;
  const int r0 = half * 7;

  for (int idx = tid; idx < 14*128; idx += 256) {
    const int r = idx >> 7, dd = idx & 127;
    sh[r][dd] = h1[((size_t)b*112 + s0 + r)*128 + dd];
  }
  __syncthreads();
  {
    float a0[14], a1[14];
    const float b0 = f1b[tid], b1 = f1b[tid + 256];
    #pragma unroll
    for (int r = 0; r < 14; r++) { a0[r] = b0; a1[r] = b1; }
    for (int kk = 0; kk < 128; kk++) {
      const float w0 = f1wt[kk*512 + tid];
      const float w1 = f1wt[kk*512 + tid + 256];
      #pragma unroll
      for (int r = 0; r < 14; r++) {
        const float xv = sh[r][kk];
        a0[r] += w0 * xv;
        a1[r] += w1 * xv;
      }
    }
    #pragma unroll
    for (int r = 0; r < 14; r++) {
      sf[r][tid]       = fmaxf(a0[r], 0.f);
      sf[r][tid + 256] = fmaxf(a1[r], 0.f);
    }
  }
  __syncthreads();
  {
    float acc[7];
    #pragma unroll
    for (int rr = 0; rr < 7; rr++) acc[rr] = f2b[d];
    for (int kk = 0; kk < 512; kk++) {
      const float wv = f2wt[kk*128 + d];
      #pragma unroll
      for (int rr = 0; rr < 7; rr++) acc[rr] += wv * sf[r0 + rr][kk];
    }
    #pragma unroll
    for (int rr = 0; rr < 7; rr++)
      sV[r0 + rr][d] = sh[r0 + rr][d] + acc[rr];
  }
  __syncthreads();
  {
    const int r = tid >> 4, j = tid & 15;
    if (r < 14) {
      float p1 = 0.f, p2 = 0.f;
      #pragma unroll
      for (int i = 0; i < 8; i++) { float v = sV[r][j*8 + i]; p1 += v; p2 += v*v; }
      #pragma unroll
      for (int m = 8; m >= 1; m >>= 1) {
        p1 += __shfl_xor(p1, m, 64);
        p2 += __shfl_xor(p2, m, 64);
      }
      if (j == 0) {
        const float mean = p1 * (1.f/128.f);
        sMean[r] = mean;
        sRstd[r] = rsqrtf(p2 * (1.f/128.f) - mean*mean + 1e-5f);
      }
    }
  }
  __syncthreads();
  for (int idx = tid; idx < 14*128; idx += 256) {
    const int r = idx >> 7, dd = idx & 127;
    h2[((size_t)b*112 + s0 + r)*128 + dd] =
        (sV[r][dd] - sMean[r]) * sRstd[r] * lg[dd] + lb[dd];
  }
}

// ---------------- rep = sum_s h2 ; classifier -> logits (f32)
__global__ __launch_bounds__(64) void k_cls(
    const float* __restrict__ h2,
    const float* __restrict__ c1w, const float* __restrict__ c1b,
    const float* __restrict__ c2w, const float* __restrict__ c2b,
    float* __restrict__ out)
{
  __shared__ float sr[128], sc[64];
  const int b = blockIdx.x, tid = threadIdx.x;
  float r0 = 0.f, r1 = 0.f;
  for (int s2 = 0; s2 < 112; s2++) {
    const float* row = h2 + ((size_t)b*112 + s2)*128;
    r0 += row[tid];
    r1 += row[tid + 64];
  }
  sr[tid] = r0; sr[tid + 64] = r1;
  __syncthreads();
  float acc = c1b[tid];
  const float* wr = c1w + (size_t)tid * 128;
  for (int kk = 0; kk < 128; kk++) acc += wr[kk] * sr[kk];
  sc[tid] = fmaxf(acc, 0.f);
  __syncthreads();
  if (tid < 2) {
    float l = c2b[tid];
    for (int kk = 0; kk < 64; kk++) l += c2w[tid*64 + kk] * sc[kk];
    out[b*2 + tid] = l;
  }
}

extern "C" void kernel_launch(void* const* d_in, const int* in_sizes, int n_in,
                              void* d_out, int out_size, void* d_ws, size_t ws_size,
                              hipStream_t stream)
{
  const float* x    = (const float*)d_in[0];
  const float* c1w  = (const float*)d_in[1];
  const float* c1b  = (const float*)d_in[2];
  const float* bn1g = (const float*)d_in[3];
  const float* bn1b = (const float*)d_in[4];
  const float* c2w  = (const float*)d_in[5];
  const float* c2b  = (const float*)d_in[6];
  const float* bn2g = (const float*)d_in[7];
  const float* bn2b = (const float*)d_in[8];
  const float* pjw  = (const float*)d_in[9];
  const float* pjb  = (const float*)d_in[10];
  const float* w1w  = (const float*)d_in[11];
  const float* w1b  = (const float*)d_in[12];
  const float* w2w  = (const float*)d_in[13];
  const float* w2b  = (const float*)d_in[14];
  const float* gw   = (const float*)d_in[15];
  const float* gb   = (const float*)d_in[16];
  const float* scw  = (const float*)d_in[17];
  const float* scb  = (const float*)d_in[18];
  const float* ipw  = (const float*)d_in[19];
  const float* ipb  = (const float*)d_in[20];
  const float* opw  = (const float*)d_in[21];
  const float* opb  = (const float*)d_in[22];
  const float* f1w  = (const float*)d_in[23];
  const float* f1b  = (const float*)d_in[24];
  const float* f2w  = (const float*)d_in[25];
  const float* f2b  = (const float*)d_in[26];
  const float* l1g  = (const float*)d_in[27];
  const float* l1b  = (const float*)d_in[28];
  const float* l2g  = (const float*)d_in[29];
  const float* l2b  = (const float*)d_in[30];
  const float* cl1w = (const float*)d_in[31];
  const float* cl1b = (const float*)d_in[32];
  const float* cl2w = (const float*)d_in[33];
  const float* cl2b = (const float*)d_in[34];

  // ---- bump allocator over d_ws (256-B aligned) ----
  char* p = (char*)d_ws;
  auto alloc = [&](size_t n) { char* r = p; p += (n + 255) & ~(size_t)255; return r; };
  u64*   mask2  = (u64*)  alloc(900    * sizeof(u64));
  int*   nbr1   = (int*)  alloc(1800   * sizeof(int));
  int*   sel    = (int*)  alloc(1792   * sizeof(int));
  float* scores = (float*)alloc(3600   * sizeof(float));
  u16*   pwh    = (u16*)  alloc(524288 * sizeof(u16));
  u16*   pwl    = (u16*)  alloc(524288 * sizeof(u16));
  u16*   wc2h   = (u16*)  alloc(36864  * sizeof(u16));
  u16*   wc2l   = (u16*)  alloc(36864  * sizeof(u16));
  float* iwt    = (float*)alloc(49152  * sizeof(float));
  float* owt    = (float*)alloc(16384  * sizeof(float));
  float* f1wt   = (float*)alloc(65536  * sizeof(float));
  float* f2wt   = (float*)alloc(65536  * sizeof(float));
  float* w1t    = (float*)alloc(16384  * sizeof(float));
  float* w2t    = (float*)alloc(16384  * sizeof(float));
  float* gwt    = (float*)alloc(32768  * sizeof(float));
  float* partial= (float*)alloc(4ull*16*225*128 * sizeof(float));  // 7.37 MB split-K
  float* a1buf  = (float*)alloc(460800 * sizeof(float));
  float* a2buf  = (float*)alloc(460800 * sizeof(float));
  float* zbuf   = (float*)alloc(460800 * sizeof(float));
  float* nodes  = (float*)alloc(460800 * sizeof(float));
  const size_t fixed_bytes = (size_t)(p - (char*)d_ws);

  const size_t qkv_bytes = 3ull * 229376ull * sizeof(float);
  const size_t per_batch = 64ull*128*128*2 + 64ull*64*64*2;   // 2,621,440 B
  int BC = 16;
  size_t s3 = 0;
  for (;; BC >>= 1) {
    s3 = (size_t)BC * per_batch; if (s3 < qkv_bytes) s3 = qkv_bytes;
    if (fixed_bytes + s3 + 65536 <= ws_size) break;
    if (BC == 1) { return; }
  }
  char* S3 = alloc(s3);

  u16*   feat1 = (u16*)S3;                              // NHWC (BC,128,128,64)
  u16*   feat2 = (u16*)(S3 + (size_t)BC * 2097152ull);  // NCHW (BC,64,64,64)
  float* qb    = (float*)S3;
  float* kb    = qb + 229376;
  float* vb    = kb + 229376;
  float* obuf  = nodes;
  float* hbuf  = nodes + 229376;

  k_adj  <<<1, 256, 0, stream>>>(nbr1, mask2);
  k_cvtw <<<512, 256, 0, stream>>>(pjw, pwh, pwl);
  k_cvtw2<<<144, 256, 0, stream>>>(c2w, bn2g, wc2h, wc2l);
  k_wt   <<<192, 256, 0, stream>>>(ipw, iwt, 384, 128);
  k_wt   <<<64,  256, 0, stream>>>(opw, owt, 128, 128);
  k_wt   <<<256, 256, 0, stream>>>(f1w, f1wt, 512, 128);
  k_wt   <<<256, 256, 0, stream>>>(f2w, f2wt, 128, 512);
  k_wt   <<<64,  256, 0, stream>>>(w1w, w1t, 128, 128);
  k_wt   <<<64,  256, 0, stream>>>(w2w, w2t, 128, 128);
  k_wt   <<<128, 256, 0, stream>>>(gw,  gwt, 128, 256);

  for (int b0 = 0; b0 < 16; b0 += BC) {
    k_conv1 <<<dim3(8,8,BC), 256, 0, stream>>>(x, c1w, c1b, bn1g, bn1b, feat1, b0);
    k_conv2m<<<dim3(4,8,BC), 256, 0, stream>>>(feat1, wc2h, wc2l, c2b, bn2g, bn2b, feat2);
    k_projm <<<dim3(4,4,BC), 256, 0, stream>>>(feat2, pwh, pwl, partial, b0);
    k_projr <<<dim3(225,BC), 128, 0, stream>>>(partial, pjb, nodes, b0);
  }

  k_agg  <<<dim3(225,16), 128, 0, stream>>>(nodes, nbr1, mask2, a1buf, a2buf);
  k_gz   <<<dim3(15,16), 256, 0, stream>>>(a1buf, a2buf, w1t, w1b, w2t, w2b,
                                           gwt, gb, scw, scb, zbuf, scores);
  k_topk <<<16, 256, 0, stream>>>(scores, sel);
  k_qkv  <<<dim3(8,16), 256, 0, stream>>>(zbuf, sel, iwt, ipb, qb, kb, vb);
  k_attn <<<dim3(4,16), 128, 0, stream>>>(qb, kb, vb, obuf);
  k_oln  <<<dim3(8,16), 256, 0, stream>>>(obuf, zbuf, sel, owt, opb, l1g, l1b, hbuf);
  k_ffn  <<<dim3(8,16), 256, 0, stream>>>(hbuf, f1wt, f1b, f2wt, f2b, l2g, l2b, hbuf);
  k_cls  <<<16, 64, 0, stream>>>(hbuf, cl1w, cl1b, cl2w, cl2b, (float*)d_out);
}

// Round 10
// 454.946 us; speedup vs baseline: 3.7760x; 1.1534x over previous
//
#include <hip/hip_runtime.h>
#include <hip/hip_bf16.h>
#include <math.h>

typedef unsigned short u16;
typedef unsigned int   u32;
typedef unsigned long long u64;
typedef __attribute__((ext_vector_type(8))) short short8v;
typedef __attribute__((ext_vector_type(4))) float f32x4;

__device__ __forceinline__ float bf2f(u16 u) {
  union { u32 i; float f; } v; v.i = ((u32)u) << 16; return v.f;
}
__device__ __forceinline__ u16 f2bf(float f) {  // round-to-nearest-even
  union { float f; u32 i; } v; v.f = f;
  u32 r = (v.i + 0x7FFFu + ((v.i >> 16) & 1u)) >> 16;
  return (u16)r;
}

// ---------------- conv1 + bn1 + relu + maxpool2 : (16,3,256,256)f32 -> (BC,128,128,64) NHWC bf16
__global__ __launch_bounds__(256) void k_conv1(
    const float* __restrict__ x, const float* __restrict__ w,
    const float* __restrict__ cb, const float* __restrict__ g, const float* __restrict__ bb,
    u16* __restrict__ feat1, int b0)
{
  __shared__ __align__(16) char sMem[36864];   // union: sIn (13872 B) then sOut (36864 B)
  float* sIn = (float*)sMem;                   // [3][34][34]
  u16 (*sOut)[72] = (u16(*)[72])sMem;          // [256][72]
  __shared__ float sW[64][27];
  __shared__ float sB[64];
  const int bl = blockIdx.z, ty = blockIdx.y, tx = blockIdx.x;
  const int b = b0 + bl;
  const int tid = threadIdx.x;
  for (int i = tid; i < 64*27; i += 256) {
    int oc = i / 27;
    float sc = g[oc] * rsqrtf(1.0f + 1e-5f);
    sW[oc][i % 27] = w[i] * sc;
  }
  if (tid < 64) {
    float sc = g[tid] * rsqrtf(1.0f + 1e-5f);
    sB[tid] = cb[tid] * sc + bb[tid];
  }
  const int iy0 = ty*32 - 1, ix0 = tx*32 - 1;
  for (int i = tid; i < 3*34*34; i += 256) {
    int c = i / (34*34); int r = (i / 34) % 34; int q = i % 34;
    int yy = iy0 + r, xx = ix0 + q;
    float v = 0.f;
    if (yy >= 0 && xx >= 0 && yy < 256 && xx < 256)
      v = x[(((size_t)b*3 + c)*256 + yy)*256 + xx];
    sIn[(c*34 + r)*34 + q] = v;
  }
  __syncthreads();
  const int py = tid >> 4, px = tid & 15;
  float win[3][4][4];
  #pragma unroll
  for (int c = 0; c < 3; c++)
    #pragma unroll
    for (int r = 0; r < 4; r++)
      #pragma unroll
      for (int q = 0; q < 4; q++)
        win[c][r][q] = sIn[(c*34 + 2*py + r)*34 + 2*px + q];
  __syncthreads();            // sIn consumed; sOut may overwrite
  u16 pend = 0;
  for (int oc = 0; oc < 64; oc++) {
    float s00=0.f, s01=0.f, s10=0.f, s11=0.f;
    #pragma unroll
    for (int c = 0; c < 3; c++)
      #pragma unroll
      for (int ky = 0; ky < 3; ky++)
        #pragma unroll
        for (int kx = 0; kx < 3; kx++) {
          float wv = sW[oc][(c*3+ky)*3+kx];
          s00 += win[c][ky  ][kx  ] * wv;
          s01 += win[c][ky  ][kx+1] * wv;
          s10 += win[c][ky+1][kx  ] * wv;
          s11 += win[c][ky+1][kx+1] * wv;
        }
    float m = fmaxf(fmaxf(s00,s01), fmaxf(s10,s11)) + sB[oc];
    u16 cur = f2bf(fmaxf(m, 0.f));
    if (oc & 1) {
      u32 pk = (u32)pend | ((u32)cur << 16);
      *reinterpret_cast<u32*>(&sOut[tid][oc - 1]) = pk;
    } else pend = cur;
  }
  __syncthreads();
  const int oy0 = ty*16, ox0 = tx*16;
  #pragma unroll
  for (int it = 0; it < 8; it++) {
    const int i4 = it*256 + tid;
    const int oc8 = i4 & 7, p2 = (i4 >> 3) & 15, r = i4 >> 7;
    uint4 v = *reinterpret_cast<const uint4*>(&sOut[r*16 + p2][oc8*8]);
    *reinterpret_cast<uint4*>(
        feat1 + (((size_t)bl*128 + oy0 + r)*128 + ox0 + p2)*64 + oc8*8) = v;
  }
}

// ---------------- conv2 weights f32 OIHW -> bf16 hi/lo [ky*3+kx][chunk][oc][icL], bn-scaled
__global__ __launch_bounds__(256) void k_cvtw2(
    const float* __restrict__ w, const float* __restrict__ g,
    u16* __restrict__ wh, u16* __restrict__ wl)
{
  const int d = blockIdx.x * 256 + threadIdx.x;      // 36864 total
  if (d >= 36864) return;
  const int icL = d & 31, oc = (d >> 5) & 63, chunk = (d >> 11) & 1, kk = d >> 12;
  const float sc = g[oc] * rsqrtf(1.0f + 1e-5f);
  const float val = w[((size_t)oc*64 + chunk*32 + icL)*9 + kk] * sc;
  const u16 hb = f2bf(val);
  wh[d] = hb;
  wl[d] = f2bf(val - bf2f(hb));
}

// ---------------- conv2 + bn2 + relu + maxpool2 via MFMA implicit GEMM
__global__ __launch_bounds__(256, 2) void k_conv2m(
    const u16* __restrict__ feat1,
    const u16* __restrict__ wh, const u16* __restrict__ wl,
    const float* __restrict__ cb, const float* __restrict__ g, const float* __restrict__ bb,
    u16* __restrict__ feat2)
{
  __shared__ __align__(16) u16 sA[18*34*40];
  __shared__ __align__(16) u16 sBh[64*40], sBl[64*40];
  __shared__ float sBias[64];
  const int tx = blockIdx.x, ty = blockIdx.y, bl = blockIdx.z;
  const int y0 = ty*16, x0 = tx*32;
  const int tid = threadIdx.x;
  const int w = tid >> 6, l = tid & 63;
  const int lr = l & 15, lk = l >> 4;

  if (tid < 64) {
    float sc = g[tid] * rsqrtf(1.0f + 1e-5f);
    sBias[tid] = cb[tid] * sc + bb[tid];
  }

  f32x4 acc[8][4];
  #pragma unroll
  for (int j = 0; j < 8; j++)
    #pragma unroll
    for (int ct = 0; ct < 4; ct++)
      acc[j][ct] = (f32x4){0.f,0.f,0.f,0.f};

  for (int chunk = 0; chunk < 2; chunk++) {
    __syncthreads();
    for (int idx = tid; idx < 612*4; idx += 256) {
      const int pix = idx >> 2, seg = idx & 3;
      const int r = pix / 34, cc = pix % 34;
      const int yy = y0 - 1 + r, xx = x0 - 1 + cc;
      uint4 v = {0u,0u,0u,0u};
      if (yy >= 0 && yy < 128 && xx >= 0 && xx < 128)
        v = *reinterpret_cast<const uint4*>(
              feat1 + (((size_t)bl*128 + yy)*128 + xx)*64 + chunk*32 + seg*8);
      *reinterpret_cast<uint4*>(&sA[(size_t)(r*34 + cc)*40 + seg*8]) = v;
    }
    for (int kk = 0; kk < 9; kk++) {
      __syncthreads();
      {
        const int oc = tid >> 2, s8 = (tid & 3)*8;
        const size_t src = (size_t)(kk*2 + chunk)*2048 + tid*8;
        *reinterpret_cast<uint4*>(&sBh[oc*40 + s8]) = *reinterpret_cast<const uint4*>(wh + src);
        *reinterpret_cast<uint4*>(&sBl[oc*40 + s8]) = *reinterpret_cast<const uint4*>(wl + src);
      }
      __syncthreads();
      const int ky = kk / 3, kx = kk % 3;
      short8v a[8];
      #pragma unroll
      for (int j = 0; j < 8; j++) {
        const int m = w*8 + j;
        const int r = (m >> 1) + ky;
        const int cc = (m & 1)*16 + lr + kx;
        a[j] = *reinterpret_cast<const short8v*>(&sA[(size_t)(r*34 + cc)*40 + lk*8]);
      }
      #pragma unroll
      for (int ct = 0; ct < 4; ct++) {
        const short8v bh = *reinterpret_cast<const short8v*>(&sBh[(ct*16 + lr)*40 + lk*8]);
        const short8v bv = *reinterpret_cast<const short8v*>(&sBl[(ct*16 + lr)*40 + lk*8]);
        #pragma unroll
        for (int j = 0; j < 8; j++) {
          acc[j][ct] = __builtin_amdgcn_mfma_f32_16x16x32_bf16(a[j], bh, acc[j][ct], 0, 0, 0);
          acc[j][ct] = __builtin_amdgcn_mfma_f32_16x16x32_bf16(a[j], bv, acc[j][ct], 0, 0, 0);
        }
      }
    }
  }
  #pragma unroll
  for (int u = 0; u < 2; u++) {
    #pragma unroll
    for (int xh = 0; xh < 2; xh++) {
      const int jA = 4*u + xh, jB = 4*u + 2 + xh;
      #pragma unroll
      for (int ct = 0; ct < 4; ct++) {
        const int oc = ct*16 + lr;
        const float bias = sBias[oc];
        const float v0 = fmaxf(fmaxf(acc[jA][ct][0], acc[jA][ct][1]),
                               fmaxf(acc[jB][ct][0], acc[jB][ct][1]));
        const float v1 = fmaxf(fmaxf(acc[jA][ct][2], acc[jA][ct][3]),
                               fmaxf(acc[jB][ct][2], acc[jB][ct][3]));
        const u16 b0v = f2bf(fmaxf(v0 + bias, 0.f));
        const u16 b1v = f2bf(fmaxf(v1 + bias, 0.f));
        const int py = ty*8 + 2*w + u;
        const int px = tx*16 + xh*8 + lk*2;
        u32 pk = (u32)b0v | ((u32)b1v << 16);
        *reinterpret_cast<u32*>(&feat2[(((size_t)bl*64 + oc)*64 + py)*64 + px]) = pk;
      }
    }
  }
}

// ---------------- adjacency (input-independent, 1 block)
__global__ __launch_bounds__(256) void k_adj(int* __restrict__ nbr1, u64* __restrict__ mask2)
{
  __shared__ int snbr[225][8];
  const int i = threadIdx.x;
  if (i < 225) {
    const int ii = i / 15, jj = i % 15;
    int bd[8], bj[8];
    #pragma unroll
    for (int t = 0; t < 8; t++) { bd[t] = 1<<30; bj[t] = -1; }
    for (int j = 0; j < 225; j++) {
      if (j == i) continue;
      int di = ii - j/15, dj = jj - j%15;
      int d2 = di*di + dj*dj;
      if (d2 < bd[7]) {
        int p = 7;
        while (p > 0 && d2 < bd[p-1]) { bd[p]=bd[p-1]; bj[p]=bj[p-1]; p--; }
        bd[p] = d2; bj[p] = j;
      }
    }
    #pragma unroll
    for (int t = 0; t < 8; t++) { snbr[i][t] = bj[t]; nbr1[i*8+t] = bj[t]; }
  }
  __syncthreads();
  if (i < 225) {
    u64 m[4] = {0,0,0,0};
    #pragma unroll
    for (int t = 0; t < 8; t++) {
      int tt = snbr[i][t];
      #pragma unroll
      for (int u = 0; u < 8; u++) {
        int j = snbr[tt][u];
        m[j >> 6] |= 1ull << (j & 63);
      }
    }
    m[i >> 6] &= ~(1ull << (i & 63));
    #pragma unroll
    for (int wd = 0; wd < 4; wd++) mask2[i*4 + wd] = m[wd];
  }
}

// ---------------- split proj_w (f32) -> hi/lo bf16
__global__ __launch_bounds__(256) void k_cvtw(
    const float* __restrict__ pw, u16* __restrict__ pwh, u16* __restrict__ pwl)
{
  const int i = (blockIdx.x * 256 + threadIdx.x) * 4;
  float4 v = *reinterpret_cast<const float4*>(pw + i);
  float e[4] = {v.x, v.y, v.z, v.w};
  ushort4 h, l;
  u16* hp = &h.x; u16* lp = &l.x;
  #pragma unroll
  for (int j = 0; j < 4; j++) {
    u16 hb = f2bf(e[j]);
    hp[j] = hb;
    lp[j] = f2bf(e[j] - bf2f(hb));
  }
  *reinterpret_cast<ushort4*>(pwh + i) = h;
  *reinterpret_cast<ushort4*>(pwl + i) = l;
}

// ---------------- generic weight transpose [O][K] -> [K][O]
__global__ __launch_bounds__(256) void k_wt(
    const float* __restrict__ src, float* __restrict__ dst, int O, int K)
{
  const int idx = blockIdx.x * 256 + threadIdx.x;
  if (idx >= O * K) return;
  const int o = idx / K, k = idx % K;
  dst[(size_t)k * O + o] = src[idx];
}

// ---------------- patch-projection MFMA GEMM, split-K=4 + register prefetch
__global__ __launch_bounds__(256, 2) void k_projm(
    const u16* __restrict__ feat2,
    const u16* __restrict__ pwh, const u16* __restrict__ pwl,
    float* __restrict__ partial, int b0)
{
  __shared__ __align__(16) u16 sA [64][40];
  __shared__ __align__(16) u16 sBh[128][40];
  __shared__ __align__(16) u16 sBl[128][40];
  const int cx = blockIdx.x, kc = blockIdx.y, bl = blockIdx.z;
  const int b  = b0 + bl;
  const int n0 = cx * 64;
  const int rows = (225 - n0) < 64 ? (225 - n0) : 64;
  const int tid = threadIdx.x;
  const int w = tid >> 6, l = tid & 63;
  const int lr = l & 15, lk = l >> 4;

  f32x4 acc[8];
  #pragma unroll
  for (int i = 0; i < 8; i++) acc[i] = (f32x4){0.f, 0.f, 0.f, 0.f};

  const int ar = tid >> 2, aci = tid & 3;
  const int an = n0 + ar;
  const int aph = an / 15, apw = an % 15;
  const int kbeg = kc * 1024, kend = kbeg + 1024;

  uint4 pA, pBh[2], pBl[2];
  auto loadstep = [&](int k0) {
    const int c  = k0 >> 6;
    const int i0 = (k0 & 63) >> 3;
    uint2 g0 = {0u,0u}, g1 = {0u,0u};
    if (ar < rows) {
      const u16* src = feat2 + (((size_t)bl*64 + c)*64 + aph*4 + i0 + aci)*64 + apw*4;
      g0 = *reinterpret_cast<const uint2*>(src);
      g1 = *reinterpret_cast<const uint2*>(src + 4);
    }
    pA.x = g0.x; pA.y = g0.y; pA.z = g1.x; pA.w = g1.y;
    #pragma unroll
    for (int p = 0; p < 2; p++) {
      const int idx = p*256 + tid;
      const int col = idx >> 2, seg = idx & 3;
      const size_t off = (size_t)col*4096 + k0 + seg*8;
      pBh[p] = *reinterpret_cast<const uint4*>(pwh + off);
      pBl[p] = *reinterpret_cast<const uint4*>(pwl + off);
    }
  };

  loadstep(kbeg);
  for (int k0 = kbeg; k0 < kend; k0 += 32) {
    __syncthreads();
    *reinterpret_cast<uint4*>(&sA[ar][aci*8]) = pA;
    #pragma unroll
    for (int p = 0; p < 2; p++) {
      const int idx = p*256 + tid;
      const int col = idx >> 2, seg = idx & 3;
      *reinterpret_cast<uint4*>(&sBh[col][seg*8]) = pBh[p];
      *reinterpret_cast<uint4*>(&sBl[col][seg*8]) = pBl[p];
    }
    __syncthreads();
    if (k0 + 32 < kend) loadstep(k0 + 32);
    short8v a = *reinterpret_cast<const short8v*>(&sA[w*16 + lr][lk*8]);
    #pragma unroll
    for (int ct = 0; ct < 8; ct++) {
      short8v bh = *reinterpret_cast<const short8v*>(&sBh[ct*16 + lr][lk*8]);
      short8v bv = *reinterpret_cast<const short8v*>(&sBl[ct*16 + lr][lk*8]);
      acc[ct] = __builtin_amdgcn_mfma_f32_16x16x32_bf16(a, bh, acc[ct], 0, 0, 0);
      acc[ct] = __builtin_amdgcn_mfma_f32_16x16x32_bf16(a, bv, acc[ct], 0, 0, 0);
    }
  }
  #pragma unroll
  for (int ct = 0; ct < 8; ct++) {
    const int col = ct*16 + lr;
    #pragma unroll
    for (int v = 0; v < 4; v++) {
      const int r = w*16 + lk*4 + v;
      if (r < rows)
        partial[(((size_t)kc*16 + b)*225 + n0 + r)*128 + col] = acc[ct][v];
    }
  }
}

// ---------------- reduce split-K partials + bias -> nodes
__global__ __launch_bounds__(128) void k_projr(
    const float* __restrict__ partial, const float* __restrict__ pb,
    float* __restrict__ nodes, int b0)
{
  const int n = blockIdx.x, bl = blockIdx.y;
  const int b = b0 + bl;
  const int d = threadIdx.x;
  float s = pb[d];
  #pragma unroll
  for (int kc = 0; kc < 4; kc++)
    s += partial[(((size_t)kc*16 + b)*225 + n)*128 + d];
  nodes[((size_t)b*225 + n)*128 + d] = s;
}

// ---------------- neighbor aggregation: a1/a2 per (b,node)
__global__ __launch_bounds__(128) void k_agg(
    const float* __restrict__ nodes, const int* __restrict__ nbr1,
    const u64* __restrict__ mask2,
    float* __restrict__ a1buf, float* __restrict__ a2buf)
{
  const int n = blockIdx.x, b = blockIdx.y;
  const int d = threadIdx.x;
  const float* nb = nodes + (size_t)b * 225 * 128;
  float a1 = 0.f;
  #pragma unroll
  for (int t = 0; t < 8; t++) a1 += nb[(size_t)nbr1[n*8+t]*128 + d];
  float a2 = 0.f;
  for (int wd = 0; wd < 4; wd++) {
    u64 m = mask2[n*4 + wd];
    while (m) {
      int j = wd*64 + __builtin_ctzll(m);
      a2 += nb[(size_t)j*128 + d];
      m &= m - 1;
    }
  }
  a1buf[((size_t)b*225 + n)*128 + d] = a1;
  a2buf[((size_t)b*225 + n)*128 + d] = a2;
}

// ---------------- z1/z2/gate/score: 2 rows per block (1800 blocks -> high TLP)
__global__ __launch_bounds__(256) void k_gz(
    const float* __restrict__ a1buf, const float* __restrict__ a2buf,
    const float* __restrict__ w1t, const float* __restrict__ w1b,
    const float* __restrict__ w2t, const float* __restrict__ w2b,
    const float* __restrict__ gwt, const float* __restrict__ gb,
    const float* __restrict__ sw, const float* __restrict__ sb,
    float* __restrict__ zbuf, float* __restrict__ scores)
{
  __shared__ float sA1[2][128], sA2[2][128], sC[2][256], sRed[2][128];
  const int row0 = blockIdx.x * 2;           // global row = b*225 + n
  const int tid = threadIdx.x;
  const int d = tid & 127, rr = tid >> 7;
  const int row = row0 + rr;
  sA1[rr][d] = a1buf[(size_t)row*128 + d];
  sA2[rr][d] = a2buf[(size_t)row*128 + d];
  __syncthreads();
  float z1 = w1b[d], z2 = w2b[d];
  #pragma unroll 4
  for (int k = 0; k < 128; k++) {
    z1 += w1t[k*128 + d] * sA1[rr][k];
    z2 += w2t[k*128 + d] * sA2[rr][k];
  }
  sC[rr][d] = z1; sC[rr][128 + d] = z2;
  __syncthreads();
  float gl = gb[d];
  #pragma unroll 4
  for (int k = 0; k < 256; k++)
    gl += gwt[k*128 + d] * sC[rr][k];
  const float gg = 1.f / (1.f + expf(-gl));
  const float zv = gg * z1 + (1.f - gg) * z2;
  zbuf[(size_t)row*128 + d] = zv;
  sRed[rr][d] = zv * sw[d];
  __syncthreads();
  if (tid < 32) {
    const int r = tid >> 4, j = tid & 15;
    float part = 0.f;
    #pragma unroll
    for (int i = 0; i < 8; i++) part += sRed[r][j*8 + i];
    #pragma unroll
    for (int m = 8; m >= 1; m >>= 1) part += __shfl_xor(part, m, 64);
    if (j == 0) scores[row0 + r] = part + sb[0];
  }
}

// ---------------- top-k (k=112) with jax tie semantics
__global__ __launch_bounds__(256) void k_topk(
    const float* __restrict__ scores, int* __restrict__ sel)
{
  __shared__ float ss[225];
  const int b = blockIdx.x, tid = threadIdx.x;
  if (tid < 112) sel[b*112 + tid] = tid;
  if (tid < 225) ss[tid] = scores[b*225 + tid];
  __syncthreads();
  if (tid < 225) {
    float s = ss[tid];
    int rank = 0;
    for (int j = 0; j < 225; j++) {
      float sj = ss[j];
      rank += (sj > s) || (sj == s && j < tid);
    }
    if (rank < 112) sel[b*112 + rank] = tid;
  }
}

// ---------------- qkv batched: 14 rows per block
__global__ __launch_bounds__(256) void k_qkv(
    const float* __restrict__ zbuf, const int* __restrict__ sel,
    const float* __restrict__ iwt, const float* __restrict__ ib,
    float* __restrict__ q, float* __restrict__ k, float* __restrict__ v)
{
  __shared__ float sx[14][128];
  const int s0 = blockIdx.x * 14, b = blockIdx.y;
  const int tid = threadIdx.x;
  const int c = tid & 127, half = tid >> 7;
  const int r0 = half * 7;

  for (int idx = tid; idx < 14*128; idx += 256) {
    const int r = idx >> 7, dd = idx & 127;
    int row = sel[b*112 + s0 + r];
    row = row < 0 ? 0 : (row > 224 ? 224 : row);
    sx[r][dd] = zbuf[((size_t)b*225 + row)*128 + dd];
  }
  __syncthreads();

  float acc[3][7];
  #pragma unroll
  for (int p = 0; p < 3; p++)
    #pragma unroll
    for (int rr = 0; rr < 7; rr++) acc[p][rr] = ib[p*128 + c];
  for (int kk = 0; kk < 128; kk++) {
    float wv[3];
    #pragma unroll
    for (int p = 0; p < 3; p++) wv[p] = iwt[kk*384 + p*128 + c];
    #pragma unroll
    for (int rr = 0; rr < 7; rr++) {
      const float xv = sx[r0 + rr][kk];
      #pragma unroll
      for (int p = 0; p < 3; p++) acc[p][rr] += wv[p] * xv;
    }
  }
  const int h = c >> 5, t = c & 31;
  float* outs[3] = {q, k, v};
  #pragma unroll
  for (int p = 0; p < 3; p++)
    #pragma unroll
    for (int rr = 0; rr < 7; rr++)
      outs[p][(((size_t)b*4 + h)*112 + s0 + r0 + rr)*32 + t] = acc[p][rr];
}

// ---------------- attention per (b, head), two-pass softmax
__global__ __launch_bounds__(128) void k_attn(
    const float* __restrict__ q, const float* __restrict__ k,
    const float* __restrict__ v, float* __restrict__ o)
{
  __shared__ float sK[112*32], sV[112*32];
  const int h = blockIdx.x, b = blockIdx.y, tid = threadIdx.x;
  const size_t base = ((size_t)b*4 + h) * 112 * 32;
  for (int i = tid; i < 112*32; i += 128) {
    sK[i] = k[base + i];
    sV[i] = v[base + i];
  }
  __syncthreads();
  if (tid < 112) {
    float qv[32];
    const float* qp = q + base + (size_t)tid*32;
    #pragma unroll
    for (int t = 0; t < 32; t++) qv[t] = qp[t];
    const float scale = 0.17677669529663687f;
    float mx = -INFINITY;
    for (int j = 0; j < 112; j++) {
      float s = 0.f;
      #pragma unroll
      for (int t = 0; t < 32; t++) s += qv[t] * sK[j*32 + t];
      mx = fmaxf(mx, s * scale);
    }
    float acc[32];
    #pragma unroll
    for (int t = 0; t < 32; t++) acc[t] = 0.f;
    float l = 0.f;
    for (int j = 0; j < 112; j++) {
      float s = 0.f;
      #pragma unroll
      for (int t = 0; t < 32; t++) s += qv[t] * sK[j*32 + t];
      float p = expf(s * scale - mx);
      l += p;
      #pragma unroll
      for (int t = 0; t < 32; t++) acc[t] += p * sV[j*32 + t];
    }
    float inv = 1.f / l;
    float* op = o + ((size_t)b*112 + tid)*128 + h*32;
    #pragma unroll
    for (int t = 0; t < 32; t++) op[t] = acc[t] * inv;
  }
}

// ---------------- out-proj + residual + LN1, batched 14 rows/block
__global__ __launch_bounds__(256) void k_oln(
    const float* __restrict__ o, const float* __restrict__ zbuf,
    const int* __restrict__ sel,
    const float* __restrict__ owt, const float* __restrict__ ob,
    const float* __restrict__ lg, const float* __restrict__ lb,
    float* __restrict__ h1)
{
  __shared__ float sO[14][128], sV[14][128];
  __shared__ float sMean[14], sRstd[14];
  const int s0 = blockIdx.x * 14, b = blockIdx.y;
  const int tid = threadIdx.x;
  const int d = tid & 127, half = tid >> 7;
  const int r0 = half * 7;

  for (int idx = tid; idx < 14*128; idx += 256) {
    const int r = idx >> 7, dd = idx & 127;
    sO[r][dd] = o[((size_t)b*112 + s0 + r)*128 + dd];
  }
  __syncthreads();

  float acc[7];
  #pragma unroll
  for (int rr = 0; rr < 7; rr++) acc[rr] = ob[d];
  for (int kk = 0; kk < 128; kk++) {
    const float wv = owt[kk*128 + d];
    #pragma unroll
    for (int rr = 0; rr < 7; rr++) acc[rr] += wv * sO[r0 + rr][kk];
  }
  #pragma unroll
  for (int rr = 0; rr < 7; rr++) {
    int row = sel[b*112 + s0 + r0 + rr];
    row = row < 0 ? 0 : (row > 224 ? 224 : row);
    acc[rr] += zbuf[((size_t)b*225 + row)*128 + d];
    sV[r0 + rr][d] = acc[rr];
  }
  __syncthreads();
  {
    const int r = tid >> 4, j = tid & 15;
    if (r < 14) {
      float p1 = 0.f, p2 = 0.f;
      #pragma unroll
      for (int i = 0; i < 8; i++) { float v = sV[r][j*8 + i]; p1 += v; p2 += v*v; }
      #pragma unroll
      for (int m = 8; m >= 1; m >>= 1) {
        p1 += __shfl_xor(p1, m, 64);
        p2 += __shfl_xor(p2, m, 64);
      }
      if (j == 0) {
        const float mean = p1 * (1.f/128.f);
        sMean[r] = mean;
        sRstd[r] = rsqrtf(p2 * (1.f/128.f) - mean*mean + 1e-5f);
      }
    }
  }
  __syncthreads();
  for (int idx = tid; idx < 14*128; idx += 256) {
    const int r = idx >> 7, dd = idx & 127;
    h1[((size_t)b*112 + s0 + r)*128 + dd] =
        (sV[r][dd] - sMean[r]) * sRstd[r] * lg[dd] + lb[dd];
  }
}

// ---------------- FFN + residual + LN2, batched 14 rows/block (in-place safe)
__global__ __launch_bounds__(256) void k_ffn(
    const float* __restrict__ h1,
    const float* __restrict__ f1wt, const float* __restrict__ f1b,
    const float* __restrict__ f2wt, const float* __restrict__ f2b,
    const float* __restrict__ lg, const float* __restrict__ lb,
    float* __restrict__ h2)
{
  __shared__ float sh[14][128];
  __shared__ float sf[14][512];
  __shared__ float sV[14][128];
  __shared__ float sMean[14], sRstd[14];
  const int s0 = blockIdx.x * 14, b = blockIdx.y;
  const int tid = threadIdx.x;
  const int d = tid & 127, half = tid >> 7;
  const int r0 = half * 7;

  for (int idx = tid; idx < 14*128; idx += 256) {
    const int r = idx >> 7, dd = idx & 127;
    sh[r][dd] = h1[((size_t)b*112 + s0 + r)*128 + dd];
  }
  __syncthreads();
  {
    float a0[14], a1[14];
    const float b0 = f1b[tid], b1 = f1b[tid + 256];
    #pragma unroll
    for (int r = 0; r < 14; r++) { a0[r] = b0; a1[r] = b1; }
    for (int kk = 0; kk < 128; kk++) {
      const float w0 = f1wt[kk*512 + tid];
      const float w1 = f1wt[kk*512 + tid + 256];
      #pragma unroll
      for (int r = 0; r < 14; r++) {
        const float xv = sh[r][kk];
        a0[r] += w0 * xv;
        a1[r] += w1 * xv;
      }
    }
    #pragma unroll
    for (int r = 0; r < 14; r++) {
      sf[r][tid]       = fmaxf(a0[r], 0.f);
      sf[r][tid + 256] = fmaxf(a1[r], 0.f);
    }
  }
  __syncthreads();
  {
    float acc[7];
    #pragma unroll
    for (int rr = 0; rr < 7; rr++) acc[rr] = f2b[d];
    for (int kk = 0; kk < 512; kk++) {
      const float wv = f2wt[kk*128 + d];
      #pragma unroll
      for (int rr = 0; rr < 7; rr++) acc[rr] += wv * sf[r0 + rr][kk];
    }
    #pragma unroll
    for (int rr = 0; rr < 7; rr++)
      sV[r0 + rr][d] = sh[r0 + rr][d] + acc[rr];
  }
  __syncthreads();
  {
    const int r = tid >> 4, j = tid & 15;
    if (r < 14) {
      float p1 = 0.f, p2 = 0.f;
      #pragma unroll
      for (int i = 0; i < 8; i++) { float v = sV[r][j*8 + i]; p1 += v; p2 += v*v; }
      #pragma unroll
      for (int m = 8; m >= 1; m >>= 1) {
        p1 += __shfl_xor(p1, m, 64);
        p2 += __shfl_xor(p2, m, 64);
      }
      if (j == 0) {
        const float mean = p1 * (1.f/128.f);
        sMean[r] = mean;
        sRstd[r] = rsqrtf(p2 * (1.f/128.f) - mean*mean + 1e-5f);
      }
    }
  }
  __syncthreads();
  for (int idx = tid; idx < 14*128; idx += 256) {
    const int r = idx >> 7, dd = idx & 127;
    h2[((size_t)b*112 + s0 + r)*128 + dd] =
        (sV[r][dd] - sMean[r]) * sRstd[r] * lg[dd] + lb[dd];
  }
}

// ---------------- rep = sum_s h2 ; classifier -> logits (f32)
__global__ __launch_bounds__(64) void k_cls(
    const float* __restrict__ h2,
    const float* __restrict__ c1w, const float* __restrict__ c1b,
    const float* __restrict__ c2w, const float* __restrict__ c2b,
    float* __restrict__ out)
{
  __shared__ float sr[128], sc[64];
  const int b = blockIdx.x, tid = threadIdx.x;
  float r0 = 0.f, r1 = 0.f;
  for (int s2 = 0; s2 < 112; s2++) {
    const float* row = h2 + ((size_t)b*112 + s2)*128;
    r0 += row[tid];
    r1 += row[tid + 64];
  }
  sr[tid] = r0; sr[tid + 64] = r1;
  __syncthreads();
  float acc = c1b[tid];
  const float* wr = c1w + (size_t)tid * 128;
  for (int kk = 0; kk < 128; kk++) acc += wr[kk] * sr[kk];
  sc[tid] = fmaxf(acc, 0.f);
  __syncthreads();
  if (tid < 2) {
    float l = c2b[tid];
    for (int kk = 0; kk < 64; kk++) l += c2w[tid*64 + kk] * sc[kk];
    out[b*2 + tid] = l;
  }
}

extern "C" void kernel_launch(void* const* d_in, const int* in_sizes, int n_in,
                              void* d_out, int out_size, void* d_ws, size_t ws_size,
                              hipStream_t stream)
{
  const float* x    = (const float*)d_in[0];
  const float* c1w  = (const float*)d_in[1];
  const float* c1b  = (const float*)d_in[2];
  const float* bn1g = (const float*)d_in[3];
  const float* bn1b = (const float*)d_in[4];
  const float* c2w  = (const float*)d_in[5];
  const float* c2b  = (const float*)d_in[6];
  const float* bn2g = (const float*)d_in[7];
  const float* bn2b = (const float*)d_in[8];
  const float* pjw  = (const float*)d_in[9];
  const float* pjb  = (const float*)d_in[10];
  const float* w1w  = (const float*)d_in[11];
  const float* w1b  = (const float*)d_in[12];
  const float* w2w  = (const float*)d_in[13];
  const float* w2b  = (const float*)d_in[14];
  const float* gw   = (const float*)d_in[15];
  const float* gb   = (const float*)d_in[16];
  const float* scw  = (const float*)d_in[17];
  const float* scb  = (const float*)d_in[18];
  const float* ipw  = (const float*)d_in[19];
  const float* ipb  = (const float*)d_in[20];
  const float* opw  = (const float*)d_in[21];
  const float* opb  = (const float*)d_in[22];
  const float* f1w  = (const float*)d_in[23];
  const float* f1b  = (const float*)d_in[24];
  const float* f2w  = (const float*)d_in[25];
  const float* f2b  = (const float*)d_in[26];
  const float* l1g  = (const float*)d_in[27];
  const float* l1b  = (const float*)d_in[28];
  const float* l2g  = (const float*)d_in[29];
  const float* l2b  = (const float*)d_in[30];
  const float* cl1w = (const float*)d_in[31];
  const float* cl1b = (const float*)d_in[32];
  const float* cl2w = (const float*)d_in[33];
  const float* cl2b = (const float*)d_in[34];

  // ---- bump allocator over d_ws (256-B aligned) ----
  char* p = (char*)d_ws;
  auto alloc = [&](size_t n) { char* r = p; p += (n + 255) & ~(size_t)255; return r; };
  u64*   mask2  = (u64*)  alloc(900    * sizeof(u64));
  int*   nbr1   = (int*)  alloc(1800   * sizeof(int));
  int*   sel    = (int*)  alloc(1792   * sizeof(int));
  float* scores = (float*)alloc(3600   * sizeof(float));
  u16*   pwh    = (u16*)  alloc(524288 * sizeof(u16));
  u16*   pwl    = (u16*)  alloc(524288 * sizeof(u16));
  u16*   wc2h   = (u16*)  alloc(36864  * sizeof(u16));
  u16*   wc2l   = (u16*)  alloc(36864  * sizeof(u16));
  float* iwt    = (float*)alloc(49152  * sizeof(float));
  float* owt    = (float*)alloc(16384  * sizeof(float));
  float* f1wt   = (float*)alloc(65536  * sizeof(float));
  float* f2wt   = (float*)alloc(65536  * sizeof(float));
  float* w1t    = (float*)alloc(16384  * sizeof(float));
  float* w2t    = (float*)alloc(16384  * sizeof(float));
  float* gwt    = (float*)alloc(32768  * sizeof(float));
  float* partial= (float*)alloc(4ull*16*225*128 * sizeof(float));  // 7.37 MB split-K
  float* a1buf  = (float*)alloc(460800 * sizeof(float));
  float* a2buf  = (float*)alloc(460800 * sizeof(float));
  float* zbuf   = (float*)alloc(460800 * sizeof(float));
  float* nodes  = (float*)alloc(460800 * sizeof(float));
  const size_t fixed_bytes = (size_t)(p - (char*)d_ws);

  const size_t qkv_bytes = 3ull * 229376ull * sizeof(float);
  const size_t per_batch = 64ull*128*128*2 + 64ull*64*64*2;   // 2,621,440 B
  int BC = 16;
  size_t s3 = 0;
  for (;; BC >>= 1) {
    s3 = (size_t)BC * per_batch; if (s3 < qkv_bytes) s3 = qkv_bytes;
    if (fixed_bytes + s3 + 65536 <= ws_size) break;
    if (BC == 1) { return; }
  }
  char* S3 = alloc(s3);

  u16*   feat1 = (u16*)S3;                              // NHWC (BC,128,128,64)
  u16*   feat2 = (u16*)(S3 + (size_t)BC * 2097152ull);  // NCHW (BC,64,64,64)
  float* qb    = (float*)S3;
  float* kb    = qb + 229376;
  float* vb    = kb + 229376;
  float* obuf  = nodes;
  float* hbuf  = nodes + 229376;

  k_adj  <<<1, 256, 0, stream>>>(nbr1, mask2);
  k_cvtw <<<512, 256, 0, stream>>>(pjw, pwh, pwl);
  k_cvtw2<<<144, 256, 0, stream>>>(c2w, bn2g, wc2h, wc2l);
  k_wt   <<<192, 256, 0, stream>>>(ipw, iwt, 384, 128);
  k_wt   <<<64,  256, 0, stream>>>(opw, owt, 128, 128);
  k_wt   <<<256, 256, 0, stream>>>(f1w, f1wt, 512, 128);
  k_wt   <<<256, 256, 0, stream>>>(f2w, f2wt, 128, 512);
  k_wt   <<<64,  256, 0, stream>>>(w1w, w1t, 128, 128);
  k_wt   <<<64,  256, 0, stream>>>(w2w, w2t, 128, 128);
  k_wt   <<<128, 256, 0, stream>>>(gw,  gwt, 128, 256);

  for (int b0 = 0; b0 < 16; b0 += BC) {
    k_conv1 <<<dim3(8,8,BC), 256, 0, stream>>>(x, c1w, c1b, bn1g, bn1b, feat1, b0);
    k_conv2m<<<dim3(4,8,BC), 256, 0, stream>>>(feat1, wc2h, wc2l, c2b, bn2g, bn2b, feat2);
    k_projm <<<dim3(4,4,BC), 256, 0, stream>>>(feat2, pwh, pwl, partial, b0);
    k_projr <<<dim3(225,BC), 128, 0, stream>>>(partial, pjb, nodes, b0);
  }

  k_agg  <<<dim3(225,16), 128, 0, stream>>>(nodes, nbr1, mask2, a1buf, a2buf);
  k_gz   <<<1800, 256, 0, stream>>>(a1buf, a2buf, w1t, w1b, w2t, w2b,
                                    gwt, gb, scw, scb, zbuf, scores);
  k_topk <<<16, 256, 0, stream>>>(scores, sel);
  k_qkv  <<<dim3(8,16), 256, 0, stream>>>(zbuf, sel, iwt, ipb, qb, kb, vb);
  k_attn <<<dim3(4,16), 128, 0, stream>>>(qb, kb, vb, obuf);
  k_oln  <<<dim3(8,16), 256, 0, stream>>>(obuf, zbuf, sel, owt, opb, l1g, l1b, hbuf);
  k_ffn  <<<dim3(8,16), 256, 0, stream>>>(hbuf, f1wt, f1b, f2wt, f2b, l2g, l2b, hbuf);
  k_cls  <<<16, 64, 0, stream>>>(hbuf, cl1w, cl1b, cl2w, cl2b, (float*)d_out);
}

// Round 11
// 363.885 us; speedup vs baseline: 4.7209x; 1.2502x over previous
//
#include <hip/hip_runtime.h>
#include <hip/hip_bf16.h>
#include <math.h>

typedef unsigned short u16;
typedef unsigned int   u32;
typedef unsigned long long u64;
typedef __attribute__((ext_vector_type(8))) short short8v;
typedef __attribute__((ext_vector_type(4))) float f32x4;

__device__ __forceinline__ float bf2f(u16 u) {
  union { u32 i; float f; } v; v.i = ((u32)u) << 16; return v.f;
}
__device__ __forceinline__ u16 f2bf(float f) {  // round-to-nearest-even
  union { float f; u32 i; } v; v.f = f;
  u32 r = (v.i + 0x7FFFu + ((v.i >> 16) & 1u)) >> 16;
  return (u16)r;
}

// ---------------- conv1 + bn1 + relu + maxpool2 : (16,3,256,256)f32 -> (BC,128,128,64) NHWC bf16
__global__ __launch_bounds__(256) void k_conv1(
    const float* __restrict__ x, const float* __restrict__ w,
    const float* __restrict__ cb, const float* __restrict__ g, const float* __restrict__ bb,
    u16* __restrict__ feat1, int b0)
{
  __shared__ __align__(16) char sMem[36864];   // union: sIn (13872 B) then sOut (36864 B)
  float* sIn = (float*)sMem;                   // [3][34][34]
  u16 (*sOut)[72] = (u16(*)[72])sMem;          // [256][72]
  __shared__ float sW[64][27];
  __shared__ float sB[64];
  const int bl = blockIdx.z, ty = blockIdx.y, tx = blockIdx.x;
  const int b = b0 + bl;
  const int tid = threadIdx.x;
  for (int i = tid; i < 64*27; i += 256) {
    int oc = i / 27;
    float sc = g[oc] * rsqrtf(1.0f + 1e-5f);
    sW[oc][i % 27] = w[i] * sc;
  }
  if (tid < 64) {
    float sc = g[tid] * rsqrtf(1.0f + 1e-5f);
    sB[tid] = cb[tid] * sc + bb[tid];
  }
  const int iy0 = ty*32 - 1, ix0 = tx*32 - 1;
  for (int i = tid; i < 3*34*34; i += 256) {
    int c = i / (34*34); int r = (i / 34) % 34; int q = i % 34;
    int yy = iy0 + r, xx = ix0 + q;
    float v = 0.f;
    if (yy >= 0 && xx >= 0 && yy < 256 && xx < 256)
      v = x[(((size_t)b*3 + c)*256 + yy)*256 + xx];
    sIn[(c*34 + r)*34 + q] = v;
  }
  __syncthreads();
  const int py = tid >> 4, px = tid & 15;
  float win[3][4][4];
  #pragma unroll
  for (int c = 0; c < 3; c++)
    #pragma unroll
    for (int r = 0; r < 4; r++)
      #pragma unroll
      for (int q = 0; q < 4; q++)
        win[c][r][q] = sIn[(c*34 + 2*py + r)*34 + 2*px + q];
  __syncthreads();            // sIn consumed; sOut may overwrite
  u16 pend = 0;
  for (int oc = 0; oc < 64; oc++) {
    float s00=0.f, s01=0.f, s10=0.f, s11=0.f;
    #pragma unroll
    for (int c = 0; c < 3; c++)
      #pragma unroll
      for (int ky = 0; ky < 3; ky++)
        #pragma unroll
        for (int kx = 0; kx < 3; kx++) {
          float wv = sW[oc][(c*3+ky)*3+kx];
          s00 += win[c][ky  ][kx  ] * wv;
          s01 += win[c][ky  ][kx+1] * wv;
          s10 += win[c][ky+1][kx  ] * wv;
          s11 += win[c][ky+1][kx+1] * wv;
        }
    float m = fmaxf(fmaxf(s00,s01), fmaxf(s10,s11)) + sB[oc];
    u16 cur = f2bf(fmaxf(m, 0.f));
    if (oc & 1) {
      u32 pk = (u32)pend | ((u32)cur << 16);
      *reinterpret_cast<u32*>(&sOut[tid][oc - 1]) = pk;
    } else pend = cur;
  }
  __syncthreads();
  const int oy0 = ty*16, ox0 = tx*16;
  #pragma unroll
  for (int it = 0; it < 8; it++) {
    const int i4 = it*256 + tid;
    const int oc8 = i4 & 7, p2 = (i4 >> 3) & 15, r = i4 >> 7;
    uint4 v = *reinterpret_cast<const uint4*>(&sOut[r*16 + p2][oc8*8]);
    *reinterpret_cast<uint4*>(
        feat1 + (((size_t)bl*128 + oy0 + r)*128 + ox0 + p2)*64 + oc8*8) = v;
  }
}

// ---------------- conv2 + bn2 + relu + maxpool2 via MFMA implicit GEMM
__global__ __launch_bounds__(256, 2) void k_conv2m(
    const u16* __restrict__ feat1,
    const u16* __restrict__ wh, const u16* __restrict__ wl,
    const float* __restrict__ cb, const float* __restrict__ g, const float* __restrict__ bb,
    u16* __restrict__ feat2)
{
  __shared__ __align__(16) u16 sA[18*34*40];
  __shared__ __align__(16) u16 sBh[64*40], sBl[64*40];
  __shared__ float sBias[64];
  const int tx = blockIdx.x, ty = blockIdx.y, bl = blockIdx.z;
  const int y0 = ty*16, x0 = tx*32;
  const int tid = threadIdx.x;
  const int w = tid >> 6, l = tid & 63;
  const int lr = l & 15, lk = l >> 4;

  if (tid < 64) {
    float sc = g[tid] * rsqrtf(1.0f + 1e-5f);
    sBias[tid] = cb[tid] * sc + bb[tid];
  }

  f32x4 acc[8][4];
  #pragma unroll
  for (int j = 0; j < 8; j++)
    #pragma unroll
    for (int ct = 0; ct < 4; ct++)
      acc[j][ct] = (f32x4){0.f,0.f,0.f,0.f};

  for (int chunk = 0; chunk < 2; chunk++) {
    __syncthreads();
    for (int idx = tid; idx < 612*4; idx += 256) {
      const int pix = idx >> 2, seg = idx & 3;
      const int r = pix / 34, cc = pix % 34;
      const int yy = y0 - 1 + r, xx = x0 - 1 + cc;
      uint4 v = {0u,0u,0u,0u};
      if (yy >= 0 && yy < 128 && xx >= 0 && xx < 128)
        v = *reinterpret_cast<const uint4*>(
              feat1 + (((size_t)bl*128 + yy)*128 + xx)*64 + chunk*32 + seg*8);
      *reinterpret_cast<uint4*>(&sA[(size_t)(r*34 + cc)*40 + seg*8]) = v;
    }
    for (int kk = 0; kk < 9; kk++) {
      __syncthreads();
      {
        const int oc = tid >> 2, s8 = (tid & 3)*8;
        const size_t src = (size_t)(kk*2 + chunk)*2048 + tid*8;
        *reinterpret_cast<uint4*>(&sBh[oc*40 + s8]) = *reinterpret_cast<const uint4*>(wh + src);
        *reinterpret_cast<uint4*>(&sBl[oc*40 + s8]) = *reinterpret_cast<const uint4*>(wl + src);
      }
      __syncthreads();
      const int ky = kk / 3, kx = kk % 3;
      short8v a[8];
      #pragma unroll
      for (int j = 0; j < 8; j++) {
        const int m = w*8 + j;
        const int r = (m >> 1) + ky;
        const int cc = (m & 1)*16 + lr + kx;
        a[j] = *reinterpret_cast<const short8v*>(&sA[(size_t)(r*34 + cc)*40 + lk*8]);
      }
      #pragma unroll
      for (int ct = 0; ct < 4; ct++) {
        const short8v bh = *reinterpret_cast<const short8v*>(&sBh[(ct*16 + lr)*40 + lk*8]);
        const short8v bv = *reinterpret_cast<const short8v*>(&sBl[(ct*16 + lr)*40 + lk*8]);
        #pragma unroll
        for (int j = 0; j < 8; j++) {
          acc[j][ct] = __builtin_amdgcn_mfma_f32_16x16x32_bf16(a[j], bh, acc[j][ct], 0, 0, 0);
          acc[j][ct] = __builtin_amdgcn_mfma_f32_16x16x32_bf16(a[j], bv, acc[j][ct], 0, 0, 0);
        }
      }
    }
  }
  #pragma unroll
  for (int u = 0; u < 2; u++) {
    #pragma unroll
    for (int xh = 0; xh < 2; xh++) {
      const int jA = 4*u + xh, jB = 4*u + 2 + xh;
      #pragma unroll
      for (int ct = 0; ct < 4; ct++) {
        const int oc = ct*16 + lr;
        const float bias = sBias[oc];
        const float v0 = fmaxf(fmaxf(acc[jA][ct][0], acc[jA][ct][1]),
                               fmaxf(acc[jB][ct][0], acc[jB][ct][1]));
        const float v1 = fmaxf(fmaxf(acc[jA][ct][2], acc[jA][ct][3]),
                               fmaxf(acc[jB][ct][2], acc[jB][ct][3]));
        const u16 b0v = f2bf(fmaxf(v0 + bias, 0.f));
        const u16 b1v = f2bf(fmaxf(v1 + bias, 0.f));
        const int py = ty*8 + 2*w + u;
        const int px = tx*16 + xh*8 + lk*2;
        u32 pk = (u32)b0v | ((u32)b1v << 16);
        *reinterpret_cast<u32*>(&feat2[(((size_t)bl*64 + oc)*64 + py)*64 + px]) = pk;
      }
    }
  }
}

// ---------------- adjacency phase 1: 8-NN per node, 225 blocks (stable (d2,j) order)
__global__ __launch_bounds__(256) void k_adj1(int* __restrict__ nbr1)
{
  __shared__ int skey[256];
  __shared__ int sred[256];
  const int i = blockIdx.x;
  const int tid = threadIdx.x;
  int key = 0x7FFFFFFF;
  if (tid < 225 && tid != i) {
    const int di = i/15 - tid/15, dj = i%15 - tid%15;
    key = (di*di + dj*dj)*256 + tid;   // lexicographic (d2, j) == stable argsort
  }
  skey[tid] = key;
  __syncthreads();
  for (int t = 0; t < 8; t++) {
    sred[tid] = skey[tid];
    __syncthreads();
    #pragma unroll
    for (int st = 128; st > 0; st >>= 1) {
      if (tid < st) sred[tid] = min(sred[tid], sred[tid+st]);
      __syncthreads();
    }
    const int wj = sred[0] & 255;
    if (tid == 0) nbr1[i*8 + t] = wj;
    __syncthreads();
    if (tid == wj) skey[tid] = 0x7FFFFFFF;
    __syncthreads();
  }
}

// ---------------- adjacency phase 2: mask2 = rows of (adj@adj>0) minus diagonal
__global__ __launch_bounds__(256) void k_adj2(
    const int* __restrict__ nbr1, u64* __restrict__ mask2)
{
  const int i = threadIdx.x;
  if (i >= 225) return;
  u64 m0=0, m1=0, m2=0, m3=0;
  #pragma unroll
  for (int t = 0; t < 8; t++) {
    const int tt = nbr1[i*8 + t];
    #pragma unroll
    for (int u = 0; u < 8; u++) {
      const int j = nbr1[tt*8 + u];
      const u64 bset = 1ull << (j & 63);
      const int wd = j >> 6;
      m0 |= (wd == 0) ? bset : 0ull;
      m1 |= (wd == 1) ? bset : 0ull;
      m2 |= (wd == 2) ? bset : 0ull;
      m3 |= (wd == 3) ? bset : 0ull;
    }
  }
  {
    const u64 bc = ~(1ull << (i & 63));
    const int wd = i >> 6;
    if (wd == 0) m0 &= bc; else if (wd == 1) m1 &= bc;
    else if (wd == 2) m2 &= bc; else m3 &= bc;
  }
  mask2[i*4+0] = m0; mask2[i*4+1] = m1; mask2[i*4+2] = m2; mask2[i*4+3] = m3;
}

// ---------------- fused weight prep: proj hi/lo split, conv2 hi/lo split, all transposes
__global__ __launch_bounds__(256) void k_prep(
    const float* __restrict__ pjw, u16* __restrict__ pwh, u16* __restrict__ pwl,
    const float* __restrict__ c2w, const float* __restrict__ bn2g,
    u16* __restrict__ wc2h, u16* __restrict__ wc2l,
    const float* __restrict__ ipw, float* __restrict__ iwt,
    const float* __restrict__ opw, float* __restrict__ owt,
    const float* __restrict__ f1w, float* __restrict__ f1wt,
    const float* __restrict__ f2w, float* __restrict__ f2wt,
    const float* __restrict__ w1w, float* __restrict__ w1t,
    const float* __restrict__ w2w, float* __restrict__ w2t,
    const float* __restrict__ gw,  float* __restrict__ gwt)
{
  const int blk = blockIdx.x, tid = threadIdx.x;
  if (blk < 512) {                       // proj_w f32 -> hi/lo bf16 (x4 elements)
    const int i = (blk*256 + tid) * 4;
    float4 v = *reinterpret_cast<const float4*>(pjw + i);
    float e[4] = {v.x, v.y, v.z, v.w};
    ushort4 h, l;
    u16* hp = &h.x; u16* lp = &l.x;
    #pragma unroll
    for (int j = 0; j < 4; j++) {
      u16 hb = f2bf(e[j]);
      hp[j] = hb;
      lp[j] = f2bf(e[j] - bf2f(hb));
    }
    *reinterpret_cast<ushort4*>(pwh + i) = h;
    *reinterpret_cast<ushort4*>(pwl + i) = l;
  } else if (blk < 656) {                // conv2 weights, bn-scaled hi/lo
    const int d = (blk - 512)*256 + tid;
    if (d < 36864) {
      const int icL = d & 31, oc = (d >> 5) & 63, chunk = (d >> 11) & 1, kk = d >> 12;
      const float sc = bn2g[oc] * rsqrtf(1.0f + 1e-5f);
      const float val = c2w[((size_t)oc*64 + chunk*32 + icL)*9 + kk] * sc;
      const u16 hb = f2bf(val);
      wc2h[d] = hb;
      wc2l[d] = f2bf(val - bf2f(hb));
    }
  } else {                               // transposes [O][K] -> [K][O]
    const float* src; float* dst; int O, K, base;
    if      (blk <  848) { src = ipw; dst = iwt;  O = 384; K = 128; base = 656;  }
    else if (blk <  912) { src = opw; dst = owt;  O = 128; K = 128; base = 848;  }
    else if (blk < 1168) { src = f1w; dst = f1wt; O = 512; K = 128; base = 912;  }
    else if (blk < 1424) { src = f2w; dst = f2wt; O = 128; K = 512; base = 1168; }
    else if (blk < 1488) { src = w1w; dst = w1t;  O = 128; K = 128; base = 1424; }
    else if (blk < 1552) { src = w2w; dst = w2t;  O = 128; K = 128; base = 1488; }
    else                 { src = gw;  dst = gwt;  O = 128; K = 256; base = 1552; }
    const int idx = (blk - base)*256 + tid;
    if (idx < O * K) {
      const int o = idx / K, k = idx % K;
      dst[(size_t)k * O + o] = src[idx];
    }
  }
}

// ---------------- patch-projection MFMA GEMM, split-K=4 + register prefetch
__global__ __launch_bounds__(256, 2) void k_projm(
    const u16* __restrict__ feat2,
    const u16* __restrict__ pwh, const u16* __restrict__ pwl,
    float* __restrict__ partial, int b0)
{
  __shared__ __align__(16) u16 sA [64][40];
  __shared__ __align__(16) u16 sBh[128][40];
  __shared__ __align__(16) u16 sBl[128][40];
  const int cx = blockIdx.x, kc = blockIdx.y, bl = blockIdx.z;
  const int b  = b0 + bl;
  const int n0 = cx * 64;
  const int rows = (225 - n0) < 64 ? (225 - n0) : 64;
  const int tid = threadIdx.x;
  const int w = tid >> 6, l = tid & 63;
  const int lr = l & 15, lk = l >> 4;

  f32x4 acc[8];
  #pragma unroll
  for (int i = 0; i < 8; i++) acc[i] = (f32x4){0.f, 0.f, 0.f, 0.f};

  const int ar = tid >> 2, aci = tid & 3;
  const int an = n0 + ar;
  const int aph = an / 15, apw = an % 15;
  const int kbeg = kc * 1024, kend = kbeg + 1024;

  uint4 pA, pBh[2], pBl[2];
  auto loadstep = [&](int k0) {
    const int c  = k0 >> 6;
    const int i0 = (k0 & 63) >> 3;
    uint2 g0 = {0u,0u}, g1 = {0u,0u};
    if (ar < rows) {
      const u16* src = feat2 + (((size_t)bl*64 + c)*64 + aph*4 + i0 + aci)*64 + apw*4;
      g0 = *reinterpret_cast<const uint2*>(src);
      g1 = *reinterpret_cast<const uint2*>(src + 4);
    }
    pA.x = g0.x; pA.y = g0.y; pA.z = g1.x; pA.w = g1.y;
    #pragma unroll
    for (int p = 0; p < 2; p++) {
      const int idx = p*256 + tid;
      const int col = idx >> 2, seg = idx & 3;
      const size_t off = (size_t)col*4096 + k0 + seg*8;
      pBh[p] = *reinterpret_cast<const uint4*>(pwh + off);
      pBl[p] = *reinterpret_cast<const uint4*>(pwl + off);
    }
  };

  loadstep(kbeg);
  for (int k0 = kbeg; k0 < kend; k0 += 32) {
    __syncthreads();
    *reinterpret_cast<uint4*>(&sA[ar][aci*8]) = pA;
    #pragma unroll
    for (int p = 0; p < 2; p++) {
      const int idx = p*256 + tid;
      const int col = idx >> 2, seg = idx & 3;
      *reinterpret_cast<uint4*>(&sBh[col][seg*8]) = pBh[p];
      *reinterpret_cast<uint4*>(&sBl[col][seg*8]) = pBl[p];
    }
    __syncthreads();
    if (k0 + 32 < kend) loadstep(k0 + 32);
    short8v a = *reinterpret_cast<const short8v*>(&sA[w*16 + lr][lk*8]);
    #pragma unroll
    for (int ct = 0; ct < 8; ct++) {
      short8v bh = *reinterpret_cast<const short8v*>(&sBh[ct*16 + lr][lk*8]);
      short8v bv = *reinterpret_cast<const short8v*>(&sBl[ct*16 + lr][lk*8]);
      acc[ct] = __builtin_amdgcn_mfma_f32_16x16x32_bf16(a, bh, acc[ct], 0, 0, 0);
      acc[ct] = __builtin_amdgcn_mfma_f32_16x16x32_bf16(a, bv, acc[ct], 0, 0, 0);
    }
  }
  #pragma unroll
  for (int ct = 0; ct < 8; ct++) {
    const int col = ct*16 + lr;
    #pragma unroll
    for (int v = 0; v < 4; v++) {
      const int r = w*16 + lk*4 + v;
      if (r < rows)
        partial[(((size_t)kc*16 + b)*225 + n0 + r)*128 + col] = acc[ct][v];
    }
  }
}

// ---------------- reduce split-K partials + bias -> nodes
__global__ __launch_bounds__(128) void k_projr(
    const float* __restrict__ partial, const float* __restrict__ pb,
    float* __restrict__ nodes, int b0)
{
  const int n = blockIdx.x, bl = blockIdx.y;
  const int b = b0 + bl;
  const int d = threadIdx.x;
  float s = pb[d];
  #pragma unroll
  for (int kc = 0; kc < 4; kc++)
    s += partial[(((size_t)kc*16 + b)*225 + n)*128 + d];
  nodes[((size_t)b*225 + n)*128 + d] = s;
}

// ---------------- neighbor aggregation: a1/a2 per (b,node)
__global__ __launch_bounds__(128) void k_agg(
    const float* __restrict__ nodes, const int* __restrict__ nbr1,
    const u64* __restrict__ mask2,
    float* __restrict__ a1buf, float* __restrict__ a2buf)
{
  const int n = blockIdx.x, b = blockIdx.y;
  const int d = threadIdx.x;
  const float* nb = nodes + (size_t)b * 225 * 128;
  float a1 = 0.f;
  #pragma unroll
  for (int t = 0; t < 8; t++) a1 += nb[(size_t)nbr1[n*8+t]*128 + d];
  float a2 = 0.f;
  for (int wd = 0; wd < 4; wd++) {
    u64 m = mask2[n*4 + wd];
    while (m) {
      int j = wd*64 + __builtin_ctzll(m);
      a2 += nb[(size_t)j*128 + d];
      m &= m - 1;
    }
  }
  a1buf[((size_t)b*225 + n)*128 + d] = a1;
  a2buf[((size_t)b*225 + n)*128 + d] = a2;
}

// ---------------- z1/z2/gate/score: 2 rows per block (1800 blocks -> high TLP)
__global__ __launch_bounds__(256) void k_gz(
    const float* __restrict__ a1buf, const float* __restrict__ a2buf,
    const float* __restrict__ w1t, const float* __restrict__ w1b,
    const float* __restrict__ w2t, const float* __restrict__ w2b,
    const float* __restrict__ gwt, const float* __restrict__ gb,
    const float* __restrict__ sw, const float* __restrict__ sb,
    float* __restrict__ zbuf, float* __restrict__ scores)
{
  __shared__ float sA1[2][128], sA2[2][128], sC[2][256], sRed[2][128];
  const int row0 = blockIdx.x * 2;
  const int tid = threadIdx.x;
  const int d = tid & 127, rr = tid >> 7;
  const int row = row0 + rr;
  sA1[rr][d] = a1buf[(size_t)row*128 + d];
  sA2[rr][d] = a2buf[(size_t)row*128 + d];
  __syncthreads();
  float z1 = w1b[d], z2 = w2b[d];
  #pragma unroll 4
  for (int k = 0; k < 128; k++) {
    z1 += w1t[k*128 + d] * sA1[rr][k];
    z2 += w2t[k*128 + d] * sA2[rr][k];
  }
  sC[rr][d] = z1; sC[rr][128 + d] = z2;
  __syncthreads();
  float gl = gb[d];
  #pragma unroll 4
  for (int k = 0; k < 256; k++)
    gl += gwt[k*128 + d] * sC[rr][k];
  const float gg = 1.f / (1.f + expf(-gl));
  const float zv = gg * z1 + (1.f - gg) * z2;
  zbuf[(size_t)row*128 + d] = zv;
  sRed[rr][d] = zv * sw[d];
  __syncthreads();
  if (tid < 32) {
    const int r = tid >> 4, j = tid & 15;
    float part = 0.f;
    #pragma unroll
    for (int i = 0; i < 8; i++) part += sRed[r][j*8 + i];
    #pragma unroll
    for (int m = 8; m >= 1; m >>= 1) part += __shfl_xor(part, m, 64);
    if (j == 0) scores[row0 + r] = part + sb[0];
  }
}

// ---------------- top-k (k=112) with jax tie semantics
__global__ __launch_bounds__(256) void k_topk(
    const float* __restrict__ scores, int* __restrict__ sel)
{
  __shared__ float ss[225];
  const int b = blockIdx.x, tid = threadIdx.x;
  if (tid < 112) sel[b*112 + tid] = tid;
  if (tid < 225) ss[tid] = scores[b*225 + tid];
  __syncthreads();
  if (tid < 225) {
    float s = ss[tid];
    int rank = 0;
    for (int j = 0; j < 225; j++) {
      float sj = ss[j];
      rank += (sj > s) || (sj == s && j < tid);
    }
    if (rank < 112) sel[b*112 + rank] = tid;
  }
}

// ---------------- qkv batched: 14 rows per block
__global__ __launch_bounds__(256) void k_qkv(
    const float* __restrict__ zbuf, const int* __restrict__ sel,
    const float* __restrict__ iwt, const float* __restrict__ ib,
    float* __restrict__ q, float* __restrict__ k, float* __restrict__ v)
{
  __shared__ float sx[14][128];
  const int s0 = blockIdx.x * 14, b = blockIdx.y;
  const int tid = threadIdx.x;
  const int c = tid & 127, half = tid >> 7;
  const int r0 = half * 7;

  for (int idx = tid; idx < 14*128; idx += 256) {
    const int r = idx >> 7, dd = idx & 127;
    int row = sel[b*112 + s0 + r];
    row = row < 0 ? 0 : (row > 224 ? 224 : row);
    sx[r][dd] = zbuf[((size_t)b*225 + row)*128 + dd];
  }
  __syncthreads();

  float acc[3][7];
  #pragma unroll
  for (int p = 0; p < 3; p++)
    #pragma unroll
    for (int rr = 0; rr < 7; rr++) acc[p][rr] = ib[p*128 + c];
  for (int kk = 0; kk < 128; kk++) {
    float wv[3];
    #pragma unroll
    for (int p = 0; p < 3; p++) wv[p] = iwt[kk*384 + p*128 + c];
    #pragma unroll
    for (int rr = 0; rr < 7; rr++) {
      const float xv = sx[r0 + rr][kk];
      #pragma unroll
      for (int p = 0; p < 3; p++) acc[p][rr] += wv[p] * xv;
    }
  }
  const int h = c >> 5, t = c & 31;
  float* outs[3] = {q, k, v};
  #pragma unroll
  for (int p = 0; p < 3; p++)
    #pragma unroll
    for (int rr = 0; rr < 7; rr++)
      outs[p][(((size_t)b*4 + h)*112 + s0 + r0 + rr)*32 + t] = acc[p][rr];
}

// ---------------- attention per (b, head), two-pass softmax
__global__ __launch_bounds__(128) void k_attn(
    const float* __restrict__ q, const float* __restrict__ k,
    const float* __restrict__ v, float* __restrict__ o)
{
  __shared__ float sK[112*32], sV[112*32];
  const int h = blockIdx.x, b = blockIdx.y, tid = threadIdx.x;
  const size_t base = ((size_t)b*4 + h) * 112 * 32;
  for (int i = tid; i < 112*32; i += 128) {
    sK[i] = k[base + i];
    sV[i] = v[base + i];
  }
  __syncthreads();
  if (tid < 112) {
    float qv[32];
    const float* qp = q + base + (size_t)tid*32;
    #pragma unroll
    for (int t = 0; t < 32; t++) qv[t] = qp[t];
    const float scale = 0.17677669529663687f;
    float mx = -INFINITY;
    for (int j = 0; j < 112; j++) {
      float s = 0.f;
      #pragma unroll
      for (int t = 0; t < 32; t++) s += qv[t] * sK[j*32 + t];
      mx = fmaxf(mx, s * scale);
    }
    float acc[32];
    #pragma unroll
    for (int t = 0; t < 32; t++) acc[t] = 0.f;
    float l = 0.f;
    for (int j = 0; j < 112; j++) {
      float s = 0.f;
      #pragma unroll
      for (int t = 0; t < 32; t++) s += qv[t] * sK[j*32 + t];
      float p = expf(s * scale - mx);
      l += p;
      #pragma unroll
      for (int t = 0; t < 32; t++) acc[t] += p * sV[j*32 + t];
    }
    float inv = 1.f / l;
    float* op = o + ((size_t)b*112 + tid)*128 + h*32;
    #pragma unroll
    for (int t = 0; t < 32; t++) op[t] = acc[t] * inv;
  }
}

// ---------------- out-proj + residual + LN1, batched 14 rows/block
__global__ __launch_bounds__(256) void k_oln(
    const float* __restrict__ o, const float* __restrict__ zbuf,
    const int* __restrict__ sel,
    const float* __restrict__ owt, const float* __restrict__ ob,
    const float* __restrict__ lg, const float* __restrict__ lb,
    float* __restrict__ h1)
{
  __shared__ float sO[14][128], sV[14][128];
  __shared__ float sMean[14], sRstd[14];
  const int s0 = blockIdx.x * 14, b = blockIdx.y;
  const int tid = threadIdx.x;
  const int d = tid & 127, half = tid >> 7;
  const int r0 = half * 7;

  for (int idx = tid; idx < 14*128; idx += 256) {
    const int r = idx >> 7, dd = idx & 127;
    sO[r][dd] = o[((size_t)b*112 + s0 + r)*128 + dd];
  }
  __syncthreads();

  float acc[7];
  #pragma unroll
  for (int rr = 0; rr < 7; rr++) acc[rr] = ob[d];
  for (int kk = 0; kk < 128; kk++) {
    const float wv = owt[kk*128 + d];
    #pragma unroll
    for (int rr = 0; rr < 7; rr++) acc[rr] += wv * sO[r0 + rr][kk];
  }
  #pragma unroll
  for (int rr = 0; rr < 7; rr++) {
    int row = sel[b*112 + s0 + r0 + rr];
    row = row < 0 ? 0 : (row > 224 ? 224 : row);
    acc[rr] += zbuf[((size_t)b*225 + row)*128 + d];
    sV[r0 + rr][d] = acc[rr];
  }
  __syncthreads();
  {
    const int r = tid >> 4, j = tid & 15;
    if (r < 14) {
      float p1 = 0.f, p2 = 0.f;
      #pragma unroll
      for (int i = 0; i < 8; i++) { float v = sV[r][j*8 + i]; p1 += v; p2 += v*v; }
      #pragma unroll
      for (int m = 8; m >= 1; m >>= 1) {
        p1 += __shfl_xor(p1, m, 64);
        p2 += __shfl_xor(p2, m, 64);
      }
      if (j == 0) {
        const float mean = p1 * (1.f/128.f);
        sMean[r] = mean;
        sRstd[r] = rsqrtf(p2 * (1.f/128.f) - mean*mean + 1e-5f);
      }
    }
  }
  __syncthreads();
  for (int idx = tid; idx < 14*128; idx += 256) {
    const int r = idx >> 7, dd = idx & 127;
    h1[((size_t)b*112 + s0 + r)*128 + dd] =
        (sV[r][dd] - sMean[r]) * sRstd[r] * lg[dd] + lb[dd];
  }
}

// ---------------- FFN + residual + LN2, batched 14 rows/block (in-place safe)
__global__ __launch_bounds__(256) void k_ffn(
    const float* __restrict__ h1,
    const float* __restrict__ f1wt, const float* __restrict__ f1b,
    const float* __restrict__ f2wt, const float* __restrict__ f2b,
    const float* __restrict__ lg, const float* __restrict__ lb,
    float* __restrict__ h2)
{
  __shared__ float sh[14][128];
  __shared__ float sf[14][512];
  __shared__ float sV[14][128];
  __shared__ float sMean[14], sRstd[14];
  const int s0 = blockIdx.x * 14, b = blockIdx.y;
  const int tid = threadIdx.x;
  const int d = tid & 127, half = tid >> 7;
  const int r0 = half * 7;

  for (int idx = tid; idx < 14*128; idx += 256) {
    const int r = idx >> 7, dd = idx & 127;
    sh[r][dd] = h1[((size_t)b*112 + s0 + r)*128 + dd];
  }
  __syncthreads();
  {
    float a0[14], a1[14];
    const float b0 = f1b[tid], b1 = f1b[tid + 256];
    #pragma unroll
    for (int r = 0; r < 14; r++) { a0[r] = b0; a1[r] = b1; }
    for (int kk = 0; kk < 128; kk++) {
      const float w0 = f1wt[kk*512 + tid];
      const float w1 = f1wt[kk*512 + tid + 256];
      #pragma unroll
      for (int r = 0; r < 14; r++) {
        const float xv = sh[r][kk];
        a0[r] += w0 * xv;
        a1[r] += w1 * xv;
      }
    }
    #pragma unroll
    for (int r = 0; r < 14; r++) {
      sf[r][tid]       = fmaxf(a0[r], 0.f);
      sf[r][tid + 256] = fmaxf(a1[r], 0.f);
    }
  }
  __syncthreads();
  {
    float acc[7];
    #pragma unroll
    for (int rr = 0; rr < 7; rr++) acc[rr] = f2b[d];
    for (int kk = 0; kk < 512; kk++) {
      const float wv = f2wt[kk*128 + d];
      #pragma unroll
      for (int rr = 0; rr < 7; rr++) acc[rr] += wv * sf[r0 + rr][kk];
    }
    #pragma unroll
    for (int rr = 0; rr < 7; rr++)
      sV[r0 + rr][d] = sh[r0 + rr][d] + acc[rr];
  }
  __syncthreads();
  {
    const int r = tid >> 4, j = tid & 15;
    if (r < 14) {
      float p1 = 0.f, p2 = 0.f;
      #pragma unroll
      for (int i = 0; i < 8; i++) { float v = sV[r][j*8 + i]; p1 += v; p2 += v*v; }
      #pragma unroll
      for (int m = 8; m >= 1; m >>= 1) {
        p1 += __shfl_xor(p1, m, 64);
        p2 += __shfl_xor(p2, m, 64);
      }
      if (j == 0) {
        const float mean = p1 * (1.f/128.f);
        sMean[r] = mean;
        sRstd[r] = rsqrtf(p2 * (1.f/128.f) - mean*mean + 1e-5f);
      }
    }
  }
  __syncthreads();
  for (int idx = tid; idx < 14*128; idx += 256) {
    const int r = idx >> 7, dd = idx & 127;
    h2[((size_t)b*112 + s0 + r)*128 + dd] =
        (sV[r][dd] - sMean[r]) * sRstd[r] * lg[dd] + lb[dd];
  }
}

// ---------------- rep = sum_s h2 ; classifier -> logits (f32)
__global__ __launch_bounds__(64) void k_cls(
    const float* __restrict__ h2,
    const float* __restrict__ c1w, const float* __restrict__ c1b,
    const float* __restrict__ c2w, const float* __restrict__ c2b,
    float* __restrict__ out)
{
  __shared__ float sr[128], sc[64];
  const int b = blockIdx.x, tid = threadIdx.x;
  float r0 = 0.f, r1 = 0.f;
  for (int s2 = 0; s2 < 112; s2++) {
    const float* row = h2 + ((size_t)b*112 + s2)*128;
    r0 += row[tid];
    r1 += row[tid + 64];
  }
  sr[tid] = r0; sr[tid + 64] = r1;
  __syncthreads();
  float acc = c1b[tid];
  const float* wr = c1w + (size_t)tid * 128;
  for (int kk = 0; kk < 128; kk++) acc += wr[kk] * sr[kk];
  sc[tid] = fmaxf(acc, 0.f);
  __syncthreads();
  if (tid < 2) {
    float l = c2b[tid];
    for (int kk = 0; kk < 64; kk++) l += c2w[tid*64 + kk] * sc[kk];
    out[b*2 + tid] = l;
  }
}

extern "C" void kernel_launch(void* const* d_in, const int* in_sizes, int n_in,
                              void* d_out, int out_size, void* d_ws, size_t ws_size,
                              hipStream_t stream)
{
  const float* x    = (const float*)d_in[0];
  const float* c1w  = (const float*)d_in[1];
  const float* c1b  = (const float*)d_in[2];
  const float* bn1g = (const float*)d_in[3];
  const float* bn1b = (const float*)d_in[4];
  const float* c2w  = (const float*)d_in[5];
  const float* c2b  = (const float*)d_in[6];
  const float* bn2g = (const float*)d_in[7];
  const float* bn2b = (const float*)d_in[8];
  const float* pjw  = (const float*)d_in[9];
  const float* pjb  = (const float*)d_in[10];
  const float* w1w  = (const float*)d_in[11];
  const float* w1b  = (const float*)d_in[12];
  const float* w2w  = (const float*)d_in[13];
  const float* w2b  = (const float*)d_in[14];
  const float* gw   = (const float*)d_in[15];
  const float* gb   = (const float*)d_in[16];
  const float* scw  = (const float*)d_in[17];
  const float* scb  = (const float*)d_in[18];
  const float* ipw  = (const float*)d_in[19];
  const float* ipb  = (const float*)d_in[20];
  const float* opw  = (const float*)d_in[21];
  const float* opb  = (const float*)d_in[22];
  const float* f1w  = (const float*)d_in[23];
  const float* f1b  = (const float*)d_in[24];
  const float* f2w  = (const float*)d_in[25];
  const float* f2b  = (const float*)d_in[26];
  const float* l1g  = (const float*)d_in[27];
  const float* l1b  = (const float*)d_in[28];
  const float* l2g  = (const float*)d_in[29];
  const float* l2b  = (const float*)d_in[30];
  const float* cl1w = (const float*)d_in[31];
  const float* cl1b = (const float*)d_in[32];
  const float* cl2w = (const float*)d_in[33];
  const float* cl2b = (const float*)d_in[34];

  // ---- bump allocator over d_ws (256-B aligned) ----
  char* p = (char*)d_ws;
  auto alloc = [&](size_t n) { char* r = p; p += (n + 255) & ~(size_t)255; return r; };
  u64*   mask2  = (u64*)  alloc(900    * sizeof(u64));
  int*   nbr1   = (int*)  alloc(1800   * sizeof(int));
  int*   sel    = (int*)  alloc(1792   * sizeof(int));
  float* scores = (float*)alloc(3600   * sizeof(float));
  u16*   pwh    = (u16*)  alloc(524288 * sizeof(u16));
  u16*   pwl    = (u16*)  alloc(524288 * sizeof(u16));
  u16*   wc2h   = (u16*)  alloc(36864  * sizeof(u16));
  u16*   wc2l   = (u16*)  alloc(36864  * sizeof(u16));
  float* iwt    = (float*)alloc(49152  * sizeof(float));
  float* owt    = (float*)alloc(16384  * sizeof(float));
  float* f1wt   = (float*)alloc(65536  * sizeof(float));
  float* f2wt   = (float*)alloc(65536  * sizeof(float));
  float* w1t    = (float*)alloc(16384  * sizeof(float));
  float* w2t    = (float*)alloc(16384  * sizeof(float));
  float* gwt    = (float*)alloc(32768  * sizeof(float));
  float* partial= (float*)alloc(4ull*16*225*128 * sizeof(float));  // 7.37 MB split-K
  float* a1buf  = (float*)alloc(460800 * sizeof(float));
  float* a2buf  = (float*)alloc(460800 * sizeof(float));
  float* zbuf   = (float*)alloc(460800 * sizeof(float));
  float* nodes  = (float*)alloc(460800 * sizeof(float));
  const size_t fixed_bytes = (size_t)(p - (char*)d_ws);

  const size_t qkv_bytes = 3ull * 229376ull * sizeof(float);
  const size_t per_batch = 64ull*128*128*2 + 64ull*64*64*2;   // 2,621,440 B
  int BC = 16;
  size_t s3 = 0;
  for (;; BC >>= 1) {
    s3 = (size_t)BC * per_batch; if (s3 < qkv_bytes) s3 = qkv_bytes;
    if (fixed_bytes + s3 + 65536 <= ws_size) break;
    if (BC == 1) { return; }
  }
  char* S3 = alloc(s3);

  u16*   feat1 = (u16*)S3;                              // NHWC (BC,128,128,64)
  u16*   feat2 = (u16*)(S3 + (size_t)BC * 2097152ull);  // NCHW (BC,64,64,64)
  float* qb    = (float*)S3;
  float* kb    = qb + 229376;
  float* vb    = kb + 229376;
  float* obuf  = nodes;
  float* hbuf  = nodes + 229376;

  k_adj1<<<225, 256, 0, stream>>>(nbr1);
  k_adj2<<<1, 256, 0, stream>>>(nbr1, mask2);
  k_prep<<<1680, 256, 0, stream>>>(pjw, pwh, pwl, c2w, bn2g, wc2h, wc2l,
                                   ipw, iwt, opw, owt, f1w, f1wt, f2w, f2wt,
                                   w1w, w1t, w2w, w2t, gw, gwt);

  for (int b0 = 0; b0 < 16; b0 += BC) {
    k_conv1 <<<dim3(8,8,BC), 256, 0, stream>>>(x, c1w, c1b, bn1g, bn1b, feat1, b0);
    k_conv2m<<<dim3(4,8,BC), 256, 0, stream>>>(feat1, wc2h, wc2l, c2b, bn2g, bn2b, feat2);
    k_projm <<<dim3(4,4,BC), 256, 0, stream>>>(feat2, pwh, pwl, partial, b0);
    k_projr <<<dim3(225,BC), 128, 0, stream>>>(partial, pjb, nodes, b0);
  }

  k_agg  <<<dim3(225,16), 128, 0, stream>>>(nodes, nbr1, mask2, a1buf, a2buf);
  k_gz   <<<1800, 256, 0, stream>>>(a1buf, a2buf, w1t, w1b, w2t, w2b,
                                    gwt, gb, scw, scb, zbuf, scores);
  k_topk <<<16, 256, 0, stream>>>(scores, sel);
  k_qkv  <<<dim3(8,16), 256, 0, stream>>>(zbuf, sel, iwt, ipb, qb, kb, vb);
  k_attn <<<dim3(4,16), 128, 0, stream>>>(qb, kb, vb, obuf);
  k_oln  <<<dim3(8,16), 256, 0, stream>>>(obuf, zbuf, sel, owt, opb, l1g, l1b, hbuf);
  k_ffn  <<<dim3(8,16), 256, 0, stream>>>(hbuf, f1wt, f1b, f2wt, f2b, l2g, l2b, hbuf);
  k_cls  <<<16, 64, 0, stream>>>(hbuf, cl1w, cl1b, cl2w, cl2b, (float*)d_out);
}

// Round 12
// 331.439 us; speedup vs baseline: 5.1830x; 1.0979x over previous
//
#include <hip/hip_runtime.h>
#include <hip/hip_bf16.h>
#include <math.h>

typedef unsigned short u16;
typedef unsigned int   u32;
typedef unsigned long long u64;
typedef __attribute__((ext_vector_type(8))) short short8v;
typedef __attribute__((ext_vector_type(4))) float f32x4;

__device__ __forceinline__ float bf2f(u16 u) {
  union { u32 i; float f; } v; v.i = ((u32)u) << 16; return v.f;
}
__device__ __forceinline__ u16 f2bf(float f) {  // round-to-nearest-even
  union { float f; u32 i; } v; v.f = f;
  u32 r = (v.i + 0x7FFFu + ((v.i >> 16) & 1u)) >> 16;
  return (u16)r;
}

// ---------------- conv1 + bn1 + relu + maxpool2 via MFMA im2col (K=32, hi/lo input split)
// (16,3,256,256) f32 -> (BC,128,128,64) NHWC bf16
__global__ __launch_bounds__(256, 2) void k_conv1m(
    const float* __restrict__ x,
    const u16* __restrict__ wh, const u16* __restrict__ wl,   // [64][32], bn-scaled
    const float* __restrict__ cb, const float* __restrict__ g, const float* __restrict__ bb,
    u16* __restrict__ feat1, int b0)
{
  __shared__ __align__(16) float sIn[3*18*18];               // 3888 B halo
  __shared__ __align__(16) u16 sAh[256*40], sAl[256*40];     // 20480 B each
  __shared__ __align__(16) u16 sBh[64*40],  sBl[64*40];      // 5120 B each
  __shared__ float sBias[64];
  const int tx = blockIdx.x, ty = blockIdx.y, bl = blockIdx.z;
  const int b = b0 + bl;
  const int y0 = ty*16, x0 = tx*16;
  const int tid = threadIdx.x;
  const int w = tid >> 6, l = tid & 63, lr = l & 15, lk = l >> 4;

  if (tid < 64) {
    float sc = g[tid] * rsqrtf(1.0f + 1e-5f);
    sBias[tid] = cb[tid] * sc + bb[tid];
  }
  {  // stage B (64 oc x 32 k, hi/lo)
    const int oc = tid >> 2, seg = tid & 3;
    *reinterpret_cast<uint4*>(&sBh[oc*40 + seg*8]) =
        *reinterpret_cast<const uint4*>(wh + oc*32 + seg*8);
    *reinterpret_cast<uint4*>(&sBl[oc*40 + seg*8]) =
        *reinterpret_cast<const uint4*>(wl + oc*32 + seg*8);
  }
  // stage input halo 3 x 18 x 18 (zero-padded at borders)
  for (int i = tid; i < 3*18*18; i += 256) {
    const int c = i / 324, r = (i / 18) % 18, q = i % 18;
    const int yy = y0 - 1 + r, xx = x0 - 1 + q;
    float v = 0.f;
    if (yy >= 0 && yy < 256 && xx >= 0 && xx < 256)
      v = x[(((size_t)b*3 + c)*256 + yy)*256 + xx];
    sIn[i] = v;
  }
  __syncthreads();
  // im2col: pixel p = tid -> row of 32 bf16 (hi & lo)
  {
    const int py = tid >> 4, px = tid & 15;
    u32 hw[16], lw[16];
    #pragma unroll
    for (int i = 0; i < 16; i++) { hw[i] = 0u; lw[i] = 0u; }
    #pragma unroll
    for (int c = 0; c < 3; c++)
      #pragma unroll
      for (int ky = 0; ky < 3; ky++)
        #pragma unroll
        for (int kx = 0; kx < 3; kx++) {
          const int k = c*9 + ky*3 + kx;
          const float v = sIn[(c*18 + py + ky)*18 + px + kx];
          const u16 h  = f2bf(v);
          const u16 lo = f2bf(v - bf2f(h));
          hw[k >> 1] |= ((u32)h)  << ((k & 1)*16);
          lw[k >> 1] |= ((u32)lo) << ((k & 1)*16);
        }
    #pragma unroll
    for (int s = 0; s < 4; s++) {
      uint4 vh, vl;
      vh.x = hw[s*4+0]; vh.y = hw[s*4+1]; vh.z = hw[s*4+2]; vh.w = hw[s*4+3];
      vl.x = lw[s*4+0]; vl.y = lw[s*4+1]; vl.z = lw[s*4+2]; vl.w = lw[s*4+3];
      *reinterpret_cast<uint4*>(&sAh[tid*40 + s*8]) = vh;
      *reinterpret_cast<uint4*>(&sAl[tid*40 + s*8]) = vl;
    }
  }
  __syncthreads();
  f32x4 acc[4][4];
  #pragma unroll
  for (int j = 0; j < 4; j++)
    #pragma unroll
    for (int ct = 0; ct < 4; ct++)
      acc[j][ct] = (f32x4){0.f,0.f,0.f,0.f};
  #pragma unroll
  for (int j = 0; j < 4; j++) {
    const int mt = w*4 + j;                      // m-tile = conv row py
    const short8v ah = *reinterpret_cast<const short8v*>(&sAh[(mt*16 + lr)*40 + lk*8]);
    const short8v al = *reinterpret_cast<const short8v*>(&sAl[(mt*16 + lr)*40 + lk*8]);
    #pragma unroll
    for (int ct = 0; ct < 4; ct++) {
      const short8v bh = *reinterpret_cast<const short8v*>(&sBh[(ct*16 + lr)*40 + lk*8]);
      const short8v bv = *reinterpret_cast<const short8v*>(&sBl[(ct*16 + lr)*40 + lk*8]);
      acc[j][ct] = __builtin_amdgcn_mfma_f32_16x16x32_bf16(ah, bh, acc[j][ct], 0, 0, 0);
      acc[j][ct] = __builtin_amdgcn_mfma_f32_16x16x32_bf16(ah, bv, acc[j][ct], 0, 0, 0);
      acc[j][ct] = __builtin_amdgcn_mfma_f32_16x16x32_bf16(al, bh, acc[j][ct], 0, 0, 0);
    }
  }
  // epilogue: maxpool2 + bias + relu -> NHWC bf16
  // acc[j'][ct][v]: conv pixel (py = w*4+j', px = lk*4+v), oc = ct*16+lr
  #pragma unroll
  for (int j = 0; j < 2; j++) {
    const int jA = 2*j, jB = 2*j + 1;
    const int oy = ty*8 + w*2 + j;
    #pragma unroll
    for (int xh = 0; xh < 2; xh++) {
      const int ox = tx*8 + lk*2 + xh;
      #pragma unroll
      for (int ct = 0; ct < 4; ct++) {
        const int oc = ct*16 + lr;
        float m = fmaxf(fmaxf(acc[jA][ct][2*xh], acc[jA][ct][2*xh+1]),
                        fmaxf(acc[jB][ct][2*xh], acc[jB][ct][2*xh+1]));
        m = fmaxf(m + sBias[oc], 0.f);
        feat1[(((size_t)bl*128 + oy)*128 + ox)*64 + oc] = f2bf(m);
      }
    }
  }
}

// ---------------- conv2 + bn2 + relu + maxpool2 via MFMA implicit GEMM
__global__ __launch_bounds__(256, 2) void k_conv2m(
    const u16* __restrict__ feat1,
    const u16* __restrict__ wh, const u16* __restrict__ wl,
    const float* __restrict__ cb, const float* __restrict__ g, const float* __restrict__ bb,
    u16* __restrict__ feat2)
{
  __shared__ __align__(16) u16 sA[18*34*40];
  __shared__ __align__(16) u16 sBh[64*40], sBl[64*40];
  __shared__ float sBias[64];
  const int tx = blockIdx.x, ty = blockIdx.y, bl = blockIdx.z;
  const int y0 = ty*16, x0 = tx*32;
  const int tid = threadIdx.x;
  const int w = tid >> 6, l = tid & 63;
  const int lr = l & 15, lk = l >> 4;

  if (tid < 64) {
    float sc = g[tid] * rsqrtf(1.0f + 1e-5f);
    sBias[tid] = cb[tid] * sc + bb[tid];
  }

  f32x4 acc[8][4];
  #pragma unroll
  for (int j = 0; j < 8; j++)
    #pragma unroll
    for (int ct = 0; ct < 4; ct++)
      acc[j][ct] = (f32x4){0.f,0.f,0.f,0.f};

  for (int chunk = 0; chunk < 2; chunk++) {
    __syncthreads();
    for (int idx = tid; idx < 612*4; idx += 256) {
      const int pix = idx >> 2, seg = idx & 3;
      const int r = pix / 34, cc = pix % 34;
      const int yy = y0 - 1 + r, xx = x0 - 1 + cc;
      uint4 v = {0u,0u,0u,0u};
      if (yy >= 0 && yy < 128 && xx >= 0 && xx < 128)
        v = *reinterpret_cast<const uint4*>(
              feat1 + (((size_t)bl*128 + yy)*128 + xx)*64 + chunk*32 + seg*8);
      *reinterpret_cast<uint4*>(&sA[(size_t)(r*34 + cc)*40 + seg*8]) = v;
    }
    for (int kk = 0; kk < 9; kk++) {
      __syncthreads();
      {
        const int oc = tid >> 2, s8 = (tid & 3)*8;
        const size_t src = (size_t)(kk*2 + chunk)*2048 + tid*8;
        *reinterpret_cast<uint4*>(&sBh[oc*40 + s8]) = *reinterpret_cast<const uint4*>(wh + src);
        *reinterpret_cast<uint4*>(&sBl[oc*40 + s8]) = *reinterpret_cast<const uint4*>(wl + src);
      }
      __syncthreads();
      const int ky = kk / 3, kx = kk % 3;
      short8v a[8];
      #pragma unroll
      for (int j = 0; j < 8; j++) {
        const int m = w*8 + j;
        const int r = (m >> 1) + ky;
        const int cc = (m & 1)*16 + lr + kx;
        a[j] = *reinterpret_cast<const short8v*>(&sA[(size_t)(r*34 + cc)*40 + lk*8]);
      }
      #pragma unroll
      for (int ct = 0; ct < 4; ct++) {
        const short8v bh = *reinterpret_cast<const short8v*>(&sBh[(ct*16 + lr)*40 + lk*8]);
        const short8v bv = *reinterpret_cast<const short8v*>(&sBl[(ct*16 + lr)*40 + lk*8]);
        #pragma unroll
        for (int j = 0; j < 8; j++) {
          acc[j][ct] = __builtin_amdgcn_mfma_f32_16x16x32_bf16(a[j], bh, acc[j][ct], 0, 0, 0);
          acc[j][ct] = __builtin_amdgcn_mfma_f32_16x16x32_bf16(a[j], bv, acc[j][ct], 0, 0, 0);
        }
      }
    }
  }
  #pragma unroll
  for (int u = 0; u < 2; u++) {
    #pragma unroll
    for (int xh = 0; xh < 2; xh++) {
      const int jA = 4*u + xh, jB = 4*u + 2 + xh;
      #pragma unroll
      for (int ct = 0; ct < 4; ct++) {
        const int oc = ct*16 + lr;
        const float bias = sBias[oc];
        const float v0 = fmaxf(fmaxf(acc[jA][ct][0], acc[jA][ct][1]),
                               fmaxf(acc[jB][ct][0], acc[jB][ct][1]));
        const float v1 = fmaxf(fmaxf(acc[jA][ct][2], acc[jA][ct][3]),
                               fmaxf(acc[jB][ct][2], acc[jB][ct][3]));
        const u16 b0v = f2bf(fmaxf(v0 + bias, 0.f));
        const u16 b1v = f2bf(fmaxf(v1 + bias, 0.f));
        const int py = ty*8 + 2*w + u;
        const int px = tx*16 + xh*8 + lk*2;
        u32 pk = (u32)b0v | ((u32)b1v << 16);
        *reinterpret_cast<u32*>(&feat2[(((size_t)bl*64 + oc)*64 + py)*64 + px]) = pk;
      }
    }
  }
}

// ---------------- adjacency phase 1: 8-NN per node, 225 blocks (stable (d2,j) order)
__global__ __launch_bounds__(256) void k_adj1(int* __restrict__ nbr1)
{
  __shared__ int skey[256];
  __shared__ int sred[256];
  const int i = blockIdx.x;
  const int tid = threadIdx.x;
  int key = 0x7FFFFFFF;
  if (tid < 225 && tid != i) {
    const int di = i/15 - tid/15, dj = i%15 - tid%15;
    key = (di*di + dj*dj)*256 + tid;
  }
  skey[tid] = key;
  __syncthreads();
  for (int t = 0; t < 8; t++) {
    sred[tid] = skey[tid];
    __syncthreads();
    #pragma unroll
    for (int st = 128; st > 0; st >>= 1) {
      if (tid < st) sred[tid] = min(sred[tid], sred[tid+st]);
      __syncthreads();
    }
    const int wj = sred[0] & 255;
    if (tid == 0) nbr1[i*8 + t] = wj;
    __syncthreads();
    if (tid == wj) skey[tid] = 0x7FFFFFFF;
    __syncthreads();
  }
}

// ---------------- adjacency phase 2: mask2 = rows of (adj@adj>0) minus diagonal
__global__ __launch_bounds__(256) void k_adj2(
    const int* __restrict__ nbr1, u64* __restrict__ mask2)
{
  const int i = threadIdx.x;
  if (i >= 225) return;
  u64 m0=0, m1=0, m2=0, m3=0;
  #pragma unroll
  for (int t = 0; t < 8; t++) {
    const int tt = nbr1[i*8 + t];
    #pragma unroll
    for (int u = 0; u < 8; u++) {
      const int j = nbr1[tt*8 + u];
      const u64 bset = 1ull << (j & 63);
      const int wd = j >> 6;
      m0 |= (wd == 0) ? bset : 0ull;
      m1 |= (wd == 1) ? bset : 0ull;
      m2 |= (wd == 2) ? bset : 0ull;
      m3 |= (wd == 3) ? bset : 0ull;
    }
  }
  {
    const u64 bc = ~(1ull << (i & 63));
    const int wd = i >> 6;
    if (wd == 0) m0 &= bc; else if (wd == 1) m1 &= bc;
    else if (wd == 2) m2 &= bc; else m3 &= bc;
  }
  mask2[i*4+0] = m0; mask2[i*4+1] = m1; mask2[i*4+2] = m2; mask2[i*4+3] = m3;
}

// ---------------- fused weight prep
__global__ __launch_bounds__(256) void k_prep(
    const float* __restrict__ pjw, u16* __restrict__ pwh, u16* __restrict__ pwl,
    const float* __restrict__ c2w, const float* __restrict__ bn2g,
    u16* __restrict__ wc2h, u16* __restrict__ wc2l,
    const float* __restrict__ c1w, const float* __restrict__ bn1g,
    u16* __restrict__ wc1h, u16* __restrict__ wc1l,
    const float* __restrict__ ipw, float* __restrict__ iwt,
    const float* __restrict__ opw, float* __restrict__ owt,
    const float* __restrict__ f1w, float* __restrict__ f1wt,
    const float* __restrict__ f2w, float* __restrict__ f2wt,
    const float* __restrict__ w1w, float* __restrict__ w1t,
    const float* __restrict__ w2w, float* __restrict__ w2t,
    const float* __restrict__ gw,  float* __restrict__ gwt)
{
  const int blk = blockIdx.x, tid = threadIdx.x;
  if (blk < 512) {                       // proj_w f32 -> hi/lo bf16 (x4 elements)
    const int i = (blk*256 + tid) * 4;
    float4 v = *reinterpret_cast<const float4*>(pjw + i);
    float e[4] = {v.x, v.y, v.z, v.w};
    ushort4 h, l;
    u16* hp = &h.x; u16* lp = &l.x;
    #pragma unroll
    for (int j = 0; j < 4; j++) {
      u16 hb = f2bf(e[j]);
      hp[j] = hb;
      lp[j] = f2bf(e[j] - bf2f(hb));
    }
    *reinterpret_cast<ushort4*>(pwh + i) = h;
    *reinterpret_cast<ushort4*>(pwl + i) = l;
  } else if (blk < 656) {                // conv2 weights, bn-scaled hi/lo
    const int d = (blk - 512)*256 + tid;
    if (d < 36864) {
      const int icL = d & 31, oc = (d >> 5) & 63, chunk = (d >> 11) & 1, kk = d >> 12;
      const float sc = bn2g[oc] * rsqrtf(1.0f + 1e-5f);
      const float val = c2w[((size_t)oc*64 + chunk*32 + icL)*9 + kk] * sc;
      const u16 hb = f2bf(val);
      wc2h[d] = hb;
      wc2l[d] = f2bf(val - bf2f(hb));
    }
  } else if (blk < 664) {                // conv1 weights [64][32] K=c*9+ky*3+kx, bn-scaled
    const int d = (blk - 656)*256 + tid;
    if (d < 2048) {
      const int k = d & 31, oc = d >> 5;
      float val = 0.f;
      if (k < 27) val = c1w[oc*27 + k] * (bn1g[oc] * rsqrtf(1.0f + 1e-5f));
      const u16 hb = f2bf(val);
      wc1h[d] = hb;
      wc1l[d] = f2bf(val - bf2f(hb));
    }
  } else {                               // transposes [O][K] -> [K][O]
    const float* src; float* dst; int O, K, base;
    if      (blk <  856) { src = ipw; dst = iwt;  O = 384; K = 128; base = 664;  }
    else if (blk <  920) { src = opw; dst = owt;  O = 128; K = 128; base = 856;  }
    else if (blk < 1176) { src = f1w; dst = f1wt; O = 512; K = 128; base = 920;  }
    else if (blk < 1432) { src = f2w; dst = f2wt; O = 128; K = 512; base = 1176; }
    else if (blk < 1496) { src = w1w; dst = w1t;  O = 128; K = 128; base = 1432; }
    else if (blk < 1560) { src = w2w; dst = w2t;  O = 128; K = 128; base = 1496; }
    else                 { src = gw;  dst = gwt;  O = 128; K = 256; base = 1560; }
    const int idx = (blk - base)*256 + tid;
    if (idx < O * K) {
      const int o = idx / K, k = idx % K;
      dst[(size_t)k * O + o] = src[idx];
    }
  }
}

// ---------------- patch-projection MFMA GEMM, split-K=4 + register prefetch
__global__ __launch_bounds__(256, 2) void k_projm(
    const u16* __restrict__ feat2,
    const u16* __restrict__ pwh, const u16* __restrict__ pwl,
    float* __restrict__ partial, int b0)
{
  __shared__ __align__(16) u16 sA [64][40];
  __shared__ __align__(16) u16 sBh[128][40];
  __shared__ __align__(16) u16 sBl[128][40];
  const int cx = blockIdx.x, kc = blockIdx.y, bl = blockIdx.z;
  const int b  = b0 + bl;
  const int n0 = cx * 64;
  const int rows = (225 - n0) < 64 ? (225 - n0) : 64;
  const int tid = threadIdx.x;
  const int w = tid >> 6, l = tid & 63;
  const int lr = l & 15, lk = l >> 4;

  f32x4 acc[8];
  #pragma unroll
  for (int i = 0; i < 8; i++) acc[i] = (f32x4){0.f, 0.f, 0.f, 0.f};

  const int ar = tid >> 2, aci = tid & 3;
  const int an = n0 + ar;
  const int aph = an / 15, apw = an % 15;
  const int kbeg = kc * 1024, kend = kbeg + 1024;

  uint4 pA, pBh[2], pBl[2];
  auto loadstep = [&](int k0) {
    const int c  = k0 >> 6;
    const int i0 = (k0 & 63) >> 3;
    uint2 g0 = {0u,0u}, g1 = {0u,0u};
    if (ar < rows) {
      const u16* src = feat2 + (((size_t)bl*64 + c)*64 + aph*4 + i0 + aci)*64 + apw*4;
      g0 = *reinterpret_cast<const uint2*>(src);
      g1 = *reinterpret_cast<const uint2*>(src + 4);
    }
    pA.x = g0.x; pA.y = g0.y; pA.z = g1.x; pA.w = g1.y;
    #pragma unroll
    for (int p = 0; p < 2; p++) {
      const int idx = p*256 + tid;
      const int col = idx >> 2, seg = idx & 3;
      const size_t off = (size_t)col*4096 + k0 + seg*8;
      pBh[p] = *reinterpret_cast<const uint4*>(pwh + off);
      pBl[p] = *reinterpret_cast<const uint4*>(pwl + off);
    }
  };

  loadstep(kbeg);
  for (int k0 = kbeg; k0 < kend; k0 += 32) {
    __syncthreads();
    *reinterpret_cast<uint4*>(&sA[ar][aci*8]) = pA;
    #pragma unroll
    for (int p = 0; p < 2; p++) {
      const int idx = p*256 + tid;
      const int col = idx >> 2, seg = idx & 3;
      *reinterpret_cast<uint4*>(&sBh[col][seg*8]) = pBh[p];
      *reinterpret_cast<uint4*>(&sBl[col][seg*8]) = pBl[p];
    }
    __syncthreads();
    if (k0 + 32 < kend) loadstep(k0 + 32);
    short8v a = *reinterpret_cast<const short8v*>(&sA[w*16 + lr][lk*8]);
    #pragma unroll
    for (int ct = 0; ct < 8; ct++) {
      short8v bh = *reinterpret_cast<const short8v*>(&sBh[ct*16 + lr][lk*8]);
      short8v bv = *reinterpret_cast<const short8v*>(&sBl[ct*16 + lr][lk*8]);
      acc[ct] = __builtin_amdgcn_mfma_f32_16x16x32_bf16(a, bh, acc[ct], 0, 0, 0);
      acc[ct] = __builtin_amdgcn_mfma_f32_16x16x32_bf16(a, bv, acc[ct], 0, 0, 0);
    }
  }
  #pragma unroll
  for (int ct = 0; ct < 8; ct++) {
    const int col = ct*16 + lr;
    #pragma unroll
    for (int v = 0; v < 4; v++) {
      const int r = w*16 + lk*4 + v;
      if (r < rows)
        partial[(((size_t)kc*16 + b)*225 + n0 + r)*128 + col] = acc[ct][v];
    }
  }
}

// ---------------- reduce split-K partials + bias -> nodes
__global__ __launch_bounds__(128) void k_projr(
    const float* __restrict__ partial, const float* __restrict__ pb,
    float* __restrict__ nodes, int b0)
{
  const int n = blockIdx.x, bl = blockIdx.y;
  const int b = b0 + bl;
  const int d = threadIdx.x;
  float s = pb[d];
  #pragma unroll
  for (int kc = 0; kc < 4; kc++)
    s += partial[(((size_t)kc*16 + b)*225 + n)*128 + d];
  nodes[((size_t)b*225 + n)*128 + d] = s;
}

// ---------------- neighbor aggregation: a1/a2 per (b,node)
__global__ __launch_bounds__(128) void k_agg(
    const float* __restrict__ nodes, const int* __restrict__ nbr1,
    const u64* __restrict__ mask2,
    float* __restrict__ a1buf, float* __restrict__ a2buf)
{
  const int n = blockIdx.x, b = blockIdx.y;
  const int d = threadIdx.x;
  const float* nb = nodes + (size_t)b * 225 * 128;
  float a1 = 0.f;
  #pragma unroll
  for (int t = 0; t < 8; t++) a1 += nb[(size_t)nbr1[n*8+t]*128 + d];
  float a2 = 0.f;
  for (int wd = 0; wd < 4; wd++) {
    u64 m = mask2[n*4 + wd];
    while (m) {
      int j = wd*64 + __builtin_ctzll(m);
      a2 += nb[(size_t)j*128 + d];
      m &= m - 1;
    }
  }
  a1buf[((size_t)b*225 + n)*128 + d] = a1;
  a2buf[((size_t)b*225 + n)*128 + d] = a2;
}

// ---------------- z1/z2/gate/score: 2 rows per block (1800 blocks -> high TLP)
__global__ __launch_bounds__(256) void k_gz(
    const float* __restrict__ a1buf, const float* __restrict__ a2buf,
    const float* __restrict__ w1t, const float* __restrict__ w1b,
    const float* __restrict__ w2t, const float* __restrict__ w2b,
    const float* __restrict__ gwt, const float* __restrict__ gb,
    const float* __restrict__ sw, const float* __restrict__ sb,
    float* __restrict__ zbuf, float* __restrict__ scores)
{
  __shared__ float sA1[2][128], sA2[2][128], sC[2][256], sRed[2][128];
  const int row0 = blockIdx.x * 2;
  const int tid = threadIdx.x;
  const int d = tid & 127, rr = tid >> 7;
  const int row = row0 + rr;
  sA1[rr][d] = a1buf[(size_t)row*128 + d];
  sA2[rr][d] = a2buf[(size_t)row*128 + d];
  __syncthreads();
  float z1 = w1b[d], z2 = w2b[d];
  #pragma unroll 4
  for (int k = 0; k < 128; k++) {
    z1 += w1t[k*128 + d] * sA1[rr][k];
    z2 += w2t[k*128 + d] * sA2[rr][k];
  }
  sC[rr][d] = z1; sC[rr][128 + d] = z2;
  __syncthreads();
  float gl = gb[d];
  #pragma unroll 4
  for (int k = 0; k < 256; k++)
    gl += gwt[k*128 + d] * sC[rr][k];
  const float gg = 1.f / (1.f + expf(-gl));
  const float zv = gg * z1 + (1.f - gg) * z2;
  zbuf[(size_t)row*128 + d] = zv;
  sRed[rr][d] = zv * sw[d];
  __syncthreads();
  if (tid < 32) {
    const int r = tid >> 4, j = tid & 15;
    float part = 0.f;
    #pragma unroll
    for (int i = 0; i < 8; i++) part += sRed[r][j*8 + i];
    #pragma unroll
    for (int m = 8; m >= 1; m >>= 1) part += __shfl_xor(part, m, 64);
    if (j == 0) scores[row0 + r] = part + sb[0];
  }
}

// ---------------- top-k (k=112) with jax tie semantics
__global__ __launch_bounds__(256) void k_topk(
    const float* __restrict__ scores, int* __restrict__ sel)
{
  __shared__ float ss[225];
  const int b = blockIdx.x, tid = threadIdx.x;
  if (tid < 112) sel[b*112 + tid] = tid;
  if (tid < 225) ss[tid] = scores[b*225 + tid];
  __syncthreads();
  if (tid < 225) {
    float s = ss[tid];
    int rank = 0;
    for (int j = 0; j < 225; j++) {
      float sj = ss[j];
      rank += (sj > s) || (sj == s && j < tid);
    }
    if (rank < 112) sel[b*112 + rank] = tid;
  }
}

// ---------------- qkv batched: 14 rows per block
__global__ __launch_bounds__(256) void k_qkv(
    const float* __restrict__ zbuf, const int* __restrict__ sel,
    const float* __restrict__ iwt, const float* __restrict__ ib,
    float* __restrict__ q, float* __restrict__ k, float* __restrict__ v)
{
  __shared__ float sx[14][128];
  const int s0 = blockIdx.x * 14, b = blockIdx.y;
  const int tid = threadIdx.x;
  const int c = tid & 127, half = tid >> 7;
  const int r0 = half * 7;

  for (int idx = tid; idx < 14*128; idx += 256) {
    const int r = idx >> 7, dd = idx & 127;
    int row = sel[b*112 + s0 + r];
    row = row < 0 ? 0 : (row > 224 ? 224 : row);
    sx[r][dd] = zbuf[((size_t)b*225 + row)*128 + dd];
  }
  __syncthreads();

  float acc[3][7];
  #pragma unroll
  for (int p = 0; p < 3; p++)
    #pragma unroll
    for (int rr = 0; rr < 7; rr++) acc[p][rr] = ib[p*128 + c];
  for (int kk = 0; kk < 128; kk++) {
    float wv[3];
    #pragma unroll
    for (int p = 0; p < 3; p++) wv[p] = iwt[kk*384 + p*128 + c];
    #pragma unroll
    for (int rr = 0; rr < 7; rr++) {
      const float xv = sx[r0 + rr][kk];
      #pragma unroll
      for (int p = 0; p < 3; p++) acc[p][rr] += wv[p] * xv;
    }
  }
  const int h = c >> 5, t = c & 31;
  float* outs[3] = {q, k, v};
  #pragma unroll
  for (int p = 0; p < 3; p++)
    #pragma unroll
    for (int rr = 0; rr < 7; rr++)
      outs[p][(((size_t)b*4 + h)*112 + s0 + r0 + rr)*32 + t] = acc[p][rr];
}

// ---------------- attention per (b, head), two-pass softmax
__global__ __launch_bounds__(128) void k_attn(
    const float* __restrict__ q, const float* __restrict__ k,
    const float* __restrict__ v, float* __restrict__ o)
{
  __shared__ float sK[112*32], sV[112*32];
  const int h = blockIdx.x, b = blockIdx.y, tid = threadIdx.x;
  const size_t base = ((size_t)b*4 + h) * 112 * 32;
  for (int i = tid; i < 112*32; i += 128) {
    sK[i] = k[base + i];
    sV[i] = v[base + i];
  }
  __syncthreads();
  if (tid < 112) {
    float qv[32];
    const float* qp = q + base + (size_t)tid*32;
    #pragma unroll
    for (int t = 0; t < 32; t++) qv[t] = qp[t];
    const float scale = 0.17677669529663687f;
    float mx = -INFINITY;
    for (int j = 0; j < 112; j++) {
      float s = 0.f;
      #pragma unroll
      for (int t = 0; t < 32; t++) s += qv[t] * sK[j*32 + t];
      mx = fmaxf(mx, s * scale);
    }
    float acc[32];
    #pragma unroll
    for (int t = 0; t < 32; t++) acc[t] = 0.f;
    float l = 0.f;
    for (int j = 0; j < 112; j++) {
      float s = 0.f;
      #pragma unroll
      for (int t = 0; t < 32; t++) s += qv[t] * sK[j*32 + t];
      float p = expf(s * scale - mx);
      l += p;
      #pragma unroll
      for (int t = 0; t < 32; t++) acc[t] += p * sV[j*32 + t];
    }
    float inv = 1.f / l;
    float* op = o + ((size_t)b*112 + tid)*128 + h*32;
    #pragma unroll
    for (int t = 0; t < 32; t++) op[t] = acc[t] * inv;
  }
}

// ---------------- out-proj + residual + LN1, batched 14 rows/block
__global__ __launch_bounds__(256) void k_oln(
    const float* __restrict__ o, const float* __restrict__ zbuf,
    const int* __restrict__ sel,
    const float* __restrict__ owt, const float* __restrict__ ob,
    const float* __restrict__ lg, const float* __restrict__ lb,
    float* __restrict__ h1)
{
  __shared__ float sO[14][128], sV[14][128];
  __shared__ float sMean[14], sRstd[14];
  const int s0 = blockIdx.x * 14, b = blockIdx.y;
  const int tid = threadIdx.x;
  const int d = tid & 127, half = tid >> 7;
  const int r0 = half * 7;

  for (int idx = tid; idx < 14*128; idx += 256) {
    const int r = idx >> 7, dd = idx & 127;
    sO[r][dd] = o[((size_t)b*112 + s0 + r)*128 + dd];
  }
  __syncthreads();

  float acc[7];
  #pragma unroll
  for (int rr = 0; rr < 7; rr++) acc[rr] = ob[d];
  for (int kk = 0; kk < 128; kk++) {
    const float wv = owt[kk*128 + d];
    #pragma unroll
    for (int rr = 0; rr < 7; rr++) acc[rr] += wv * sO[r0 + rr][kk];
  }
  #pragma unroll
  for (int rr = 0; rr < 7; rr++) {
    int row = sel[b*112 + s0 + r0 + rr];
    row = row < 0 ? 0 : (row > 224 ? 224 : row);
    acc[rr] += zbuf[((size_t)b*225 + row)*128 + d];
    sV[r0 + rr][d] = acc[rr];
  }
  __syncthreads();
  {
    const int r = tid >> 4, j = tid & 15;
    if (r < 14) {
      float p1 = 0.f, p2 = 0.f;
      #pragma unroll
      for (int i = 0; i < 8; i++) { float v = sV[r][j*8 + i]; p1 += v; p2 += v*v; }
      #pragma unroll
      for (int m = 8; m >= 1; m >>= 1) {
        p1 += __shfl_xor(p1, m, 64);
        p2 += __shfl_xor(p2, m, 64);
      }
      if (j == 0) {
        const float mean = p1 * (1.f/128.f);
        sMean[r] = mean;
        sRstd[r] = rsqrtf(p2 * (1.f/128.f) - mean*mean + 1e-5f);
      }
    }
  }
  __syncthreads();
  for (int idx = tid; idx < 14*128; idx += 256) {
    const int r = idx >> 7, dd = idx & 127;
    h1[((size_t)b*112 + s0 + r)*128 + dd] =
        (sV[r][dd] - sMean[r]) * sRstd[r] * lg[dd] + lb[dd];
  }
}

// ---------------- FFN + residual + LN2, batched 14 rows/block (in-place safe)
__global__ __launch_bounds__(256) void k_ffn(
    const float* __restrict__ h1,
    const float* __restrict__ f1wt, const float* __restrict__ f1b,
    const float* __restrict__ f2wt, const float* __restrict__ f2b,
    const float* __restrict__ lg, const float* __restrict__ lb,
    float* __restrict__ h2)
{
  __shared__ float sh[14][128];
  __shared__ float sf[14][512];
  __shared__ float sV[14][128];
  __shared__ float sMean[14], sRstd[14];
  const int s0 = blockIdx.x * 14, b = blockIdx.y;
  const int tid = threadIdx.x;
  const int d = tid & 127, half = tid >> 7;
  const int r0 = half * 7;

  for (int idx = tid; idx < 14*128; idx += 256) {
    const int r = idx >> 7, dd = idx & 127;
    sh[r][dd] = h1[((size_t)b*112 + s0 + r)*128 + dd];
  }
  __syncthreads();
  {
    float a0[14], a1[14];
    const float b0 = f1b[tid], b1 = f1b[tid + 256];
    #pragma unroll
    for (int r = 0; r < 14; r++) { a0[r] = b0; a1[r] = b1; }
    for (int kk = 0; kk < 128; kk++) {
      const float w0 = f1wt[kk*512 + tid];
      const float w1 = f1wt[kk*512 + tid + 256];
      #pragma unroll
      for (int r = 0; r < 14; r++) {
        const float xv = sh[r][kk];
        a0[r] += w0 * xv;
        a1[r] += w1 * xv;
      }
    }
    #pragma unroll
    for (int r = 0; r < 14; r++) {
      sf[r][tid]       = fmaxf(a0[r], 0.f);
      sf[r][tid + 256] = fmaxf(a1[r], 0.f);
    }
  }
  __syncthreads();
  {
    float acc[7];
    #pragma unroll
    for (int rr = 0; rr < 7; rr++) acc[rr] = f2b[d];
    for (int kk = 0; kk < 512; kk++) {
      const float wv = f2wt[kk*128 + d];
      #pragma unroll
      for (int rr = 0; rr < 7; rr++) acc[rr] += wv * sf[r0 + rr][kk];
    }
    #pragma unroll
    for (int rr = 0; rr < 7; rr++)
      sV[r0 + rr][d] = sh[r0 + rr][d] + acc[rr];
  }
  __syncthreads();
  {
    const int r = tid >> 4, j = tid & 15;
    if (r < 14) {
      float p1 = 0.f, p2 = 0.f;
      #pragma unroll
      for (int i = 0; i < 8; i++) { float v = sV[r][j*8 + i]; p1 += v; p2 += v*v; }
      #pragma unroll
      for (int m = 8; m >= 1; m >>= 1) {
        p1 += __shfl_xor(p1, m, 64);
        p2 += __shfl_xor(p2, m, 64);
      }
      if (j == 0) {
        const float mean = p1 * (1.f/128.f);
        sMean[r] = mean;
        sRstd[r] = rsqrtf(p2 * (1.f/128.f) - mean*mean + 1e-5f);
      }
    }
  }
  __syncthreads();
  for (int idx = tid; idx < 14*128; idx += 256) {
    const int r = idx >> 7, dd = idx & 127;
    h2[((size_t)b*112 + s0 + r)*128 + dd] =
        (sV[r][dd] - sMean[r]) * sRstd[r] * lg[dd] + lb[dd];
  }
}

// ---------------- rep = sum_s h2 ; classifier -> logits (f32)
__global__ __launch_bounds__(64) void k_cls(
    const float* __restrict__ h2,
    const float* __restrict__ c1w, const float* __restrict__ c1b,
    const float* __restrict__ c2w, const float* __restrict__ c2b,
    float* __restrict__ out)
{
  __shared__ float sr[128], sc[64];
  const int b = blockIdx.x, tid = threadIdx.x;
  float r0 = 0.f, r1 = 0.f;
  for (int s2 = 0; s2 < 112; s2++) {
    const float* row = h2 + ((size_t)b*112 + s2)*128;
    r0 += row[tid];
    r1 += row[tid + 64];
  }
  sr[tid] = r0; sr[tid + 64] = r1;
  __syncthreads();
  float acc = c1b[tid];
  const float* wr = c1w + (size_t)tid * 128;
  for (int kk = 0; kk < 128; kk++) acc += wr[kk] * sr[kk];
  sc[tid] = fmaxf(acc, 0.f);
  __syncthreads();
  if (tid < 2) {
    float l = c2b[tid];
    for (int kk = 0; kk < 64; kk++) l += c2w[tid*64 + kk] * sc[kk];
    out[b*2 + tid] = l;
  }
}

extern "C" void kernel_launch(void* const* d_in, const int* in_sizes, int n_in,
                              void* d_out, int out_size, void* d_ws, size_t ws_size,
                              hipStream_t stream)
{
  const float* x    = (const float*)d_in[0];
  const float* c1w  = (const float*)d_in[1];
  const float* c1b  = (const float*)d_in[2];
  const float* bn1g = (const float*)d_in[3];
  const float* bn1b = (const float*)d_in[4];
  const float* c2w  = (const float*)d_in[5];
  const float* c2b  = (const float*)d_in[6];
  const float* bn2g = (const float*)d_in[7];
  const float* bn2b = (const float*)d_in[8];
  const float* pjw  = (const float*)d_in[9];
  const float* pjb  = (const float*)d_in[10];
  const float* w1w  = (const float*)d_in[11];
  const float* w1b  = (const float*)d_in[12];
  const float* w2w  = (const float*)d_in[13];
  const float* w2b  = (const float*)d_in[14];
  const float* gw   = (const float*)d_in[15];
  const float* gb   = (const float*)d_in[16];
  const float* scw  = (const float*)d_in[17];
  const float* scb  = (const float*)d_in[18];
  const float* ipw  = (const float*)d_in[19];
  const float* ipb  = (const float*)d_in[20];
  const float* opw  = (const float*)d_in[21];
  const float* opb  = (const float*)d_in[22];
  const float* f1w  = (const float*)d_in[23];
  const float* f1b  = (const float*)d_in[24];
  const float* f2w  = (const float*)d_in[25];
  const float* f2b  = (const float*)d_in[26];
  const float* l1g  = (const float*)d_in[27];
  const float* l1b  = (const float*)d_in[28];
  const float* l2g  = (const float*)d_in[29];
  const float* l2b  = (const float*)d_in[30];
  const float* cl1w = (const float*)d_in[31];
  const float* cl1b = (const float*)d_in[32];
  const float* cl2w = (const float*)d_in[33];
  const float* cl2b = (const float*)d_in[34];

  // ---- bump allocator over d_ws (256-B aligned) ----
  char* p = (char*)d_ws;
  auto alloc = [&](size_t n) { char* r = p; p += (n + 255) & ~(size_t)255; return r; };
  u64*   mask2  = (u64*)  alloc(900    * sizeof(u64));
  int*   nbr1   = (int*)  alloc(1800   * sizeof(int));
  int*   sel    = (int*)  alloc(1792   * sizeof(int));
  float* scores = (float*)alloc(3600   * sizeof(float));
  u16*   pwh    = (u16*)  alloc(524288 * sizeof(u16));
  u16*   pwl    = (u16*)  alloc(524288 * sizeof(u16));
  u16*   wc2h   = (u16*)  alloc(36864  * sizeof(u16));
  u16*   wc2l   = (u16*)  alloc(36864  * sizeof(u16));
  u16*   wc1h   = (u16*)  alloc(2048   * sizeof(u16));
  u16*   wc1l   = (u16*)  alloc(2048   * sizeof(u16));
  float* iwt    = (float*)alloc(49152  * sizeof(float));
  float* owt    = (float*)alloc(16384  * sizeof(float));
  float* f1wt   = (float*)alloc(65536  * sizeof(float));
  float* f2wt   = (float*)alloc(65536  * sizeof(float));
  float* w1t    = (float*)alloc(16384  * sizeof(float));
  float* w2t    = (float*)alloc(16384  * sizeof(float));
  float* gwt    = (float*)alloc(32768  * sizeof(float));
  float* partial= (float*)alloc(4ull*16*225*128 * sizeof(float));  // 7.37 MB split-K
  float* a1buf  = (float*)alloc(460800 * sizeof(float));
  float* a2buf  = (float*)alloc(460800 * sizeof(float));
  float* zbuf   = (float*)alloc(460800 * sizeof(float));
  float* nodes  = (float*)alloc(460800 * sizeof(float));
  const size_t fixed_bytes = (size_t)(p - (char*)d_ws);

  const size_t qkv_bytes = 3ull * 229376ull * sizeof(float);
  const size_t per_batch = 64ull*128*128*2 + 64ull*64*64*2;   // 2,621,440 B
  int BC = 16;
  size_t s3 = 0;
  for (;; BC >>= 1) {
    s3 = (size_t)BC * per_batch; if (s3 < qkv_bytes) s3 = qkv_bytes;
    if (fixed_bytes + s3 + 65536 <= ws_size) break;
    if (BC == 1) { return; }
  }
  char* S3 = alloc(s3);

  u16*   feat1 = (u16*)S3;                              // NHWC (BC,128,128,64)
  u16*   feat2 = (u16*)(S3 + (size_t)BC * 2097152ull);  // NCHW (BC,64,64,64)
  float* qb    = (float*)S3;
  float* kb    = qb + 229376;
  float* vb    = kb + 229376;
  float* obuf  = nodes;
  float* hbuf  = nodes + 229376;

  k_adj1<<<225, 256, 0, stream>>>(nbr1);
  k_adj2<<<1, 256, 0, stream>>>(nbr1, mask2);
  k_prep<<<1688, 256, 0, stream>>>(pjw, pwh, pwl, c2w, bn2g, wc2h, wc2l,
                                   c1w, bn1g, wc1h, wc1l,
                                   ipw, iwt, opw, owt, f1w, f1wt, f2w, f2wt,
                                   w1w, w1t, w2w, w2t, gw, gwt);

  for (int b0 = 0; b0 < 16; b0 += BC) {
    k_conv1m<<<dim3(16,16,BC), 256, 0, stream>>>(x, wc1h, wc1l, c1b, bn1g, bn1b, feat1, b0);
    k_conv2m<<<dim3(4,8,BC), 256, 0, stream>>>(feat1, wc2h, wc2l, c2b, bn2g, bn2b, feat2);
    k_projm <<<dim3(4,4,BC), 256, 0, stream>>>(feat2, pwh, pwl, partial, b0);
    k_projr <<<dim3(225,BC), 128, 0, stream>>>(partial, pjb, nodes, b0);
  }

  k_agg  <<<dim3(225,16), 128, 0, stream>>>(nodes, nbr1, mask2, a1buf, a2buf);
  k_gz   <<<1800, 256, 0, stream>>>(a1buf, a2buf, w1t, w1b, w2t, w2b,
                                    gwt, gb, scw, scb, zbuf, scores);
  k_topk <<<16, 256, 0, stream>>>(scores, sel);
  k_qkv  <<<dim3(8,16), 256, 0, stream>>>(zbuf, sel, iwt, ipb, qb, kb, vb);
  k_attn <<<dim3(4,16), 128, 0, stream>>>(qb, kb, vb, obuf);
  k_oln  <<<dim3(8,16), 256, 0, stream>>>(obuf, zbuf, sel, owt, opb, l1g, l1b, hbuf);
  k_ffn  <<<dim3(8,16), 256, 0, stream>>>(hbuf, f1wt, f1b, f2wt, f2b, l2g, l2b, hbuf);
  k_cls  <<<16, 64, 0, stream>>>(hbuf, cl1w, cl1b, cl2w, cl2b, (float*)d_out);
}

// Round 13
// 291.088 us; speedup vs baseline: 5.9015x; 1.1386x over previous
//
#include <hip/hip_runtime.h>
#include <hip/hip_bf16.h>
#include <math.h>

typedef unsigned short u16;
typedef unsigned int   u32;
typedef unsigned long long u64;
typedef __attribute__((ext_vector_type(8))) short short8v;
typedef __attribute__((ext_vector_type(4))) float f32x4;

__device__ __forceinline__ float bf2f(u16 u) {
  union { u32 i; float f; } v; v.i = ((u32)u) << 16; return v.f;
}
__device__ __forceinline__ u16 f2bf(float f) {  // round-to-nearest-even
  union { float f; u32 i; } v; v.f = f;
  u32 r = (v.i + 0x7FFFu + ((v.i >> 16) & 1u)) >> 16;
  return (u16)r;
}

// ---------------- conv1 + bn1 + relu + maxpool2 via MFMA im2col (K=32, hi/lo input split)
__global__ __launch_bounds__(256, 2) void k_conv1m(
    const float* __restrict__ x,
    const u16* __restrict__ wh, const u16* __restrict__ wl,   // [64][32], bn-scaled
    const float* __restrict__ cb, const float* __restrict__ g, const float* __restrict__ bb,
    u16* __restrict__ feat1, int b0)
{
  __shared__ __align__(16) float sIn[3*18*18];
  __shared__ __align__(16) u16 sAh[256*40], sAl[256*40];
  __shared__ __align__(16) u16 sBh[64*40],  sBl[64*40];
  __shared__ float sBias[64];
  const int tx = blockIdx.x, ty = blockIdx.y, bl = blockIdx.z;
  const int b = b0 + bl;
  const int y0 = ty*16, x0 = tx*16;
  const int tid = threadIdx.x;
  const int w = tid >> 6, l = tid & 63, lr = l & 15, lk = l >> 4;

  if (tid < 64) {
    float sc = g[tid] * rsqrtf(1.0f + 1e-5f);
    sBias[tid] = cb[tid] * sc + bb[tid];
  }
  {  // stage B (64 oc x 32 k, hi/lo)
    const int oc = tid >> 2, seg = tid & 3;
    *reinterpret_cast<uint4*>(&sBh[oc*40 + seg*8]) =
        *reinterpret_cast<const uint4*>(wh + oc*32 + seg*8);
    *reinterpret_cast<uint4*>(&sBl[oc*40 + seg*8]) =
        *reinterpret_cast<const uint4*>(wl + oc*32 + seg*8);
  }
  for (int i = tid; i < 3*18*18; i += 256) {
    const int c = i / 324, r = (i / 18) % 18, q = i % 18;
    const int yy = y0 - 1 + r, xx = x0 - 1 + q;
    float v = 0.f;
    if (yy >= 0 && yy < 256 && xx >= 0 && xx < 256)
      v = x[(((size_t)b*3 + c)*256 + yy)*256 + xx];
    sIn[i] = v;
  }
  __syncthreads();
  {
    const int py = tid >> 4, px = tid & 15;
    u32 hw[16], lw[16];
    #pragma unroll
    for (int i = 0; i < 16; i++) { hw[i] = 0u; lw[i] = 0u; }
    #pragma unroll
    for (int c = 0; c < 3; c++)
      #pragma unroll
      for (int ky = 0; ky < 3; ky++)
        #pragma unroll
        for (int kx = 0; kx < 3; kx++) {
          const int k = c*9 + ky*3 + kx;
          const float v = sIn[(c*18 + py + ky)*18 + px + kx];
          const u16 h  = f2bf(v);
          const u16 lo = f2bf(v - bf2f(h));
          hw[k >> 1] |= ((u32)h)  << ((k & 1)*16);
          lw[k >> 1] |= ((u32)lo) << ((k & 1)*16);
        }
    #pragma unroll
    for (int s = 0; s < 4; s++) {
      uint4 vh, vl;
      vh.x = hw[s*4+0]; vh.y = hw[s*4+1]; vh.z = hw[s*4+2]; vh.w = hw[s*4+3];
      vl.x = lw[s*4+0]; vl.y = lw[s*4+1]; vl.z = lw[s*4+2]; vl.w = lw[s*4+3];
      *reinterpret_cast<uint4*>(&sAh[tid*40 + s*8]) = vh;
      *reinterpret_cast<uint4*>(&sAl[tid*40 + s*8]) = vl;
    }
  }
  __syncthreads();
  f32x4 acc[4][4];
  #pragma unroll
  for (int j = 0; j < 4; j++)
    #pragma unroll
    for (int ct = 0; ct < 4; ct++)
      acc[j][ct] = (f32x4){0.f,0.f,0.f,0.f};
  #pragma unroll
  for (int j = 0; j < 4; j++) {
    const int mt = w*4 + j;
    const short8v ah = *reinterpret_cast<const short8v*>(&sAh[(mt*16 + lr)*40 + lk*8]);
    const short8v al = *reinterpret_cast<const short8v*>(&sAl[(mt*16 + lr)*40 + lk*8]);
    #pragma unroll
    for (int ct = 0; ct < 4; ct++) {
      const short8v bh = *reinterpret_cast<const short8v*>(&sBh[(ct*16 + lr)*40 + lk*8]);
      const short8v bv = *reinterpret_cast<const short8v*>(&sBl[(ct*16 + lr)*40 + lk*8]);
      acc[j][ct] = __builtin_amdgcn_mfma_f32_16x16x32_bf16(ah, bh, acc[j][ct], 0, 0, 0);
      acc[j][ct] = __builtin_amdgcn_mfma_f32_16x16x32_bf16(ah, bv, acc[j][ct], 0, 0, 0);
      acc[j][ct] = __builtin_amdgcn_mfma_f32_16x16x32_bf16(al, bh, acc[j][ct], 0, 0, 0);
      acc[j][ct] = __builtin_amdgcn_mfma_f32_16x16x32_bf16(al, bv, acc[j][ct], 0, 0, 0);
    }
  }
  #pragma unroll
  for (int j = 0; j < 2; j++) {
    const int jA = 2*j, jB = 2*j + 1;
    const int oy = ty*8 + w*2 + j;
    #pragma unroll
    for (int xh = 0; xh < 2; xh++) {
      const int ox = tx*8 + lk*2 + xh;
      #pragma unroll
      for (int ct = 0; ct < 4; ct++) {
        const int oc = ct*16 + lr;
        float m = fmaxf(fmaxf(acc[jA][ct][2*xh], acc[jA][ct][2*xh+1]),
                        fmaxf(acc[jB][ct][2*xh], acc[jB][ct][2*xh+1]));
        m = fmaxf(m + sBias[oc], 0.f);
        feat1[(((size_t)bl*128 + oy)*128 + ox)*64 + oc] = f2bf(m);
      }
    }
  }
}

// ---------------- conv2 + bn2 + relu + maxpool2 via MFMA implicit GEMM
__global__ __launch_bounds__(256, 2) void k_conv2m(
    const u16* __restrict__ feat1,
    const u16* __restrict__ wh, const u16* __restrict__ wl,
    const float* __restrict__ cb, const float* __restrict__ g, const float* __restrict__ bb,
    u16* __restrict__ feat2)
{
  __shared__ __align__(16) u16 sA[18*34*40];
  __shared__ __align__(16) u16 sBh[64*40], sBl[64*40];
  __shared__ float sBias[64];
  const int tx = blockIdx.x, ty = blockIdx.y, bl = blockIdx.z;
  const int y0 = ty*16, x0 = tx*32;
  const int tid = threadIdx.x;
  const int w = tid >> 6, l = tid & 63;
  const int lr = l & 15, lk = l >> 4;

  if (tid < 64) {
    float sc = g[tid] * rsqrtf(1.0f + 1e-5f);
    sBias[tid] = cb[tid] * sc + bb[tid];
  }

  f32x4 acc[8][4];
  #pragma unroll
  for (int j = 0; j < 8; j++)
    #pragma unroll
    for (int ct = 0; ct < 4; ct++)
      acc[j][ct] = (f32x4){0.f,0.f,0.f,0.f};

  for (int chunk = 0; chunk < 2; chunk++) {
    __syncthreads();
    for (int idx = tid; idx < 612*4; idx += 256) {
      const int pix = idx >> 2, seg = idx & 3;
      const int r = pix / 34, cc = pix % 34;
      const int yy = y0 - 1 + r, xx = x0 - 1 + cc;
      uint4 v = {0u,0u,0u,0u};
      if (yy >= 0 && yy < 128 && xx >= 0 && xx < 128)
        v = *reinterpret_cast<const uint4*>(
              feat1 + (((size_t)bl*128 + yy)*128 + xx)*64 + chunk*32 + seg*8);
      *reinterpret_cast<uint4*>(&sA[(size_t)(r*34 + cc)*40 + seg*8]) = v;
    }
    for (int kk = 0; kk < 9; kk++) {
      __syncthreads();
      {
        const int oc = tid >> 2, s8 = (tid & 3)*8;
        const size_t src = (size_t)(kk*2 + chunk)*2048 + tid*8;
        *reinterpret_cast<uint4*>(&sBh[oc*40 + s8]) = *reinterpret_cast<const uint4*>(wh + src);
        *reinterpret_cast<uint4*>(&sBl[oc*40 + s8]) = *reinterpret_cast<const uint4*>(wl + src);
      }
      __syncthreads();
      const int ky = kk / 3, kx = kk % 3;
      short8v a[8];
      #pragma unroll
      for (int j = 0; j < 8; j++) {
        const int m = w*8 + j;
        const int r = (m >> 1) + ky;
        const int cc = (m & 1)*16 + lr + kx;
        a[j] = *reinterpret_cast<const short8v*>(&sA[(size_t)(r*34 + cc)*40 + lk*8]);
      }
      #pragma unroll
      for (int ct = 0; ct < 4; ct++) {
        const short8v bh = *reinterpret_cast<const short8v*>(&sBh[(ct*16 + lr)*40 + lk*8]);
        const short8v bv = *reinterpret_cast<const short8v*>(&sBl[(ct*16 + lr)*40 + lk*8]);
        #pragma unroll
        for (int j = 0; j < 8; j++) {
          acc[j][ct] = __builtin_amdgcn_mfma_f32_16x16x32_bf16(a[j], bh, acc[j][ct], 0, 0, 0);
          acc[j][ct] = __builtin_amdgcn_mfma_f32_16x16x32_bf16(a[j], bv, acc[j][ct], 0, 0, 0);
        }
      }
    }
  }
  #pragma unroll
  for (int u = 0; u < 2; u++) {
    #pragma unroll
    for (int xh = 0; xh < 2; xh++) {
      const int jA = 4*u + xh, jB = 4*u + 2 + xh;
      #pragma unroll
      for (int ct = 0; ct < 4; ct++) {
        const int oc = ct*16 + lr;
        const float bias = sBias[oc];
        const float v0 = fmaxf(fmaxf(acc[jA][ct][0], acc[jA][ct][1]),
                               fmaxf(acc[jB][ct][0], acc[jB][ct][1]));
        const float v1 = fmaxf(fmaxf(acc[jA][ct][2], acc[jA][ct][3]),
                               fmaxf(acc[jB][ct][2], acc[jB][ct][3]));
        const u16 b0v = f2bf(fmaxf(v0 + bias, 0.f));
        const u16 b1v = f2bf(fmaxf(v1 + bias, 0.f));
        const int py = ty*8 + 2*w + u;
        const int px = tx*16 + xh*8 + lk*2;
        u32 pk = (u32)b0v | ((u32)b1v << 16);
        *reinterpret_cast<u32*>(&feat2[(((size_t)bl*64 + oc)*64 + py)*64 + px]) = pk;
      }
    }
  }
}

// ---------------- adjacency phase 1: 8-NN per node, 225 blocks (stable (d2,j) order)
__global__ __launch_bounds__(256) void k_adj1(int* __restrict__ nbr1)
{
  __shared__ int skey[256];
  __shared__ int sred[256];
  const int i = blockIdx.x;
  const int tid = threadIdx.x;
  int key = 0x7FFFFFFF;
  if (tid < 225 && tid != i) {
    const int di = i/15 - tid/15, dj = i%15 - tid%15;
    key = (di*di + dj*dj)*256 + tid;
  }
  skey[tid] = key;
  __syncthreads();
  for (int t = 0; t < 8; t++) {
    sred[tid] = skey[tid];
    __syncthreads();
    #pragma unroll
    for (int st = 128; st > 0; st >>= 1) {
      if (tid < st) sred[tid] = min(sred[tid], sred[tid+st]);
      __syncthreads();
    }
    const int wj = sred[0] & 255;
    if (tid == 0) nbr1[i*8 + t] = wj;
    __syncthreads();
    if (tid == wj) skey[tid] = 0x7FFFFFFF;
    __syncthreads();
  }
}

// ---------------- adjacency phase 2: mask2 = rows of (adj@adj>0) minus diagonal
__global__ __launch_bounds__(256) void k_adj2(
    const int* __restrict__ nbr1, u64* __restrict__ mask2)
{
  const int i = threadIdx.x;
  if (i >= 225) return;
  u64 m0=0, m1=0, m2=0, m3=0;
  #pragma unroll
  for (int t = 0; t < 8; t++) {
    const int tt = nbr1[i*8 + t];
    #pragma unroll
    for (int u = 0; u < 8; u++) {
      const int j = nbr1[tt*8 + u];
      const u64 bset = 1ull << (j & 63);
      const int wd = j >> 6;
      m0 |= (wd == 0) ? bset : 0ull;
      m1 |= (wd == 1) ? bset : 0ull;
      m2 |= (wd == 2) ? bset : 0ull;
      m3 |= (wd == 3) ? bset : 0ull;
    }
  }
  {
    const u64 bc = ~(1ull << (i & 63));
    const int wd = i >> 6;
    if (wd == 0) m0 &= bc; else if (wd == 1) m1 &= bc;
    else if (wd == 2) m2 &= bc; else m3 &= bc;
  }
  mask2[i*4+0] = m0; mask2[i*4+1] = m1; mask2[i*4+2] = m2; mask2[i*4+3] = m3;
}

// ---------------- fused weight prep
__global__ __launch_bounds__(256) void k_prep(
    const float* __restrict__ pjw, u16* __restrict__ pwh, u16* __restrict__ pwl,
    const float* __restrict__ c2w, const float* __restrict__ bn2g,
    u16* __restrict__ wc2h, u16* __restrict__ wc2l,
    const float* __restrict__ c1w, const float* __restrict__ bn1g,
    u16* __restrict__ wc1h, u16* __restrict__ wc1l,
    const float* __restrict__ ipw, float* __restrict__ iwt,
    const float* __restrict__ opw, float* __restrict__ owt,
    const float* __restrict__ f1w, float* __restrict__ f1wt,
    const float* __restrict__ f2w, float* __restrict__ f2wt,
    const float* __restrict__ w1w, float* __restrict__ w1t,
    const float* __restrict__ w2w, float* __restrict__ w2t,
    const float* __restrict__ gw,  float* __restrict__ gwt)
{
  const int blk = blockIdx.x, tid = threadIdx.x;
  if (blk < 512) {
    const int i = (blk*256 + tid) * 4;
    float4 v = *reinterpret_cast<const float4*>(pjw + i);
    float e[4] = {v.x, v.y, v.z, v.w};
    ushort4 h, l;
    u16* hp = &h.x; u16* lp = &l.x;
    #pragma unroll
    for (int j = 0; j < 4; j++) {
      u16 hb = f2bf(e[j]);
      hp[j] = hb;
      lp[j] = f2bf(e[j] - bf2f(hb));
    }
    *reinterpret_cast<ushort4*>(pwh + i) = h;
    *reinterpret_cast<ushort4*>(pwl + i) = l;
  } else if (blk < 656) {
    const int d = (blk - 512)*256 + tid;
    if (d < 36864) {
      const int icL = d & 31, oc = (d >> 5) & 63, chunk = (d >> 11) & 1, kk = d >> 12;
      const float sc = bn2g[oc] * rsqrtf(1.0f + 1e-5f);
      const float val = c2w[((size_t)oc*64 + chunk*32 + icL)*9 + kk] * sc;
      const u16 hb = f2bf(val);
      wc2h[d] = hb;
      wc2l[d] = f2bf(val - bf2f(hb));
    }
  } else if (blk < 664) {
    const int d = (blk - 656)*256 + tid;
    if (d < 2048) {
      const int k = d & 31, oc = d >> 5;
      float val = 0.f;
      if (k < 27) val = c1w[oc*27 + k] * (bn1g[oc] * rsqrtf(1.0f + 1e-5f));
      const u16 hb = f2bf(val);
      wc1h[d] = hb;
      wc1l[d] = f2bf(val - bf2f(hb));
    }
  } else {
    const float* src; float* dst; int O, K, base;
    if      (blk <  856) { src = ipw; dst = iwt;  O = 384; K = 128; base = 664;  }
    else if (blk <  920) { src = opw; dst = owt;  O = 128; K = 128; base = 856;  }
    else if (blk < 1176) { src = f1w; dst = f1wt; O = 512; K = 128; base = 920;  }
    else if (blk < 1432) { src = f2w; dst = f2wt; O = 128; K = 512; base = 1176; }
    else if (blk < 1496) { src = w1w; dst = w1t;  O = 128; K = 128; base = 1432; }
    else if (blk < 1560) { src = w2w; dst = w2t;  O = 128; K = 128; base = 1496; }
    else                 { src = gw;  dst = gwt;  O = 128; K = 256; base = 1560; }
    const int idx = (blk - base)*256 + tid;
    if (idx < O * K) {
      const int o = idx / K, k = idx % K;
      dst[(size_t)k * O + o] = src[idx];
    }
  }
}

// ---------------- patch-projection MFMA GEMM, split-K=4 + register prefetch
__global__ __launch_bounds__(256, 2) void k_projm(
    const u16* __restrict__ feat2,
    const u16* __restrict__ pwh, const u16* __restrict__ pwl,
    float* __restrict__ partial, int b0)
{
  __shared__ __align__(16) u16 sA [64][40];
  __shared__ __align__(16) u16 sBh[128][40];
  __shared__ __align__(16) u16 sBl[128][40];
  const int cx = blockIdx.x, kc = blockIdx.y, bl = blockIdx.z;
  const int b  = b0 + bl;
  const int n0 = cx * 64;
  const int rows = (225 - n0) < 64 ? (225 - n0) : 64;
  const int tid = threadIdx.x;
  const int w = tid >> 6, l = tid & 63;
  const int lr = l & 15, lk = l >> 4;

  f32x4 acc[8];
  #pragma unroll
  for (int i = 0; i < 8; i++) acc[i] = (f32x4){0.f, 0.f, 0.f, 0.f};

  const int ar = tid >> 2, aci = tid & 3;
  const int an = n0 + ar;
  const int aph = an / 15, apw = an % 15;
  const int kbeg = kc * 1024, kend = kbeg + 1024;

  uint4 pA, pBh[2], pBl[2];
  auto loadstep = [&](int k0) {
    const int c  = k0 >> 6;
    const int i0 = (k0 & 63) >> 3;
    uint2 g0 = {0u,0u}, g1 = {0u,0u};
    if (ar < rows) {
      const u16* src = feat2 + (((size_t)bl*64 + c)*64 + aph*4 + i0 + aci)*64 + apw*4;
      g0 = *reinterpret_cast<const uint2*>(src);
      g1 = *reinterpret_cast<const uint2*>(src + 4);
    }
    pA.x = g0.x; pA.y = g0.y; pA.z = g1.x; pA.w = g1.y;
    #pragma unroll
    for (int p = 0; p < 2; p++) {
      const int idx = p*256 + tid;
      const int col = idx >> 2, seg = idx & 3;
      const size_t off = (size_t)col*4096 + k0 + seg*8;
      pBh[p] = *reinterpret_cast<const uint4*>(pwh + off);
      pBl[p] = *reinterpret_cast<const uint4*>(pwl + off);
    }
  };

  loadstep(kbeg);
  for (int k0 = kbeg; k0 < kend; k0 += 32) {
    __syncthreads();
    *reinterpret_cast<uint4*>(&sA[ar][aci*8]) = pA;
    #pragma unroll
    for (int p = 0; p < 2; p++) {
      const int idx = p*256 + tid;
      const int col = idx >> 2, seg = idx & 3;
      *reinterpret_cast<uint4*>(&sBh[col][seg*8]) = pBh[p];
      *reinterpret_cast<uint4*>(&sBl[col][seg*8]) = pBl[p];
    }
    __syncthreads();
    if (k0 + 32 < kend) loadstep(k0 + 32);
    short8v a = *reinterpret_cast<const short8v*>(&sA[w*16 + lr][lk*8]);
    #pragma unroll
    for (int ct = 0; ct < 8; ct++) {
      short8v bh = *reinterpret_cast<const short8v*>(&sBh[ct*16 + lr][lk*8]);
      short8v bv = *reinterpret_cast<const short8v*>(&sBl[ct*16 + lr][lk*8]);
      acc[ct] = __builtin_amdgcn_mfma_f32_16x16x32_bf16(a, bh, acc[ct], 0, 0, 0);
      acc[ct] = __builtin_amdgcn_mfma_f32_16x16x32_bf16(a, bv, acc[ct], 0, 0, 0);
    }
  }
  #pragma unroll
  for (int ct = 0; ct < 8; ct++) {
    const int col = ct*16 + lr;
    #pragma unroll
    for (int v = 0; v < 4; v++) {
      const int r = w*16 + lk*4 + v;
      if (r < rows)
        partial[(((size_t)kc*16 + b)*225 + n0 + r)*128 + col] = acc[ct][v];
    }
  }
}

// ---------------- reduce split-K partials + bias -> nodes
__global__ __launch_bounds__(128) void k_projr(
    const float* __restrict__ partial, const float* __restrict__ pb,
    float* __restrict__ nodes, int b0)
{
  const int n = blockIdx.x, bl = blockIdx.y;
  const int b = b0 + bl;
  const int d = threadIdx.x;
  float s = pb[d];
  #pragma unroll
  for (int kc = 0; kc < 4; kc++)
    s += partial[(((size_t)kc*16 + b)*225 + n)*128 + d];
  nodes[((size_t)b*225 + n)*128 + d] = s;
}

// ---------------- neighbor aggregation: a1/a2 per (b,node)
__global__ __launch_bounds__(128) void k_agg(
    const float* __restrict__ nodes, const int* __restrict__ nbr1,
    const u64* __restrict__ mask2,
    float* __restrict__ a1buf, float* __restrict__ a2buf)
{
  const int n = blockIdx.x, b = blockIdx.y;
  const int d = threadIdx.x;
  const float* nb = nodes + (size_t)b * 225 * 128;
  float a1 = 0.f;
  #pragma unroll
  for (int t = 0; t < 8; t++) a1 += nb[(size_t)nbr1[n*8+t]*128 + d];
  float a2 = 0.f;
  for (int wd = 0; wd < 4; wd++) {
    u64 m = mask2[n*4 + wd];
    while (m) {
      int j = wd*64 + __builtin_ctzll(m);
      a2 += nb[(size_t)j*128 + d];
      m &= m - 1;
    }
  }
  a1buf[((size_t)b*225 + n)*128 + d] = a1;
  a2buf[((size_t)b*225 + n)*128 + d] = a2;
}

// ---------------- z1/z2/gate/score: 2 rows per block (1800 blocks -> high TLP)
__global__ __launch_bounds__(256) void k_gz(
    const float* __restrict__ a1buf, const float* __restrict__ a2buf,
    const float* __restrict__ w1t, const float* __restrict__ w1b,
    const float* __restrict__ w2t, const float* __restrict__ w2b,
    const float* __restrict__ gwt, const float* __restrict__ gb,
    const float* __restrict__ sw, const float* __restrict__ sb,
    float* __restrict__ zbuf, float* __restrict__ scores)
{
  __shared__ float sA1[2][128], sA2[2][128], sC[2][256], sRed[2][128];
  const int row0 = blockIdx.x * 2;
  const int tid = threadIdx.x;
  const int d = tid & 127, rr = tid >> 7;
  const int row = row0 + rr;
  sA1[rr][d] = a1buf[(size_t)row*128 + d];
  sA2[rr][d] = a2buf[(size_t)row*128 + d];
  __syncthreads();
  float z1 = w1b[d], z2 = w2b[d];
  #pragma unroll 4
  for (int k = 0; k < 128; k++) {
    z1 += w1t[k*128 + d] * sA1[rr][k];
    z2 += w2t[k*128 + d] * sA2[rr][k];
  }
  sC[rr][d] = z1; sC[rr][128 + d] = z2;
  __syncthreads();
  float gl = gb[d];
  #pragma unroll 4
  for (int k = 0; k < 256; k++)
    gl += gwt[k*128 + d] * sC[rr][k];
  const float gg = 1.f / (1.f + expf(-gl));
  const float zv = gg * z1 + (1.f - gg) * z2;
  zbuf[(size_t)row*128 + d] = zv;
  sRed[rr][d] = zv * sw[d];
  __syncthreads();
  if (tid < 32) {
    const int r = tid >> 4, j = tid & 15;
    float part = 0.f;
    #pragma unroll
    for (int i = 0; i < 8; i++) part += sRed[r][j*8 + i];
    #pragma unroll
    for (int m = 8; m >= 1; m >>= 1) part += __shfl_xor(part, m, 64);
    if (j == 0) scores[row0 + r] = part + sb[0];
  }
}

// ---------------- top-k (k=112) with jax tie semantics
__global__ __launch_bounds__(256) void k_topk(
    const float* __restrict__ scores, int* __restrict__ sel)
{
  __shared__ float ss[225];
  const int b = blockIdx.x, tid = threadIdx.x;
  if (tid < 112) sel[b*112 + tid] = tid;
  if (tid < 225) ss[tid] = scores[b*225 + tid];
  __syncthreads();
  if (tid < 225) {
    float s = ss[tid];
    int rank = 0;
    for (int j = 0; j < 225; j++) {
      float sj = ss[j];
      rank += (sj > s) || (sj == s && j < tid);
    }
    if (rank < 112) sel[b*112 + rank] = tid;
  }
}

// ---------------- qkv batched: 14 rows per block
__global__ __launch_bounds__(256) void k_qkv(
    const float* __restrict__ zbuf, const int* __restrict__ sel,
    const float* __restrict__ iwt, const float* __restrict__ ib,
    float* __restrict__ q, float* __restrict__ k, float* __restrict__ v)
{
  __shared__ float sx[14][128];
  const int s0 = blockIdx.x * 14, b = blockIdx.y;
  const int tid = threadIdx.x;
  const int c = tid & 127, half = tid >> 7;
  const int r0 = half * 7;

  for (int idx = tid; idx < 14*128; idx += 256) {
    const int r = idx >> 7, dd = idx & 127;
    int row = sel[b*112 + s0 + r];
    row = row < 0 ? 0 : (row > 224 ? 224 : row);
    sx[r][dd] = zbuf[((size_t)b*225 + row)*128 + dd];
  }
  __syncthreads();

  float acc[3][7];
  #pragma unroll
  for (int p = 0; p < 3; p++)
    #pragma unroll
    for (int rr = 0; rr < 7; rr++) acc[p][rr] = ib[p*128 + c];
  for (int kk = 0; kk < 128; kk++) {
    float wv[3];
    #pragma unroll
    for (int p = 0; p < 3; p++) wv[p] = iwt[kk*384 + p*128 + c];
    #pragma unroll
    for (int rr = 0; rr < 7; rr++) {
      const float xv = sx[r0 + rr][kk];
      #pragma unroll
      for (int p = 0; p < 3; p++) acc[p][rr] += wv[p] * xv;
    }
  }
  const int h = c >> 5, t = c & 31;
  float* outs[3] = {q, k, v};
  #pragma unroll
  for (int p = 0; p < 3; p++)
    #pragma unroll
    for (int rr = 0; rr < 7; rr++)
      outs[p][(((size_t)b*4 + h)*112 + s0 + r0 + rr)*32 + t] = acc[p][rr];
}

// ---------------- attention: 512 blocks (8 q-chunks x 4 heads x 16 b), 16 thr/query
__global__ __launch_bounds__(256) void k_attn(
    const float* __restrict__ q, const float* __restrict__ k,
    const float* __restrict__ v, float* __restrict__ o)
{
  __shared__ float sK[112*33], sV[112*33];   // pitch 33: conflict-free strided dots
  __shared__ float sQ[14*33];
  __shared__ float sP[14][112];
  const int qc = blockIdx.x, h = blockIdx.y, b = blockIdx.z;
  const size_t base = ((size_t)b*4 + h) * 112 * 32;
  const int tid = threadIdx.x;
  for (int i = tid; i < 112*32; i += 256) {
    const int r = i >> 5, c = i & 31;
    sK[r*33 + c] = k[base + i];
    sV[r*33 + c] = v[base + i];
  }
  for (int i = tid; i < 14*32; i += 256) {
    const int r = i >> 5, c = i & 31;
    sQ[r*33 + c] = q[base + (size_t)(qc*14)*32 + i];
  }
  __syncthreads();
  const int qg = tid >> 4, j = tid & 15;
  if (qg < 14) {
    const float scale = 0.17677669529663687f;
    float pv[7];
    float mx = -INFINITY;
    #pragma unroll
    for (int t7 = 0; t7 < 7; t7++) {
      const int kk = j + t7*16;
      float s = 0.f;
      #pragma unroll
      for (int t = 0; t < 32; t++) s += sQ[qg*33 + t] * sK[kk*33 + t];
      pv[t7] = s * scale;
      mx = fmaxf(mx, pv[t7]);
    }
    #pragma unroll
    for (int m = 8; m >= 1; m >>= 1) mx = fmaxf(mx, __shfl_xor(mx, m, 16));
    float lsum = 0.f;
    #pragma unroll
    for (int t7 = 0; t7 < 7; t7++) { pv[t7] = expf(pv[t7] - mx); lsum += pv[t7]; }
    #pragma unroll
    for (int m = 8; m >= 1; m >>= 1) lsum += __shfl_xor(lsum, m, 16);
    const float inv = 1.f / lsum;
    #pragma unroll
    for (int t7 = 0; t7 < 7; t7++) sP[qg][j + t7*16] = pv[t7] * inv;
  }
  __syncthreads();
  if (qg < 14) {
    const int s = qc*14 + qg;
    float o0 = 0.f, o1 = 0.f;
    for (int kk = 0; kk < 112; kk++) {
      const float p = sP[qg][kk];
      o0 += p * sV[kk*33 + j];
      o1 += p * sV[kk*33 + j + 16];
    }
    float* op = o + ((size_t)b*112 + s)*128 + h*32;
    op[j] = o0;
    op[j + 16] = o1;
  }
}

// ---------------- out-proj + residual + LN1, batched 14 rows/block
__global__ __launch_bounds__(256) void k_oln(
    const float* __restrict__ o, const float* __restrict__ zbuf,
    const int* __restrict__ sel,
    const float* __restrict__ owt, const float* __restrict__ ob,
    const float* __restrict__ lg, const float* __restrict__ lb,
    float* __restrict__ h1)
{
  __shared__ float sO[14][128], sV[14][128];
  __shared__ float sMean[14], sRstd[14];
  const int s0 = blockIdx.x * 14, b = blockIdx.y;
  const int tid = threadIdx.x;
  const int d = tid & 127, half = tid >> 7;
  const int r0 = half * 7;

  for (int idx = tid; idx < 14*128; idx += 256) {
    const int r = idx >> 7, dd = idx & 127;
    sO[r][dd] = o[((size_t)b*112 + s0 + r)*128 + dd];
  }
  __syncthreads();

  float acc[7];
  #pragma unroll
  for (int rr = 0; rr < 7; rr++) acc[rr] = ob[d];
  for (int kk = 0; kk < 128; kk++) {
    const float wv = owt[kk*128 + d];
    #pragma unroll
    for (int rr = 0; rr < 7; rr++) acc[rr] += wv * sO[r0 + rr][kk];
  }
  #pragma unroll
  for (int rr = 0; rr < 7; rr++) {
    int row = sel[b*112 + s0 + r0 + rr];
    row = row < 0 ? 0 : (row > 224 ? 224 : row);
    acc[rr] += zbuf[((size_t)b*225 + row)*128 + d];
    sV[r0 + rr][d] = acc[rr];
  }
  __syncthreads();
  {
    const int r = tid >> 4, j = tid & 15;
    if (r < 14) {
      float p1 = 0.f, p2 = 0.f;
      #pragma unroll
      for (int i = 0; i < 8; i++) { float v = sV[r][j*8 + i]; p1 += v; p2 += v*v; }
      #pragma unroll
      for (int m = 8; m >= 1; m >>= 1) {
        p1 += __shfl_xor(p1, m, 64);
        p2 += __shfl_xor(p2, m, 64);
      }
      if (j == 0) {
        const float mean = p1 * (1.f/128.f);
        sMean[r] = mean;
        sRstd[r] = rsqrtf(p2 * (1.f/128.f) - mean*mean + 1e-5f);
      }
    }
  }
  __syncthreads();
  for (int idx = tid; idx < 14*128; idx += 256) {
    const int r = idx >> 7, dd = idx & 127;
    h1[((size_t)b*112 + s0 + r)*128 + dd] =
        (sV[r][dd] - sMean[r]) * sRstd[r] * lg[dd] + lb[dd];
  }
}

// ---------------- FFN + residual + LN2, batched 14 rows/block (in-place safe)
__global__ __launch_bounds__(256) void k_ffn(
    const float* __restrict__ h1,
    const float* __restrict__ f1wt, const float* __restrict__ f1b,
    const float* __restrict__ f2wt, const float* __restrict__ f2b,
    const float* __restrict__ lg, const float* __restrict__ lb,
    float* __restrict__ h2)
{
  __shared__ float sh[14][128];
  __shared__ float sf[14][512];
  __shared__ float sV[14][128];
  __shared__ float sMean[14], sRstd[14];
  const int s0 = blockIdx.x * 14, b = blockIdx.y;
  const int tid = threadIdx.x;
  const int d = tid & 127, half = tid >> 7;
  const int r0 = half * 7;

  for (int idx = tid; idx < 14*128; idx += 256) {
    const int r = idx >> 7, dd = idx & 127;
    sh[r][dd] = h1[((size_t)b*112 + s0 + r)*128 + dd];
  }
  __syncthreads();
  {
    float a0[14], a1[14];
    const float b0 = f1b[tid], b1 = f1b[tid + 256];
    #pragma unroll
    for (int r = 0; r < 14; r++) { a0[r] = b0; a1[r] = b1; }
    for (int kk = 0; kk < 128; kk++) {
      const float w0 = f1wt[kk*512 + tid];
      const float w1 = f1wt[kk*512 + tid + 256];
      #pragma unroll
      for (int r = 0; r < 14; r++) {
        const float xv = sh[r][kk];
        a0[r] += w0 * xv;
        a1[r] += w1 * xv;
      }
    }
    #pragma unroll
    for (int r = 0; r < 14; r++) {
      sf[r][tid]       = fmaxf(a0[r], 0.f);
      sf[r][tid + 256] = fmaxf(a1[r], 0.f);
    }
  }
  __syncthreads();
  {
    float acc[7];
    #pragma unroll
    for (int rr = 0; rr < 7; rr++) acc[rr] = f2b[d];
    for (int kk = 0; kk < 512; kk++) {
      const float wv = f2wt[kk*128 + d];
      #pragma unroll
      for (int rr = 0; rr < 7; rr++) acc[rr] += wv * sf[r0 + rr][kk];
    }
    #pragma unroll
    for (int rr = 0; rr < 7; rr++)
      sV[r0 + rr][d] = sh[r0 + rr][d] + acc[rr];
  }
  __syncthreads();
  {
    const int r = tid >> 4, j = tid & 15;
    if (r < 14) {
      float p1 = 0.f, p2 = 0.f;
      #pragma unroll
      for (int i = 0; i < 8; i++) { float v = sV[r][j*8 + i]; p1 += v; p2 += v*v; }
      #pragma unroll
      for (int m = 8; m >= 1; m >>= 1) {
        p1 += __shfl_xor(p1, m, 64);
        p2 += __shfl_xor(p2, m, 64);
      }
      if (j == 0) {
        const float mean = p1 * (1.f/128.f);
        sMean[r] = mean;
        sRstd[r] = rsqrtf(p2 * (1.f/128.f) - mean*mean + 1e-5f);
      }
    }
  }
  __syncthreads();
  for (int idx = tid; idx < 14*128; idx += 256) {
    const int r = idx >> 7, dd = idx & 127;
    h2[((size_t)b*112 + s0 + r)*128 + dd] =
        (sV[r][dd] - sMean[r]) * sRstd[r] * lg[dd] + lb[dd];
  }
}

// ---------------- rep = sum_s h2 ; classifier -> logits (f32)
__global__ __launch_bounds__(64) void k_cls(
    const float* __restrict__ h2,
    const float* __restrict__ c1w, const float* __restrict__ c1b,
    const float* __restrict__ c2w, const float* __restrict__ c2b,
    float* __restrict__ out)
{
  __shared__ float sr[128], sc[64];
  const int b = blockIdx.x, tid = threadIdx.x;
  float r0 = 0.f, r1 = 0.f;
  for (int s2 = 0; s2 < 112; s2++) {
    const float* row = h2 + ((size_t)b*112 + s2)*128;
    r0 += row[tid];
    r1 += row[tid + 64];
  }
  sr[tid] = r0; sr[tid + 64] = r1;
  __syncthreads();
  float acc = c1b[tid];
  const float* wr = c1w + (size_t)tid * 128;
  for (int kk = 0; kk < 128; kk++) acc += wr[kk] * sr[kk];
  sc[tid] = fmaxf(acc, 0.f);
  __syncthreads();
  if (tid < 2) {
    float l = c2b[tid];
    for (int kk = 0; kk < 64; kk++) l += c2w[tid*64 + kk] * sc[kk];
    out[b*2 + tid] = l;
  }
}

extern "C" void kernel_launch(void* const* d_in, const int* in_sizes, int n_in,
                              void* d_out, int out_size, void* d_ws, size_t ws_size,
                              hipStream_t stream)
{
  const float* x    = (const float*)d_in[0];
  const float* c1w  = (const float*)d_in[1];
  const float* c1b  = (const float*)d_in[2];
  const float* bn1g = (const float*)d_in[3];
  const float* bn1b = (const float*)d_in[4];
  const float* c2w  = (const float*)d_in[5];
  const float* c2b  = (const float*)d_in[6];
  const float* bn2g = (const float*)d_in[7];
  const float* bn2b = (const float*)d_in[8];
  const float* pjw  = (const float*)d_in[9];
  const float* pjb  = (const float*)d_in[10];
  const float* w1w  = (const float*)d_in[11];
  const float* w1b  = (const float*)d_in[12];
  const float* w2w  = (const float*)d_in[13];
  const float* w2b  = (const float*)d_in[14];
  const float* gw   = (const float*)d_in[15];
  const float* gb   = (const float*)d_in[16];
  const float* scw  = (const float*)d_in[17];
  const float* scb  = (const float*)d_in[18];
  const float* ipw  = (const float*)d_in[19];
  const float* ipb  = (const float*)d_in[20];
  const float* opw  = (const float*)d_in[21];
  const float* opb  = (const float*)d_in[22];
  const float* f1w  = (const float*)d_in[23];
  const float* f1b  = (const float*)d_in[24];
  const float* f2w  = (const float*)d_in[25];
  const float* f2b  = (const float*)d_in[26];
  const float* l1g  = (const float*)d_in[27];
  const float* l1b  = (const float*)d_in[28];
  const float* l2g  = (const float*)d_in[29];
  const float* l2b  = (const float*)d_in[30];
  const float* cl1w = (const float*)d_in[31];
  const float* cl1b = (const float*)d_in[32];
  const float* cl2w = (const float*)d_in[33];
  const float* cl2b = (const float*)d_in[34];

  // ---- bump allocator over d_ws (256-B aligned) ----
  char* p = (char*)d_ws;
  auto alloc = [&](size_t n) { char* r = p; p += (n + 255) & ~(size_t)255; return r; };
  u64*   mask2  = (u64*)  alloc(900    * sizeof(u64));
  int*   nbr1   = (int*)  alloc(1800   * sizeof(int));
  int*   sel    = (int*)  alloc(1792   * sizeof(int));
  float* scores = (float*)alloc(3600   * sizeof(float));
  u16*   pwh    = (u16*)  alloc(524288 * sizeof(u16));
  u16*   pwl    = (u16*)  alloc(524288 * sizeof(u16));
  u16*   wc2h   = (u16*)  alloc(36864  * sizeof(u16));
  u16*   wc2l   = (u16*)  alloc(36864  * sizeof(u16));
  u16*   wc1h   = (u16*)  alloc(2048   * sizeof(u16));
  u16*   wc1l   = (u16*)  alloc(2048   * sizeof(u16));
  float* iwt    = (float*)alloc(49152  * sizeof(float));
  float* owt    = (float*)alloc(16384  * sizeof(float));
  float* f1wt   = (float*)alloc(65536  * sizeof(float));
  float* f2wt   = (float*)alloc(65536  * sizeof(float));
  float* w1t    = (float*)alloc(16384  * sizeof(float));
  float* w2t    = (float*)alloc(16384  * sizeof(float));
  float* gwt    = (float*)alloc(32768  * sizeof(float));
  float* partial= (float*)alloc(4ull*16*225*128 * sizeof(float));
  float* a1buf  = (float*)alloc(460800 * sizeof(float));
  float* a2buf  = (float*)alloc(460800 * sizeof(float));
  float* zbuf   = (float*)alloc(460800 * sizeof(float));
  float* nodes  = (float*)alloc(460800 * sizeof(float));
  const size_t fixed_bytes = (size_t)(p - (char*)d_ws);

  const size_t qkv_bytes = 3ull * 229376ull * sizeof(float);
  const size_t per_batch = 64ull*128*128*2 + 64ull*64*64*2;   // 2,621,440 B
  int BC = 16;
  size_t s3 = 0;
  for (;; BC >>= 1) {
    s3 = (size_t)BC * per_batch; if (s3 < qkv_bytes) s3 = qkv_bytes;
    if (fixed_bytes + s3 + 65536 <= ws_size) break;
    if (BC == 1) { return; }
  }
  char* S3 = alloc(s3);

  u16*   feat1 = (u16*)S3;                              // NHWC (BC,128,128,64)
  u16*   feat2 = (u16*)(S3 + (size_t)BC * 2097152ull);  // NCHW (BC,64,64,64)
  float* qb    = (float*)S3;
  float* kb    = qb + 229376;
  float* vb    = kb + 229376;
  float* obuf  = nodes;
  float* hbuf  = nodes + 229376;

  k_adj1<<<225, 256, 0, stream>>>(nbr1);
  k_adj2<<<1, 256, 0, stream>>>(nbr1, mask2);
  k_prep<<<1688, 256, 0, stream>>>(pjw, pwh, pwl, c2w, bn2g, wc2h, wc2l,
                                   c1w, bn1g, wc1h, wc1l,
                                   ipw, iwt, opw, owt, f1w, f1wt, f2w, f2wt,
                                   w1w, w1t, w2w, w2t, gw, gwt);

  for (int b0 = 0; b0 < 16; b0 += BC) {
    k_conv1m<<<dim3(16,16,BC), 256, 0, stream>>>(x, wc1h, wc1l, c1b, bn1g, bn1b, feat1, b0);
    k_conv2m<<<dim3(4,8,BC), 256, 0, stream>>>(feat1, wc2h, wc2l, c2b, bn2g, bn2b, feat2);
    k_projm <<<dim3(4,4,BC), 256, 0, stream>>>(feat2, pwh, pwl, partial, b0);
    k_projr <<<dim3(225,BC), 128, 0, stream>>>(partial, pjb, nodes, b0);
  }

  k_agg  <<<dim3(225,16), 128, 0, stream>>>(nodes, nbr1, mask2, a1buf, a2buf);
  k_gz   <<<1800, 256, 0, stream>>>(a1buf, a2buf, w1t, w1b, w2t, w2b,
                                    gwt, gb, scw, scb, zbuf, scores);
  k_topk <<<16, 256, 0, stream>>>(scores, sel);
  k_qkv  <<<dim3(8,16), 256, 0, stream>>>(zbuf, sel, iwt, ipb, qb, kb, vb);
  k_attn <<<dim3(8,4,16), 256, 0, stream>>>(qb, kb, vb, obuf);
  k_oln  <<<dim3(8,16), 256, 0, stream>>>(obuf, zbuf, sel, owt, opb, l1g, l1b, hbuf);
  k_ffn  <<<dim3(8,16), 256, 0, stream>>>(hbuf, f1wt, f1b, f2wt, f2b, l2g, l2b, hbuf);
  k_cls  <<<16, 64, 0, stream>>>(hbuf, cl1w, cl1b, cl2w, cl2b, (float*)d_out);
}

// Round 14
// 288.015 us; speedup vs baseline: 5.9645x; 1.0107x over previous
//
#include <hip/hip_runtime.h>
#include <hip/hip_bf16.h>
#include <math.h>

typedef unsigned short u16;
typedef unsigned int   u32;
typedef unsigned long long u64;
typedef __attribute__((ext_vector_type(8))) short short8v;
typedef __attribute__((ext_vector_type(4))) float f32x4;

__device__ __forceinline__ float bf2f(u16 u) {
  union { u32 i; float f; } v; v.i = ((u32)u) << 16; return v.f;
}
__device__ __forceinline__ u16 f2bf(float f) {  // round-to-nearest-even
  union { float f; u32 i; } v; v.f = f;
  u32 r = (v.i + 0x7FFFu + ((v.i >> 16) & 1u)) >> 16;
  return (u16)r;
}

// ---------------- conv1 + bn1 + relu + maxpool2 via MFMA im2col (K=32, hi/lo input split)
__global__ __launch_bounds__(256, 2) void k_conv1m(
    const float* __restrict__ x,
    const u16* __restrict__ wh, const u16* __restrict__ wl,   // [64][32], bn-scaled
    const float* __restrict__ cb, const float* __restrict__ g, const float* __restrict__ bb,
    u16* __restrict__ feat1, int b0)
{
  __shared__ __align__(16) float sIn[3*18*18];
  __shared__ __align__(16) u16 sAh[256*40], sAl[256*40];
  __shared__ __align__(16) u16 sBh[64*40],  sBl[64*40];
  __shared__ float sBias[64];
  const int tx = blockIdx.x, ty = blockIdx.y, bl = blockIdx.z;
  const int b = b0 + bl;
  const int y0 = ty*16, x0 = tx*16;
  const int tid = threadIdx.x;
  const int w = tid >> 6, l = tid & 63, lr = l & 15, lk = l >> 4;

  if (tid < 64) {
    float sc = g[tid] * rsqrtf(1.0f + 1e-5f);
    sBias[tid] = cb[tid] * sc + bb[tid];
  }
  {
    const int oc = tid >> 2, seg = tid & 3;
    *reinterpret_cast<uint4*>(&sBh[oc*40 + seg*8]) =
        *reinterpret_cast<const uint4*>(wh + oc*32 + seg*8);
    *reinterpret_cast<uint4*>(&sBl[oc*40 + seg*8]) =
        *reinterpret_cast<const uint4*>(wl + oc*32 + seg*8);
  }
  for (int i = tid; i < 3*18*18; i += 256) {
    const int c = i / 324, r = (i / 18) % 18, q = i % 18;
    const int yy = y0 - 1 + r, xx = x0 - 1 + q;
    float v = 0.f;
    if (yy >= 0 && yy < 256 && xx >= 0 && xx < 256)
      v = x[(((size_t)b*3 + c)*256 + yy)*256 + xx];
    sIn[i] = v;
  }
  __syncthreads();
  {
    const int py = tid >> 4, px = tid & 15;
    u32 hw[16], lw[16];
    #pragma unroll
    for (int i = 0; i < 16; i++) { hw[i] = 0u; lw[i] = 0u; }
    #pragma unroll
    for (int c = 0; c < 3; c++)
      #pragma unroll
      for (int ky = 0; ky < 3; ky++)
        #pragma unroll
        for (int kx = 0; kx < 3; kx++) {
          const int k = c*9 + ky*3 + kx;
          const float v = sIn[(c*18 + py + ky)*18 + px + kx];
          const u16 h  = f2bf(v);
          const u16 lo = f2bf(v - bf2f(h));
          hw[k >> 1] |= ((u32)h)  << ((k & 1)*16);
          lw[k >> 1] |= ((u32)lo) << ((k & 1)*16);
        }
    #pragma unroll
    for (int s = 0; s < 4; s++) {
      uint4 vh, vl;
      vh.x = hw[s*4+0]; vh.y = hw[s*4+1]; vh.z = hw[s*4+2]; vh.w = hw[s*4+3];
      vl.x = lw[s*4+0]; vl.y = lw[s*4+1]; vl.z = lw[s*4+2]; vl.w = lw[s*4+3];
      *reinterpret_cast<uint4*>(&sAh[tid*40 + s*8]) = vh;
      *reinterpret_cast<uint4*>(&sAl[tid*40 + s*8]) = vl;
    }
  }
  __syncthreads();
  f32x4 acc[4][4];
  #pragma unroll
  for (int j = 0; j < 4; j++)
    #pragma unroll
    for (int ct = 0; ct < 4; ct++)
      acc[j][ct] = (f32x4){0.f,0.f,0.f,0.f};
  #pragma unroll
  for (int j = 0; j < 4; j++) {
    const int mt = w*4 + j;
    const short8v ah = *reinterpret_cast<const short8v*>(&sAh[(mt*16 + lr)*40 + lk*8]);
    const short8v al = *reinterpret_cast<const short8v*>(&sAl[(mt*16 + lr)*40 + lk*8]);
    #pragma unroll
    for (int ct = 0; ct < 4; ct++) {
      const short8v bh = *reinterpret_cast<const short8v*>(&sBh[(ct*16 + lr)*40 + lk*8]);
      const short8v bv = *reinterpret_cast<const short8v*>(&sBl[(ct*16 + lr)*40 + lk*8]);
      acc[j][ct] = __builtin_amdgcn_mfma_f32_16x16x32_bf16(ah, bh, acc[j][ct], 0, 0, 0);
      acc[j][ct] = __builtin_amdgcn_mfma_f32_16x16x32_bf16(ah, bv, acc[j][ct], 0, 0, 0);
      acc[j][ct] = __builtin_amdgcn_mfma_f32_16x16x32_bf16(al, bh, acc[j][ct], 0, 0, 0);
      acc[j][ct] = __builtin_amdgcn_mfma_f32_16x16x32_bf16(al, bv, acc[j][ct], 0, 0, 0);
    }
  }
  #pragma unroll
  for (int j = 0; j < 2; j++) {
    const int jA = 2*j, jB = 2*j + 1;
    const int oy = ty*8 + w*2 + j;
    #pragma unroll
    for (int xh = 0; xh < 2; xh++) {
      const int ox = tx*8 + lk*2 + xh;
      #pragma unroll
      for (int ct = 0; ct < 4; ct++) {
        const int oc = ct*16 + lr;
        float m = fmaxf(fmaxf(acc[jA][ct][2*xh], acc[jA][ct][2*xh+1]),
                        fmaxf(acc[jB][ct][2*xh], acc[jB][ct][2*xh+1]));
        m = fmaxf(m + sBias[oc], 0.f);
        feat1[(((size_t)bl*128 + oy)*128 + ox)*64 + oc] = f2bf(m);
      }
    }
  }
}

// ---------------- conv2 + bn2 + relu + maxpool2 via MFMA implicit GEMM
__global__ __launch_bounds__(256, 2) void k_conv2m(
    const u16* __restrict__ feat1,
    const u16* __restrict__ wh, const u16* __restrict__ wl,
    const float* __restrict__ cb, const float* __restrict__ g, const float* __restrict__ bb,
    u16* __restrict__ feat2)
{
  __shared__ __align__(16) u16 sA[18*34*40];
  __shared__ __align__(16) u16 sBh[64*40], sBl[64*40];
  __shared__ float sBias[64];
  const int tx = blockIdx.x, ty = blockIdx.y, bl = blockIdx.z;
  const int y0 = ty*16, x0 = tx*32;
  const int tid = threadIdx.x;
  const int w = tid >> 6, l = tid & 63;
  const int lr = l & 15, lk = l >> 4;

  if (tid < 64) {
    float sc = g[tid] * rsqrtf(1.0f + 1e-5f);
    sBias[tid] = cb[tid] * sc + bb[tid];
  }

  f32x4 acc[8][4];
  #pragma unroll
  for (int j = 0; j < 8; j++)
    #pragma unroll
    for (int ct = 0; ct < 4; ct++)
      acc[j][ct] = (f32x4){0.f,0.f,0.f,0.f};

  for (int chunk = 0; chunk < 2; chunk++) {
    __syncthreads();
    for (int idx = tid; idx < 612*4; idx += 256) {
      const int pix = idx >> 2, seg = idx & 3;
      const int r = pix / 34, cc = pix % 34;
      const int yy = y0 - 1 + r, xx = x0 - 1 + cc;
      uint4 v = {0u,0u,0u,0u};
      if (yy >= 0 && yy < 128 && xx >= 0 && xx < 128)
        v = *reinterpret_cast<const uint4*>(
              feat1 + (((size_t)bl*128 + yy)*128 + xx)*64 + chunk*32 + seg*8);
      *reinterpret_cast<uint4*>(&sA[(size_t)(r*34 + cc)*40 + seg*8]) = v;
    }
    for (int kk = 0; kk < 9; kk++) {
      __syncthreads();
      {
        const int oc = tid >> 2, s8 = (tid & 3)*8;
        const size_t src = (size_t)(kk*2 + chunk)*2048 + tid*8;
        *reinterpret_cast<uint4*>(&sBh[oc*40 + s8]) = *reinterpret_cast<const uint4*>(wh + src);
        *reinterpret_cast<uint4*>(&sBl[oc*40 + s8]) = *reinterpret_cast<const uint4*>(wl + src);
      }
      __syncthreads();
      const int ky = kk / 3, kx = kk % 3;
      short8v a[8];
      #pragma unroll
      for (int j = 0; j < 8; j++) {
        const int m = w*8 + j;
        const int r = (m >> 1) + ky;
        const int cc = (m & 1)*16 + lr + kx;
        a[j] = *reinterpret_cast<const short8v*>(&sA[(size_t)(r*34 + cc)*40 + lk*8]);
      }
      #pragma unroll
      for (int ct = 0; ct < 4; ct++) {
        const short8v bh = *reinterpret_cast<const short8v*>(&sBh[(ct*16 + lr)*40 + lk*8]);
        const short8v bv = *reinterpret_cast<const short8v*>(&sBl[(ct*16 + lr)*40 + lk*8]);
        #pragma unroll
        for (int j = 0; j < 8; j++) {
          acc[j][ct] = __builtin_amdgcn_mfma_f32_16x16x32_bf16(a[j], bh, acc[j][ct], 0, 0, 0);
          acc[j][ct] = __builtin_amdgcn_mfma_f32_16x16x32_bf16(a[j], bv, acc[j][ct], 0, 0, 0);
        }
      }
    }
  }
  #pragma unroll
  for (int u = 0; u < 2; u++) {
    #pragma unroll
    for (int xh = 0; xh < 2; xh++) {
      const int jA = 4*u + xh, jB = 4*u + 2 + xh;
      #pragma unroll
      for (int ct = 0; ct < 4; ct++) {
        const int oc = ct*16 + lr;
        const float bias = sBias[oc];
        const float v0 = fmaxf(fmaxf(acc[jA][ct][0], acc[jA][ct][1]),
                               fmaxf(acc[jB][ct][0], acc[jB][ct][1]));
        const float v1 = fmaxf(fmaxf(acc[jA][ct][2], acc[jA][ct][3]),
                               fmaxf(acc[jB][ct][2], acc[jB][ct][3]));
        const u16 b0v = f2bf(fmaxf(v0 + bias, 0.f));
        const u16 b1v = f2bf(fmaxf(v1 + bias, 0.f));
        const int py = ty*8 + 2*w + u;
        const int px = tx*16 + xh*8 + lk*2;
        u32 pk = (u32)b0v | ((u32)b1v << 16);
        *reinterpret_cast<u32*>(&feat2[(((size_t)bl*64 + oc)*64 + py)*64 + px]) = pk;
      }
    }
  }
}

// ---------------- adjacency phase 1: 8-NN per node, 225 blocks (stable (d2,j) order)
__global__ __launch_bounds__(256) void k_adj1(int* __restrict__ nbr1)
{
  __shared__ int skey[256];
  __shared__ int sred[256];
  const int i = blockIdx.x;
  const int tid = threadIdx.x;
  int key = 0x7FFFFFFF;
  if (tid < 225 && tid != i) {
    const int di = i/15 - tid/15, dj = i%15 - tid%15;
    key = (di*di + dj*dj)*256 + tid;
  }
  skey[tid] = key;
  __syncthreads();
  for (int t = 0; t < 8; t++) {
    sred[tid] = skey[tid];
    __syncthreads();
    #pragma unroll
    for (int st = 128; st > 0; st >>= 1) {
      if (tid < st) sred[tid] = min(sred[tid], sred[tid+st]);
      __syncthreads();
    }
    const int wj = sred[0] & 255;
    if (tid == 0) nbr1[i*8 + t] = wj;
    __syncthreads();
    if (tid == wj) skey[tid] = 0x7FFFFFFF;
    __syncthreads();
  }
}

// ---------------- adjacency phase 2: mask2 = rows of (adj@adj>0) minus diagonal
__global__ __launch_bounds__(256) void k_adj2(
    const int* __restrict__ nbr1, u64* __restrict__ mask2)
{
  const int i = threadIdx.x;
  if (i >= 225) return;
  u64 m0=0, m1=0, m2=0, m3=0;
  #pragma unroll
  for (int t = 0; t < 8; t++) {
    const int tt = nbr1[i*8 + t];
    #pragma unroll
    for (int u = 0; u < 8; u++) {
      const int j = nbr1[tt*8 + u];
      const u64 bset = 1ull << (j & 63);
      const int wd = j >> 6;
      m0 |= (wd == 0) ? bset : 0ull;
      m1 |= (wd == 1) ? bset : 0ull;
      m2 |= (wd == 2) ? bset : 0ull;
      m3 |= (wd == 3) ? bset : 0ull;
    }
  }
  {
    const u64 bc = ~(1ull << (i & 63));
    const int wd = i >> 6;
    if (wd == 0) m0 &= bc; else if (wd == 1) m1 &= bc;
    else if (wd == 2) m2 &= bc; else m3 &= bc;
  }
  mask2[i*4+0] = m0; mask2[i*4+1] = m1; mask2[i*4+2] = m2; mask2[i*4+3] = m3;
}

// ---------------- fused weight prep
__global__ __launch_bounds__(256) void k_prep(
    const float* __restrict__ pjw, u16* __restrict__ pwh, u16* __restrict__ pwl,
    const float* __restrict__ c2w, const float* __restrict__ bn2g,
    u16* __restrict__ wc2h, u16* __restrict__ wc2l,
    const float* __restrict__ c1w, const float* __restrict__ bn1g,
    u16* __restrict__ wc1h, u16* __restrict__ wc1l,
    const float* __restrict__ ipw, float* __restrict__ iwt,
    const float* __restrict__ opw, float* __restrict__ owt,
    const float* __restrict__ f1w, float* __restrict__ f1wt,
    const float* __restrict__ f2w, float* __restrict__ f2wt,
    const float* __restrict__ w1w, float* __restrict__ w1t,
    const float* __restrict__ w2w, float* __restrict__ w2t,
    const float* __restrict__ gw,  float* __restrict__ gwt)
{
  const int blk = blockIdx.x, tid = threadIdx.x;
  if (blk < 512) {
    const int i = (blk*256 + tid) * 4;
    float4 v = *reinterpret_cast<const float4*>(pjw + i);
    float e[4] = {v.x, v.y, v.z, v.w};
    ushort4 h, l;
    u16* hp = &h.x; u16* lp = &l.x;
    #pragma unroll
    for (int j = 0; j < 4; j++) {
      u16 hb = f2bf(e[j]);
      hp[j] = hb;
      lp[j] = f2bf(e[j] - bf2f(hb));
    }
    *reinterpret_cast<ushort4*>(pwh + i) = h;
    *reinterpret_cast<ushort4*>(pwl + i) = l;
  } else if (blk < 656) {
    const int d = (blk - 512)*256 + tid;
    if (d < 36864) {
      const int icL = d & 31, oc = (d >> 5) & 63, chunk = (d >> 11) & 1, kk = d >> 12;
      const float sc = bn2g[oc] * rsqrtf(1.0f + 1e-5f);
      const float val = c2w[((size_t)oc*64 + chunk*32 + icL)*9 + kk] * sc;
      const u16 hb = f2bf(val);
      wc2h[d] = hb;
      wc2l[d] = f2bf(val - bf2f(hb));
    }
  } else if (blk < 664) {
    const int d = (blk - 656)*256 + tid;
    if (d < 2048) {
      const int k = d & 31, oc = d >> 5;
      float val = 0.f;
      if (k < 27) val = c1w[oc*27 + k] * (bn1g[oc] * rsqrtf(1.0f + 1e-5f));
      const u16 hb = f2bf(val);
      wc1h[d] = hb;
      wc1l[d] = f2bf(val - bf2f(hb));
    }
  } else {
    const float* src; float* dst; int O, K, base;
    if      (blk <  856) { src = ipw; dst = iwt;  O = 384; K = 128; base = 664;  }
    else if (blk <  920) { src = opw; dst = owt;  O = 128; K = 128; base = 856;  }
    else if (blk < 1176) { src = f1w; dst = f1wt; O = 512; K = 128; base = 920;  }
    else if (blk < 1432) { src = f2w; dst = f2wt; O = 128; K = 512; base = 1176; }
    else if (blk < 1496) { src = w1w; dst = w1t;  O = 128; K = 128; base = 1432; }
    else if (blk < 1560) { src = w2w; dst = w2t;  O = 128; K = 128; base = 1496; }
    else                 { src = gw;  dst = gwt;  O = 128; K = 256; base = 1560; }
    const int idx = (blk - base)*256 + tid;
    if (idx < O * K) {
      const int o = idx / K, k = idx % K;
      dst[(size_t)k * O + o] = src[idx];
    }
  }
}

// ---------------- patch-projection MFMA GEMM, split-K=8 + register prefetch
// grid (4 n-tiles, 8 k-chunks, BC) = 512 blocks -> 2 blocks/CU co-residency
__global__ __launch_bounds__(256, 2) void k_projm(
    const u16* __restrict__ feat2,
    const u16* __restrict__ pwh, const u16* __restrict__ pwl,
    float* __restrict__ partial, int b0)
{
  __shared__ __align__(16) u16 sA [64][40];
  __shared__ __align__(16) u16 sBh[128][40];
  __shared__ __align__(16) u16 sBl[128][40];
  const int cx = blockIdx.x, kc = blockIdx.y, bl = blockIdx.z;
  const int b  = b0 + bl;
  const int n0 = cx * 64;
  const int rows = (225 - n0) < 64 ? (225 - n0) : 64;
  const int tid = threadIdx.x;
  const int w = tid >> 6, l = tid & 63;
  const int lr = l & 15, lk = l >> 4;

  f32x4 acc[8];
  #pragma unroll
  for (int i = 0; i < 8; i++) acc[i] = (f32x4){0.f, 0.f, 0.f, 0.f};

  const int ar = tid >> 2, aci = tid & 3;
  const int an = n0 + ar;
  const int aph = an / 15, apw = an % 15;
  const int kbeg = kc * 512, kend = kbeg + 512;

  uint4 pA, pBh[2], pBl[2];
  auto loadstep = [&](int k0) {
    const int c  = k0 >> 6;
    const int i0 = (k0 & 63) >> 3;
    uint2 g0 = {0u,0u}, g1 = {0u,0u};
    if (ar < rows) {
      const u16* src = feat2 + (((size_t)bl*64 + c)*64 + aph*4 + i0 + aci)*64 + apw*4;
      g0 = *reinterpret_cast<const uint2*>(src);
      g1 = *reinterpret_cast<const uint2*>(src + 4);
    }
    pA.x = g0.x; pA.y = g0.y; pA.z = g1.x; pA.w = g1.y;
    #pragma unroll
    for (int p = 0; p < 2; p++) {
      const int idx = p*256 + tid;
      const int col = idx >> 2, seg = idx & 3;
      const size_t off = (size_t)col*4096 + k0 + seg*8;
      pBh[p] = *reinterpret_cast<const uint4*>(pwh + off);
      pBl[p] = *reinterpret_cast<const uint4*>(pwl + off);
    }
  };

  loadstep(kbeg);
  for (int k0 = kbeg; k0 < kend; k0 += 32) {
    __syncthreads();
    *reinterpret_cast<uint4*>(&sA[ar][aci*8]) = pA;
    #pragma unroll
    for (int p = 0; p < 2; p++) {
      const int idx = p*256 + tid;
      const int col = idx >> 2, seg = idx & 3;
      *reinterpret_cast<uint4*>(&sBh[col][seg*8]) = pBh[p];
      *reinterpret_cast<uint4*>(&sBl[col][seg*8]) = pBl[p];
    }
    __syncthreads();
    if (k0 + 32 < kend) loadstep(k0 + 32);
    short8v a = *reinterpret_cast<const short8v*>(&sA[w*16 + lr][lk*8]);
    #pragma unroll
    for (int ct = 0; ct < 8; ct++) {
      short8v bh = *reinterpret_cast<const short8v*>(&sBh[ct*16 + lr][lk*8]);
      short8v bv = *reinterpret_cast<const short8v*>(&sBl[ct*16 + lr][lk*8]);
      acc[ct] = __builtin_amdgcn_mfma_f32_16x16x32_bf16(a, bh, acc[ct], 0, 0, 0);
      acc[ct] = __builtin_amdgcn_mfma_f32_16x16x32_bf16(a, bv, acc[ct], 0, 0, 0);
    }
  }
  #pragma unroll
  for (int ct = 0; ct < 8; ct++) {
    const int col = ct*16 + lr;
    #pragma unroll
    for (int v = 0; v < 4; v++) {
      const int r = w*16 + lk*4 + v;
      if (r < rows)
        partial[(((size_t)kc*16 + b)*225 + n0 + r)*128 + col] = acc[ct][v];
    }
  }
}

// ---------------- reduce split-K partials + bias -> nodes
__global__ __launch_bounds__(128) void k_projr(
    const float* __restrict__ partial, const float* __restrict__ pb,
    float* __restrict__ nodes, int b0)
{
  const int n = blockIdx.x, bl = blockIdx.y;
  const int b = b0 + bl;
  const int d = threadIdx.x;
  float s = pb[d];
  #pragma unroll
  for (int kc = 0; kc < 8; kc++)
    s += partial[(((size_t)kc*16 + b)*225 + n)*128 + d];
  nodes[((size_t)b*225 + n)*128 + d] = s;
}

// ---------------- neighbor aggregation: a1/a2 per (b,node)
__global__ __launch_bounds__(128) void k_agg(
    const float* __restrict__ nodes, const int* __restrict__ nbr1,
    const u64* __restrict__ mask2,
    float* __restrict__ a1buf, float* __restrict__ a2buf)
{
  const int n = blockIdx.x, b = blockIdx.y;
  const int d = threadIdx.x;
  const float* nb = nodes + (size_t)b * 225 * 128;
  float a1 = 0.f;
  #pragma unroll
  for (int t = 0; t < 8; t++) a1 += nb[(size_t)nbr1[n*8+t]*128 + d];
  float a2 = 0.f;
  for (int wd = 0; wd < 4; wd++) {
    u64 m = mask2[n*4 + wd];
    while (m) {
      int j = wd*64 + __builtin_ctzll(m);
      a2 += nb[(size_t)j*128 + d];
      m &= m - 1;
    }
  }
  a1buf[((size_t)b*225 + n)*128 + d] = a1;
  a2buf[((size_t)b*225 + n)*128 + d] = a2;
}

// ---------------- z1/z2/gate/score: 2 rows per block (1800 blocks -> high TLP)
__global__ __launch_bounds__(256) void k_gz(
    const float* __restrict__ a1buf, const float* __restrict__ a2buf,
    const float* __restrict__ w1t, const float* __restrict__ w1b,
    const float* __restrict__ w2t, const float* __restrict__ w2b,
    const float* __restrict__ gwt, const float* __restrict__ gb,
    const float* __restrict__ sw, const float* __restrict__ sb,
    float* __restrict__ zbuf, float* __restrict__ scores)
{
  __shared__ float sA1[2][128], sA2[2][128], sC[2][256], sRed[2][128];
  const int row0 = blockIdx.x * 2;
  const int tid = threadIdx.x;
  const int d = tid & 127, rr = tid >> 7;
  const int row = row0 + rr;
  sA1[rr][d] = a1buf[(size_t)row*128 + d];
  sA2[rr][d] = a2buf[(size_t)row*128 + d];
  __syncthreads();
  float z1 = w1b[d], z2 = w2b[d];
  #pragma unroll 4
  for (int k = 0; k < 128; k++) {
    z1 += w1t[k*128 + d] * sA1[rr][k];
    z2 += w2t[k*128 + d] * sA2[rr][k];
  }
  sC[rr][d] = z1; sC[rr][128 + d] = z2;
  __syncthreads();
  float gl = gb[d];
  #pragma unroll 4
  for (int k = 0; k < 256; k++)
    gl += gwt[k*128 + d] * sC[rr][k];
  const float gg = 1.f / (1.f + expf(-gl));
  const float zv = gg * z1 + (1.f - gg) * z2;
  zbuf[(size_t)row*128 + d] = zv;
  sRed[rr][d] = zv * sw[d];
  __syncthreads();
  if (tid < 32) {
    const int r = tid >> 4, j = tid & 15;
    float part = 0.f;
    #pragma unroll
    for (int i = 0; i < 8; i++) part += sRed[r][j*8 + i];
    #pragma unroll
    for (int m = 8; m >= 1; m >>= 1) part += __shfl_xor(part, m, 64);
    if (j == 0) scores[row0 + r] = part + sb[0];
  }
}

// ---------------- top-k (k=112) with jax tie semantics
__global__ __launch_bounds__(256) void k_topk(
    const float* __restrict__ scores, int* __restrict__ sel)
{
  __shared__ float ss[225];
  const int b = blockIdx.x, tid = threadIdx.x;
  if (tid < 112) sel[b*112 + tid] = tid;
  if (tid < 225) ss[tid] = scores[b*225 + tid];
  __syncthreads();
  if (tid < 225) {
    float s = ss[tid];
    int rank = 0;
    for (int j = 0; j < 225; j++) {
      float sj = ss[j];
      rank += (sj > s) || (sj == s && j < tid);
    }
    if (rank < 112) sel[b*112 + rank] = tid;
  }
}

// ---------------- qkv batched: 14 rows per block
__global__ __launch_bounds__(256) void k_qkv(
    const float* __restrict__ zbuf, const int* __restrict__ sel,
    const float* __restrict__ iwt, const float* __restrict__ ib,
    float* __restrict__ q, float* __restrict__ k, float* __restrict__ v)
{
  __shared__ float sx[14][128];
  const int s0 = blockIdx.x * 14, b = blockIdx.y;
  const int tid = threadIdx.x;
  const int c = tid & 127, half = tid >> 7;
  const int r0 = half * 7;

  for (int idx = tid; idx < 14*128; idx += 256) {
    const int r = idx >> 7, dd = idx & 127;
    int row = sel[b*112 + s0 + r];
    row = row < 0 ? 0 : (row > 224 ? 224 : row);
    sx[r][dd] = zbuf[((size_t)b*225 + row)*128 + dd];
  }
  __syncthreads();

  float acc[3][7];
  #pragma unroll
  for (int p = 0; p < 3; p++)
    #pragma unroll
    for (int rr = 0; rr < 7; rr++) acc[p][rr] = ib[p*128 + c];
  for (int kk = 0; kk < 128; kk++) {
    float wv[3];
    #pragma unroll
    for (int p = 0; p < 3; p++) wv[p] = iwt[kk*384 + p*128 + c];
    #pragma unroll
    for (int rr = 0; rr < 7; rr++) {
      const float xv = sx[r0 + rr][kk];
      #pragma unroll
      for (int p = 0; p < 3; p++) acc[p][rr] += wv[p] * xv;
    }
  }
  const int h = c >> 5, t = c & 31;
  float* outs[3] = {q, k, v};
  #pragma unroll
  for (int p = 0; p < 3; p++)
    #pragma unroll
    for (int rr = 0; rr < 7; rr++)
      outs[p][(((size_t)b*4 + h)*112 + s0 + r0 + rr)*32 + t] = acc[p][rr];
}

// ---------------- attention: 512 blocks (8 q-chunks x 4 heads x 16 b), 16 thr/query
__global__ __launch_bounds__(256) void k_attn(
    const float* __restrict__ q, const float* __restrict__ k,
    const float* __restrict__ v, float* __restrict__ o)
{
  __shared__ float sK[112*33], sV[112*33];
  __shared__ float sQ[14*33];
  __shared__ float sP[14][112];
  const int qc = blockIdx.x, h = blockIdx.y, b = blockIdx.z;
  const size_t base = ((size_t)b*4 + h) * 112 * 32;
  const int tid = threadIdx.x;
  for (int i = tid; i < 112*32; i += 256) {
    const int r = i >> 5, c = i & 31;
    sK[r*33 + c] = k[base + i];
    sV[r*33 + c] = v[base + i];
  }
  for (int i = tid; i < 14*32; i += 256) {
    const int r = i >> 5, c = i & 31;
    sQ[r*33 + c] = q[base + (size_t)(qc*14)*32 + i];
  }
  __syncthreads();
  const int qg = tid >> 4, j = tid & 15;
  if (qg < 14) {
    const float scale = 0.17677669529663687f;
    float pv[7];
    float mx = -INFINITY;
    #pragma unroll
    for (int t7 = 0; t7 < 7; t7++) {
      const int kk = j + t7*16;
      float s = 0.f;
      #pragma unroll
      for (int t = 0; t < 32; t++) s += sQ[qg*33 + t] * sK[kk*33 + t];
      pv[t7] = s * scale;
      mx = fmaxf(mx, pv[t7]);
    }
    #pragma unroll
    for (int m = 8; m >= 1; m >>= 1) mx = fmaxf(mx, __shfl_xor(mx, m, 16));
    float lsum = 0.f;
    #pragma unroll
    for (int t7 = 0; t7 < 7; t7++) { pv[t7] = expf(pv[t7] - mx); lsum += pv[t7]; }
    #pragma unroll
    for (int m = 8; m >= 1; m >>= 1) lsum += __shfl_xor(lsum, m, 16);
    const float inv = 1.f / lsum;
    #pragma unroll
    for (int t7 = 0; t7 < 7; t7++) sP[qg][j + t7*16] = pv[t7] * inv;
  }
  __syncthreads();
  if (qg < 14) {
    const int s = qc*14 + qg;
    float o0 = 0.f, o1 = 0.f;
    for (int kk = 0; kk < 112; kk++) {
      const float p = sP[qg][kk];
      o0 += p * sV[kk*33 + j];
      o1 += p * sV[kk*33 + j + 16];
    }
    float* op = o + ((size_t)b*112 + s)*128 + h*32;
    op[j] = o0;
    op[j + 16] = o1;
  }
}

// ---------------- out-proj + residual + LN1, batched 14 rows/block
__global__ __launch_bounds__(256) void k_oln(
    const float* __restrict__ o, const float* __restrict__ zbuf,
    const int* __restrict__ sel,
    const float* __restrict__ owt, const float* __restrict__ ob,
    const float* __restrict__ lg, const float* __restrict__ lb,
    float* __restrict__ h1)
{
  __shared__ float sO[14][128], sV[14][128];
  __shared__ float sMean[14], sRstd[14];
  const int s0 = blockIdx.x * 14, b = blockIdx.y;
  const int tid = threadIdx.x;
  const int d = tid & 127, half = tid >> 7;
  const int r0 = half * 7;

  for (int idx = tid; idx < 14*128; idx += 256) {
    const int r = idx >> 7, dd = idx & 127;
    sO[r][dd] = o[((size_t)b*112 + s0 + r)*128 + dd];
  }
  __syncthreads();

  float acc[7];
  #pragma unroll
  for (int rr = 0; rr < 7; rr++) acc[rr] = ob[d];
  for (int kk = 0; kk < 128; kk++) {
    const float wv = owt[kk*128 + d];
    #pragma unroll
    for (int rr = 0; rr < 7; rr++) acc[rr] += wv * sO[r0 + rr][kk];
  }
  #pragma unroll
  for (int rr = 0; rr < 7; rr++) {
    int row = sel[b*112 + s0 + r0 + rr];
    row = row < 0 ? 0 : (row > 224 ? 224 : row);
    acc[rr] += zbuf[((size_t)b*225 + row)*128 + d];
    sV[r0 + rr][d] = acc[rr];
  }
  __syncthreads();
  {
    const int r = tid >> 4, j = tid & 15;
    if (r < 14) {
      float p1 = 0.f, p2 = 0.f;
      #pragma unroll
      for (int i = 0; i < 8; i++) { float v = sV[r][j*8 + i]; p1 += v; p2 += v*v; }
      #pragma unroll
      for (int m = 8; m >= 1; m >>= 1) {
        p1 += __shfl_xor(p1, m, 64);
        p2 += __shfl_xor(p2, m, 64);
      }
      if (j == 0) {
        const float mean = p1 * (1.f/128.f);
        sMean[r] = mean;
        sRstd[r] = rsqrtf(p2 * (1.f/128.f) - mean*mean + 1e-5f);
      }
    }
  }
  __syncthreads();
  for (int idx = tid; idx < 14*128; idx += 256) {
    const int r = idx >> 7, dd = idx & 127;
    h1[((size_t)b*112 + s0 + r)*128 + dd] =
        (sV[r][dd] - sMean[r]) * sRstd[r] * lg[dd] + lb[dd];
  }
}

// ---------------- FFN + residual + LN2, batched 14 rows/block (in-place safe)
__global__ __launch_bounds__(256) void k_ffn(
    const float* __restrict__ h1,
    const float* __restrict__ f1wt, const float* __restrict__ f1b,
    const float* __restrict__ f2wt, const float* __restrict__ f2b,
    const float* __restrict__ lg, const float* __restrict__ lb,
    float* __restrict__ h2)
{
  __shared__ float sh[14][128];
  __shared__ float sf[14][512];
  __shared__ float sV[14][128];
  __shared__ float sMean[14], sRstd[14];
  const int s0 = blockIdx.x * 14, b = blockIdx.y;
  const int tid = threadIdx.x;
  const int d = tid & 127, half = tid >> 7;
  const int r0 = half * 7;

  for (int idx = tid; idx < 14*128; idx += 256) {
    const int r = idx >> 7, dd = idx & 127;
    sh[r][dd] = h1[((size_t)b*112 + s0 + r)*128 + dd];
  }
  __syncthreads();
  {
    float a0[14], a1[14];
    const float b0 = f1b[tid], b1 = f1b[tid + 256];
    #pragma unroll
    for (int r = 0; r < 14; r++) { a0[r] = b0; a1[r] = b1; }
    for (int kk = 0; kk < 128; kk++) {
      const float w0 = f1wt[kk*512 + tid];
      const float w1 = f1wt[kk*512 + tid + 256];
      #pragma unroll
      for (int r = 0; r < 14; r++) {
        const float xv = sh[r][kk];
        a0[r] += w0 * xv;
        a1[r] += w1 * xv;
      }
    }
    #pragma unroll
    for (int r = 0; r < 14; r++) {
      sf[r][tid]       = fmaxf(a0[r], 0.f);
      sf[r][tid + 256] = fmaxf(a1[r], 0.f);
    }
  }
  __syncthreads();
  {
    float acc[7];
    #pragma unroll
    for (int rr = 0; rr < 7; rr++) acc[rr] = f2b[d];
    for (int kk = 0; kk < 512; kk++) {
      const float wv = f2wt[kk*128 + d];
      #pragma unroll
      for (int rr = 0; rr < 7; rr++) acc[rr] += wv * sf[r0 + rr][kk];
    }
    #pragma unroll
    for (int rr = 0; rr < 7; rr++)
      sV[r0 + rr][d] = sh[r0 + rr][d] + acc[rr];
  }
  __syncthreads();
  {
    const int r = tid >> 4, j = tid & 15;
    if (r < 14) {
      float p1 = 0.f, p2 = 0.f;
      #pragma unroll
      for (int i = 0; i < 8; i++) { float v = sV[r][j*8 + i]; p1 += v; p2 += v*v; }
      #pragma unroll
      for (int m = 8; m >= 1; m >>= 1) {
        p1 += __shfl_xor(p1, m, 64);
        p2 += __shfl_xor(p2, m, 64);
      }
      if (j == 0) {
        const float mean = p1 * (1.f/128.f);
        sMean[r] = mean;
        sRstd[r] = rsqrtf(p2 * (1.f/128.f) - mean*mean + 1e-5f);
      }
    }
  }
  __syncthreads();
  for (int idx = tid; idx < 14*128; idx += 256) {
    const int r = idx >> 7, dd = idx & 127;
    h2[((size_t)b*112 + s0 + r)*128 + dd] =
        (sV[r][dd] - sMean[r]) * sRstd[r] * lg[dd] + lb[dd];
  }
}

// ---------------- rep = sum_s h2 ; classifier -> logits (f32)
__global__ __launch_bounds__(64) void k_cls(
    const float* __restrict__ h2,
    const float* __restrict__ c1w, const float* __restrict__ c1b,
    const float* __restrict__ c2w, const float* __restrict__ c2b,
    float* __restrict__ out)
{
  __shared__ float sr[128], sc[64];
  const int b = blockIdx.x, tid = threadIdx.x;
  float r0 = 0.f, r1 = 0.f;
  for (int s2 = 0; s2 < 112; s2++) {
    const float* row = h2 + ((size_t)b*112 + s2)*128;
    r0 += row[tid];
    r1 += row[tid + 64];
  }
  sr[tid] = r0; sr[tid + 64] = r1;
  __syncthreads();
  float acc = c1b[tid];
  const float* wr = c1w + (size_t)tid * 128;
  for (int kk = 0; kk < 128; kk++) acc += wr[kk] * sr[kk];
  sc[tid] = fmaxf(acc, 0.f);
  __syncthreads();
  if (tid < 2) {
    float l = c2b[tid];
    for (int kk = 0; kk < 64; kk++) l += c2w[tid*64 + kk] * sc[kk];
    out[b*2 + tid] = l;
  }
}

extern "C" void kernel_launch(void* const* d_in, const int* in_sizes, int n_in,
                              void* d_out, int out_size, void* d_ws, size_t ws_size,
                              hipStream_t stream)
{
  const float* x    = (const float*)d_in[0];
  const float* c1w  = (const float*)d_in[1];
  const float* c1b  = (const float*)d_in[2];
  const float* bn1g = (const float*)d_in[3];
  const float* bn1b = (const float*)d_in[4];
  const float* c2w  = (const float*)d_in[5];
  const float* c2b  = (const float*)d_in[6];
  const float* bn2g = (const float*)d_in[7];
  const float* bn2b = (const float*)d_in[8];
  const float* pjw  = (const float*)d_in[9];
  const float* pjb  = (const float*)d_in[10];
  const float* w1w  = (const float*)d_in[11];
  const float* w1b  = (const float*)d_in[12];
  const float* w2w  = (const float*)d_in[13];
  const float* w2b  = (const float*)d_in[14];
  const float* gw   = (const float*)d_in[15];
  const float* gb   = (const float*)d_in[16];
  const float* scw  = (const float*)d_in[17];
  const float* scb  = (const float*)d_in[18];
  const float* ipw  = (const float*)d_in[19];
  const float* ipb  = (const float*)d_in[20];
  const float* opw  = (const float*)d_in[21];
  const float* opb  = (const float*)d_in[22];
  const float* f1w  = (const float*)d_in[23];
  const float* f1b  = (const float*)d_in[24];
  const float* f2w  = (const float*)d_in[25];
  const float* f2b  = (const float*)d_in[26];
  const float* l1g  = (const float*)d_in[27];
  const float* l1b  = (const float*)d_in[28];
  const float* l2g  = (const float*)d_in[29];
  const float* l2b  = (const float*)d_in[30];
  const float* cl1w = (const float*)d_in[31];
  const float* cl1b = (const float*)d_in[32];
  const float* cl2w = (const float*)d_in[33];
  const float* cl2b = (const float*)d_in[34];

  // ---- bump allocator over d_ws (256-B aligned) ----
  char* p = (char*)d_ws;
  auto alloc = [&](size_t n) { char* r = p; p += (n + 255) & ~(size_t)255; return r; };
  u64*   mask2  = (u64*)  alloc(900    * sizeof(u64));
  int*   nbr1   = (int*)  alloc(1800   * sizeof(int));
  int*   sel    = (int*)  alloc(1792   * sizeof(int));
  float* scores = (float*)alloc(3600   * sizeof(float));
  u16*   pwh    = (u16*)  alloc(524288 * sizeof(u16));
  u16*   pwl    = (u16*)  alloc(524288 * sizeof(u16));
  u16*   wc2h   = (u16*)  alloc(36864  * sizeof(u16));
  u16*   wc2l   = (u16*)  alloc(36864  * sizeof(u16));
  u16*   wc1h   = (u16*)  alloc(2048   * sizeof(u16));
  u16*   wc1l   = (u16*)  alloc(2048   * sizeof(u16));
  float* iwt    = (float*)alloc(49152  * sizeof(float));
  float* owt    = (float*)alloc(16384  * sizeof(float));
  float* f1wt   = (float*)alloc(65536  * sizeof(float));
  float* f2wt   = (float*)alloc(65536  * sizeof(float));
  float* w1t    = (float*)alloc(16384  * sizeof(float));
  float* w2t    = (float*)alloc(16384  * sizeof(float));
  float* gwt    = (float*)alloc(32768  * sizeof(float));
  float* partial= (float*)alloc(8ull*16*225*128 * sizeof(float));  // 14.7 MB split-K=8
  float* a1buf  = (float*)alloc(460800 * sizeof(float));
  float* a2buf  = (float*)alloc(460800 * sizeof(float));
  float* zbuf   = (float*)alloc(460800 * sizeof(float));
  float* nodes  = (float*)alloc(460800 * sizeof(float));
  const size_t fixed_bytes = (size_t)(p - (char*)d_ws);

  const size_t qkv_bytes = 3ull * 229376ull * sizeof(float);
  const size_t per_batch = 64ull*128*128*2 + 64ull*64*64*2;   // 2,621,440 B
  int BC = 16;
  size_t s3 = 0;
  for (;; BC >>= 1) {
    s3 = (size_t)BC * per_batch; if (s3 < qkv_bytes) s3 = qkv_bytes;
    if (fixed_bytes + s3 + 65536 <= ws_size) break;
    if (BC == 1) { return; }
  }
  char* S3 = alloc(s3);

  u16*   feat1 = (u16*)S3;                              // NHWC (BC,128,128,64)
  u16*   feat2 = (u16*)(S3 + (size_t)BC * 2097152ull);  // NCHW (BC,64,64,64)
  float* qb    = (float*)S3;
  float* kb    = qb + 229376;
  float* vb    = kb + 229376;
  float* obuf  = nodes;
  float* hbuf  = nodes + 229376;

  k_adj1<<<225, 256, 0, stream>>>(nbr1);
  k_adj2<<<1, 256, 0, stream>>>(nbr1, mask2);
  k_prep<<<1688, 256, 0, stream>>>(pjw, pwh, pwl, c2w, bn2g, wc2h, wc2l,
                                   c1w, bn1g, wc1h, wc1l,
                                   ipw, iwt, opw, owt, f1w, f1wt, f2w, f2wt,
                                   w1w, w1t, w2w, w2t, gw, gwt);

  for (int b0 = 0; b0 < 16; b0 += BC) {
    k_conv1m<<<dim3(16,16,BC), 256, 0, stream>>>(x, wc1h, wc1l, c1b, bn1g, bn1b, feat1, b0);
    k_conv2m<<<dim3(4,8,BC), 256, 0, stream>>>(feat1, wc2h, wc2l, c2b, bn2g, bn2b, feat2);
    k_projm <<<dim3(4,8,BC), 256, 0, stream>>>(feat2, pwh, pwl, partial, b0);
    k_projr <<<dim3(225,BC), 128, 0, stream>>>(partial, pjb, nodes, b0);
  }

  k_agg  <<<dim3(225,16), 128, 0, stream>>>(nodes, nbr1, mask2, a1buf, a2buf);
  k_gz   <<<1800, 256, 0, stream>>>(a1buf, a2buf, w1t, w1b, w2t, w2b,
                                    gwt, gb, scw, scb, zbuf, scores);
  k_topk <<<16, 256, 0, stream>>>(scores, sel);
  k_qkv  <<<dim3(8,16), 256, 0, stream>>>(zbuf, sel, iwt, ipb, qb, kb, vb);
  k_attn <<<dim3(8,4,16), 256, 0, stream>>>(qb, kb, vb, obuf);
  k_oln  <<<dim3(8,16), 256, 0, stream>>>(obuf, zbuf, sel, owt, opb, l1g, l1b, hbuf);
  k_ffn  <<<dim3(8,16), 256, 0, stream>>>(hbuf, f1wt, f1b, f2wt, f2b, l2g, l2b, hbuf);
  k_cls  <<<16, 64, 0, stream>>>(hbuf, cl1w, cl1b, cl2w, cl2b, (float*)d_out);
}